// Round 8
// baseline (6489.809 us; speedup 1.0000x reference)
//
#include <hip/hip_runtime.h>
#include <math.h>

#define DIVUP(a,b) (((a)+(b)-1)/(b))

namespace {

constexpr int B=8, T=12, N=883, CIN=3, C=64, E=10, H=8, HD=8, TOPK=48, L=8;
constexpr int SKC=256, F7=7, T13=13;
constexpr int NP=896;   // padded N for bf16 support matrices

typedef __attribute__((ext_vector_type(8))) short bf16x8;
typedef __attribute__((ext_vector_type(4))) float f32x4;

__device__ __forceinline__ float geluf(float x){ return 0.5f*x*(1.0f+erff(x*0.7071067811865475f)); }
__device__ __forceinline__ float sigmf(float x){ return 1.0f/(1.0f+expf(-x)); }
__device__ __forceinline__ float us2f(unsigned short u){ return __uint_as_float(((unsigned)u)<<16); }
__device__ __forceinline__ unsigned short f2us(float f){
  unsigned x=__float_as_uint(f);
  return (unsigned short)((x + 0x7fffu + ((x>>16)&1u))>>16);
}

// 16x16 output tile: A from LDS (bf16 split, [row][k], row stride STRIDE),
// B from global W (bf16 split, [col][k], row stride KW). 3-term split product.
template<int KK, int STRIDE, int KW>
__device__ __forceinline__ f32x4 tile_mm(
    const unsigned short* sAh, const unsigned short* sAl,
    const unsigned short* __restrict__ Wh, const unsigned short* __restrict__ Wl,
    int colBase, int lane, f32x4 acc){
  int lr=lane&15, lg=lane>>4;
  #pragma unroll
  for(int k0=0;k0<KK;k0+=32){
    bf16x8 ah=*(const bf16x8*)&sAh[lr*STRIDE+k0+8*lg];
    bf16x8 al=*(const bf16x8*)&sAl[lr*STRIDE+k0+8*lg];
    bf16x8 bh=*(const bf16x8*)&Wh[(size_t)(colBase+lr)*KW+k0+8*lg];
    bf16x8 bl=*(const bf16x8*)&Wl[(size_t)(colBase+lr)*KW+k0+8*lg];
    acc=__builtin_amdgcn_mfma_f32_16x16x32_bf16(ah,bh,acc,0,0,0);
    acc=__builtin_amdgcn_mfma_f32_16x16x32_bf16(ah,bl,acc,0,0,0);
    acc=__builtin_amdgcn_mfma_f32_16x16x32_bf16(al,bh,acc,0,0,0);
  }
  return acc;
}

// ---------------- graph generation ----------------
__global__ void k_dft(const float* __restrict__ x, float* __restrict__ xf){
  int idx = blockIdx.x*256 + threadIdx.x;
  if(idx >= B*F7*N) return;
  int n = idx % N; int f = (idx/N) % F7; int b = idx/(N*F7);
  float re=0.f, im=0.f;
  for(int t=0;t<T;t++){
    float v = x[((size_t)(b*T+t)*N+n)*CIN];
    float ang = -6.283185307179586f * (float)(f*t) / 12.0f;
    re += v*cosf(ang); im += v*sinf(ang);
  }
  xf[idx] = sqrtf(re*re+im*im);
}

__global__ void k_l2f(float* __restrict__ xf){
  int idx = blockIdx.x*256 + threadIdx.x;
  if(idx >= B*N) return;
  int n = idx % N; int b = idx / N;
  float s=0.f;
  for(int f=0;f<F7;f++){ float v=xf[((size_t)b*F7+f)*N+n]; s+=v*v; }
  float inv = 1.0f/fmaxf(sqrtf(s), 1e-12f);
  for(int f=0;f<F7;f++) xf[((size_t)b*F7+f)*N+n] *= inv;
}

__global__ void k_l2n(float* __restrict__ xf){
  int bf = blockIdx.x; int tid = threadIdx.x;
  __shared__ float red[256];
  size_t base = (size_t)bf*N;
  float s=0.f;
  for(int i=tid;i<N;i+=256){ float v=xf[base+i]; s+=v*v; }
  red[tid]=s; __syncthreads();
  for(int k=128;k>0;k>>=1){ if(tid<k) red[tid]+=red[tid+k]; __syncthreads(); }
  float inv = 1.0f/fmaxf(sqrtf(red[0]), 1e-12f);
  __syncthreads();
  for(int i=tid;i<N;i+=256) xf[base+i]*=inv;
}

__global__ void k_x1(const float* __restrict__ x, const float* __restrict__ xf,
                     const float* __restrict__ E3, const float* __restrict__ TiD,
                     const float* __restrict__ DiW, const float* __restrict__ Wx,
                     const float* __restrict__ Wd, float* __restrict__ x1){
  int idx = blockIdx.x*256+threadIdx.x;
  if(idx>=B*N) return;
  int n=idx%N, b=idx/N;
  float xc[40];
  for(int d=0;d<E;d++){
    float a=0.f;
    for(int f=0;f<F7;f++) a += xf[((size_t)b*F7+f)*N+n]*Wx[f*E+d];
    xc[d]=a;
  }
  for(int d=0;d<E;d++) xc[10+d]=E3[n*E+d];
  int ti = (int)(x[((size_t)(b*T+(T-1))*N+n)*CIN+1]*288.0f);
  int dw = (int)(x[((size_t)(b*T+(T-1))*N+n)*CIN+2]);
  for(int d=0;d<E;d++) xc[20+d]=TiD[ti*E+d];
  for(int d=0;d<E;d++) xc[30+d]=DiW[dw*E+d];
  for(int e=0;e<E;e++){
    float a=0.f;
    for(int f=0;f<40;f++) a += xc[f]*Wd[((size_t)n*40+f)*E+e];
    x1[(size_t)idx*E+e]=fmaxf(a,0.f);
  }
}

__global__ void k_lnstats(const float* __restrict__ x1, float* __restrict__ st){
  int b=blockIdx.x, tid=threadIdx.x;
  __shared__ float rs[256], rq[256];
  const int M=N*E;
  float s=0.f,q=0.f;
  for(int i=tid;i<M;i+=256){ float v=x1[(size_t)b*M+i]; s+=v; q+=v*v; }
  rs[tid]=s; rq[tid]=q; __syncthreads();
  for(int k=128;k>0;k>>=1){ if(tid<k){ rs[tid]+=rs[tid+k]; rq[tid]+=rq[tid+k]; } __syncthreads(); }
  if(tid==0){ float mu=rs[0]/M; float var=rq[0]/M-mu*mu; st[b*2]=mu; st[b*2+1]=var; }
}

__global__ void k_dew(const float* __restrict__ x1, const float* __restrict__ st,
                      const float* __restrict__ Wxabs, float* __restrict__ dew){
  int idx=blockIdx.x*256+threadIdx.x;
  if(idx>=B*N) return;
  int b=idx/N;
  float mu=st[b*2], var=st[b*2+1];
  float rs=rsqrtf(var+1e-8f);
  float xk[E];
  for(int e=0;e<E;e++) xk[e]=(x1[(size_t)idx*E+e]-mu)*rs;
  for(int k=0;k<E;k++){
    float a=0.f;
    for(int e=0;e<E;e++) a+=xk[e]*Wxabs[e*E+k];
    dew[(size_t)idx*E+k]=a;
  }
}

__global__ void k_adp(const float* __restrict__ dew, const float* __restrict__ x1,
                      float* __restrict__ adp){
  size_t idx=(size_t)blockIdx.x*256+threadIdx.x;
  if(idx>=(size_t)B*N*N) return;
  int m=(int)(idx%N); int n=(int)((idx/N)%N); int b=(int)(idx/((size_t)N*N));
  const float* dr=dew+((size_t)b*N+n)*E;
  const float* xr=x1+((size_t)b*N+m)*E;
  float a=0.f;
  for(int k=0;k<E;k++) a+=dr[k]*xr[k];
  adp[idx]=fmaxf(a,0.f);
}

__global__ void k_topk(float* __restrict__ adp,
                       unsigned short* __restrict__ ADhi, unsigned short* __restrict__ ADlo){
  int row=blockIdx.x, tid=threadIdx.x;
  __shared__ float orig[N];
  __shared__ float work[N];
  __shared__ float rv[256];
  __shared__ int   ri[256];
  for(int i=tid;i<N;i+=256){ float v=adp[(size_t)row*N+i]; orig[i]=v; work[i]=v; }
  __syncthreads();
  for(int k=0;k<TOPK;k++){
    float bv=-1.f; int bi=N;
    for(int i=tid;i<N;i+=256){ float v=work[i]; if(v>bv){bv=v;bi=i;} }
    rv[tid]=bv; ri[tid]=bi; __syncthreads();
    for(int s=128;s>0;s>>=1){
      if(tid<s){
        if(rv[tid+s]>rv[tid] || (rv[tid+s]==rv[tid] && ri[tid+s]<ri[tid])){
          rv[tid]=rv[tid+s]; ri[tid]=ri[tid+s];
        }
      }
      __syncthreads();
    }
    if(tid==0) work[ri[0]] = -2.f;
    __syncthreads();
  }
  float lm=0.f;
  for(int i=tid;i<N;i+=256){ float p=(work[i]<-1.f)?orig[i]:0.f; lm=fmaxf(lm,p); }
  rv[tid]=lm; __syncthreads();
  for(int s=128;s>0;s>>=1){ if(tid<s) rv[tid]=fmaxf(rv[tid],rv[tid+s]); __syncthreads(); }
  float m=rv[0]; __syncthreads();
  float ls=0.f;
  for(int i=tid;i<N;i+=256){ float p=(work[i]<-1.f)?orig[i]:0.f; ls+=expf(p-m); }
  rv[tid]=ls; __syncthreads();
  for(int s=128;s>0;s>>=1){ if(tid<s) rv[tid]+=rv[tid+s]; __syncthreads(); }
  float invZ=1.0f/rv[0]; __syncthreads();
  size_t base=((size_t)(row/N)*NP + (size_t)(row%N))*NP;
  for(int i=tid;i<N;i+=256){
    float p=(work[i]<-1.f)?orig[i]:0.f;
    float f=expf(p-m)*invZ;
    unsigned short h=f2us(f);
    ADhi[base+i]=h; ADlo[base+i]=f2us(f-us2f(h));
  }
}

__global__ void k_adap(const float* __restrict__ E1, const float* __restrict__ E2,
                       unsigned short* __restrict__ Mh, unsigned short* __restrict__ Ml){
  int v=blockIdx.x, tid=threadIdx.x;
  __shared__ float rowv[N];
  __shared__ float rv[256];
  float e1[E];
  for(int e=0;e<E;e++) e1[e]=E1[v*E+e];
  for(int j=tid;j<N;j+=256){
    float s=0.f;
    for(int e=0;e<E;e++) s+=e1[e]*E2[j*E+e];
    rowv[j]=fmaxf(s,0.f);
  }
  __syncthreads();
  float lm=-1e30f;
  for(int j=tid;j<N;j+=256) lm=fmaxf(lm,rowv[j]);
  rv[tid]=lm; __syncthreads();
  for(int s=128;s>0;s>>=1){ if(tid<s) rv[tid]=fmaxf(rv[tid],rv[tid+s]); __syncthreads(); }
  float m=rv[0]; __syncthreads();
  float ls=0.f;
  for(int j=tid;j<N;j+=256) ls+=expf(rowv[j]-m);
  rv[tid]=ls; __syncthreads();
  for(int s=128;s>0;s>>=1){ if(tid<s) rv[tid]+=rv[tid+s]; __syncthreads(); }
  float invZ=1.0f/rv[0];
  for(int j=tid;j<N;j+=256){
    float f=expf(rowv[j]-m)*invZ;
    unsigned short h=f2us(f);
    Mh[(size_t)j*NP+v]=h; Ml[(size_t)j*NP+v]=f2us(f-us2f(h));
  }
}

__global__ void k_cvtT(const float* __restrict__ A, unsigned short* __restrict__ Mh,
                       unsigned short* __restrict__ Ml){
  int idx=blockIdx.x*256+threadIdx.x;
  if(idx>=N*N) return;
  int w=idx/N, v=idx%N;
  float f=A[(size_t)v*N+w];
  unsigned short h=f2us(f);
  Mh[(size_t)w*NP+v]=h;
  Ml[(size_t)w*NP+v]=f2us(f-us2f(h));
}

// ---- weight transpose+split conversions (run once) ----
__global__ void k_cvt_qkv(const float* __restrict__ Wq, const float* __restrict__ Wk,
                          const float* __restrict__ Wv,
                          unsigned short* __restrict__ dh, unsigned short* __restrict__ dl){
  int idx=blockIdx.x*256+threadIdx.x;
  if(idx>=L*192*64) return;
  int l=idx/12288, rem=idx%12288, col=rem/64, k=rem%64;
  int mat=col>>6, o=col&63;
  const float* W=(mat==0)?Wq:((mat==1)?Wk:Wv);
  float v=W[(size_t)l*4096 + k*64 + o];
  unsigned short h=f2us(v);
  dh[idx]=h; dl[idx]=f2us(v-us2f(h));
}
__global__ void k_cvt_w1(const float* __restrict__ W1,
                         unsigned short* __restrict__ dh, unsigned short* __restrict__ dl){
  int idx=blockIdx.x*256+threadIdx.x;
  if(idx>=L*256*64) return;
  int l=idx/16384, rem=idx%16384, col=rem/64, k=rem%64;
  float v=W1[(size_t)l*16384 + k*256 + col];
  unsigned short h=f2us(v);
  dh[idx]=h; dl[idx]=f2us(v-us2f(h));
}
__global__ void k_cvt_w2(const float* __restrict__ W2,
                         unsigned short* __restrict__ dh, unsigned short* __restrict__ dl){
  int idx=blockIdx.x*256+threadIdx.x;
  if(idx>=L*64*256) return;
  int l=idx/16384, rem=idx%16384, col=rem/256, k=rem%256;
  float v=W2[(size_t)l*16384 + k*64 + col];
  unsigned short h=f2us(v);
  dh[idx]=h; dl[idx]=f2us(v-us2f(h));
}
__global__ void k_cvt_conv(const float* __restrict__ fw, const float* __restrict__ gw,
                           unsigned short* __restrict__ dh, unsigned short* __restrict__ dl){
  int idx=blockIdx.x*256+threadIdx.x;
  if(idx>=L*128*128) return;
  int l=idx/16384, rem=idx%16384, col=rem/128, k=rem%128;
  int c=col&63, fg=col>>6, tap=k>>6, i=k&63;
  const float* W=fg?gw:fw;
  float v=W[(size_t)l*8192 + tap*4096 + i*64 + c];
  unsigned short h=f2us(v);
  dh[idx]=h; dl[idx]=f2us(v-us2f(h));
}

__global__ void k_zero(float* __restrict__ p, int n){
  int idx=blockIdx.x*256+threadIdx.x;
  if(idx<n) p[idx]=0.f;
}
__global__ void k_zeroUS(unsigned short* __restrict__ p, long long n){
  long long idx=(long long)blockIdx.x*256+threadIdx.x;
  if(idx<n) p[idx]=0;
}

// ---------------- trunk ----------------
__global__ void k_start(const float* __restrict__ x, const float* __restrict__ sw,
                        const float* __restrict__ sb, float* __restrict__ h){
  int idx=blockIdx.x*256+threadIdx.x;
  if(idx>=B*C*N*T13) return;
  int t=idx%T13; int n=(idx/T13)%N; int o=(idx/(T13*N))%C; int b=idx/(T13*N*C);
  float a=sb[o];
  if(t>0){
    size_t xb=((size_t)(b*T+(t-1))*N+n)*CIN;
    for(int i=0;i<CIN;i++) a += sw[i*C+o]*x[xb+i];
  }
  h[idx]=a;
}

// Fused per-(b,n) MFMA transformer block: QKV+attn+FFN+residual+conv+skip.
template<int TC, int D>
__global__ __launch_bounds__(256) void k_attconv(const float* __restrict__ hin,
  const unsigned short* __restrict__ Wqkvh, const unsigned short* __restrict__ Wqkvl,
  const unsigned short* __restrict__ W1h,   const unsigned short* __restrict__ W1l,
  const unsigned short* __restrict__ W2h,   const unsigned short* __restrict__ W2l,
  const unsigned short* __restrict__ Wch,   const unsigned short* __restrict__ Wcl,
  const float* __restrict__ bq, const float* __restrict__ bk, const float* __restrict__ bv,
  const float* __restrict__ b1, const float* __restrict__ b2,
  const float* __restrict__ fb, const float* __restrict__ gb,
  const float* __restrict__ skw, const float* __restrict__ skb,
  unsigned short* __restrict__ hThi, unsigned short* __restrict__ hTlo,
  float* __restrict__ skipacc){
  constexpr int TN = TC - D;
  int bn=blockIdx.x; int tid=threadIdx.x;
  int n=bn%N, b=bn/N;
  int lane=tid&63, wid=tid>>6;
  int lr=lane&15, lg=lane>>4;
  __shared__ __align__(16) float sxa[16*64];
  __shared__ __align__(16) float sq [16*64];
  __shared__ __align__(16) float sk [16*64];
  __shared__ __align__(16) float sv [16*64];
  __shared__ __align__(16) unsigned short sA1h[16*72], sA1l[16*72];
  __shared__ __align__(16) unsigned short sA2h[16*264], sA2l[16*264];
  __shared__ __align__(16) float sfg[16*128];

  // phase 1: stage input -> fp32 sxa + split bf16 sA1 (rows t>=TC zeroed)
  for(int idx=tid; idx<TC*C; idx+=256){
    int c=idx/TC, t=idx%TC;
    float v=hin[(((size_t)b*C+c)*N+n)*TC+t];
    sxa[t*64+c]=v;
    unsigned short h=f2us(v);
    sA1h[t*72+c]=h; sA1l[t*72+c]=f2us(v-us2f(h));
  }
  for(int idx=tid; idx<(16-TC)*C; idx+=256){
    int t=TC+(idx>>6), c=idx&63;
    sxa[t*64+c]=0.f; sA1h[t*72+c]=0; sA1l[t*72+c]=0;
  }
  __syncthreads();

  // phase 2: QKV (12 tiles of 16x16, K=64) + bias + gelu
  #pragma unroll
  for(int it=0; it<3; ++it){
    int tile=it*4+wid;
    f32x4 acc={0.f,0.f,0.f,0.f};
    acc=tile_mm<64,72,64>(sA1h,sA1l,Wqkvh,Wqkvl,tile*16,lane,acc);
    int col=tile*16+lr; int mat=col>>6, o=col&63;
    const float* bm=(mat==0)?bq:((mat==1)?bk:bv);
    float* dst=(mat==0)?sq:((mat==1)?sk:sv);
    float bias=bm[o];
    #pragma unroll
    for(int r=0;r<4;r++){
      int t=lg*4+r;
      if(t<TC) dst[t*64+o]=geluf(acc[r]+bias);
    }
  }
  __syncthreads();

  // phase 3: causal attention (scalar); writes `so` as split bf16 into sA1
  if(tid<H*TC){
    int hh=tid/TC, t=tid%TC;
    const float* qr=&sq[t*64+hh*HD];
    float att[TC];
    float m=-1e30f;
    #pragma unroll
    for(int s=0;s<TC;s++){
      float a=0.f;
      #pragma unroll
      for(int d=0;d<HD;d++) a+=qr[d]*sk[s*64+hh*HD+d];
      a*=0.3535533905932738f;
      a=(s<=t)?a:-1e30f;
      att[s]=a; m=fmaxf(m,a);
    }
    float Z=0.f;
    #pragma unroll
    for(int s=0;s<TC;s++){ float e=expf(att[s]-m); att[s]=e; Z+=e; }
    float invZ=1.0f/Z;
    #pragma unroll
    for(int d=0;d<HD;d++){
      float o=0.f;
      #pragma unroll
      for(int s=0;s<TC;s++) o+=att[s]*sv[s*64+hh*HD+d];
      float v=o*invZ;
      unsigned short h=f2us(v);
      sA1h[t*72+hh*8+d]=h; sA1l[t*72+hh*8+d]=f2us(v-us2f(h));
    }
  }
  __syncthreads();

  // phase 4: FFN1 (16 tiles, K=64) + bias + gelu -> split bf16 sA2 (stride 264)
  #pragma unroll
  for(int it=0; it<4; ++it){
    int tile=it*4+wid;
    f32x4 acc={0.f,0.f,0.f,0.f};
    acc=tile_mm<64,72,64>(sA1h,sA1l,W1h,W1l,tile*16,lane,acc);
    int col=tile*16+lr;
    float bias=b1[col];
    #pragma unroll
    for(int r=0;r<4;r++){
      int t=lg*4+r;
      float v=(t<TC)?geluf(acc[r]+bias):0.f;
      unsigned short h=f2us(v);
      sA2h[t*264+col]=h; sA2l[t*264+col]=f2us(v-us2f(h));
    }
  }
  __syncthreads();

  // phase 5: FFN2 (4 tiles, K=256) + bias + residual -> xc (reuse sq)
  {
    int tile=wid;
    f32x4 acc={0.f,0.f,0.f,0.f};
    acc=tile_mm<256,264,256>(sA2h,sA2l,W2h,W2l,tile*16,lane,acc);
    int col=tile*16+lr;
    float bias=b2[col];
    #pragma unroll
    for(int r=0;r<4;r++){
      int t=lg*4+r;
      if(t<TC) sq[t*64+col]=acc[r]+bias+sxa[t*64+col];
    }
  }
  __syncthreads();

  // phase 6: build conv A [16][128] split bf16 into sA2 (stride 136)
  for(int idx=tid; idx<16*128; idx+=256){
    int t=idx>>7, k=idx&127;
    int c=k&63;
    float v=0.f;
    if(t<TN) v=sq[((k<64)?t:(t+D))*64+c];
    unsigned short h=f2us(v);
    sA2h[t*136+k]=h; sA2l[t*136+k]=f2us(v-us2f(h));
  }
  __syncthreads();

  // phase 7: conv (8 tiles, K=128) + bias + activation -> sfg [tt][128]
  #pragma unroll
  for(int it=0; it<2; ++it){
    int tile=it*4+wid;
    f32x4 acc={0.f,0.f,0.f,0.f};
    acc=tile_mm<128,136,128>(sA2h,sA2l,Wch,Wcl,tile*16,lane,acc);
    int col=tile*16+lr;
    float bias=(col<64)?fb[col]:gb[col&63];
    #pragma unroll
    for(int r=0;r<4;r++){
      int t=lg*4+r;
      float v=acc[r]+bias;
      sfg[t*128+col]=(col<64)?tanhf(v):sigmf(v);
    }
  }
  __syncthreads();

  // phase 8: last-column conv output for skip
  if(tid<C) sk[tid]=sfg[(TN-1)*128+tid]*sfg[(TN-1)*128+64+tid];
  __syncthreads();

  // phase 9: skip projection + hT write
  {
    float a=skb[tid];
    for(int i=0;i<C;i++) a+=sk[i]*skw[i*SKC+tid];
    skipacc[((size_t)b*SKC+tid)*N+n]+=a;
  }
  size_t obase=(size_t)bn*C*TN;
  for(int idx=tid; idx<C*TN; idx+=256){
    int c=idx/TN, tt=idx%TN;
    float v=sfg[tt*128+c]*sfg[tt*128+64+c];
    unsigned short h=f2us(v);
    hThi[obase+idx]=h;
    hTlo[obase+idx]=f2us(v-us2f(h));
  }
}

// ---- MFMA spatial GEMM (unchanged from round 7) ----
__global__ __launch_bounds__(256) void k_spatmm(
    const unsigned short* __restrict__ Ah, const unsigned short* __restrict__ Al,
    long long aStride,
    const unsigned short* __restrict__ Xh, const unsigned short* __restrict__ Xl,
    unsigned short* __restrict__ Yh, unsigned short* __restrict__ Yl, int M){
  __shared__ unsigned short sAh[64*40];
  __shared__ unsigned short sAl[64*40];
  __shared__ unsigned short sXh[64*40];
  __shared__ unsigned short sXl[64*40];
  int b=blockIdx.z;
  const unsigned short* Abh=Ah+(size_t)b*aStride;
  const unsigned short* Abl=Al+(size_t)b*aStride;
  const unsigned short* Xbh=Xh+(size_t)b*N*M;
  const unsigned short* Xbl=Xl+(size_t)b*N*M;
  int tid=threadIdx.x;
  int w0=blockIdx.x*64, c0=blockIdx.y*64;
  int lane=tid&63, wid=tid>>6;
  int wr=wid>>1, wc=wid&1;
  int lr=lane&15, lg=lane>>4;
  f32x4 acc[2][2];
  #pragma unroll
  for(int j=0;j<2;j++){
    #pragma unroll
    for(int i=0;i<2;i++){ acc[j][i][0]=0.f; acc[j][i][1]=0.f; acc[j][i][2]=0.f; acc[j][i][3]=0.f; }
  }
  const int ar=tid>>2, akb=(tid&3)*8;
  const int xk=tid>>3, xcb=(tid&7)*8;
  const int xkx=xk ^ (8*((xcb>>3)&3));
  for(int k0=0;k0<N;k0+=32){
    {
      uint4 qh=*(const uint4*)&Abh[(size_t)(w0+ar)*NP + k0+akb];
      uint4 ql=*(const uint4*)&Abl[(size_t)(w0+ar)*NP + k0+akb];
      *(uint4*)&sAh[ar*40+akb]=qh;
      *(uint4*)&sAl[ar*40+akb]=ql;
    }
    {
      uint4 qh={0,0,0,0}, ql={0,0,0,0};
      if(k0+xk<N){
        qh=*(const uint4*)&Xbh[(size_t)(k0+xk)*M + c0+xcb];
        ql=*(const uint4*)&Xbl[(size_t)(k0+xk)*M + c0+xcb];
      }
      unsigned short uh[8], ul[8];
      uh[0]=(unsigned short)(qh.x&0xffff); uh[1]=(unsigned short)(qh.x>>16);
      uh[2]=(unsigned short)(qh.y&0xffff); uh[3]=(unsigned short)(qh.y>>16);
      uh[4]=(unsigned short)(qh.z&0xffff); uh[5]=(unsigned short)(qh.z>>16);
      uh[6]=(unsigned short)(qh.w&0xffff); uh[7]=(unsigned short)(qh.w>>16);
      ul[0]=(unsigned short)(ql.x&0xffff); ul[1]=(unsigned short)(ql.x>>16);
      ul[2]=(unsigned short)(ql.y&0xffff); ul[3]=(unsigned short)(ql.y>>16);
      ul[4]=(unsigned short)(ql.z&0xffff); ul[5]=(unsigned short)(ql.z>>16);
      ul[6]=(unsigned short)(ql.w&0xffff); ul[7]=(unsigned short)(ql.w>>16);
      #pragma unroll
      for(int j=0;j<8;j++){
        sXh[(xcb+j)*40+xkx]=uh[j];
        sXl[(xcb+j)*40+xkx]=ul[j];
      }
    }
    __syncthreads();
    bf16x8 a_h[2], a_l[2], x_h[2], x_l[2];
    #pragma unroll
    for(int j=0;j<2;j++){
      int r=32*wr+16*j+lr;
      a_h[j]=*(const bf16x8*)&sAh[r*40+8*lg];
      a_l[j]=*(const bf16x8*)&sAl[r*40+8*lg];
    }
    #pragma unroll
    for(int i=0;i<2;i++){
      int cc=32*wc+16*i+lr;
      int g=lg ^ ((cc>>3)&3);
      x_h[i]=*(const bf16x8*)&sXh[cc*40+8*g];
      x_l[i]=*(const bf16x8*)&sXl[cc*40+8*g];
    }
    #pragma unroll
    for(int j=0;j<2;j++){
      #pragma unroll
      for(int i=0;i<2;i++){
        acc[j][i]=__builtin_amdgcn_mfma_f32_16x16x32_bf16(a_h[j],x_h[i],acc[j][i],0,0,0);
        acc[j][i]=__builtin_amdgcn_mfma_f32_16x16x32_bf16(a_h[j],x_l[i],acc[j][i],0,0,0);
        acc[j][i]=__builtin_amdgcn_mfma_f32_16x16x32_bf16(a_l[j],x_h[i],acc[j][i],0,0,0);
      }
    }
    __syncthreads();
  }
  #pragma unroll
  for(int j=0;j<2;j++){
    int rbase=w0+32*wr+16*j+lg*4;
    #pragma unroll
    for(int i=0;i<2;i++){
      int col=c0+32*wc+16*i+lr;
      #pragma unroll
      for(int r=0;r<4;r++){
        int row=rbase+r;
        if(row<N){
          float v=acc[j][i][r];
          unsigned short h=f2us(v);
          unsigned short lo=f2us(v-us2f(h));
          size_t o=((size_t)b*N+row)*M+col;
          Yh[o]=h; Yl[o]=lo;
        }
      }
    }
  }
}

// fused GCN projection (unchanged)
template<int TN, int FIRST>
__global__ __launch_bounds__(256) void k_gcnprojB(
    const unsigned short* __restrict__ S0h, const unsigned short* __restrict__ S0l,
    const unsigned short* __restrict__ Ph, const unsigned short* __restrict__ Pl,
    const unsigned short* __restrict__ Qh, const unsigned short* __restrict__ Ql,
    const float* __restrict__ Wg, const float* __restrict__ gb,
    const float* __restrict__ res, float* __restrict__ acc, int Tc){
  constexpr int NS=FIRST+2;
  constexpr int SL=C*TN;
  constexpr int LDSF=((NS*C>256)?NS*C:256)*TN;
  int bn=blockIdx.x; int tid=threadIdx.x;
  int n=bn%N, b=bn/N;
  __shared__ float sx[LDSF];
  size_t base=(size_t)bn*SL;
  if(FIRST){
    for(int i=tid;i<SL;i+=256) sx[i]=us2f(S0h[base+i])+us2f(S0l[base+i]);
  }
  for(int i=tid;i<SL;i+=256){
    sx[(FIRST+0)*SL+i]=us2f(Ph[base+i])+us2f(Pl[base+i]);
    sx[(FIRST+1)*SL+i]=us2f(Qh[base+i])+us2f(Ql[base+i]);
  }
  __syncthreads();
  int o=tid&63, part=tid>>6;
  float a[TN];
  #pragma unroll
  for(int tt=0;tt<TN;tt++) a[tt]=0.f;
  for(int j=0;j<NS;j++){
    const float* Wj=Wg+(size_t)j*C*C;
    const float* xj=&sx[j*SL];
    for(int ii=0;ii<16;ii++){
      int i=part*16+ii;
      float w=Wj[i*C+o];
      #pragma unroll
      for(int tt=0;tt<TN;tt++) a[tt]+=w*xj[i*TN+tt];
    }
  }
  __syncthreads();
  float* red=sx;
  #pragma unroll
  for(int tt=0;tt<TN;tt++) red[(part*64+o)*TN+tt]=a[tt];
  __syncthreads();
  if(part==0){
    size_t ob=(((size_t)b*C+o)*N+n)*TN;
    float v[TN];
    #pragma unroll
    for(int tt=0;tt<TN;tt++)
      v[tt]=red[o*TN+tt]+red[(64+o)*TN+tt]+red[(128+o)*TN+tt]+red[(192+o)*TN+tt];
    if(FIRST){
      float g=gb[o];
      size_t rb=(((size_t)b*C+o)*N+n)*Tc+(Tc-TN);
      #pragma unroll
      for(int tt=0;tt<TN;tt++) acc[ob+tt]=v[tt]+g+res[rb+tt];
    }else{
      #pragma unroll
      for(int tt=0;tt<TN;tt++) acc[ob+tt]+=v[tt];
    }
  }
}

__global__ void k_bnstats(const float* __restrict__ h, float* __restrict__ st, int tn){
  int c=blockIdx.x, tid=threadIdx.x;
  __shared__ float rs[256], rq[256];
  const int Mi=N*tn;
  const int M=B*Mi;
  float s=0.f,q=0.f;
  for(int idx=tid; idx<M; idx+=256){
    int b=idx/Mi; int inner=idx%Mi;
    float v=h[(size_t)b*C*Mi + (size_t)c*Mi + inner];
    s+=v; q+=v*v;
  }
  rs[tid]=s; rq[tid]=q; __syncthreads();
  for(int k=128;k>0;k>>=1){ if(tid<k){ rs[tid]+=rs[tid+k]; rq[tid]+=rq[tid+k]; } __syncthreads(); }
  if(tid==0){
    float mu=rs[0]/M; float var=rq[0]/M-mu*mu;
    st[c]=mu; st[C+c]=rsqrtf(var+1e-5f);
  }
}

__global__ void k_bnapply(float* __restrict__ h, const float* __restrict__ st,
                          const float* __restrict__ g, const float* __restrict__ bb, int tn){
  int idx=blockIdx.x*256+threadIdx.x;
  if(idx>=B*C*N*tn) return;
  int c=(idx/(N*tn))%C;
  float v=h[idx];
  h[idx]=(v-st[c])*st[C+c]*g[c]+bb[c];
}

__global__ void k_head(const float* __restrict__ skipacc, const float* __restrict__ W1,
  const float* __restrict__ b1, const float* __restrict__ W2, const float* __restrict__ b2,
  float* __restrict__ out){
  int gid=blockIdx.x; int tid=threadIdx.x;  // 512 threads
  int n=gid%N; int b=gid/N;
  __shared__ float s[SKC];
  __shared__ float hid[512];
  if(tid<SKC){
    float v=skipacc[((size_t)b*SKC+tid)*N+n];
    s[tid]=fmaxf(v,0.f);
  }
  __syncthreads();
  {
    float a=b1[tid];
    for(int i=0;i<SKC;i++) a+=s[i]*W1[(size_t)i*512+tid];
    hid[tid]=fmaxf(a,0.f);
  }
  __syncthreads();
  if(tid<T){
    float a=b2[tid];
    for(int j=0;j<512;j++) a+=hid[j]*W2[(size_t)j*T+tid];
    out[((size_t)b*T+tid)*N+n]=a;
  }
}

// ---------------- host-side layer driver ----------------
struct Ctx {
  const float *bq,*bk,*bv,*b1,*b2,*filt_b,*gate_b,*skip_w,*skip_b,*gcn_w,*gcn_b,*bn_g,*bn_b;
  const unsigned short *qkvTh,*qkvTl,*w1Th,*w1Tl,*w2Th,*w2Tl,*cvTh,*cvTl;
  const unsigned short* matH[4];
  const unsigned short* matL[4];
  long long matStride[4];
  float *pH,*pAlt,*skipacc,*bnst;
  unsigned short *hThi,*hTlo,*Phi,*Plo,*Qhi,*Qlo;
  hipStream_t stream;
};

template<int TC, int D>
void run_layer(Ctx& c, int l, bool last){
  constexpr int TN=TC-D;
  const size_t CC=(size_t)C*C;
  k_attconv<TC,D><<<B*N,256,0,c.stream>>>(c.pH,
    c.qkvTh+(size_t)l*12288, c.qkvTl+(size_t)l*12288,
    c.w1Th+(size_t)l*16384,  c.w1Tl+(size_t)l*16384,
    c.w2Th+(size_t)l*16384,  c.w2Tl+(size_t)l*16384,
    c.cvTh+(size_t)l*16384,  c.cvTl+(size_t)l*16384,
    c.bq+(size_t)l*C, c.bk+(size_t)l*C, c.bv+(size_t)l*C,
    c.b1+(size_t)l*4*C, c.b2+(size_t)l*C,
    c.filt_b+(size_t)l*C, c.gate_b+(size_t)l*C,
    c.skip_w+(size_t)l*C*SKC, c.skip_b+(size_t)l*SKC,
    c.hThi, c.hTlo, c.skipacc);
  if(!last){
    int M=C*TN, nMB=M/64;
    const float* Wl=c.gcn_w+(size_t)l*9*CC;
    dim3 sg(DIVUP(N,64), nMB, B);
    for(int s=0;s<4;s++){
      k_spatmm<<<sg,256,0,c.stream>>>(c.matH[s],c.matL[s],c.matStride[s],
          c.hThi,c.hTlo, c.Phi,c.Plo, M);
      k_spatmm<<<sg,256,0,c.stream>>>(c.matH[s],c.matL[s],c.matStride[s],
          c.Phi,c.Plo, c.Qhi,c.Qlo, M);
      if(s==0){
        k_gcnprojB<TN,1><<<B*N,256,0,c.stream>>>(c.hThi,c.hTlo,
            c.Phi,c.Plo,c.Qhi,c.Qlo,
            Wl, c.gcn_b+(size_t)l*C, c.pH, c.pAlt, TC);
      }else{
        k_gcnprojB<TN,0><<<B*N,256,0,c.stream>>>(nullptr,nullptr,
            c.Phi,c.Plo,c.Qhi,c.Qlo,
            Wl+(size_t)(1+2*s)*CC, nullptr, nullptr, c.pAlt, TC);
      }
    }
    k_bnstats<<<C,256,0,c.stream>>>(c.pAlt, c.bnst, TN);
    k_bnapply<<<DIVUP(B*C*N*TN,256),256,0,c.stream>>>(c.pAlt, c.bnst,
      c.bn_g+(size_t)l*C, c.bn_b+(size_t)l*C, TN);
    float* tmp=c.pH; c.pH=c.pAlt; c.pAlt=tmp;
  }
}

} // namespace

extern "C" void kernel_launch(void* const* d_in, const int* in_sizes, int n_in,
                              void* d_out, int out_size, void* d_ws, size_t ws_size,
                              hipStream_t stream){
  (void)in_sizes; (void)n_in;
  const float* x      =(const float*)d_in[0];
  const float* sup0   =(const float*)d_in[1];
  const float* sup1   =(const float*)d_in[2];
  const float* TiD    =(const float*)d_in[3];
  const float* DiW    =(const float*)d_in[4];
  const float* E1     =(const float*)d_in[5];
  const float* E2     =(const float*)d_in[6];
  const float* E3     =(const float*)d_in[7];
  const float* Wx     =(const float*)d_in[8];
  const float* Wd     =(const float*)d_in[9];
  const float* Wxabs  =(const float*)d_in[10];
  const float* start_w=(const float*)d_in[11];
  const float* start_b=(const float*)d_in[12];
  const float* Wq     =(const float*)d_in[13];
  const float* Wk     =(const float*)d_in[15];
  const float* Wv     =(const float*)d_in[17];
  const float* W1     =(const float*)d_in[19];
  const float* W2     =(const float*)d_in[21];
  const float* filt_w =(const float*)d_in[23];
  const float* gate_w =(const float*)d_in[25];

  Ctx c;
  c.bq=(const float*)d_in[14];
  c.bk=(const float*)d_in[16];
  c.bv=(const float*)d_in[18];
  c.b1=(const float*)d_in[20];
  c.b2=(const float*)d_in[22];
  c.filt_b=(const float*)d_in[24];
  c.gate_b=(const float*)d_in[26];
  c.skip_w=(const float*)d_in[27]; c.skip_b=(const float*)d_in[28];
  c.gcn_w =(const float*)d_in[29]; c.gcn_b =(const float*)d_in[30];
  c.bn_g  =(const float*)d_in[31]; c.bn_b  =(const float*)d_in[32];
  const float* end1_w =(const float*)d_in[33];
  const float* end1_b =(const float*)d_in[34];
  const float* end2_w =(const float*)d_in[35];
  const float* end2_b =(const float*)d_in[36];
  c.stream=stream;

  // workspace carve (16B-aligned)
  size_t off=0;
  auto allocF=[&](size_t nf)->float*{
    nf=(nf+3)&~(size_t)3;
    float* p=(float*)((char*)d_ws+off);
    off += nf*sizeof(float);
    return p;
  };
  auto allocU=[&](size_t nu)->unsigned short*{
    nu=(nu+7)&~(size_t)7;
    unsigned short* p=(unsigned short*)((char*)d_ws+off);
    off += nu*sizeof(unsigned short);
    return p;
  };
  const size_t HMAX =(size_t)B*C*N*T13;
  const size_t XSZ  =(size_t)B*C*N*12;
  const size_t SUPP =(size_t)NP*NP;
  const size_t ADSZ =(size_t)B*NP*NP;

  float* xf     = allocF((size_t)B*F7*N);
  float* gx1    = allocF((size_t)B*N*E);
  float* gdew   = allocF((size_t)B*N*E);
  float* gst    = allocF(16);
  c.bnst        = allocF(2*C);
  float* adp    = allocF((size_t)B*N*N);
  c.pH          = allocF(HMAX);
  c.pAlt        = allocF(HMAX);
  c.skipacc     = allocF((size_t)B*SKC*N);
  unsigned short* matRegion=(unsigned short*)((char*)d_ws+off);
  unsigned short* s0h = allocU(SUPP);
  unsigned short* s0l = allocU(SUPP);
  unsigned short* s1h = allocU(SUPP);
  unsigned short* s1l = allocU(SUPP);
  unsigned short* aph = allocU(SUPP);
  unsigned short* apl = allocU(SUPP);
  unsigned short* adh = allocU(ADSZ);
  unsigned short* adl = allocU(ADSZ);
  long long matRegionN = (long long)(( (unsigned short*)((char*)d_ws+off) ) - matRegion);
  c.hThi = allocU(XSZ);  c.hTlo = allocU(XSZ);
  c.Phi  = allocU(XSZ);  c.Plo  = allocU(XSZ);
  c.Qhi  = allocU(XSZ);  c.Qlo  = allocU(XSZ);
  // converted transformer weights
  unsigned short* qkvTh = allocU((size_t)L*12288);
  unsigned short* qkvTl = allocU((size_t)L*12288);
  unsigned short* w1Th  = allocU((size_t)L*16384);
  unsigned short* w1Tl  = allocU((size_t)L*16384);
  unsigned short* w2Th  = allocU((size_t)L*16384);
  unsigned short* w2Tl  = allocU((size_t)L*16384);
  unsigned short* cvTh  = allocU((size_t)L*16384);
  unsigned short* cvTl  = allocU((size_t)L*16384);
  if(off > ws_size){
    k_zero<<<DIVUP(out_size,256),256,0,stream>>>((float*)d_out, out_size);
    return;
  }
  c.qkvTh=qkvTh; c.qkvTl=qkvTl; c.w1Th=w1Th; c.w1Tl=w1Tl;
  c.w2Th=w2Th; c.w2Tl=w2Tl; c.cvTh=cvTh; c.cvTl=cvTl;
  c.matH[0]=s0h; c.matL[0]=s0l; c.matStride[0]=0;
  c.matH[1]=s1h; c.matL[1]=s1l; c.matStride[1]=0;
  c.matH[2]=aph; c.matL[2]=apl; c.matStride[2]=0;
  c.matH[3]=adh; c.matL[3]=adl; c.matStride[3]=(long long)NP*NP;

  // ---- graph generation + conversions ----
  k_zeroUS<<<(int)DIVUP(matRegionN,256),256,0,stream>>>(matRegion, matRegionN);
  k_cvt_qkv <<<DIVUP(L*192*64,256),256,0,stream>>>(Wq,Wk,Wv,qkvTh,qkvTl);
  k_cvt_w1  <<<DIVUP(L*256*64,256),256,0,stream>>>(W1,w1Th,w1Tl);
  k_cvt_w2  <<<DIVUP(L*64*256,256),256,0,stream>>>(W2,w2Th,w2Tl);
  k_cvt_conv<<<DIVUP(L*128*128,256),256,0,stream>>>(filt_w,gate_w,cvTh,cvTl);
  k_dft <<<DIVUP(B*F7*N,256),256,0,stream>>>(x, xf);
  k_l2f <<<DIVUP(B*N,256),256,0,stream>>>(xf);
  k_l2n <<<B*F7,256,0,stream>>>(xf);
  k_x1  <<<DIVUP(B*N,256),256,0,stream>>>(x, xf, E3, TiD, DiW, Wx, Wd, gx1);
  k_lnstats<<<B,256,0,stream>>>(gx1, gst);
  k_dew <<<DIVUP(B*N,256),256,0,stream>>>(gx1, gst, Wxabs, gdew);
  k_adp <<<DIVUP(B*N*N,256),256,0,stream>>>(gdew, gx1, adp);
  k_topk<<<B*N,256,0,stream>>>(adp, adh, adl);
  k_adap<<<N,256,0,stream>>>(E1, E2, aph, apl);
  k_cvtT<<<DIVUP(N*N,256),256,0,stream>>>(sup0, s0h, s0l);
  k_cvtT<<<DIVUP(N*N,256),256,0,stream>>>(sup1, s1h, s1l);

  // ---- trunk ----
  k_zero<<<DIVUP(B*SKC*N,256),256,0,stream>>>(c.skipacc, B*SKC*N);
  k_start<<<DIVUP(B*C*N*T13,256),256,0,stream>>>(x, start_w, start_b, c.pH);

  run_layer<13,1>(c,0,false);
  run_layer<12,2>(c,1,false);
  run_layer<10,1>(c,2,false);
  run_layer< 9,2>(c,3,false);
  run_layer< 7,1>(c,4,false);
  run_layer< 6,2>(c,5,false);
  run_layer< 4,1>(c,6,false);
  run_layer< 3,2>(c,7,true);

  k_head<<<B*N,512,0,stream>>>(c.skipacc, end1_w, end1_b, end2_w, end2_b, (float*)d_out);
}

// Round 9
// 6355.618 us; speedup vs baseline: 1.0211x; 1.0211x over previous
//
#include <hip/hip_runtime.h>
#include <math.h>

#define DIVUP(a,b) (((a)+(b)-1)/(b))

namespace {

constexpr int B=8, T=12, N=883, CIN=3, C=64, E=10, H=8, HD=8, TOPK=48, L=8;
constexpr int SKC=256, F7=7, T13=13;
constexpr int NP=896;   // padded N for bf16 support matrices / transposed X

typedef __attribute__((ext_vector_type(8))) short bf16x8;
typedef __attribute__((ext_vector_type(4))) float f32x4;

__device__ __forceinline__ float geluf(float x){ return 0.5f*x*(1.0f+erff(x*0.7071067811865475f)); }
__device__ __forceinline__ float sigmf(float x){ return 1.0f/(1.0f+expf(-x)); }
__device__ __forceinline__ float us2f(unsigned short u){ return __uint_as_float(((unsigned)u)<<16); }
__device__ __forceinline__ unsigned short f2us(float f){
  unsigned x=__float_as_uint(f);
  return (unsigned short)((x + 0x7fffu + ((x>>16)&1u))>>16);
}

// 16x16 output tile: A from LDS (bf16 split, [row][k], row stride STRIDE),
// B from global W (bf16 split, [col][k], row stride KW). 3-term split product.
template<int KK, int STRIDE, int KW>
__device__ __forceinline__ f32x4 tile_mm(
    const unsigned short* sAh, const unsigned short* sAl,
    const unsigned short* __restrict__ Wh, const unsigned short* __restrict__ Wl,
    int colBase, int lane, f32x4 acc){
  int lr=lane&15, lg=lane>>4;
  #pragma unroll
  for(int k0=0;k0<KK;k0+=32){
    bf16x8 ah=*(const bf16x8*)&sAh[lr*STRIDE+k0+8*lg];
    bf16x8 al=*(const bf16x8*)&sAl[lr*STRIDE+k0+8*lg];
    bf16x8 bh=*(const bf16x8*)&Wh[(size_t)(colBase+lr)*KW+k0+8*lg];
    bf16x8 bl=*(const bf16x8*)&Wl[(size_t)(colBase+lr)*KW+k0+8*lg];
    acc=__builtin_amdgcn_mfma_f32_16x16x32_bf16(ah,bh,acc,0,0,0);
    acc=__builtin_amdgcn_mfma_f32_16x16x32_bf16(ah,bl,acc,0,0,0);
    acc=__builtin_amdgcn_mfma_f32_16x16x32_bf16(al,bh,acc,0,0,0);
  }
  return acc;
}

// ---------------- graph generation ----------------
__global__ void k_dft(const float* __restrict__ x, float* __restrict__ xf){
  int idx = blockIdx.x*256 + threadIdx.x;
  if(idx >= B*F7*N) return;
  int n = idx % N; int f = (idx/N) % F7; int b = idx/(N*F7);
  float re=0.f, im=0.f;
  for(int t=0;t<T;t++){
    float v = x[((size_t)(b*T+t)*N+n)*CIN];
    float ang = -6.283185307179586f * (float)(f*t) / 12.0f;
    re += v*cosf(ang); im += v*sinf(ang);
  }
  xf[idx] = sqrtf(re*re+im*im);
}

__global__ void k_l2f(float* __restrict__ xf){
  int idx = blockIdx.x*256 + threadIdx.x;
  if(idx >= B*N) return;
  int n = idx % N; int b = idx / N;
  float s=0.f;
  for(int f=0;f<F7;f++){ float v=xf[((size_t)b*F7+f)*N+n]; s+=v*v; }
  float inv = 1.0f/fmaxf(sqrtf(s), 1e-12f);
  for(int f=0;f<F7;f++) xf[((size_t)b*F7+f)*N+n] *= inv;
}

__global__ void k_l2n(float* __restrict__ xf){
  int bf = blockIdx.x; int tid = threadIdx.x;
  __shared__ float red[256];
  size_t base = (size_t)bf*N;
  float s=0.f;
  for(int i=tid;i<N;i+=256){ float v=xf[base+i]; s+=v*v; }
  red[tid]=s; __syncthreads();
  for(int k=128;k>0;k>>=1){ if(tid<k) red[tid]+=red[tid+k]; __syncthreads(); }
  float inv = 1.0f/fmaxf(sqrtf(red[0]), 1e-12f);
  __syncthreads();
  for(int i=tid;i<N;i+=256) xf[base+i]*=inv;
}

__global__ void k_x1(const float* __restrict__ x, const float* __restrict__ xf,
                     const float* __restrict__ E3, const float* __restrict__ TiD,
                     const float* __restrict__ DiW, const float* __restrict__ Wx,
                     const float* __restrict__ Wd, float* __restrict__ x1){
  int idx = blockIdx.x*256+threadIdx.x;
  if(idx>=B*N) return;
  int n=idx%N, b=idx/N;
  float xc[40];
  for(int d=0;d<E;d++){
    float a=0.f;
    for(int f=0;f<F7;f++) a += xf[((size_t)b*F7+f)*N+n]*Wx[f*E+d];
    xc[d]=a;
  }
  for(int d=0;d<E;d++) xc[10+d]=E3[n*E+d];
  int ti = (int)(x[((size_t)(b*T+(T-1))*N+n)*CIN+1]*288.0f);
  int dw = (int)(x[((size_t)(b*T+(T-1))*N+n)*CIN+2]);
  for(int d=0;d<E;d++) xc[20+d]=TiD[ti*E+d];
  for(int d=0;d<E;d++) xc[30+d]=DiW[dw*E+d];
  for(int e=0;e<E;e++){
    float a=0.f;
    for(int f=0;f<40;f++) a += xc[f]*Wd[((size_t)n*40+f)*E+e];
    x1[(size_t)idx*E+e]=fmaxf(a,0.f);
  }
}

__global__ void k_lnstats(const float* __restrict__ x1, float* __restrict__ st){
  int b=blockIdx.x, tid=threadIdx.x;
  __shared__ float rs[256], rq[256];
  const int M=N*E;
  float s=0.f,q=0.f;
  for(int i=tid;i<M;i+=256){ float v=x1[(size_t)b*M+i]; s+=v; q+=v*v; }
  rs[tid]=s; rq[tid]=q; __syncthreads();
  for(int k=128;k>0;k>>=1){ if(tid<k){ rs[tid]+=rs[tid+k]; rq[tid]+=rq[tid+k]; } __syncthreads(); }
  if(tid==0){ float mu=rs[0]/M; float var=rq[0]/M-mu*mu; st[b*2]=mu; st[b*2+1]=var; }
}

__global__ void k_dew(const float* __restrict__ x1, const float* __restrict__ st,
                      const float* __restrict__ Wxabs, float* __restrict__ dew){
  int idx=blockIdx.x*256+threadIdx.x;
  if(idx>=B*N) return;
  int b=idx/N;
  float mu=st[b*2], var=st[b*2+1];
  float rs=rsqrtf(var+1e-8f);
  float xk[E];
  for(int e=0;e<E;e++) xk[e]=(x1[(size_t)idx*E+e]-mu)*rs;
  for(int k=0;k<E;k++){
    float a=0.f;
    for(int e=0;e<E;e++) a+=xk[e]*Wxabs[e*E+k];
    dew[(size_t)idx*E+k]=a;
  }
}

__global__ void k_adp(const float* __restrict__ dew, const float* __restrict__ x1,
                      float* __restrict__ adp){
  size_t idx=(size_t)blockIdx.x*256+threadIdx.x;
  if(idx>=(size_t)B*N*N) return;
  int m=(int)(idx%N); int n=(int)((idx/N)%N); int b=(int)(idx/((size_t)N*N));
  const float* dr=dew+((size_t)b*N+n)*E;
  const float* xr=x1+((size_t)b*N+m)*E;
  float a=0.f;
  for(int k=0;k<E;k++) a+=dr[k]*xr[k];
  adp[idx]=fmaxf(a,0.f);
}

// wave-per-row top-48 + masked softmax, written as bf16 hi/lo into padded AD mats.
// 4 rows per 256-thread block, one wave each, zero barriers.
__global__ __launch_bounds__(256) void k_topk(const float* __restrict__ adp,
                       unsigned short* __restrict__ ADhi, unsigned short* __restrict__ ADlo){
  int row = blockIdx.x*4 + (threadIdx.x>>6);
  int lane = threadIdx.x & 63;
  const float* rp = adp + (size_t)row*N;
  float v[14];
  #pragma unroll
  for(int j=0;j<14;j++){
    int i = lane + j*64;
    v[j] = (i<N) ? rp[i] : -1.f;
  }
  unsigned sel = 0u;
  float m0 = 0.f;
  for(int k=0;k<TOPK;k++){
    float bv = -2.f; int bi = 1<<20;
    #pragma unroll
    for(int j=0;j<14;j++){
      if(!((sel>>j)&1u) && v[j] > bv){ bv = v[j]; bi = lane + j*64; }
    }
    #pragma unroll
    for(int off=1; off<64; off<<=1){
      float ov = __shfl_xor(bv, off);
      int   oi = __shfl_xor(bi, off);
      if(ov > bv || (ov==bv && oi<bi)){ bv=ov; bi=oi; }
    }
    if(k==0) m0 = bv;           // global row max (>=0 since relu)
    if((bi&63)==lane) sel |= 1u << (bi>>6);
  }
  float pv[14];
  float ls = 0.f;
  #pragma unroll
  for(int j=0;j<14;j++){
    int i = lane + j*64;
    float p = ((sel>>j)&1u) ? v[j] : 0.f;
    pv[j] = p;
    if(i<N) ls += expf(p - m0);
  }
  #pragma unroll
  for(int off=1; off<64; off<<=1) ls += __shfl_xor(ls, off);
  float invZ = 1.f/ls;
  size_t base = ((size_t)(row/N)*NP + (size_t)(row%N))*NP;
  #pragma unroll
  for(int j=0;j<14;j++){
    int i = lane + j*64;
    if(i<N){
      float f = expf(pv[j]-m0)*invZ;
      unsigned short h=f2us(f);
      ADhi[base+i]=h; ADlo[base+i]=f2us(f-us2f(h));
    }
  }
}

__global__ void k_adap(const float* __restrict__ E1, const float* __restrict__ E2,
                       unsigned short* __restrict__ Mh, unsigned short* __restrict__ Ml){
  int v=blockIdx.x, tid=threadIdx.x;
  __shared__ float rowv[N];
  __shared__ float rv[256];
  float e1[E];
  for(int e=0;e<E;e++) e1[e]=E1[v*E+e];
  for(int j=tid;j<N;j+=256){
    float s=0.f;
    for(int e=0;e<E;e++) s+=e1[e]*E2[j*E+e];
    rowv[j]=fmaxf(s,0.f);
  }
  __syncthreads();
  float lm=-1e30f;
  for(int j=tid;j<N;j+=256) lm=fmaxf(lm,rowv[j]);
  rv[tid]=lm; __syncthreads();
  for(int s=128;s>0;s>>=1){ if(tid<s) rv[tid]=fmaxf(rv[tid],rv[tid+s]); __syncthreads(); }
  float m=rv[0]; __syncthreads();
  float ls=0.f;
  for(int j=tid;j<N;j+=256) ls+=expf(rowv[j]-m);
  rv[tid]=ls; __syncthreads();
  for(int s=128;s>0;s>>=1){ if(tid<s) rv[tid]+=rv[tid+s]; __syncthreads(); }
  float invZ=1.0f/rv[0];
  for(int j=tid;j<N;j+=256){
    float f=expf(rowv[j]-m)*invZ;
    unsigned short h=f2us(f);
    Mh[(size_t)j*NP+v]=h; Ml[(size_t)j*NP+v]=f2us(f-us2f(h));
  }
}

__global__ void k_cvtT(const float* __restrict__ A, unsigned short* __restrict__ Mh,
                       unsigned short* __restrict__ Ml){
  int idx=blockIdx.x*256+threadIdx.x;
  if(idx>=N*N) return;
  int w=idx/N, v=idx%N;
  float f=A[(size_t)v*N+w];
  unsigned short h=f2us(f);
  Mh[(size_t)w*NP+v]=h;
  Ml[(size_t)w*NP+v]=f2us(f-us2f(h));
}

// ---- weight transpose+split conversions (run once) ----
__global__ void k_cvt_qkv(const float* __restrict__ Wq, const float* __restrict__ Wk,
                          const float* __restrict__ Wv,
                          unsigned short* __restrict__ dh, unsigned short* __restrict__ dl){
  int idx=blockIdx.x*256+threadIdx.x;
  if(idx>=L*192*64) return;
  int l=idx/12288, rem=idx%12288, col=rem/64, k=rem%64;
  int mat=col>>6, o=col&63;
  const float* W=(mat==0)?Wq:((mat==1)?Wk:Wv);
  float v=W[(size_t)l*4096 + k*64 + o];
  unsigned short h=f2us(v);
  dh[idx]=h; dl[idx]=f2us(v-us2f(h));
}
__global__ void k_cvt_w1(const float* __restrict__ W1,
                         unsigned short* __restrict__ dh, unsigned short* __restrict__ dl){
  int idx=blockIdx.x*256+threadIdx.x;
  if(idx>=L*256*64) return;
  int l=idx/16384, rem=idx%16384, col=rem/64, k=rem%64;
  float v=W1[(size_t)l*16384 + k*256 + col];
  unsigned short h=f2us(v);
  dh[idx]=h; dl[idx]=f2us(v-us2f(h));
}
__global__ void k_cvt_w2(const float* __restrict__ W2,
                         unsigned short* __restrict__ dh, unsigned short* __restrict__ dl){
  int idx=blockIdx.x*256+threadIdx.x;
  if(idx>=L*64*256) return;
  int l=idx/16384, rem=idx%16384, col=rem/256, k=rem%256;
  float v=W2[(size_t)l*16384 + k*64 + col];
  unsigned short h=f2us(v);
  dh[idx]=h; dl[idx]=f2us(v-us2f(h));
}
__global__ void k_cvt_conv(const float* __restrict__ fw, const float* __restrict__ gw,
                           unsigned short* __restrict__ dh, unsigned short* __restrict__ dl){
  int idx=blockIdx.x*256+threadIdx.x;
  if(idx>=L*128*128) return;
  int l=idx/16384, rem=idx%16384, col=rem/128, k=rem%128;
  int c=col&63, fg=col>>6, tap=k>>6, i=k&63;
  const float* W=fg?gw:fw;
  float v=W[(size_t)l*8192 + tap*4096 + i*64 + c];
  unsigned short h=f2us(v);
  dh[idx]=h; dl[idx]=f2us(v-us2f(h));
}

__global__ void k_zero(float* __restrict__ p, int n){
  int idx=blockIdx.x*256+threadIdx.x;
  if(idx<n) p[idx]=0.f;
}
__global__ void k_zeroUS(unsigned short* __restrict__ p, long long n){
  long long idx=(long long)blockIdx.x*256+threadIdx.x;
  if(idx<n) p[idx]=0;
}

// tiled transpose: S [b][n<N][m<M] (split bf16 pair) -> D [b][m][v<NP] (zero-padded nodes)
__global__ __launch_bounds__(256) void k_trx(
    const unsigned short* __restrict__ Sh, const unsigned short* __restrict__ Sl,
    unsigned short* __restrict__ Dh, unsigned short* __restrict__ Dl, int M){
  __shared__ unsigned short th[64][66], tl[64][66];
  int b=blockIdx.z;
  int m0=blockIdx.x*64, n0=blockIdx.y*64;
  int tid=threadIdx.x;
  const unsigned short* sbh=Sh + (size_t)b*N*M;
  const unsigned short* sbl=Sl + (size_t)b*N*M;
  for(int idx=tid; idx<64*64; idx+=256){
    int i=idx>>6, j=idx&63;          // i: node offset, j: m offset (contiguous)
    int n=n0+i;
    unsigned short vh=0, vl=0;
    if(n<N){
      size_t o=(size_t)n*M + m0+j;
      vh=sbh[o]; vl=sbl[o];
    }
    th[j][i]=vh; tl[j][i]=vl;
  }
  __syncthreads();
  unsigned short* dbh=Dh + (size_t)b*M*NP;
  unsigned short* dbl=Dl + (size_t)b*M*NP;
  for(int idx=tid; idx<64*64; idx+=256){
    int r=idx>>6, cc=idx&63;         // r: m offset, cc: node offset (contiguous)
    size_t o=(size_t)(m0+r)*NP + n0+cc;
    dbh[o]=th[r][cc]; dbl[o]=tl[r][cc];
  }
}

// ---------------- trunk ----------------
__global__ void k_start(const float* __restrict__ x, const float* __restrict__ sw,
                        const float* __restrict__ sb, float* __restrict__ h){
  int idx=blockIdx.x*256+threadIdx.x;
  if(idx>=B*C*N*T13) return;
  int t=idx%T13; int n=(idx/T13)%N; int o=(idx/(T13*N))%C; int b=idx/(T13*N*C);
  float a=sb[o];
  if(t>0){
    size_t xb=((size_t)(b*T+(t-1))*N+n)*CIN;
    for(int i=0;i<CIN;i++) a += sw[i*C+o]*x[xb+i];
  }
  h[idx]=a;
}

// Fused per-(b,n) MFMA transformer block (unchanged from round 8)
template<int TC, int D>
__global__ __launch_bounds__(256) void k_attconv(const float* __restrict__ hin,
  const unsigned short* __restrict__ Wqkvh, const unsigned short* __restrict__ Wqkvl,
  const unsigned short* __restrict__ W1h,   const unsigned short* __restrict__ W1l,
  const unsigned short* __restrict__ W2h,   const unsigned short* __restrict__ W2l,
  const unsigned short* __restrict__ Wch,   const unsigned short* __restrict__ Wcl,
  const float* __restrict__ bq, const float* __restrict__ bk, const float* __restrict__ bv,
  const float* __restrict__ b1, const float* __restrict__ b2,
  const float* __restrict__ fb, const float* __restrict__ gb,
  const float* __restrict__ skw, const float* __restrict__ skb,
  unsigned short* __restrict__ hThi, unsigned short* __restrict__ hTlo,
  float* __restrict__ skipacc){
  constexpr int TN = TC - D;
  int bn=blockIdx.x; int tid=threadIdx.x;
  int n=bn%N, b=bn/N;
  int lane=tid&63, wid=tid>>6;
  int lr=lane&15, lg=lane>>4;
  __shared__ __align__(16) float sxa[16*64];
  __shared__ __align__(16) float sq [16*64];
  __shared__ __align__(16) float sk [16*64];
  __shared__ __align__(16) float sv [16*64];
  __shared__ __align__(16) float so [16*64];
  __shared__ __align__(16) unsigned short sA1h[16*72], sA1l[16*72];
  __shared__ __align__(16) unsigned short sA2h[16*264], sA2l[16*264];
  __shared__ __align__(16) float sfg[16*128];

  for(int idx=tid; idx<TC*C; idx+=256){
    int c=idx/TC, t=idx%TC;
    float v=hin[(((size_t)b*C+c)*N+n)*TC+t];
    sxa[t*64+c]=v;
    unsigned short h=f2us(v);
    sA1h[t*72+c]=h; sA1l[t*72+c]=f2us(v-us2f(h));
  }
  for(int idx=tid; idx<(16-TC)*C; idx+=256){
    int t=TC+(idx>>6), c=idx&63;
    sxa[t*64+c]=0.f; sA1h[t*72+c]=0; sA1l[t*72+c]=0;
  }
  __syncthreads();

  #pragma unroll
  for(int it=0; it<3; ++it){
    int tile=it*4+wid;
    f32x4 acc={0.f,0.f,0.f,0.f};
    acc=tile_mm<64,72,64>(sA1h,sA1l,Wqkvh,Wqkvl,tile*16,lane,acc);
    int col=tile*16+lr; int mat=col>>6, o=col&63;
    const float* bm=(mat==0)?bq:((mat==1)?bk:bv);
    float* dst=(mat==0)?sq:((mat==1)?sk:sv);
    float bias=bm[o];
    #pragma unroll
    for(int r=0;r<4;r++){
      int t=lg*4+r;
      if(t<TC) dst[t*64+o]=geluf(acc[r]+bias);
    }
  }
  __syncthreads();

  if(tid<H*TC){
    int hh=tid/TC, t=tid%TC;
    const float* qr=&sq[t*64+hh*HD];
    float att[TC];
    float m=-1e30f;
    #pragma unroll
    for(int s=0;s<TC;s++){
      float a=0.f;
      #pragma unroll
      for(int d=0;d<HD;d++) a+=qr[d]*sk[s*64+hh*HD+d];
      a*=0.3535533905932738f;
      a=(s<=t)?a:-1e30f;
      att[s]=a; m=fmaxf(m,a);
    }
    float Z=0.f;
    #pragma unroll
    for(int s=0;s<TC;s++){ float e=expf(att[s]-m); att[s]=e; Z+=e; }
    float invZ=1.0f/Z;
    #pragma unroll
    for(int d=0;d<HD;d++){
      float o=0.f;
      #pragma unroll
      for(int s=0;s<TC;s++) o+=att[s]*sv[s*64+hh*HD+d];
      float v=o*invZ;
      unsigned short h=f2us(v);
      sA1h[t*72+hh*8+d]=h; sA1l[t*72+hh*8+d]=f2us(v-us2f(h));
    }
  }
  __syncthreads();

  #pragma unroll
  for(int it=0; it<4; ++it){
    int tile=it*4+wid;
    f32x4 acc={0.f,0.f,0.f,0.f};
    acc=tile_mm<64,72,64>(sA1h,sA1l,W1h,W1l,tile*16,lane,acc);
    int col=tile*16+lr;
    float bias=b1[col];
    #pragma unroll
    for(int r=0;r<4;r++){
      int t=lg*4+r;
      float v=(t<TC)?geluf(acc[r]+bias):0.f;
      unsigned short h=f2us(v);
      sA2h[t*264+col]=h; sA2l[t*264+col]=f2us(v-us2f(h));
    }
  }
  __syncthreads();

  {
    int tile=wid;
    f32x4 acc={0.f,0.f,0.f,0.f};
    acc=tile_mm<256,264,256>(sA2h,sA2l,W2h,W2l,tile*16,lane,acc);
    int col=tile*16+lr;
    float bias=b2[col];
    #pragma unroll
    for(int r=0;r<4;r++){
      int t=lg*4+r;
      if(t<TC) sq[t*64+col]=acc[r]+bias+sxa[t*64+col];
    }
  }
  __syncthreads();

  for(int idx=tid; idx<16*128; idx+=256){
    int t=idx>>7, k=idx&127;
    int c=k&63;
    float v=0.f;
    if(t<TN) v=sq[((k<64)?t:(t+D))*64+c];
    unsigned short h=f2us(v);
    sA2h[t*136+k]=h; sA2l[t*136+k]=f2us(v-us2f(h));
  }
  __syncthreads();

  #pragma unroll
  for(int it=0; it<2; ++it){
    int tile=it*4+wid;
    f32x4 acc={0.f,0.f,0.f,0.f};
    acc=tile_mm<128,136,128>(sA2h,sA2l,Wch,Wcl,tile*16,lane,acc);
    int col=tile*16+lr;
    float bias=(col<64)?fb[col]:gb[col&63];
    #pragma unroll
    for(int r=0;r<4;r++){
      int t=lg*4+r;
      float v=acc[r]+bias;
      sfg[t*128+col]=(col<64)?tanhf(v):sigmf(v);
    }
  }
  __syncthreads();

  if(tid<C) sk[tid]=sfg[(TN-1)*128+tid]*sfg[(TN-1)*128+64+tid];
  __syncthreads();

  {
    float a=skb[tid];
    for(int i=0;i<C;i++) a+=sk[i]*skw[i*SKC+tid];
    skipacc[((size_t)b*SKC+tid)*N+n]+=a;
  }
  size_t obase=(size_t)bn*C*TN;
  for(int idx=tid; idx<C*TN; idx+=256){
    int c=idx/TN, tt=idx%TN;
    float v=sfg[tt*128+c]*sfg[tt*128+64+c];
    unsigned short h=f2us(v);
    hThi[obase+idx]=h;
    hTlo[obase+idx]=f2us(v-us2f(h));
  }
}

// ---- MFMA spatial GEMM ----
// A: bf16 split row-major [w][v] stride NP (padded/zeroed).
// X source: xT==1 -> XTh/XTl transposed [b][M][NP] (clean staging);
//           xT==0 -> Xh/Xl row-major [b][N][M] (scatter staging).
// Y: row-major split [b][N][M]; optional YT: transposed split [b][M][NP].
__global__ __launch_bounds__(256) void k_spatmm(
    const unsigned short* __restrict__ Ah, const unsigned short* __restrict__ Al,
    long long aStride,
    const unsigned short* __restrict__ Xh, const unsigned short* __restrict__ Xl,
    const unsigned short* __restrict__ XTh, const unsigned short* __restrict__ XTl,
    int xT,
    unsigned short* __restrict__ Yh, unsigned short* __restrict__ Yl,
    unsigned short* __restrict__ YTh, unsigned short* __restrict__ YTl,
    int M){
  __shared__ unsigned short sAh[64*40];
  __shared__ unsigned short sAl[64*40];
  __shared__ unsigned short sXh[64*40];
  __shared__ unsigned short sXl[64*40];
  int b=blockIdx.z;
  const unsigned short* Abh=Ah+(size_t)b*aStride;
  const unsigned short* Abl=Al+(size_t)b*aStride;
  int tid=threadIdx.x;
  int w0=blockIdx.x*64, c0=blockIdx.y*64;
  int lane=tid&63, wid=tid>>6;
  int wr=wid>>1, wc=wid&1;
  int lr=lane&15, lg=lane>>4;
  f32x4 acc[2][2];
  #pragma unroll
  for(int j=0;j<2;j++){
    #pragma unroll
    for(int i=0;i<2;i++){ acc[j][i][0]=0.f; acc[j][i][1]=0.f; acc[j][i][2]=0.f; acc[j][i][3]=0.f; }
  }
  const int ar=tid>>2, akb=(tid&3)*8;
  const int xk=tid>>3, xcb=(tid&7)*8;
  const int xkx=xk ^ (8*((xcb>>3)&3));
  for(int k0=0;k0<N;k0+=32){
    {
      uint4 qh=*(const uint4*)&Abh[(size_t)(w0+ar)*NP + k0+akb];
      uint4 ql=*(const uint4*)&Abl[(size_t)(w0+ar)*NP + k0+akb];
      *(uint4*)&sAh[ar*40+akb]=qh;
      *(uint4*)&sAl[ar*40+akb]=ql;
    }
    if(xT){
      const unsigned short* Xbth=XTh+(size_t)b*M*NP;
      const unsigned short* Xbtl=XTl+(size_t)b*M*NP;
      uint4 qh=*(const uint4*)&Xbth[(size_t)(c0+ar)*NP + k0+akb];
      uint4 ql=*(const uint4*)&Xbtl[(size_t)(c0+ar)*NP + k0+akb];
      *(uint4*)&sXh[ar*40+akb]=qh;
      *(uint4*)&sXl[ar*40+akb]=ql;
    }else{
      const unsigned short* Xbh=Xh+(size_t)b*N*M;
      const unsigned short* Xbl=Xl+(size_t)b*N*M;
      uint4 qh={0,0,0,0}, ql={0,0,0,0};
      if(k0+xk<N){
        qh=*(const uint4*)&Xbh[(size_t)(k0+xk)*M + c0+xcb];
        ql=*(const uint4*)&Xbl[(size_t)(k0+xk)*M + c0+xcb];
      }
      unsigned short uh[8], ul[8];
      uh[0]=(unsigned short)(qh.x&0xffff); uh[1]=(unsigned short)(qh.x>>16);
      uh[2]=(unsigned short)(qh.y&0xffff); uh[3]=(unsigned short)(qh.y>>16);
      uh[4]=(unsigned short)(qh.z&0xffff); uh[5]=(unsigned short)(qh.z>>16);
      uh[6]=(unsigned short)(qh.w&0xffff); uh[7]=(unsigned short)(qh.w>>16);
      ul[0]=(unsigned short)(ql.x&0xffff); ul[1]=(unsigned short)(ql.x>>16);
      ul[2]=(unsigned short)(ql.y&0xffff); ul[3]=(unsigned short)(ql.y>>16);
      ul[4]=(unsigned short)(ql.z&0xffff); ul[5]=(unsigned short)(ql.z>>16);
      ul[6]=(unsigned short)(ql.w&0xffff); ul[7]=(unsigned short)(ql.w>>16);
      #pragma unroll
      for(int j=0;j<8;j++){
        sXh[(xcb+j)*40+xkx]=uh[j];
        sXl[(xcb+j)*40+xkx]=ul[j];
      }
    }
    __syncthreads();
    bf16x8 a_h[2], a_l[2], x_h[2], x_l[2];
    #pragma unroll
    for(int j=0;j<2;j++){
      int r=32*wr+16*j+lr;
      a_h[j]=*(const bf16x8*)&sAh[r*40+8*lg];
      a_l[j]=*(const bf16x8*)&sAl[r*40+8*lg];
    }
    #pragma unroll
    for(int i=0;i<2;i++){
      int cc=32*wc+16*i+lr;
      int g = xT ? lg : (lg ^ ((cc>>3)&3));
      x_h[i]=*(const bf16x8*)&sXh[cc*40+8*g];
      x_l[i]=*(const bf16x8*)&sXl[cc*40+8*g];
    }
    #pragma unroll
    for(int j=0;j<2;j++){
      #pragma unroll
      for(int i=0;i<2;i++){
        acc[j][i]=__builtin_amdgcn_mfma_f32_16x16x32_bf16(a_h[j],x_h[i],acc[j][i],0,0,0);
        acc[j][i]=__builtin_amdgcn_mfma_f32_16x16x32_bf16(a_h[j],x_l[i],acc[j][i],0,0,0);
        acc[j][i]=__builtin_amdgcn_mfma_f32_16x16x32_bf16(a_l[j],x_h[i],acc[j][i],0,0,0);
      }
    }
    __syncthreads();
  }
  // epilogue: C/D layout col=lane&15, row=(lane>>4)*4+reg [m89]
  #pragma unroll
  for(int j=0;j<2;j++){
    int rbase=w0+32*wr+16*j+lg*4;
    #pragma unroll
    for(int i=0;i<2;i++){
      int col=c0+32*wc+16*i+lr;
      unsigned short hh[4], ll[4];
      #pragma unroll
      for(int r=0;r<4;r++){
        float v=acc[j][i][r];
        hh[r]=f2us(v);
        ll[r]=f2us(v-us2f(hh[r]));
      }
      #pragma unroll
      for(int r=0;r<4;r++){
        int row=rbase+r;
        if(row<N){
          size_t o=((size_t)b*N+row)*M+col;
          Yh[o]=hh[r]; Yl[o]=ll[r];
        }
      }
      if(YTh){
        size_t o=(size_t)b*M*NP + (size_t)col*NP + rbase;
        ushort4 ph; ph.x=hh[0]; ph.y=hh[1]; ph.z=hh[2]; ph.w=hh[3];
        ushort4 pl; pl.x=ll[0]; pl.y=ll[1]; pl.z=ll[2]; pl.w=ll[3];
        *(ushort4*)&YTh[o]=ph;
        *(ushort4*)&YTl[o]=pl;
      }
    }
  }
}

// fused GCN projection (unchanged)
template<int TN, int FIRST>
__global__ __launch_bounds__(256) void k_gcnprojB(
    const unsigned short* __restrict__ S0h, const unsigned short* __restrict__ S0l,
    const unsigned short* __restrict__ Ph, const unsigned short* __restrict__ Pl,
    const unsigned short* __restrict__ Qh, const unsigned short* __restrict__ Ql,
    const float* __restrict__ Wg, const float* __restrict__ gb,
    const float* __restrict__ res, float* __restrict__ acc, int Tc){
  constexpr int NS=FIRST+2;
  constexpr int SL=C*TN;
  constexpr int LDSF=((NS*C>256)?NS*C:256)*TN;
  int bn=blockIdx.x; int tid=threadIdx.x;
  int n=bn%N, b=bn/N;
  __shared__ float sx[LDSF];
  size_t base=(size_t)bn*SL;
  if(FIRST){
    for(int i=tid;i<SL;i+=256) sx[i]=us2f(S0h[base+i])+us2f(S0l[base+i]);
  }
  for(int i=tid;i<SL;i+=256){
    sx[(FIRST+0)*SL+i]=us2f(Ph[base+i])+us2f(Pl[base+i]);
    sx[(FIRST+1)*SL+i]=us2f(Qh[base+i])+us2f(Ql[base+i]);
  }
  __syncthreads();
  int o=tid&63, part=tid>>6;
  float a[TN];
  #pragma unroll
  for(int tt=0;tt<TN;tt++) a[tt]=0.f;
  for(int j=0;j<NS;j++){
    const float* Wj=Wg+(size_t)j*C*C;
    const float* xj=&sx[j*SL];
    for(int ii=0;ii<16;ii++){
      int i=part*16+ii;
      float w=Wj[i*C+o];
      #pragma unroll
      for(int tt=0;tt<TN;tt++) a[tt]+=w*xj[i*TN+tt];
    }
  }
  __syncthreads();
  float* red=sx;
  #pragma unroll
  for(int tt=0;tt<TN;tt++) red[(part*64+o)*TN+tt]=a[tt];
  __syncthreads();
  if(part==0){
    size_t ob=(((size_t)b*C+o)*N+n)*TN;
    float v[TN];
    #pragma unroll
    for(int tt=0;tt<TN;tt++)
      v[tt]=red[o*TN+tt]+red[(64+o)*TN+tt]+red[(128+o)*TN+tt]+red[(192+o)*TN+tt];
    if(FIRST){
      float g=gb[o];
      size_t rb=(((size_t)b*C+o)*N+n)*Tc+(Tc-TN);
      #pragma unroll
      for(int tt=0;tt<TN;tt++) acc[ob+tt]=v[tt]+g+res[rb+tt];
    }else{
      #pragma unroll
      for(int tt=0;tt<TN;tt++) acc[ob+tt]+=v[tt];
    }
  }
}

__global__ void k_bnstats(const float* __restrict__ h, float* __restrict__ st, int tn){
  int c=blockIdx.x, tid=threadIdx.x;
  __shared__ float rs[256], rq[256];
  const int Mi=N*tn;
  const int M=B*Mi;
  float s=0.f,q=0.f;
  for(int idx=tid; idx<M; idx+=256){
    int b=idx/Mi; int inner=idx%Mi;
    float v=h[(size_t)b*C*Mi + (size_t)c*Mi + inner];
    s+=v; q+=v*v;
  }
  rs[tid]=s; rq[tid]=q; __syncthreads();
  for(int k=128;k>0;k>>=1){ if(tid<k){ rs[tid]+=rs[tid+k]; rq[tid]+=rq[tid+k]; } __syncthreads(); }
  if(tid==0){
    float mu=rs[0]/M; float var=rq[0]/M-mu*mu;
    st[c]=mu; st[C+c]=rsqrtf(var+1e-5f);
  }
}

__global__ void k_bnapply(float* __restrict__ h, const float* __restrict__ st,
                          const float* __restrict__ g, const float* __restrict__ bb, int tn){
  int idx=blockIdx.x*256+threadIdx.x;
  if(idx>=B*C*N*tn) return;
  int c=(idx/(N*tn))%C;
  float v=h[idx];
  h[idx]=(v-st[c])*st[C+c]*g[c]+bb[c];
}

__global__ void k_head(const float* __restrict__ skipacc, const float* __restrict__ W1,
  const float* __restrict__ b1, const float* __restrict__ W2, const float* __restrict__ b2,
  float* __restrict__ out){
  int gid=blockIdx.x; int tid=threadIdx.x;  // 512 threads
  int n=gid%N; int b=gid/N;
  __shared__ float s[SKC];
  __shared__ float hid[512];
  if(tid<SKC){
    float v=skipacc[((size_t)b*SKC+tid)*N+n];
    s[tid]=fmaxf(v,0.f);
  }
  __syncthreads();
  {
    float a=b1[tid];
    for(int i=0;i<SKC;i++) a+=s[i]*W1[(size_t)i*512+tid];
    hid[tid]=fmaxf(a,0.f);
  }
  __syncthreads();
  if(tid<T){
    float a=b2[tid];
    for(int j=0;j<512;j++) a+=hid[j]*W2[(size_t)j*T+tid];
    out[((size_t)b*T+tid)*N+n]=a;
  }
}

// ---------------- host-side layer driver ----------------
struct Ctx {
  const float *bq,*bk,*bv,*b1,*b2,*filt_b,*gate_b,*skip_w,*skip_b,*gcn_w,*gcn_b,*bn_g,*bn_b;
  const unsigned short *qkvTh,*qkvTl,*w1Th,*w1Tl,*w2Th,*w2Tl,*cvTh,*cvTl;
  const unsigned short* matH[4];
  const unsigned short* matL[4];
  long long matStride[4];
  float *pH,*pAlt,*skipacc,*bnst;
  unsigned short *hThi,*hTlo,*Phi,*Plo,*Qhi,*Qlo;
  unsigned short *hTth,*hTtl,*PTh,*PTl;   // transposed X buffers (PT may be null)
  hipStream_t stream;
};

template<int TC, int D>
void run_layer(Ctx& c, int l, bool last){
  constexpr int TN=TC-D;
  const size_t CC=(size_t)C*C;
  k_attconv<TC,D><<<B*N,256,0,c.stream>>>(c.pH,
    c.qkvTh+(size_t)l*12288, c.qkvTl+(size_t)l*12288,
    c.w1Th+(size_t)l*16384,  c.w1Tl+(size_t)l*16384,
    c.w2Th+(size_t)l*16384,  c.w2Tl+(size_t)l*16384,
    c.cvTh+(size_t)l*16384,  c.cvTl+(size_t)l*16384,
    c.bq+(size_t)l*C, c.bk+(size_t)l*C, c.bv+(size_t)l*C,
    c.b1+(size_t)l*4*C, c.b2+(size_t)l*C,
    c.filt_b+(size_t)l*C, c.gate_b+(size_t)l*C,
    c.skip_w+(size_t)l*C*SKC, c.skip_b+(size_t)l*SKC,
    c.hThi, c.hTlo, c.skipacc);
  if(!last){
    int M=C*TN, nMB=M/64;
    const float* Wl=c.gcn_w+(size_t)l*9*CC;
    dim3 sg(DIVUP(N,64), nMB, B);
    k_trx<<<dim3(M/64,DIVUP(NP,64),B),256,0,c.stream>>>(c.hThi,c.hTlo, c.hTth,c.hTtl, M);
    for(int s=0;s<4;s++){
      // hop 1: X = hT_T (clean staging); write P (+ P_T if available)
      k_spatmm<<<sg,256,0,c.stream>>>(c.matH[s],c.matL[s],c.matStride[s],
          nullptr,nullptr, c.hTth,c.hTtl, 1,
          c.Phi,c.Plo, c.PTh,c.PTl, M);
      // hop 2: X = P_T (clean) or P row-major (scatter fallback)
      if(c.PTh){
        k_spatmm<<<sg,256,0,c.stream>>>(c.matH[s],c.matL[s],c.matStride[s],
            nullptr,nullptr, c.PTh,c.PTl, 1,
            c.Qhi,c.Qlo, nullptr,nullptr, M);
      }else{
        k_spatmm<<<sg,256,0,c.stream>>>(c.matH[s],c.matL[s],c.matStride[s],
            c.Phi,c.Plo, nullptr,nullptr, 0,
            c.Qhi,c.Qlo, nullptr,nullptr, M);
      }
      if(s==0){
        k_gcnprojB<TN,1><<<B*N,256,0,c.stream>>>(c.hThi,c.hTlo,
            c.Phi,c.Plo,c.Qhi,c.Qlo,
            Wl, c.gcn_b+(size_t)l*C, c.pH, c.pAlt, TC);
      }else{
        k_gcnprojB<TN,0><<<B*N,256,0,c.stream>>>(nullptr,nullptr,
            c.Phi,c.Plo,c.Qhi,c.Qlo,
            Wl+(size_t)(1+2*s)*CC, nullptr, nullptr, c.pAlt, TC);
      }
    }
    k_bnstats<<<C,256,0,c.stream>>>(c.pAlt, c.bnst, TN);
    k_bnapply<<<DIVUP(B*C*N*TN,256),256,0,c.stream>>>(c.pAlt, c.bnst,
      c.bn_g+(size_t)l*C, c.bn_b+(size_t)l*C, TN);
    float* tmp=c.pH; c.pH=c.pAlt; c.pAlt=tmp;
  }
}

} // namespace

extern "C" void kernel_launch(void* const* d_in, const int* in_sizes, int n_in,
                              void* d_out, int out_size, void* d_ws, size_t ws_size,
                              hipStream_t stream){
  (void)in_sizes; (void)n_in;
  const float* x      =(const float*)d_in[0];
  const float* sup0   =(const float*)d_in[1];
  const float* sup1   =(const float*)d_in[2];
  const float* TiD    =(const float*)d_in[3];
  const float* DiW    =(const float*)d_in[4];
  const float* E1     =(const float*)d_in[5];
  const float* E2     =(const float*)d_in[6];
  const float* E3     =(const float*)d_in[7];
  const float* Wx     =(const float*)d_in[8];
  const float* Wd     =(const float*)d_in[9];
  const float* Wxabs  =(const float*)d_in[10];
  const float* start_w=(const float*)d_in[11];
  const float* start_b=(const float*)d_in[12];
  const float* Wq     =(const float*)d_in[13];
  const float* Wk     =(const float*)d_in[15];
  const float* Wv     =(const float*)d_in[17];
  const float* W1     =(const float*)d_in[19];
  const float* W2     =(const float*)d_in[21];
  const float* filt_w =(const float*)d_in[23];
  const float* gate_w =(const float*)d_in[25];

  Ctx c;
  c.bq=(const float*)d_in[14];
  c.bk=(const float*)d_in[16];
  c.bv=(const float*)d_in[18];
  c.b1=(const float*)d_in[20];
  c.b2=(const float*)d_in[22];
  c.filt_b=(const float*)d_in[24];
  c.gate_b=(const float*)d_in[26];
  c.skip_w=(const float*)d_in[27]; c.skip_b=(const float*)d_in[28];
  c.gcn_w =(const float*)d_in[29]; c.gcn_b =(const float*)d_in[30];
  c.bn_g  =(const float*)d_in[31]; c.bn_b  =(const float*)d_in[32];
  const float* end1_w =(const float*)d_in[33];
  const float* end1_b =(const float*)d_in[34];
  const float* end2_w =(const float*)d_in[35];
  const float* end2_b =(const float*)d_in[36];
  c.stream=stream;

  // workspace carve (16B-aligned)
  size_t off=0;
  auto allocF=[&](size_t nf)->float*{
    nf=(nf+3)&~(size_t)3;
    float* p=(float*)((char*)d_ws+off);
    off += nf*sizeof(float);
    return p;
  };
  auto allocU=[&](size_t nu)->unsigned short*{
    nu=(nu+7)&~(size_t)7;
    unsigned short* p=(unsigned short*)((char*)d_ws+off);
    off += nu*sizeof(unsigned short);
    return p;
  };
  const size_t HMAX =(size_t)B*C*N*T13;
  const size_t XSZ  =(size_t)B*C*N*12;
  const size_t XTSZ =(size_t)768*NP*B;     // transposed X: [b][M<=768][896]
  const size_t SUPP =(size_t)NP*NP;
  const size_t ADSZ =(size_t)B*NP*NP;

  float* xf     = allocF((size_t)B*F7*N);
  float* gx1    = allocF((size_t)B*N*E);
  float* gdew   = allocF((size_t)B*N*E);
  float* gst    = allocF(16);
  c.bnst        = allocF(2*C);
  float* adp    = allocF((size_t)B*N*N);   // dead after k_topk; hosts hT_T overlay
  c.pH          = allocF(HMAX);
  c.pAlt        = allocF(HMAX);
  c.skipacc     = allocF((size_t)B*SKC*N);
  unsigned short* matRegion=(unsigned short*)((char*)d_ws+off);
  unsigned short* s0h = allocU(SUPP);
  unsigned short* s0l = allocU(SUPP);
  unsigned short* s1h = allocU(SUPP);
  unsigned short* s1l = allocU(SUPP);
  unsigned short* aph = allocU(SUPP);
  unsigned short* apl = allocU(SUPP);
  unsigned short* adh = allocU(ADSZ);
  unsigned short* adl = allocU(ADSZ);
  long long matRegionN = (long long)(( (unsigned short*)((char*)d_ws+off) ) - matRegion);
  c.hThi = allocU(XSZ);  c.hTlo = allocU(XSZ);
  c.Phi  = allocU(XSZ);  c.Plo  = allocU(XSZ);
  c.Qhi  = allocU(XSZ);  c.Qlo  = allocU(XSZ);
  unsigned short* qkvTh = allocU((size_t)L*12288);
  unsigned short* qkvTl = allocU((size_t)L*12288);
  unsigned short* w1Th  = allocU((size_t)L*16384);
  unsigned short* w1Tl  = allocU((size_t)L*16384);
  unsigned short* w2Th  = allocU((size_t)L*16384);
  unsigned short* w2Tl  = allocU((size_t)L*16384);
  unsigned short* cvTh  = allocU((size_t)L*16384);
  unsigned short* cvTl  = allocU((size_t)L*16384);
  if(off > ws_size){
    k_zero<<<DIVUP(out_size,256),256,0,stream>>>((float*)d_out, out_size);
    return;
  }
  // hT_T overlays the (dead-after-topk) adp region: 2*768*896*8*2B = 22.0MB <= 24.9MB
  c.hTth = (unsigned short*)adp;
  c.hTtl = c.hTth + XTSZ;
  // P_T is tier-guarded: allocate only if workspace allows; else hop-2 uses scatter path
  {
    size_t save=off;
    c.PTh = allocU(XTSZ);
    c.PTl = allocU(XTSZ);
    if(off > ws_size){ c.PTh=nullptr; c.PTl=nullptr; off=save; }
  }
  c.qkvTh=qkvTh; c.qkvTl=qkvTl; c.w1Th=w1Th; c.w1Tl=w1Tl;
  c.w2Th=w2Th; c.w2Tl=w2Tl; c.cvTh=cvTh; c.cvTl=cvTl;
  c.matH[0]=s0h; c.matL[0]=s0l; c.matStride[0]=0;
  c.matH[1]=s1h; c.matL[1]=s1l; c.matStride[1]=0;
  c.matH[2]=aph; c.matL[2]=apl; c.matStride[2]=0;
  c.matH[3]=adh; c.matL[3]=adl; c.matStride[3]=(long long)NP*NP;

  // ---- graph generation + conversions ----
  k_zeroUS<<<(int)DIVUP(matRegionN,256),256,0,stream>>>(matRegion, matRegionN);
  k_cvt_qkv <<<DIVUP(L*192*64,256),256,0,stream>>>(Wq,Wk,Wv,qkvTh,qkvTl);
  k_cvt_w1  <<<DIVUP(L*256*64,256),256,0,stream>>>(W1,w1Th,w1Tl);
  k_cvt_w2  <<<DIVUP(L*64*256,256),256,0,stream>>>(W2,w2Th,w2Tl);
  k_cvt_conv<<<DIVUP(L*128*128,256),256,0,stream>>>(filt_w,gate_w,cvTh,cvTl);
  k_dft <<<DIVUP(B*F7*N,256),256,0,stream>>>(x, xf);
  k_l2f <<<DIVUP(B*N,256),256,0,stream>>>(xf);
  k_l2n <<<B*F7,256,0,stream>>>(xf);
  k_x1  <<<DIVUP(B*N,256),256,0,stream>>>(x, xf, E3, TiD, DiW, Wx, Wd, gx1);
  k_lnstats<<<B,256,0,stream>>>(gx1, gst);
  k_dew <<<DIVUP(B*N,256),256,0,stream>>>(gx1, gst, Wxabs, gdew);
  k_adp <<<DIVUP(B*N*N,256),256,0,stream>>>(gdew, gx1, adp);
  k_topk<<<(B*N)/4,256,0,stream>>>(adp, adh, adl);
  k_adap<<<N,256,0,stream>>>(E1, E2, aph, apl);
  k_cvtT<<<DIVUP(N*N,256),256,0,stream>>>(sup0, s0h, s0l);
  k_cvtT<<<DIVUP(N*N,256),256,0,stream>>>(sup1, s1h, s1l);

  // ---- trunk ----
  k_zero<<<DIVUP(B*SKC*N,256),256,0,stream>>>(c.skipacc, B*SKC*N);
  k_start<<<DIVUP(B*C*N*T13,256),256,0,stream>>>(x, start_w, start_b, c.pH);

  run_layer<13,1>(c,0,false);
  run_layer<12,2>(c,1,false);
  run_layer<10,1>(c,2,false);
  run_layer< 9,2>(c,3,false);
  run_layer< 7,1>(c,4,false);
  run_layer< 6,2>(c,5,false);
  run_layer< 4,1>(c,6,false);
  run_layer< 3,2>(c,7,true);

  k_head<<<B*N,512,0,stream>>>(c.skipacc, end1_w, end1_b, end2_w, end2_b, (float*)d_out);
}

// Round 10
// 5683.513 us; speedup vs baseline: 1.1419x; 1.1183x over previous
//
#include <hip/hip_runtime.h>
#include <math.h>

#define DIVUP(a,b) (((a)+(b)-1)/(b))

namespace {

constexpr int B=8, T=12, N=883, CIN=3, C=64, E=10, H=8, HD=8, TOPK=48, L=8;
constexpr int SKC=256, F7=7, T13=13;
constexpr int NP=896;   // padded N for bf16 support matrices / transposed X

typedef __attribute__((ext_vector_type(8))) short bf16x8;
typedef __attribute__((ext_vector_type(4))) float f32x4;

__device__ __forceinline__ float geluf(float x){ return 0.5f*x*(1.0f+erff(x*0.7071067811865475f)); }
__device__ __forceinline__ float sigmf(float x){ return 1.0f/(1.0f+expf(-x)); }
__device__ __forceinline__ float us2f(unsigned short u){ return __uint_as_float(((unsigned)u)<<16); }
__device__ __forceinline__ unsigned short f2us(float f){
  unsigned x=__float_as_uint(f);
  return (unsigned short)((x + 0x7fffu + ((x>>16)&1u))>>16);
}

// 16x16 output tile: A from LDS (bf16 split, [row][k], row stride STRIDE),
// B from global W (bf16 split, [col][k], row stride KW). 3-term split product.
template<int KK, int STRIDE, int KW>
__device__ __forceinline__ f32x4 tile_mm(
    const unsigned short* sAh, const unsigned short* sAl,
    const unsigned short* __restrict__ Wh, const unsigned short* __restrict__ Wl,
    int colBase, int lane, f32x4 acc){
  int lr=lane&15, lg=lane>>4;
  #pragma unroll
  for(int k0=0;k0<KK;k0+=32){
    bf16x8 ah=*(const bf16x8*)&sAh[lr*STRIDE+k0+8*lg];
    bf16x8 al=*(const bf16x8*)&sAl[lr*STRIDE+k0+8*lg];
    bf16x8 bh=*(const bf16x8*)&Wh[(size_t)(colBase+lr)*KW+k0+8*lg];
    bf16x8 bl=*(const bf16x8*)&Wl[(size_t)(colBase+lr)*KW+k0+8*lg];
    acc=__builtin_amdgcn_mfma_f32_16x16x32_bf16(ah,bh,acc,0,0,0);
    acc=__builtin_amdgcn_mfma_f32_16x16x32_bf16(ah,bl,acc,0,0,0);
    acc=__builtin_amdgcn_mfma_f32_16x16x32_bf16(al,bh,acc,0,0,0);
  }
  return acc;
}

// ---------------- graph generation ----------------
__global__ void k_dft(const float* __restrict__ x, float* __restrict__ xf){
  int idx = blockIdx.x*256 + threadIdx.x;
  if(idx >= B*F7*N) return;
  int n = idx % N; int f = (idx/N) % F7; int b = idx/(N*F7);
  float re=0.f, im=0.f;
  for(int t=0;t<T;t++){
    float v = x[((size_t)(b*T+t)*N+n)*CIN];
    float ang = -6.283185307179586f * (float)(f*t) / 12.0f;
    re += v*cosf(ang); im += v*sinf(ang);
  }
  xf[idx] = sqrtf(re*re+im*im);
}

__global__ void k_l2f(float* __restrict__ xf){
  int idx = blockIdx.x*256 + threadIdx.x;
  if(idx >= B*N) return;
  int n = idx % N; int b = idx / N;
  float s=0.f;
  for(int f=0;f<F7;f++){ float v=xf[((size_t)b*F7+f)*N+n]; s+=v*v; }
  float inv = 1.0f/fmaxf(sqrtf(s), 1e-12f);
  for(int f=0;f<F7;f++) xf[((size_t)b*F7+f)*N+n] *= inv;
}

__global__ void k_l2n(float* __restrict__ xf){
  int bf = blockIdx.x; int tid = threadIdx.x;
  __shared__ float red[256];
  size_t base = (size_t)bf*N;
  float s=0.f;
  for(int i=tid;i<N;i+=256){ float v=xf[base+i]; s+=v*v; }
  red[tid]=s; __syncthreads();
  for(int k=128;k>0;k>>=1){ if(tid<k) red[tid]+=red[tid+k]; __syncthreads(); }
  float inv = 1.0f/fmaxf(sqrtf(red[0]), 1e-12f);
  __syncthreads();
  for(int i=tid;i<N;i+=256) xf[base+i]*=inv;
}

__global__ void k_x1(const float* __restrict__ x, const float* __restrict__ xf,
                     const float* __restrict__ E3, const float* __restrict__ TiD,
                     const float* __restrict__ DiW, const float* __restrict__ Wx,
                     const float* __restrict__ Wd, float* __restrict__ x1){
  int idx = blockIdx.x*256+threadIdx.x;
  if(idx>=B*N) return;
  int n=idx%N, b=idx/N;
  float xc[40];
  for(int d=0;d<E;d++){
    float a=0.f;
    for(int f=0;f<F7;f++) a += xf[((size_t)b*F7+f)*N+n]*Wx[f*E+d];
    xc[d]=a;
  }
  for(int d=0;d<E;d++) xc[10+d]=E3[n*E+d];
  int ti = (int)(x[((size_t)(b*T+(T-1))*N+n)*CIN+1]*288.0f);
  int dw = (int)(x[((size_t)(b*T+(T-1))*N+n)*CIN+2]);
  for(int d=0;d<E;d++) xc[20+d]=TiD[ti*E+d];
  for(int d=0;d<E;d++) xc[30+d]=DiW[dw*E+d];
  for(int e=0;e<E;e++){
    float a=0.f;
    for(int f=0;f<40;f++) a += xc[f]*Wd[((size_t)n*40+f)*E+e];
    x1[(size_t)idx*E+e]=fmaxf(a,0.f);
  }
}

__global__ void k_lnstats(const float* __restrict__ x1, float* __restrict__ st){
  int b=blockIdx.x, tid=threadIdx.x;
  __shared__ float rs[256], rq[256];
  const int M=N*E;
  float s=0.f,q=0.f;
  for(int i=tid;i<M;i+=256){ float v=x1[(size_t)b*M+i]; s+=v; q+=v*v; }
  rs[tid]=s; rq[tid]=q; __syncthreads();
  for(int k=128;k>0;k>>=1){ if(tid<k){ rs[tid]+=rs[tid+k]; rq[tid]+=rq[tid+k]; } __syncthreads(); }
  if(tid==0){ float mu=rs[0]/M; float var=rq[0]/M-mu*mu; st[b*2]=mu; st[b*2+1]=var; }
}

__global__ void k_dew(const float* __restrict__ x1, const float* __restrict__ st,
                      const float* __restrict__ Wxabs, float* __restrict__ dew){
  int idx=blockIdx.x*256+threadIdx.x;
  if(idx>=B*N) return;
  int b=idx/N;
  float mu=st[b*2], var=st[b*2+1];
  float rs=rsqrtf(var+1e-8f);
  float xk[E];
  for(int e=0;e<E;e++) xk[e]=(x1[(size_t)idx*E+e]-mu)*rs;
  for(int k=0;k<E;k++){
    float a=0.f;
    for(int e=0;e<E;e++) a+=xk[e]*Wxabs[e*E+k];
    dew[(size_t)idx*E+k]=a;
  }
}

__global__ void k_adp(const float* __restrict__ dew, const float* __restrict__ x1,
                      float* __restrict__ adp){
  size_t idx=(size_t)blockIdx.x*256+threadIdx.x;
  if(idx>=(size_t)B*N*N) return;
  int m=(int)(idx%N); int n=(int)((idx/N)%N); int b=(int)(idx/((size_t)N*N));
  const float* dr=dew+((size_t)b*N+n)*E;
  const float* xr=x1+((size_t)b*N+m)*E;
  float a=0.f;
  for(int k=0;k<E;k++) a+=dr[k]*xr[k];
  adp[idx]=fmaxf(a,0.f);
}

// wave-per-row top-48 + masked softmax -> bf16 hi/lo padded AD mats; zero barriers.
__global__ __launch_bounds__(256) void k_topk(const float* __restrict__ adp,
                       unsigned short* __restrict__ ADhi, unsigned short* __restrict__ ADlo){
  int row = blockIdx.x*4 + (threadIdx.x>>6);
  int lane = threadIdx.x & 63;
  const float* rp = adp + (size_t)row*N;
  float v[14];
  #pragma unroll
  for(int j=0;j<14;j++){
    int i = lane + j*64;
    v[j] = (i<N) ? rp[i] : -1.f;
  }
  unsigned sel = 0u;
  float m0 = 0.f;
  for(int k=0;k<TOPK;k++){
    float bv = -2.f; int bi = 1<<20;
    #pragma unroll
    for(int j=0;j<14;j++){
      if(!((sel>>j)&1u) && v[j] > bv){ bv = v[j]; bi = lane + j*64; }
    }
    #pragma unroll
    for(int off=1; off<64; off<<=1){
      float ov = __shfl_xor(bv, off);
      int   oi = __shfl_xor(bi, off);
      if(ov > bv || (ov==bv && oi<bi)){ bv=ov; bi=oi; }
    }
    if(k==0) m0 = bv;
    if((bi&63)==lane) sel |= 1u << (bi>>6);
  }
  float pv[14];
  float ls = 0.f;
  #pragma unroll
  for(int j=0;j<14;j++){
    int i = lane + j*64;
    float p = ((sel>>j)&1u) ? v[j] : 0.f;
    pv[j] = p;
    if(i<N) ls += expf(p - m0);
  }
  #pragma unroll
  for(int off=1; off<64; off<<=1) ls += __shfl_xor(ls, off);
  float invZ = 1.f/ls;
  size_t base = ((size_t)(row/N)*NP + (size_t)(row%N))*NP;
  #pragma unroll
  for(int j=0;j<14;j++){
    int i = lane + j*64;
    if(i<N){
      float f = expf(pv[j]-m0)*invZ;
      unsigned short h=f2us(f);
      ADhi[base+i]=h; ADlo[base+i]=f2us(f-us2f(h));
    }
  }
}

__global__ void k_adap(const float* __restrict__ E1, const float* __restrict__ E2,
                       unsigned short* __restrict__ Mh, unsigned short* __restrict__ Ml){
  int v=blockIdx.x, tid=threadIdx.x;
  __shared__ float rowv[N];
  __shared__ float rv[256];
  float e1[E];
  for(int e=0;e<E;e++) e1[e]=E1[v*E+e];
  for(int j=tid;j<N;j+=256){
    float s=0.f;
    for(int e=0;e<E;e++) s+=e1[e]*E2[j*E+e];
    rowv[j]=fmaxf(s,0.f);
  }
  __syncthreads();
  float lm=-1e30f;
  for(int j=tid;j<N;j+=256) lm=fmaxf(lm,rowv[j]);
  rv[tid]=lm; __syncthreads();
  for(int s=128;s>0;s>>=1){ if(tid<s) rv[tid]=fmaxf(rv[tid],rv[tid+s]); __syncthreads(); }
  float m=rv[0]; __syncthreads();
  float ls=0.f;
  for(int j=tid;j<N;j+=256) ls+=expf(rowv[j]-m);
  rv[tid]=ls; __syncthreads();
  for(int s=128;s>0;s>>=1){ if(tid<s) rv[tid]+=rv[tid+s]; __syncthreads(); }
  float invZ=1.0f/rv[0];
  for(int j=tid;j<N;j+=256){
    float f=expf(rowv[j]-m)*invZ;
    unsigned short h=f2us(f);
    Mh[(size_t)j*NP+v]=h; Ml[(size_t)j*NP+v]=f2us(f-us2f(h));
  }
}

__global__ void k_cvtT(const float* __restrict__ A, unsigned short* __restrict__ Mh,
                       unsigned short* __restrict__ Ml){
  int idx=blockIdx.x*256+threadIdx.x;
  if(idx>=N*N) return;
  int w=idx/N, v=idx%N;
  float f=A[(size_t)v*N+w];
  unsigned short h=f2us(f);
  Mh[(size_t)w*NP+v]=h;
  Ml[(size_t)w*NP+v]=f2us(f-us2f(h));
}

// ---- weight transpose+split conversions (run once) ----
__global__ void k_cvt_qkv(const float* __restrict__ Wq, const float* __restrict__ Wk,
                          const float* __restrict__ Wv,
                          unsigned short* __restrict__ dh, unsigned short* __restrict__ dl){
  int idx=blockIdx.x*256+threadIdx.x;
  if(idx>=L*192*64) return;
  int l=idx/12288, rem=idx%12288, col=rem/64, k=rem%64;
  int mat=col>>6, o=col&63;
  const float* W=(mat==0)?Wq:((mat==1)?Wk:Wv);
  float v=W[(size_t)l*4096 + k*64 + o];
  unsigned short h=f2us(v);
  dh[idx]=h; dl[idx]=f2us(v-us2f(h));
}
__global__ void k_cvt_w1(const float* __restrict__ W1,
                         unsigned short* __restrict__ dh, unsigned short* __restrict__ dl){
  int idx=blockIdx.x*256+threadIdx.x;
  if(idx>=L*256*64) return;
  int l=idx/16384, rem=idx%16384, col=rem/64, k=rem%64;
  float v=W1[(size_t)l*16384 + k*256 + col];
  unsigned short h=f2us(v);
  dh[idx]=h; dl[idx]=f2us(v-us2f(h));
}
__global__ void k_cvt_w2(const float* __restrict__ W2,
                         unsigned short* __restrict__ dh, unsigned short* __restrict__ dl){
  int idx=blockIdx.x*256+threadIdx.x;
  if(idx>=L*64*256) return;
  int l=idx/16384, rem=idx%16384, col=rem/256, k=rem%256;
  float v=W2[(size_t)l*16384 + k*64 + col];
  unsigned short h=f2us(v);
  dh[idx]=h; dl[idx]=f2us(v-us2f(h));
}
__global__ void k_cvt_conv(const float* __restrict__ fw, const float* __restrict__ gw,
                           unsigned short* __restrict__ dh, unsigned short* __restrict__ dl){
  int idx=blockIdx.x*256+threadIdx.x;
  if(idx>=L*128*128) return;
  int l=idx/16384, rem=idx%16384, col=rem/128, k=rem%128;
  int c=col&63, fg=col>>6, tap=k>>6, i=k&63;
  const float* W=fg?gw:fw;
  float v=W[(size_t)l*8192 + tap*4096 + i*64 + c];
  unsigned short h=f2us(v);
  dh[idx]=h; dl[idx]=f2us(v-us2f(h));
}
// gcn_w (L,576,64) -> [l][o][k=576] bf16 split
__global__ void k_cvt_gcn(const float* __restrict__ Wg,
                          unsigned short* __restrict__ dh, unsigned short* __restrict__ dl){
  int idx=blockIdx.x*256+threadIdx.x;
  if(idx>=L*64*576) return;
  int l=idx/36864, rem=idx%36864, o=rem/576, k=rem%576;
  float v=Wg[((size_t)l*576 + k)*64 + o];
  unsigned short h=f2us(v);
  dh[idx]=h; dl[idx]=f2us(v-us2f(h));
}

__global__ void k_zero(float* __restrict__ p, int n){
  int idx=blockIdx.x*256+threadIdx.x;
  if(idx<n) p[idx]=0.f;
}
__global__ void k_zeroUS(unsigned short* __restrict__ p, long long n){
  long long idx=(long long)blockIdx.x*256+threadIdx.x;
  if(idx<n) p[idx]=0;
}

// tiled transpose: S [b][n<N][m<M] (split bf16 pair) -> D [b][m][v<NP]
__global__ __launch_bounds__(256) void k_trx(
    const unsigned short* __restrict__ Sh, const unsigned short* __restrict__ Sl,
    unsigned short* __restrict__ Dh, unsigned short* __restrict__ Dl, int M){
  __shared__ unsigned short th[64][66], tl[64][66];
  int b=blockIdx.z;
  int m0=blockIdx.x*64, n0=blockIdx.y*64;
  int tid=threadIdx.x;
  const unsigned short* sbh=Sh + (size_t)b*N*M;
  const unsigned short* sbl=Sl + (size_t)b*N*M;
  for(int idx=tid; idx<64*64; idx+=256){
    int i=idx>>6, j=idx&63;
    int n=n0+i;
    unsigned short vh=0, vl=0;
    if(n<N){
      size_t o=(size_t)n*M + m0+j;
      vh=sbh[o]; vl=sbl[o];
    }
    th[j][i]=vh; tl[j][i]=vl;
  }
  __syncthreads();
  unsigned short* dbh=Dh + (size_t)b*M*NP;
  unsigned short* dbl=Dl + (size_t)b*M*NP;
  for(int idx=tid; idx<64*64; idx+=256){
    int r=idx>>6, cc=idx&63;
    size_t o=(size_t)(m0+r)*NP + n0+cc;
    dbh[o]=th[r][cc]; dbl[o]=tl[r][cc];
  }
}

// ---------------- trunk ----------------
// h layout: [b][n][t][c]
__global__ void k_start(const float* __restrict__ x, const float* __restrict__ sw,
                        const float* __restrict__ sb, float* __restrict__ h){
  int idx=blockIdx.x*256+threadIdx.x;
  if(idx>=B*N*T13*C) return;
  int c=idx&63; int t=(idx>>6)%T13; int n=(idx/(64*T13))%N; int b=idx/(64*T13*N);
  float a=sb[c];
  if(t>0){
    size_t xb=((size_t)(b*T+(t-1))*N+n)*CIN;
    for(int i=0;i<CIN;i++) a += sw[i*C+c]*x[xb+i];
  }
  h[idx]=a;
}

// Fused per-(b,n) MFMA transformer block; hin [b][n][t][c]; hT write [bn][tt*64+c]
template<int TC, int D>
__global__ __launch_bounds__(256) void k_attconv(const float* __restrict__ hin,
  const unsigned short* __restrict__ Wqkvh, const unsigned short* __restrict__ Wqkvl,
  const unsigned short* __restrict__ W1h,   const unsigned short* __restrict__ W1l,
  const unsigned short* __restrict__ W2h,   const unsigned short* __restrict__ W2l,
  const unsigned short* __restrict__ Wch,   const unsigned short* __restrict__ Wcl,
  const float* __restrict__ bq, const float* __restrict__ bk, const float* __restrict__ bv,
  const float* __restrict__ b1, const float* __restrict__ b2,
  const float* __restrict__ fb, const float* __restrict__ gb,
  const float* __restrict__ skw, const float* __restrict__ skb,
  unsigned short* __restrict__ hThi, unsigned short* __restrict__ hTlo,
  float* __restrict__ skipacc){
  constexpr int TN = TC - D;
  int bn=blockIdx.x; int tid=threadIdx.x;
  int n=bn%N, b=bn/N;
  int lane=tid&63, wid=tid>>6;
  int lr=lane&15, lg=lane>>4;
  __shared__ __align__(16) float sxa[16*64];
  __shared__ __align__(16) float sq [16*64];
  __shared__ __align__(16) float sk [16*64];
  __shared__ __align__(16) float sv [16*64];
  __shared__ __align__(16) unsigned short sA1h[16*72], sA1l[16*72];
  __shared__ __align__(16) unsigned short sA2h[16*264], sA2l[16*264];
  __shared__ __align__(16) float sfg[16*128];

  // phase 1: contiguous staging from [bn][t][c]
  const float* hp = hin + (size_t)bn*TC*64;
  for(int idx=tid; idx<TC*64; idx+=256){
    int t=idx>>6, c=idx&63;
    float v=hp[idx];
    sxa[idx]=v;
    unsigned short h=f2us(v);
    sA1h[t*72+c]=h; sA1l[t*72+c]=f2us(v-us2f(h));
  }
  for(int idx=tid; idx<(16-TC)*64; idx+=256){
    int t=TC+(idx>>6), c=idx&63;
    sxa[t*64+c]=0.f; sA1h[t*72+c]=0; sA1l[t*72+c]=0;
  }
  __syncthreads();

  // phase 2: QKV + bias + gelu
  #pragma unroll
  for(int it=0; it<3; ++it){
    int tile=it*4+wid;
    f32x4 acc={0.f,0.f,0.f,0.f};
    acc=tile_mm<64,72,64>(sA1h,sA1l,Wqkvh,Wqkvl,tile*16,lane,acc);
    int col=tile*16+lr; int mat=col>>6, o=col&63;
    const float* bm=(mat==0)?bq:((mat==1)?bk:bv);
    float* dst=(mat==0)?sq:((mat==1)?sk:sv);
    float bias=bm[o];
    #pragma unroll
    for(int r=0;r<4;r++){
      int t=lg*4+r;
      if(t<TC) dst[t*64+o]=geluf(acc[r]+bias);
    }
  }
  __syncthreads();

  // phase 3: causal attention -> split bf16 into sA1
  if(tid<H*TC){
    int hh=tid/TC, t=tid%TC;
    const float* qr=&sq[t*64+hh*HD];
    float att[TC];
    float m=-1e30f;
    #pragma unroll
    for(int s=0;s<TC;s++){
      float a=0.f;
      #pragma unroll
      for(int d=0;d<HD;d++) a+=qr[d]*sk[s*64+hh*HD+d];
      a*=0.3535533905932738f;
      a=(s<=t)?a:-1e30f;
      att[s]=a; m=fmaxf(m,a);
    }
    float Z=0.f;
    #pragma unroll
    for(int s=0;s<TC;s++){ float e=expf(att[s]-m); att[s]=e; Z+=e; }
    float invZ=1.0f/Z;
    #pragma unroll
    for(int d=0;d<HD;d++){
      float o=0.f;
      #pragma unroll
      for(int s=0;s<TC;s++) o+=att[s]*sv[s*64+hh*HD+d];
      float v=o*invZ;
      unsigned short h=f2us(v);
      sA1h[t*72+hh*8+d]=h; sA1l[t*72+hh*8+d]=f2us(v-us2f(h));
    }
  }
  __syncthreads();

  // phase 4: FFN1 + bias + gelu -> split bf16 sA2 (stride 264)
  #pragma unroll
  for(int it=0; it<4; ++it){
    int tile=it*4+wid;
    f32x4 acc={0.f,0.f,0.f,0.f};
    acc=tile_mm<64,72,64>(sA1h,sA1l,W1h,W1l,tile*16,lane,acc);
    int col=tile*16+lr;
    float bias=b1[col];
    #pragma unroll
    for(int r=0;r<4;r++){
      int t=lg*4+r;
      float v=(t<TC)?geluf(acc[r]+bias):0.f;
      unsigned short h=f2us(v);
      sA2h[t*264+col]=h; sA2l[t*264+col]=f2us(v-us2f(h));
    }
  }
  __syncthreads();

  // phase 5: FFN2 + bias + residual -> xc (reuse sq)
  {
    int tile=wid;
    f32x4 acc={0.f,0.f,0.f,0.f};
    acc=tile_mm<256,264,256>(sA2h,sA2l,W2h,W2l,tile*16,lane,acc);
    int col=tile*16+lr;
    float bias=b2[col];
    #pragma unroll
    for(int r=0;r<4;r++){
      int t=lg*4+r;
      if(t<TC) sq[t*64+col]=acc[r]+bias+sxa[t*64+col];
    }
  }
  __syncthreads();

  // phase 6: build conv A [16][128] split bf16 into sA2 (stride 136)
  for(int idx=tid; idx<16*128; idx+=256){
    int t=idx>>7, k=idx&127;
    int c=k&63;
    float v=0.f;
    if(t<TN) v=sq[((k<64)?t:(t+D))*64+c];
    unsigned short h=f2us(v);
    sA2h[t*136+k]=h; sA2l[t*136+k]=f2us(v-us2f(h));
  }
  __syncthreads();

  // phase 7: conv + bias + activation -> sfg [tt][128]
  #pragma unroll
  for(int it=0; it<2; ++it){
    int tile=it*4+wid;
    f32x4 acc={0.f,0.f,0.f,0.f};
    acc=tile_mm<128,136,128>(sA2h,sA2l,Wch,Wcl,tile*16,lane,acc);
    int col=tile*16+lr;
    float bias=(col<64)?fb[col]:gb[col&63];
    #pragma unroll
    for(int r=0;r<4;r++){
      int t=lg*4+r;
      float v=acc[r]+bias;
      sfg[t*128+col]=(col<64)?tanhf(v):sigmf(v);
    }
  }
  __syncthreads();

  // phase 8: last-column conv output for skip
  if(tid<C) sk[tid]=sfg[(TN-1)*128+tid]*sfg[(TN-1)*128+64+tid];
  __syncthreads();

  // phase 9: skip projection + hT write ([bn][tt*64+c], coalesced)
  {
    float a=skb[tid];
    for(int i=0;i<C;i++) a+=sk[i]*skw[i*SKC+tid];
    skipacc[((size_t)b*SKC+tid)*N+n]+=a;
  }
  size_t obase=(size_t)bn*64*TN;
  for(int idx=tid; idx<TN*64; idx+=256){
    int tt=idx>>6, c=idx&63;
    float v=sfg[tt*128+c]*sfg[tt*128+64+c];
    unsigned short h=f2us(v);
    hThi[obase+idx]=h;
    hTlo[obase+idx]=f2us(v-us2f(h));
  }
}

// ---- MFMA spatial GEMM (unchanged; M columns are (tt,c) now) ----
__global__ __launch_bounds__(256) void k_spatmm(
    const unsigned short* __restrict__ Ah, const unsigned short* __restrict__ Al,
    long long aStride,
    const unsigned short* __restrict__ Xh, const unsigned short* __restrict__ Xl,
    const unsigned short* __restrict__ XTh, const unsigned short* __restrict__ XTl,
    int xT,
    unsigned short* __restrict__ Yh, unsigned short* __restrict__ Yl,
    unsigned short* __restrict__ YTh, unsigned short* __restrict__ YTl,
    int M){
  __shared__ unsigned short sAh[64*40];
  __shared__ unsigned short sAl[64*40];
  __shared__ unsigned short sXh[64*40];
  __shared__ unsigned short sXl[64*40];
  int b=blockIdx.z;
  const unsigned short* Abh=Ah+(size_t)b*aStride;
  const unsigned short* Abl=Al+(size_t)b*aStride;
  int tid=threadIdx.x;
  int w0=blockIdx.x*64, c0=blockIdx.y*64;
  int lane=tid&63, wid=tid>>6;
  int wr=wid>>1, wc=wid&1;
  int lr=lane&15, lg=lane>>4;
  f32x4 acc[2][2];
  #pragma unroll
  for(int j=0;j<2;j++){
    #pragma unroll
    for(int i=0;i<2;i++){ acc[j][i][0]=0.f; acc[j][i][1]=0.f; acc[j][i][2]=0.f; acc[j][i][3]=0.f; }
  }
  const int ar=tid>>2, akb=(tid&3)*8;
  const int xk=tid>>3, xcb=(tid&7)*8;
  const int xkx=xk ^ (8*((xcb>>3)&3));
  for(int k0=0;k0<N;k0+=32){
    {
      uint4 qh=*(const uint4*)&Abh[(size_t)(w0+ar)*NP + k0+akb];
      uint4 ql=*(const uint4*)&Abl[(size_t)(w0+ar)*NP + k0+akb];
      *(uint4*)&sAh[ar*40+akb]=qh;
      *(uint4*)&sAl[ar*40+akb]=ql;
    }
    if(xT){
      const unsigned short* Xbth=XTh+(size_t)b*M*NP;
      const unsigned short* Xbtl=XTl+(size_t)b*M*NP;
      uint4 qh=*(const uint4*)&Xbth[(size_t)(c0+ar)*NP + k0+akb];
      uint4 ql=*(const uint4*)&Xbtl[(size_t)(c0+ar)*NP + k0+akb];
      *(uint4*)&sXh[ar*40+akb]=qh;
      *(uint4*)&sXl[ar*40+akb]=ql;
    }else{
      const unsigned short* Xbh=Xh+(size_t)b*N*M;
      const unsigned short* Xbl=Xl+(size_t)b*N*M;
      uint4 qh={0,0,0,0}, ql={0,0,0,0};
      if(k0+xk<N){
        qh=*(const uint4*)&Xbh[(size_t)(k0+xk)*M + c0+xcb];
        ql=*(const uint4*)&Xbl[(size_t)(k0+xk)*M + c0+xcb];
      }
      unsigned short uh[8], ul[8];
      uh[0]=(unsigned short)(qh.x&0xffff); uh[1]=(unsigned short)(qh.x>>16);
      uh[2]=(unsigned short)(qh.y&0xffff); uh[3]=(unsigned short)(qh.y>>16);
      uh[4]=(unsigned short)(qh.z&0xffff); uh[5]=(unsigned short)(qh.z>>16);
      uh[6]=(unsigned short)(qh.w&0xffff); uh[7]=(unsigned short)(qh.w>>16);
      ul[0]=(unsigned short)(ql.x&0xffff); ul[1]=(unsigned short)(ql.x>>16);
      ul[2]=(unsigned short)(ql.y&0xffff); ul[3]=(unsigned short)(ql.y>>16);
      ul[4]=(unsigned short)(ql.z&0xffff); ul[5]=(unsigned short)(ql.z>>16);
      ul[6]=(unsigned short)(ql.w&0xffff); ul[7]=(unsigned short)(ql.w>>16);
      #pragma unroll
      for(int j=0;j<8;j++){
        sXh[(xcb+j)*40+xkx]=uh[j];
        sXl[(xcb+j)*40+xkx]=ul[j];
      }
    }
    __syncthreads();
    bf16x8 a_h[2], a_l[2], x_h[2], x_l[2];
    #pragma unroll
    for(int j=0;j<2;j++){
      int r=32*wr+16*j+lr;
      a_h[j]=*(const bf16x8*)&sAh[r*40+8*lg];
      a_l[j]=*(const bf16x8*)&sAl[r*40+8*lg];
    }
    #pragma unroll
    for(int i=0;i<2;i++){
      int cc=32*wc+16*i+lr;
      int g = xT ? lg : (lg ^ ((cc>>3)&3));
      x_h[i]=*(const bf16x8*)&sXh[cc*40+8*g];
      x_l[i]=*(const bf16x8*)&sXl[cc*40+8*g];
    }
    #pragma unroll
    for(int j=0;j<2;j++){
      #pragma unroll
      for(int i=0;i<2;i++){
        acc[j][i]=__builtin_amdgcn_mfma_f32_16x16x32_bf16(a_h[j],x_h[i],acc[j][i],0,0,0);
        acc[j][i]=__builtin_amdgcn_mfma_f32_16x16x32_bf16(a_h[j],x_l[i],acc[j][i],0,0,0);
        acc[j][i]=__builtin_amdgcn_mfma_f32_16x16x32_bf16(a_l[j],x_h[i],acc[j][i],0,0,0);
      }
    }
    __syncthreads();
  }
  #pragma unroll
  for(int j=0;j<2;j++){
    int rbase=w0+32*wr+16*j+lg*4;
    #pragma unroll
    for(int i=0;i<2;i++){
      int col=c0+32*wc+16*i+lr;
      unsigned short hh[4], ll[4];
      #pragma unroll
      for(int r=0;r<4;r++){
        float v=acc[j][i][r];
        hh[r]=f2us(v);
        ll[r]=f2us(v-us2f(hh[r]));
      }
      #pragma unroll
      for(int r=0;r<4;r++){
        int row=rbase+r;
        if(row<N){
          size_t o=((size_t)b*N+row)*M+col;
          Yh[o]=hh[r]; Yl[o]=ll[r];
        }
      }
      if(YTh){
        size_t o=(size_t)b*M*NP + (size_t)col*NP + rbase;
        ushort4 ph; ph.x=hh[0]; ph.y=hh[1]; ph.z=hh[2]; ph.w=hh[3];
        ushort4 pl; pl.x=ll[0]; pl.y=ll[1]; pl.z=ll[2]; pl.w=ll[3];
        *(ushort4*)&YTh[o]=ph;
        *(ushort4*)&YTl[o]=pl;
      }
    }
  }
}

// ---- MFMA GCN projection ----
// Per block: 4 nodes, rows=(ni,tt) 64, cols=o 64, K=NS*64 over slices.
// Slices [bn][tt*64+i] bf16 split; W [o][576] bf16 split, kOff selects chunk range.
// FIRST: slices {hT,P,Q}, out = acc + gb + res (write). else: slices {P,Q}, out += acc.
template<int TN, int FIRST>
__global__ __launch_bounds__(256) void k_gcnmm(
    const unsigned short* __restrict__ S0h, const unsigned short* __restrict__ S0l,
    const unsigned short* __restrict__ S1h, const unsigned short* __restrict__ S1l,
    const unsigned short* __restrict__ S2h, const unsigned short* __restrict__ S2l,
    const unsigned short* __restrict__ Wbh, const unsigned short* __restrict__ Wbl,
    int kOff,
    const float* __restrict__ gb, const float* __restrict__ res,
    float* __restrict__ acc, int Tc){
  constexpr int SL=64*TN;
  constexpr int NS=FIRST?3:2;
  constexpr int KK=NS*64;
  __shared__ unsigned short sAh[64*40], sAl[64*40];
  int bn0=blockIdx.x*4;
  int tid=threadIdx.x, lane=tid&63, wid=tid>>6;
  int lr=lane&15, lg=lane>>4;
  f32x4 a4[4];
  #pragma unroll
  for(int rt=0;rt<4;rt++){ a4[rt][0]=0.f; a4[rt][1]=0.f; a4[rt][2]=0.f; a4[rt][3]=0.f; }
  const int ar=tid>>2, akb=(tid&3)*8;
  const int ani=ar>>4, att_=ar&15;
  #pragma unroll
  for(int kc=0; kc<KK/32; ++kc){
    int k0=kc*32; int j=k0>>6; int i0=k0&63;
    const unsigned short* sh=(j==0)?S0h:((j==1)?S1h:S2h);
    const unsigned short* sl=(j==0)?S0l:((j==1)?S1l:S2l);
    uint4 qh={0,0,0,0}, ql={0,0,0,0};
    if(att_<TN){
      size_t o=(size_t)(bn0+ani)*SL + att_*64 + i0 + akb;
      qh=*(const uint4*)&sh[o]; ql=*(const uint4*)&sl[o];
    }
    *(uint4*)&sAh[ar*40+akb]=qh;
    *(uint4*)&sAl[ar*40+akb]=ql;
    __syncthreads();
    bf16x8 bh=*(const bf16x8*)&Wbh[(size_t)(wid*16+lr)*576 + kOff + k0 + 8*lg];
    bf16x8 bl=*(const bf16x8*)&Wbl[(size_t)(wid*16+lr)*576 + kOff + k0 + 8*lg];
    #pragma unroll
    for(int rt=0;rt<4;rt++){
      bf16x8 ah=*(const bf16x8*)&sAh[(rt*16+lr)*40+8*lg];
      bf16x8 al=*(const bf16x8*)&sAl[(rt*16+lr)*40+8*lg];
      a4[rt]=__builtin_amdgcn_mfma_f32_16x16x32_bf16(ah,bh,a4[rt],0,0,0);
      a4[rt]=__builtin_amdgcn_mfma_f32_16x16x32_bf16(ah,bl,a4[rt],0,0,0);
      a4[rt]=__builtin_amdgcn_mfma_f32_16x16x32_bf16(al,bh,a4[rt],0,0,0);
    }
    __syncthreads();
  }
  int o=wid*16+lr;
  #pragma unroll
  for(int rt=0;rt<4;rt++){
    int bn=bn0+rt;
    #pragma unroll
    for(int r=0;r<4;r++){
      int t2=lg*4+r;
      if(t2<TN){
        size_t oi=((size_t)bn*TN + t2)*64 + o;
        float v=a4[rt][r];
        if(FIRST){
          v += gb[o] + res[((size_t)bn*Tc + (Tc-TN) + t2)*64 + o];
          acc[oi]=v;
        }else{
          acc[oi]+=v;
        }
      }
    }
  }
}

// BN stats (layout [b][n][tt][c]), two-stage
__global__ __launch_bounds__(256) void k_bnstats1(const float* __restrict__ h,
                                                  float* __restrict__ part, int R){
  int tid=threadIdx.x;
  int c=tid&63, rg=tid>>6;
  float s=0.f,q=0.f;
  for(int r=blockIdx.x*4+rg; r<R; r+=1024){
    float v=h[(size_t)r*64+c];
    s+=v; q+=v*v;
  }
  __shared__ float ls[256], lq[256];
  ls[tid]=s; lq[tid]=q; __syncthreads();
  if(rg==0){
    s=ls[c]+ls[64+c]+ls[128+c]+ls[192+c];
    q=lq[c]+lq[64+c]+lq[128+c]+lq[192+c];
    part[blockIdx.x*128+c]=s;
    part[blockIdx.x*128+64+c]=q;
  }
}
__global__ __launch_bounds__(256) void k_bnstats2(const float* __restrict__ part,
                                                  float* __restrict__ st, int R){
  int tid=threadIdx.x;
  int c=tid&63, g=tid>>6;
  float s=0.f,q=0.f;
  for(int p=g;p<256;p+=4){ s+=part[p*128+c]; q+=part[p*128+64+c]; }
  __shared__ float ls[256], lq[256];
  ls[tid]=s; lq[tid]=q; __syncthreads();
  if(g==0){
    s=ls[c]+ls[64+c]+ls[128+c]+ls[192+c];
    q=lq[c]+lq[64+c]+lq[128+c]+lq[192+c];
    float mu=s/R;
    float var=q/R-mu*mu;
    st[c]=mu; st[64+c]=rsqrtf(var+1e-5f);
  }
}

__global__ void k_bnapply(float* __restrict__ h, const float* __restrict__ st,
                          const float* __restrict__ g, const float* __restrict__ bb, int total){
  int idx=blockIdx.x*256+threadIdx.x;
  if(idx>=total) return;
  int c=idx&63;
  float v=h[idx];
  h[idx]=(v-st[c])*st[64+c]*g[c]+bb[c];
}

__global__ void k_head(const float* __restrict__ skipacc, const float* __restrict__ W1,
  const float* __restrict__ b1, const float* __restrict__ W2, const float* __restrict__ b2,
  float* __restrict__ out){
  int gid=blockIdx.x; int tid=threadIdx.x;  // 512 threads
  int n=gid%N; int b=gid/N;
  __shared__ float s[SKC];
  __shared__ float hid[512];
  if(tid<SKC){
    float v=skipacc[((size_t)b*SKC+tid)*N+n];
    s[tid]=fmaxf(v,0.f);
  }
  __syncthreads();
  {
    float a=b1[tid];
    for(int i=0;i<SKC;i++) a+=s[i]*W1[(size_t)i*512+tid];
    hid[tid]=fmaxf(a,0.f);
  }
  __syncthreads();
  if(tid<T){
    float a=b2[tid];
    for(int j=0;j<512;j++) a+=hid[j]*W2[(size_t)j*T+tid];
    out[((size_t)b*T+tid)*N+n]=a;
  }
}

// ---------------- host-side layer driver ----------------
struct Ctx {
  const float *bq,*bk,*bv,*b1,*b2,*filt_b,*gate_b,*skip_w,*skip_b,*gcn_b,*bn_g,*bn_b;
  const unsigned short *qkvTh,*qkvTl,*w1Th,*w1Tl,*w2Th,*w2Tl,*cvTh,*cvTl,*wgh,*wgl;
  const unsigned short* matH[4];
  const unsigned short* matL[4];
  long long matStride[4];
  float *pH,*pAlt,*skipacc,*bnst,*bnpart;
  unsigned short *hThi,*hTlo,*Phi,*Plo,*Qhi,*Qlo;
  unsigned short *hTth,*hTtl,*PTh,*PTl;
  hipStream_t stream;
};

template<int TC, int D>
void run_layer(Ctx& c, int l, bool last){
  constexpr int TN=TC-D;
  k_attconv<TC,D><<<B*N,256,0,c.stream>>>(c.pH,
    c.qkvTh+(size_t)l*12288, c.qkvTl+(size_t)l*12288,
    c.w1Th+(size_t)l*16384,  c.w1Tl+(size_t)l*16384,
    c.w2Th+(size_t)l*16384,  c.w2Tl+(size_t)l*16384,
    c.cvTh+(size_t)l*16384,  c.cvTl+(size_t)l*16384,
    c.bq+(size_t)l*C, c.bk+(size_t)l*C, c.bv+(size_t)l*C,
    c.b1+(size_t)l*4*C, c.b2+(size_t)l*C,
    c.filt_b+(size_t)l*C, c.gate_b+(size_t)l*C,
    c.skip_w+(size_t)l*C*SKC, c.skip_b+(size_t)l*SKC,
    c.hThi, c.hTlo, c.skipacc);
  if(!last){
    int M=C*TN, nMB=M/64;
    const unsigned short* Wh=c.wgh+(size_t)l*36864;
    const unsigned short* Wl=c.wgl+(size_t)l*36864;
    dim3 sg(DIVUP(N,64), nMB, B);
    k_trx<<<dim3(M/64,DIVUP(NP,64),B),256,0,c.stream>>>(c.hThi,c.hTlo, c.hTth,c.hTtl, M);
    for(int s=0;s<4;s++){
      k_spatmm<<<sg,256,0,c.stream>>>(c.matH[s],c.matL[s],c.matStride[s],
          nullptr,nullptr, c.hTth,c.hTtl, 1,
          c.Phi,c.Plo, c.PTh,c.PTl, M);
      if(c.PTh){
        k_spatmm<<<sg,256,0,c.stream>>>(c.matH[s],c.matL[s],c.matStride[s],
            nullptr,nullptr, c.PTh,c.PTl, 1,
            c.Qhi,c.Qlo, nullptr,nullptr, M);
      }else{
        k_spatmm<<<sg,256,0,c.stream>>>(c.matH[s],c.matL[s],c.matStride[s],
            c.Phi,c.Plo, nullptr,nullptr, 0,
            c.Qhi,c.Qlo, nullptr,nullptr, M);
      }
      if(s==0){
        k_gcnmm<TN,1><<<(B*N)/4,256,0,c.stream>>>(
            c.hThi,c.hTlo, c.Phi,c.Plo, c.Qhi,c.Qlo,
            Wh,Wl, 0, c.gcn_b+(size_t)l*C, c.pH, c.pAlt, TC);
      }else{
        k_gcnmm<TN,0><<<(B*N)/4,256,0,c.stream>>>(
            c.Phi,c.Plo, c.Qhi,c.Qlo, nullptr,nullptr,
            Wh,Wl, (1+2*s)*64, nullptr, nullptr, c.pAlt, TC);
      }
    }
    int R=B*N*TN;
    k_bnstats1<<<256,256,0,c.stream>>>(c.pAlt, c.bnpart, R);
    k_bnstats2<<<1,256,0,c.stream>>>(c.bnpart, c.bnst, R);
    k_bnapply<<<DIVUP(R*64,256),256,0,c.stream>>>(c.pAlt, c.bnst,
      c.bn_g+(size_t)l*C, c.bn_b+(size_t)l*C, R*64);
    float* tmp=c.pH; c.pH=c.pAlt; c.pAlt=tmp;
  }
}

} // namespace

extern "C" void kernel_launch(void* const* d_in, const int* in_sizes, int n_in,
                              void* d_out, int out_size, void* d_ws, size_t ws_size,
                              hipStream_t stream){
  (void)in_sizes; (void)n_in;
  const float* x      =(const float*)d_in[0];
  const float* sup0   =(const float*)d_in[1];
  const float* sup1   =(const float*)d_in[2];
  const float* TiD    =(const float*)d_in[3];
  const float* DiW    =(const float*)d_in[4];
  const float* E1     =(const float*)d_in[5];
  const float* E2     =(const float*)d_in[6];
  const float* E3     =(const float*)d_in[7];
  const float* Wx     =(const float*)d_in[8];
  const float* Wd     =(const float*)d_in[9];
  const float* Wxabs  =(const float*)d_in[10];
  const float* start_w=(const float*)d_in[11];
  const float* start_b=(const float*)d_in[12];
  const float* Wq     =(const float*)d_in[13];
  const float* Wk     =(const float*)d_in[15];
  const float* Wv     =(const float*)d_in[17];
  const float* W1     =(const float*)d_in[19];
  const float* W2     =(const float*)d_in[21];
  const float* filt_w =(const float*)d_in[23];
  const float* gate_w =(const float*)d_in[25];
  const float* gcn_w  =(const float*)d_in[29];

  Ctx c;
  c.bq=(const float*)d_in[14];
  c.bk=(const float*)d_in[16];
  c.bv=(const float*)d_in[18];
  c.b1=(const float*)d_in[20];
  c.b2=(const float*)d_in[22];
  c.filt_b=(const float*)d_in[24];
  c.gate_b=(const float*)d_in[26];
  c.skip_w=(const float*)d_in[27]; c.skip_b=(const float*)d_in[28];
  c.gcn_b =(const float*)d_in[30];
  c.bn_g  =(const float*)d_in[31]; c.bn_b  =(const float*)d_in[32];
  const float* end1_w =(const float*)d_in[33];
  const float* end1_b =(const float*)d_in[34];
  const float* end2_w =(const float*)d_in[35];
  const float* end2_b =(const float*)d_in[36];
  c.stream=stream;

  // workspace carve (16B-aligned)
  size_t off=0;
  auto allocF=[&](size_t nf)->float*{
    nf=(nf+3)&~(size_t)3;
    float* p=(float*)((char*)d_ws+off);
    off += nf*sizeof(float);
    return p;
  };
  auto allocU=[&](size_t nu)->unsigned short*{
    nu=(nu+7)&~(size_t)7;
    unsigned short* p=(unsigned short*)((char*)d_ws+off);
    off += nu*sizeof(unsigned short);
    return p;
  };
  const size_t HMAX =(size_t)B*C*N*T13;
  const size_t XSZ  =(size_t)B*C*N*12;
  const size_t XTSZ =(size_t)768*NP*B;
  const size_t SUPP =(size_t)NP*NP;
  const size_t ADSZ =(size_t)B*NP*NP;

  float* xf     = allocF((size_t)B*F7*N);
  float* gx1    = allocF((size_t)B*N*E);
  float* gdew   = allocF((size_t)B*N*E);
  float* gst    = allocF(16);
  c.bnst        = allocF(2*C);
  c.bnpart      = allocF(256*128);
  float* adp    = allocF((size_t)B*N*N);   // dead after k_topk; hosts hT_T overlay
  c.pH          = allocF(HMAX);
  c.pAlt        = allocF(HMAX);
  c.skipacc     = allocF((size_t)B*SKC*N);
  unsigned short* matRegion=(unsigned short*)((char*)d_ws+off);
  unsigned short* s0h = allocU(SUPP);
  unsigned short* s0l = allocU(SUPP);
  unsigned short* s1h = allocU(SUPP);
  unsigned short* s1l = allocU(SUPP);
  unsigned short* aph = allocU(SUPP);
  unsigned short* apl = allocU(SUPP);
  unsigned short* adh = allocU(ADSZ);
  unsigned short* adl = allocU(ADSZ);
  long long matRegionN = (long long)(( (unsigned short*)((char*)d_ws+off) ) - matRegion);
  c.hThi = allocU(XSZ);  c.hTlo = allocU(XSZ);
  c.Phi  = allocU(XSZ);  c.Plo  = allocU(XSZ);
  c.Qhi  = allocU(XSZ);  c.Qlo  = allocU(XSZ);
  unsigned short* qkvTh = allocU((size_t)L*12288);
  unsigned short* qkvTl = allocU((size_t)L*12288);
  unsigned short* w1Th  = allocU((size_t)L*16384);
  unsigned short* w1Tl  = allocU((size_t)L*16384);
  unsigned short* w2Th  = allocU((size_t)L*16384);
  unsigned short* w2Tl  = allocU((size_t)L*16384);
  unsigned short* cvTh  = allocU((size_t)L*16384);
  unsigned short* cvTl  = allocU((size_t)L*16384);
  unsigned short* wgh   = allocU((size_t)L*36864);
  unsigned short* wgl   = allocU((size_t)L*36864);
  if(off > ws_size){
    k_zero<<<DIVUP(out_size,256),256,0,stream>>>((float*)d_out, out_size);
    return;
  }
  c.hTth = (unsigned short*)adp;
  c.hTtl = c.hTth + XTSZ;
  {
    size_t save=off;
    c.PTh = allocU(XTSZ);
    c.PTl = allocU(XTSZ);
    if(off > ws_size){ c.PTh=nullptr; c.PTl=nullptr; off=save; }
  }
  c.qkvTh=qkvTh; c.qkvTl=qkvTl; c.w1Th=w1Th; c.w1Tl=w1Tl;
  c.w2Th=w2Th; c.w2Tl=w2Tl; c.cvTh=cvTh; c.cvTl=cvTl;
  c.wgh=wgh; c.wgl=wgl;
  c.matH[0]=s0h; c.matL[0]=s0l; c.matStride[0]=0;
  c.matH[1]=s1h; c.matL[1]=s1l; c.matStride[1]=0;
  c.matH[2]=aph; c.matL[2]=apl; c.matStride[2]=0;
  c.matH[3]=adh; c.matL[3]=adl; c.matStride[3]=(long long)NP*NP;

  // ---- graph generation + conversions ----
  k_zeroUS<<<(int)DIVUP(matRegionN,256),256,0,stream>>>(matRegion, matRegionN);
  k_cvt_qkv <<<DIVUP(L*192*64,256),256,0,stream>>>(Wq,Wk,Wv,qkvTh,qkvTl);
  k_cvt_w1  <<<DIVUP(L*256*64,256),256,0,stream>>>(W1,w1Th,w1Tl);
  k_cvt_w2  <<<DIVUP(L*64*256,256),256,0,stream>>>(W2,w2Th,w2Tl);
  k_cvt_conv<<<DIVUP(L*128*128,256),256,0,stream>>>(filt_w,gate_w,cvTh,cvTl);
  k_cvt_gcn <<<DIVUP(L*64*576,256),256,0,stream>>>(gcn_w,wgh,wgl);
  k_dft <<<DIVUP(B*F7*N,256),256,0,stream>>>(x, xf);
  k_l2f <<<DIVUP(B*N,256),256,0,stream>>>(xf);
  k_l2n <<<B*F7,256,0,stream>>>(xf);
  k_x1  <<<DIVUP(B*N,256),256,0,stream>>>(x, xf, E3, TiD, DiW, Wx, Wd, gx1);
  k_lnstats<<<B,256,0,stream>>>(gx1, gst);
  k_dew <<<DIVUP(B*N,256),256,0,stream>>>(gx1, gst, Wxabs, gdew);
  k_adp <<<DIVUP(B*N*N,256),256,0,stream>>>(gdew, gx1, adp);
  k_topk<<<(B*N)/4,256,0,stream>>>(adp, adh, adl);
  k_adap<<<N,256,0,stream>>>(E1, E2, aph, apl);
  k_cvtT<<<DIVUP(N*N,256),256,0,stream>>>(sup0, s0h, s0l);
  k_cvtT<<<DIVUP(N*N,256),256,0,stream>>>(sup1, s1h, s1l);

  // ---- trunk ----
  k_zero<<<DIVUP(B*SKC*N,256),256,0,stream>>>(c.skipacc, B*SKC*N);
  k_start<<<DIVUP(B*N*T13*C,256),256,0,stream>>>(x, start_w, start_b, c.pH);

  run_layer<13,1>(c,0,false);
  run_layer<12,2>(c,1,false);
  run_layer<10,1>(c,2,false);
  run_layer< 9,2>(c,3,false);
  run_layer< 7,1>(c,4,false);
  run_layer< 6,2>(c,5,false);
  run_layer< 4,1>(c,6,false);
  run_layer< 3,2>(c,7,true);

  k_head<<<B*N,512,0,stream>>>(c.skipacc, end1_w, end1_b, end2_w, end2_b, (float*)d_out);
}

// Round 11
// 5656.110 us; speedup vs baseline: 1.1474x; 1.0048x over previous
//
#include <hip/hip_runtime.h>
#include <math.h>

#define DIVUP(a,b) (((a)+(b)-1)/(b))

namespace {

constexpr int B=8, T=12, N=883, CIN=3, C=64, E=10, H=8, HD=8, TOPK=48, L=8;
constexpr int SKC=256, F7=7, T13=13;
constexpr int NP=896;   // padded N for bf16 support matrices / transposed X

typedef __attribute__((ext_vector_type(8))) short bf16x8;
typedef __attribute__((ext_vector_type(4))) float f32x4;

__device__ __forceinline__ float geluf(float x){ return 0.5f*x*(1.0f+erff(x*0.7071067811865475f)); }
__device__ __forceinline__ float sigmf(float x){ return 1.0f/(1.0f+expf(-x)); }
__device__ __forceinline__ float us2f(unsigned short u){ return __uint_as_float(((unsigned)u)<<16); }
__device__ __forceinline__ unsigned short f2us(float f){
  unsigned x=__float_as_uint(f);
  return (unsigned short)((x + 0x7fffu + ((x>>16)&1u))>>16);
}

// 16x16 output tile: A from LDS (bf16 split, [row][k], row stride STRIDE),
// B from global W (bf16 split, [col][k], row stride KW). 3-term split product.
template<int KK, int STRIDE, int KW>
__device__ __forceinline__ f32x4 tile_mm(
    const unsigned short* sAh, const unsigned short* sAl,
    const unsigned short* __restrict__ Wh, const unsigned short* __restrict__ Wl,
    int colBase, int lane, f32x4 acc){
  int lr=lane&15, lg=lane>>4;
  #pragma unroll
  for(int k0=0;k0<KK;k0+=32){
    bf16x8 ah=*(const bf16x8*)&sAh[lr*STRIDE+k0+8*lg];
    bf16x8 al=*(const bf16x8*)&sAl[lr*STRIDE+k0+8*lg];
    bf16x8 bh=*(const bf16x8*)&Wh[(size_t)(colBase+lr)*KW+k0+8*lg];
    bf16x8 bl=*(const bf16x8*)&Wl[(size_t)(colBase+lr)*KW+k0+8*lg];
    acc=__builtin_amdgcn_mfma_f32_16x16x32_bf16(ah,bh,acc,0,0,0);
    acc=__builtin_amdgcn_mfma_f32_16x16x32_bf16(ah,bl,acc,0,0,0);
    acc=__builtin_amdgcn_mfma_f32_16x16x32_bf16(al,bh,acc,0,0,0);
  }
  return acc;
}

// ---------------- graph generation ----------------
__global__ void k_dft(const float* __restrict__ x, float* __restrict__ xf){
  int idx = blockIdx.x*256 + threadIdx.x;
  if(idx >= B*F7*N) return;
  int n = idx % N; int f = (idx/N) % F7; int b = idx/(N*F7);
  float re=0.f, im=0.f;
  for(int t=0;t<T;t++){
    float v = x[((size_t)(b*T+t)*N+n)*CIN];
    float ang = -6.283185307179586f * (float)(f*t) / 12.0f;
    re += v*cosf(ang); im += v*sinf(ang);
  }
  xf[idx] = sqrtf(re*re+im*im);
}

__global__ void k_l2f(float* __restrict__ xf){
  int idx = blockIdx.x*256 + threadIdx.x;
  if(idx >= B*N) return;
  int n = idx % N; int b = idx / N;
  float s=0.f;
  for(int f=0;f<F7;f++){ float v=xf[((size_t)b*F7+f)*N+n]; s+=v*v; }
  float inv = 1.0f/fmaxf(sqrtf(s), 1e-12f);
  for(int f=0;f<F7;f++) xf[((size_t)b*F7+f)*N+n] *= inv;
}

__global__ void k_l2n(float* __restrict__ xf){
  int bf = blockIdx.x; int tid = threadIdx.x;
  __shared__ float red[256];
  size_t base = (size_t)bf*N;
  float s=0.f;
  for(int i=tid;i<N;i+=256){ float v=xf[base+i]; s+=v*v; }
  red[tid]=s; __syncthreads();
  for(int k=128;k>0;k>>=1){ if(tid<k) red[tid]+=red[tid+k]; __syncthreads(); }
  float inv = 1.0f/fmaxf(sqrtf(red[0]), 1e-12f);
  __syncthreads();
  for(int i=tid;i<N;i+=256) xf[base+i]*=inv;
}

__global__ void k_x1(const float* __restrict__ x, const float* __restrict__ xf,
                     const float* __restrict__ E3, const float* __restrict__ TiD,
                     const float* __restrict__ DiW, const float* __restrict__ Wx,
                     const float* __restrict__ Wd, float* __restrict__ x1){
  int idx = blockIdx.x*256+threadIdx.x;
  if(idx>=B*N) return;
  int n=idx%N, b=idx/N;
  float xc[40];
  for(int d=0;d<E;d++){
    float a=0.f;
    for(int f=0;f<F7;f++) a += xf[((size_t)b*F7+f)*N+n]*Wx[f*E+d];
    xc[d]=a;
  }
  for(int d=0;d<E;d++) xc[10+d]=E3[n*E+d];
  int ti = (int)(x[((size_t)(b*T+(T-1))*N+n)*CIN+1]*288.0f);
  int dw = (int)(x[((size_t)(b*T+(T-1))*N+n)*CIN+2]);
  for(int d=0;d<E;d++) xc[20+d]=TiD[ti*E+d];
  for(int d=0;d<E;d++) xc[30+d]=DiW[dw*E+d];
  for(int e=0;e<E;e++){
    float a=0.f;
    for(int f=0;f<40;f++) a += xc[f]*Wd[((size_t)n*40+f)*E+e];
    x1[(size_t)idx*E+e]=fmaxf(a,0.f);
  }
}

__global__ void k_lnstats(const float* __restrict__ x1, float* __restrict__ st){
  int b=blockIdx.x, tid=threadIdx.x;
  __shared__ float rs[256], rq[256];
  const int M=N*E;
  float s=0.f,q=0.f;
  for(int i=tid;i<M;i+=256){ float v=x1[(size_t)b*M+i]; s+=v; q+=v*v; }
  rs[tid]=s; rq[tid]=q; __syncthreads();
  for(int k=128;k>0;k>>=1){ if(tid<k){ rs[tid]+=rs[tid+k]; rq[tid]+=rq[tid+k]; } __syncthreads(); }
  if(tid==0){ float mu=rs[0]/M; float var=rq[0]/M-mu*mu; st[b*2]=mu; st[b*2+1]=var; }
}

__global__ void k_dew(const float* __restrict__ x1, const float* __restrict__ st,
                      const float* __restrict__ Wxabs, float* __restrict__ dew){
  int idx=blockIdx.x*256+threadIdx.x;
  if(idx>=B*N) return;
  int b=idx/N;
  float mu=st[b*2], var=st[b*2+1];
  float rs=rsqrtf(var+1e-8f);
  float xk[E];
  for(int e=0;e<E;e++) xk[e]=(x1[(size_t)idx*E+e]-mu)*rs;
  for(int k=0;k<E;k++){
    float a=0.f;
    for(int e=0;e<E;e++) a+=xk[e]*Wxabs[e*E+k];
    dew[(size_t)idx*E+k]=a;
  }
}

__global__ void k_adp(const float* __restrict__ dew, const float* __restrict__ x1,
                      float* __restrict__ adp){
  size_t idx=(size_t)blockIdx.x*256+threadIdx.x;
  if(idx>=(size_t)B*N*N) return;
  int m=(int)(idx%N); int n=(int)((idx/N)%N); int b=(int)(idx/((size_t)N*N));
  const float* dr=dew+((size_t)b*N+n)*E;
  const float* xr=x1+((size_t)b*N+m)*E;
  float a=0.f;
  for(int k=0;k<E;k++) a+=dr[k]*xr[k];
  adp[idx]=fmaxf(a,0.f);
}

// wave-per-row top-48 + masked softmax -> bf16 hi/lo padded AD mats; zero barriers.
__global__ __launch_bounds__(256) void k_topk(const float* __restrict__ adp,
                       unsigned short* __restrict__ ADhi, unsigned short* __restrict__ ADlo){
  int row = blockIdx.x*4 + (threadIdx.x>>6);
  int lane = threadIdx.x & 63;
  const float* rp = adp + (size_t)row*N;
  float v[14];
  #pragma unroll
  for(int j=0;j<14;j++){
    int i = lane + j*64;
    v[j] = (i<N) ? rp[i] : -1.f;
  }
  unsigned sel = 0u;
  float m0 = 0.f;
  for(int k=0;k<TOPK;k++){
    float bv = -2.f; int bi = 1<<20;
    #pragma unroll
    for(int j=0;j<14;j++){
      if(!((sel>>j)&1u) && v[j] > bv){ bv = v[j]; bi = lane + j*64; }
    }
    #pragma unroll
    for(int off=1; off<64; off<<=1){
      float ov = __shfl_xor(bv, off);
      int   oi = __shfl_xor(bi, off);
      if(ov > bv || (ov==bv && oi<bi)){ bv=ov; bi=oi; }
    }
    if(k==0) m0 = bv;
    if((bi&63)==lane) sel |= 1u << (bi>>6);
  }
  float pv[14];
  float ls = 0.f;
  #pragma unroll
  for(int j=0;j<14;j++){
    int i = lane + j*64;
    float p = ((sel>>j)&1u) ? v[j] : 0.f;
    pv[j] = p;
    if(i<N) ls += expf(p - m0);
  }
  #pragma unroll
  for(int off=1; off<64; off<<=1) ls += __shfl_xor(ls, off);
  float invZ = 1.f/ls;
  size_t base = ((size_t)(row/N)*NP + (size_t)(row%N))*NP;
  #pragma unroll
  for(int j=0;j<14;j++){
    int i = lane + j*64;
    if(i<N){
      float f = expf(pv[j]-m0)*invZ;
      unsigned short h=f2us(f);
      ADhi[base+i]=h; ADlo[base+i]=f2us(f-us2f(h));
    }
  }
}

__global__ void k_adap(const float* __restrict__ E1, const float* __restrict__ E2,
                       unsigned short* __restrict__ Mh, unsigned short* __restrict__ Ml){
  int v=blockIdx.x, tid=threadIdx.x;
  __shared__ float rowv[N];
  __shared__ float rv[256];
  float e1[E];
  for(int e=0;e<E;e++) e1[e]=E1[v*E+e];
  for(int j=tid;j<N;j+=256){
    float s=0.f;
    for(int e=0;e<E;e++) s+=e1[e]*E2[j*E+e];
    rowv[j]=fmaxf(s,0.f);
  }
  __syncthreads();
  float lm=-1e30f;
  for(int j=tid;j<N;j+=256) lm=fmaxf(lm,rowv[j]);
  rv[tid]=lm; __syncthreads();
  for(int s=128;s>0;s>>=1){ if(tid<s) rv[tid]=fmaxf(rv[tid],rv[tid+s]); __syncthreads(); }
  float m=rv[0]; __syncthreads();
  float ls=0.f;
  for(int j=tid;j<N;j+=256) ls+=expf(rowv[j]-m);
  rv[tid]=ls; __syncthreads();
  for(int s=128;s>0;s>>=1){ if(tid<s) rv[tid]+=rv[tid+s]; __syncthreads(); }
  float invZ=1.0f/rv[0];
  for(int j=tid;j<N;j+=256){
    float f=expf(rowv[j]-m)*invZ;
    unsigned short h=f2us(f);
    Mh[(size_t)j*NP+v]=h; Ml[(size_t)j*NP+v]=f2us(f-us2f(h));
  }
}

__global__ void k_cvtT(const float* __restrict__ A, unsigned short* __restrict__ Mh,
                       unsigned short* __restrict__ Ml){
  int idx=blockIdx.x*256+threadIdx.x;
  if(idx>=N*N) return;
  int w=idx/N, v=idx%N;
  float f=A[(size_t)v*N+w];
  unsigned short h=f2us(f);
  Mh[(size_t)w*NP+v]=h;
  Ml[(size_t)w*NP+v]=f2us(f-us2f(h));
}

// ---- weight transpose+split conversions (run once) ----
__global__ void k_cvt_qkv(const float* __restrict__ Wq, const float* __restrict__ Wk,
                          const float* __restrict__ Wv,
                          unsigned short* __restrict__ dh, unsigned short* __restrict__ dl){
  int idx=blockIdx.x*256+threadIdx.x;
  if(idx>=L*192*64) return;
  int l=idx/12288, rem=idx%12288, col=rem/64, k=rem%64;
  int mat=col>>6, o=col&63;
  const float* W=(mat==0)?Wq:((mat==1)?Wk:Wv);
  float v=W[(size_t)l*4096 + k*64 + o];
  unsigned short h=f2us(v);
  dh[idx]=h; dl[idx]=f2us(v-us2f(h));
}
__global__ void k_cvt_w1(const float* __restrict__ W1,
                         unsigned short* __restrict__ dh, unsigned short* __restrict__ dl){
  int idx=blockIdx.x*256+threadIdx.x;
  if(idx>=L*256*64) return;
  int l=idx/16384, rem=idx%16384, col=rem/64, k=rem%64;
  float v=W1[(size_t)l*16384 + k*256 + col];
  unsigned short h=f2us(v);
  dh[idx]=h; dl[idx]=f2us(v-us2f(h));
}
__global__ void k_cvt_w2(const float* __restrict__ W2,
                         unsigned short* __restrict__ dh, unsigned short* __restrict__ dl){
  int idx=blockIdx.x*256+threadIdx.x;
  if(idx>=L*64*256) return;
  int l=idx/16384, rem=idx%16384, col=rem/256, k=rem%256;
  float v=W2[(size_t)l*16384 + k*64 + col];
  unsigned short h=f2us(v);
  dh[idx]=h; dl[idx]=f2us(v-us2f(h));
}
__global__ void k_cvt_conv(const float* __restrict__ fw, const float* __restrict__ gw,
                           unsigned short* __restrict__ dh, unsigned short* __restrict__ dl){
  int idx=blockIdx.x*256+threadIdx.x;
  if(idx>=L*128*128) return;
  int l=idx/16384, rem=idx%16384, col=rem/128, k=rem%128;
  int c=col&63, fg=col>>6, tap=k>>6, i=k&63;
  const float* W=fg?gw:fw;
  float v=W[(size_t)l*8192 + tap*4096 + i*64 + c];
  unsigned short h=f2us(v);
  dh[idx]=h; dl[idx]=f2us(v-us2f(h));
}
// gcn_w (L,576,64) -> [l][o][k=576] bf16 split
__global__ void k_cvt_gcn(const float* __restrict__ Wg,
                          unsigned short* __restrict__ dh, unsigned short* __restrict__ dl){
  int idx=blockIdx.x*256+threadIdx.x;
  if(idx>=L*64*576) return;
  int l=idx/36864, rem=idx%36864, o=rem/576, k=rem%576;
  float v=Wg[((size_t)l*576 + k)*64 + o];
  unsigned short h=f2us(v);
  dh[idx]=h; dl[idx]=f2us(v-us2f(h));
}

__global__ void k_zero(float* __restrict__ p, int n){
  int idx=blockIdx.x*256+threadIdx.x;
  if(idx<n) p[idx]=0.f;
}
__global__ void k_zeroUS(unsigned short* __restrict__ p, long long n){
  long long idx=(long long)blockIdx.x*256+threadIdx.x;
  if(idx<n) p[idx]=0;
}

// tiled transpose: S [b][n<N][m<M] (split bf16 pair) -> D [b][m][v<NP]
__global__ __launch_bounds__(256) void k_trx(
    const unsigned short* __restrict__ Sh, const unsigned short* __restrict__ Sl,
    unsigned short* __restrict__ Dh, unsigned short* __restrict__ Dl, int M){
  __shared__ unsigned short th[64][66], tl[64][66];
  int b=blockIdx.z;
  int m0=blockIdx.x*64, n0=blockIdx.y*64;
  int tid=threadIdx.x;
  const unsigned short* sbh=Sh + (size_t)b*N*M;
  const unsigned short* sbl=Sl + (size_t)b*N*M;
  for(int idx=tid; idx<64*64; idx+=256){
    int i=idx>>6, j=idx&63;
    int n=n0+i;
    unsigned short vh=0, vl=0;
    if(n<N){
      size_t o=(size_t)n*M + m0+j;
      vh=sbh[o]; vl=sbl[o];
    }
    th[j][i]=vh; tl[j][i]=vl;
  }
  __syncthreads();
  unsigned short* dbh=Dh + (size_t)b*M*NP;
  unsigned short* dbl=Dl + (size_t)b*M*NP;
  for(int idx=tid; idx<64*64; idx+=256){
    int r=idx>>6, cc=idx&63;
    size_t o=(size_t)(m0+r)*NP + n0+cc;
    dbh[o]=th[r][cc]; dbl[o]=tl[r][cc];
  }
}

// ---------------- trunk ----------------
// h layout: [b][n][t][c]
__global__ void k_start(const float* __restrict__ x, const float* __restrict__ sw,
                        const float* __restrict__ sb, float* __restrict__ h){
  int idx=blockIdx.x*256+threadIdx.x;
  if(idx>=B*N*T13*C) return;
  int c=idx&63; int t=(idx>>6)%T13; int n=(idx/(64*T13))%N; int b=idx/(64*T13*N);
  float a=sb[c];
  if(t>0){
    size_t xb=((size_t)(b*T+(t-1))*N+n)*CIN;
    for(int i=0;i<CIN;i++) a += sw[i*C+c]*x[xb+i];
  }
  h[idx]=a;
}

// Fused per-(b,n) MFMA transformer block; hin [b][n][t][c] (pre-BN; BN fused if bng!=0)
template<int TC, int D>
__global__ __launch_bounds__(256) void k_attconv(const float* __restrict__ hin,
  const unsigned short* __restrict__ Wqkvh, const unsigned short* __restrict__ Wqkvl,
  const unsigned short* __restrict__ W1h,   const unsigned short* __restrict__ W1l,
  const unsigned short* __restrict__ W2h,   const unsigned short* __restrict__ W2l,
  const unsigned short* __restrict__ Wch,   const unsigned short* __restrict__ Wcl,
  const float* __restrict__ bq, const float* __restrict__ bk, const float* __restrict__ bv,
  const float* __restrict__ b1, const float* __restrict__ b2,
  const float* __restrict__ fb, const float* __restrict__ gb,
  const float* __restrict__ skw, const float* __restrict__ skb,
  const float* __restrict__ bnst, const float* __restrict__ bng, const float* __restrict__ bnb,
  unsigned short* __restrict__ hThi, unsigned short* __restrict__ hTlo,
  float* __restrict__ skipacc, int first){
  constexpr int TN = TC - D;
  int bn=blockIdx.x; int tid=threadIdx.x;
  int lane=tid&63, wid=tid>>6;
  int lr=lane&15, lg=lane>>4;
  __shared__ __align__(16) float sxa[16*64];
  __shared__ __align__(16) float sq [16*64];
  __shared__ __align__(16) float sk [16*64];
  __shared__ __align__(16) float sv [16*64];
  __shared__ __align__(16) unsigned short sA1h[16*72], sA1l[16*72];
  __shared__ __align__(16) unsigned short sA2h[16*264], sA2l[16*264];
  __shared__ __align__(16) float sfg[16*128];

  // phase 1: contiguous staging from [bn][t][c], BN fused
  const float* hp = hin + (size_t)bn*TC*64;
  for(int idx=tid; idx<TC*64; idx+=256){
    int t=idx>>6, c=idx&63;
    float v=hp[idx];
    if(bng) v=(v-bnst[c])*bnst[64+c]*bng[c]+bnb[c];
    sxa[idx]=v;
    unsigned short h=f2us(v);
    sA1h[t*72+c]=h; sA1l[t*72+c]=f2us(v-us2f(h));
  }
  for(int idx=tid; idx<(16-TC)*64; idx+=256){
    int t=TC+(idx>>6), c=idx&63;
    sxa[t*64+c]=0.f; sA1h[t*72+c]=0; sA1l[t*72+c]=0;
  }
  __syncthreads();

  // phase 2: QKV + bias + gelu
  #pragma unroll
  for(int it=0; it<3; ++it){
    int tile=it*4+wid;
    f32x4 acc={0.f,0.f,0.f,0.f};
    acc=tile_mm<64,72,64>(sA1h,sA1l,Wqkvh,Wqkvl,tile*16,lane,acc);
    int col=tile*16+lr; int mat=col>>6, o=col&63;
    const float* bm=(mat==0)?bq:((mat==1)?bk:bv);
    float* dst=(mat==0)?sq:((mat==1)?sk:sv);
    float bias=bm[o];
    #pragma unroll
    for(int r=0;r<4;r++){
      int t=lg*4+r;
      if(t<TC) dst[t*64+o]=geluf(acc[r]+bias);
    }
  }
  __syncthreads();

  // phase 3: causal attention -> split bf16 into sA1
  if(tid<H*TC){
    int hh=tid/TC, t=tid%TC;
    const float* qr=&sq[t*64+hh*HD];
    float att[TC];
    float m=-1e30f;
    #pragma unroll
    for(int s=0;s<TC;s++){
      float a=0.f;
      #pragma unroll
      for(int d=0;d<HD;d++) a+=qr[d]*sk[s*64+hh*HD+d];
      a*=0.3535533905932738f;
      a=(s<=t)?a:-1e30f;
      att[s]=a; m=fmaxf(m,a);
    }
    float Z=0.f;
    #pragma unroll
    for(int s=0;s<TC;s++){ float e=expf(att[s]-m); att[s]=e; Z+=e; }
    float invZ=1.0f/Z;
    #pragma unroll
    for(int d=0;d<HD;d++){
      float o=0.f;
      #pragma unroll
      for(int s=0;s<TC;s++) o+=att[s]*sv[s*64+hh*HD+d];
      float v=o*invZ;
      unsigned short h=f2us(v);
      sA1h[t*72+hh*8+d]=h; sA1l[t*72+hh*8+d]=f2us(v-us2f(h));
    }
  }
  __syncthreads();

  // phase 4: FFN1 + bias + gelu -> split bf16 sA2 (stride 264)
  #pragma unroll
  for(int it=0; it<4; ++it){
    int tile=it*4+wid;
    f32x4 acc={0.f,0.f,0.f,0.f};
    acc=tile_mm<64,72,64>(sA1h,sA1l,W1h,W1l,tile*16,lane,acc);
    int col=tile*16+lr;
    float bias=b1[col];
    #pragma unroll
    for(int r=0;r<4;r++){
      int t=lg*4+r;
      float v=(t<TC)?geluf(acc[r]+bias):0.f;
      unsigned short h=f2us(v);
      sA2h[t*264+col]=h; sA2l[t*264+col]=f2us(v-us2f(h));
    }
  }
  __syncthreads();

  // phase 5: FFN2 + bias + residual -> xc (reuse sq)
  {
    int tile=wid;
    f32x4 acc={0.f,0.f,0.f,0.f};
    acc=tile_mm<256,264,256>(sA2h,sA2l,W2h,W2l,tile*16,lane,acc);
    int col=tile*16+lr;
    float bias=b2[col];
    #pragma unroll
    for(int r=0;r<4;r++){
      int t=lg*4+r;
      if(t<TC) sq[t*64+col]=acc[r]+bias+sxa[t*64+col];
    }
  }
  __syncthreads();

  // phase 6: build conv A [16][128] split bf16 into sA2 (stride 136)
  for(int idx=tid; idx<16*128; idx+=256){
    int t=idx>>7, k=idx&127;
    int c=k&63;
    float v=0.f;
    if(t<TN) v=sq[((k<64)?t:(t+D))*64+c];
    unsigned short h=f2us(v);
    sA2h[t*136+k]=h; sA2l[t*136+k]=f2us(v-us2f(h));
  }
  __syncthreads();

  // phase 7: conv + bias + activation -> sfg [tt][128]
  #pragma unroll
  for(int it=0; it<2; ++it){
    int tile=it*4+wid;
    f32x4 acc={0.f,0.f,0.f,0.f};
    acc=tile_mm<128,136,128>(sA2h,sA2l,Wch,Wcl,tile*16,lane,acc);
    int col=tile*16+lr;
    float bias=(col<64)?fb[col]:gb[col&63];
    #pragma unroll
    for(int r=0;r<4;r++){
      int t=lg*4+r;
      float v=acc[r]+bias;
      sfg[t*128+col]=(col<64)?tanhf(v):sigmf(v);
    }
  }
  __syncthreads();

  // phase 8: last-column conv output for skip
  if(tid<C) sk[tid]=sfg[(TN-1)*128+tid]*sfg[(TN-1)*128+64+tid];
  __syncthreads();

  // phase 9: skip projection (contiguous [bn][256]) + hT write
  {
    float a=skb[tid];
    for(int i=0;i<C;i++) a+=sk[i]*skw[i*SKC+tid];
    size_t so_=(size_t)bn*SKC+tid;
    if(first) skipacc[so_]=a; else skipacc[so_]+=a;
  }
  size_t obase=(size_t)bn*64*TN;
  for(int idx=tid; idx<TN*64; idx+=256){
    int tt=idx>>6, c=idx&63;
    float v=sfg[tt*128+c]*sfg[tt*128+64+c];
    unsigned short h=f2us(v);
    hThi[obase+idx]=h;
    hTlo[obase+idx]=f2us(v-us2f(h));
  }
}

// ---- MFMA spatial GEMM (unchanged) ----
__global__ __launch_bounds__(256) void k_spatmm(
    const unsigned short* __restrict__ Ah, const unsigned short* __restrict__ Al,
    long long aStride,
    const unsigned short* __restrict__ Xh, const unsigned short* __restrict__ Xl,
    const unsigned short* __restrict__ XTh, const unsigned short* __restrict__ XTl,
    int xT,
    unsigned short* __restrict__ Yh, unsigned short* __restrict__ Yl,
    unsigned short* __restrict__ YTh, unsigned short* __restrict__ YTl,
    int M){
  __shared__ unsigned short sAh[64*40];
  __shared__ unsigned short sAl[64*40];
  __shared__ unsigned short sXh[64*40];
  __shared__ unsigned short sXl[64*40];
  int b=blockIdx.z;
  const unsigned short* Abh=Ah+(size_t)b*aStride;
  const unsigned short* Abl=Al+(size_t)b*aStride;
  int tid=threadIdx.x;
  int w0=blockIdx.x*64, c0=blockIdx.y*64;
  int lane=tid&63, wid=tid>>6;
  int wr=wid>>1, wc=wid&1;
  int lr=lane&15, lg=lane>>4;
  f32x4 acc[2][2];
  #pragma unroll
  for(int j=0;j<2;j++){
    #pragma unroll
    for(int i=0;i<2;i++){ acc[j][i][0]=0.f; acc[j][i][1]=0.f; acc[j][i][2]=0.f; acc[j][i][3]=0.f; }
  }
  const int ar=tid>>2, akb=(tid&3)*8;
  const int xk=tid>>3, xcb=(tid&7)*8;
  const int xkx=xk ^ (8*((xcb>>3)&3));
  for(int k0=0;k0<N;k0+=32){
    {
      uint4 qh=*(const uint4*)&Abh[(size_t)(w0+ar)*NP + k0+akb];
      uint4 ql=*(const uint4*)&Abl[(size_t)(w0+ar)*NP + k0+akb];
      *(uint4*)&sAh[ar*40+akb]=qh;
      *(uint4*)&sAl[ar*40+akb]=ql;
    }
    if(xT){
      const unsigned short* Xbth=XTh+(size_t)b*M*NP;
      const unsigned short* Xbtl=XTl+(size_t)b*M*NP;
      uint4 qh=*(const uint4*)&Xbth[(size_t)(c0+ar)*NP + k0+akb];
      uint4 ql=*(const uint4*)&Xbtl[(size_t)(c0+ar)*NP + k0+akb];
      *(uint4*)&sXh[ar*40+akb]=qh;
      *(uint4*)&sXl[ar*40+akb]=ql;
    }else{
      const unsigned short* Xbh=Xh+(size_t)b*N*M;
      const unsigned short* Xbl=Xl+(size_t)b*N*M;
      uint4 qh={0,0,0,0}, ql={0,0,0,0};
      if(k0+xk<N){
        qh=*(const uint4*)&Xbh[(size_t)(k0+xk)*M + c0+xcb];
        ql=*(const uint4*)&Xbl[(size_t)(k0+xk)*M + c0+xcb];
      }
      unsigned short uh[8], ul[8];
      uh[0]=(unsigned short)(qh.x&0xffff); uh[1]=(unsigned short)(qh.x>>16);
      uh[2]=(unsigned short)(qh.y&0xffff); uh[3]=(unsigned short)(qh.y>>16);
      uh[4]=(unsigned short)(qh.z&0xffff); uh[5]=(unsigned short)(qh.z>>16);
      uh[6]=(unsigned short)(qh.w&0xffff); uh[7]=(unsigned short)(qh.w>>16);
      ul[0]=(unsigned short)(ql.x&0xffff); ul[1]=(unsigned short)(ql.x>>16);
      ul[2]=(unsigned short)(ql.y&0xffff); ul[3]=(unsigned short)(ql.y>>16);
      ul[4]=(unsigned short)(ql.z&0xffff); ul[5]=(unsigned short)(ql.z>>16);
      ul[6]=(unsigned short)(ql.w&0xffff); ul[7]=(unsigned short)(ql.w>>16);
      #pragma unroll
      for(int j=0;j<8;j++){
        sXh[(xcb+j)*40+xkx]=uh[j];
        sXl[(xcb+j)*40+xkx]=ul[j];
      }
    }
    __syncthreads();
    bf16x8 a_h[2], a_l[2], x_h[2], x_l[2];
    #pragma unroll
    for(int j=0;j<2;j++){
      int r=32*wr+16*j+lr;
      a_h[j]=*(const bf16x8*)&sAh[r*40+8*lg];
      a_l[j]=*(const bf16x8*)&sAl[r*40+8*lg];
    }
    #pragma unroll
    for(int i=0;i<2;i++){
      int cc=32*wc+16*i+lr;
      int g = xT ? lg : (lg ^ ((cc>>3)&3));
      x_h[i]=*(const bf16x8*)&sXh[cc*40+8*g];
      x_l[i]=*(const bf16x8*)&sXl[cc*40+8*g];
    }
    #pragma unroll
    for(int j=0;j<2;j++){
      #pragma unroll
      for(int i=0;i<2;i++){
        acc[j][i]=__builtin_amdgcn_mfma_f32_16x16x32_bf16(a_h[j],x_h[i],acc[j][i],0,0,0);
        acc[j][i]=__builtin_amdgcn_mfma_f32_16x16x32_bf16(a_h[j],x_l[i],acc[j][i],0,0,0);
        acc[j][i]=__builtin_amdgcn_mfma_f32_16x16x32_bf16(a_l[j],x_h[i],acc[j][i],0,0,0);
      }
    }
    __syncthreads();
  }
  #pragma unroll
  for(int j=0;j<2;j++){
    int rbase=w0+32*wr+16*j+lg*4;
    #pragma unroll
    for(int i=0;i<2;i++){
      int col=c0+32*wc+16*i+lr;
      unsigned short hh[4], ll[4];
      #pragma unroll
      for(int r=0;r<4;r++){
        float v=acc[j][i][r];
        hh[r]=f2us(v);
        ll[r]=f2us(v-us2f(hh[r]));
      }
      #pragma unroll
      for(int r=0;r<4;r++){
        int row=rbase+r;
        if(row<N){
          size_t o=((size_t)b*N+row)*M+col;
          Yh[o]=hh[r]; Yl[o]=ll[r];
        }
      }
      if(YTh){
        size_t o=(size_t)b*M*NP + (size_t)col*NP + rbase;
        ushort4 ph; ph.x=hh[0]; ph.y=hh[1]; ph.z=hh[2]; ph.w=hh[3];
        ushort4 pl; pl.x=ll[0]; pl.y=ll[1]; pl.z=ll[2]; pl.w=ll[3];
        *(ushort4*)&YTh[o]=ph;
        *(ushort4*)&YTl[o]=pl;
      }
    }
  }
}

// ---- MFMA GCN projection (residual BN fused) ----
template<int TN, int FIRST>
__global__ __launch_bounds__(256) void k_gcnmm(
    const unsigned short* __restrict__ S0h, const unsigned short* __restrict__ S0l,
    const unsigned short* __restrict__ S1h, const unsigned short* __restrict__ S1l,
    const unsigned short* __restrict__ S2h, const unsigned short* __restrict__ S2l,
    const unsigned short* __restrict__ Wbh, const unsigned short* __restrict__ Wbl,
    int kOff,
    const float* __restrict__ gb, const float* __restrict__ res,
    const float* __restrict__ bnst, const float* __restrict__ bng, const float* __restrict__ bnb,
    float* __restrict__ acc, int Tc){
  constexpr int SL=64*TN;
  constexpr int NS=FIRST?3:2;
  constexpr int KK=NS*64;
  __shared__ unsigned short sAh[64*40], sAl[64*40];
  int bn0=blockIdx.x*4;
  int tid=threadIdx.x, lane=tid&63, wid=tid>>6;
  int lr=lane&15, lg=lane>>4;
  f32x4 a4[4];
  #pragma unroll
  for(int rt=0;rt<4;rt++){ a4[rt][0]=0.f; a4[rt][1]=0.f; a4[rt][2]=0.f; a4[rt][3]=0.f; }
  const int ar=tid>>2, akb=(tid&3)*8;
  const int ani=ar>>4, att_=ar&15;
  #pragma unroll
  for(int kc=0; kc<KK/32; ++kc){
    int k0=kc*32; int j=k0>>6; int i0=k0&63;
    const unsigned short* sh=(j==0)?S0h:((j==1)?S1h:S2h);
    const unsigned short* sl=(j==0)?S0l:((j==1)?S1l:S2l);
    uint4 qh={0,0,0,0}, ql={0,0,0,0};
    if(att_<TN){
      size_t o=(size_t)(bn0+ani)*SL + att_*64 + i0 + akb;
      qh=*(const uint4*)&sh[o]; ql=*(const uint4*)&sl[o];
    }
    *(uint4*)&sAh[ar*40+akb]=qh;
    *(uint4*)&sAl[ar*40+akb]=ql;
    __syncthreads();
    bf16x8 bh=*(const bf16x8*)&Wbh[(size_t)(wid*16+lr)*576 + kOff + k0 + 8*lg];
    bf16x8 bl=*(const bf16x8*)&Wbl[(size_t)(wid*16+lr)*576 + kOff + k0 + 8*lg];
    #pragma unroll
    for(int rt=0;rt<4;rt++){
      bf16x8 ah=*(const bf16x8*)&sAh[(rt*16+lr)*40+8*lg];
      bf16x8 al=*(const bf16x8*)&sAl[(rt*16+lr)*40+8*lg];
      a4[rt]=__builtin_amdgcn_mfma_f32_16x16x32_bf16(ah,bh,a4[rt],0,0,0);
      a4[rt]=__builtin_amdgcn_mfma_f32_16x16x32_bf16(ah,bl,a4[rt],0,0,0);
      a4[rt]=__builtin_amdgcn_mfma_f32_16x16x32_bf16(al,bh,a4[rt],0,0,0);
    }
    __syncthreads();
  }
  int o=wid*16+lr;
  #pragma unroll
  for(int rt=0;rt<4;rt++){
    int bn=bn0+rt;
    #pragma unroll
    for(int r=0;r<4;r++){
      int t2=lg*4+r;
      if(t2<TN){
        size_t oi=((size_t)bn*TN + t2)*64 + o;
        float v=a4[rt][r];
        if(FIRST){
          float rr=res[((size_t)bn*Tc + (Tc-TN) + t2)*64 + o];
          if(bng) rr=(rr-bnst[o])*bnst[64+o]*bng[o]+bnb[o];
          v += gb[o] + rr;
          acc[oi]=v;
        }else{
          acc[oi]+=v;
        }
      }
    }
  }
}

// BN stats (layout [b][n][tt][c]), two-stage
__global__ __launch_bounds__(256) void k_bnstats1(const float* __restrict__ h,
                                                  float* __restrict__ part, int R){
  int tid=threadIdx.x;
  int c=tid&63, rg=tid>>6;
  float s=0.f,q=0.f;
  for(int r=blockIdx.x*4+rg; r<R; r+=1024){
    float v=h[(size_t)r*64+c];
    s+=v; q+=v*v;
  }
  __shared__ float ls[256], lq[256];
  ls[tid]=s; lq[tid]=q; __syncthreads();
  if(rg==0){
    s=ls[c]+ls[64+c]+ls[128+c]+ls[192+c];
    q=lq[c]+lq[64+c]+lq[128+c]+lq[192+c];
    part[blockIdx.x*128+c]=s;
    part[blockIdx.x*128+64+c]=q;
  }
}
__global__ __launch_bounds__(256) void k_bnstats2(const float* __restrict__ part,
                                                  float* __restrict__ st, int R){
  int tid=threadIdx.x;
  int c=tid&63, g=tid>>6;
  float s=0.f,q=0.f;
  for(int p=g;p<256;p+=4){ s+=part[p*128+c]; q+=part[p*128+64+c]; }
  __shared__ float ls[256], lq[256];
  ls[tid]=s; lq[tid]=q; __syncthreads();
  if(g==0){
    s=ls[c]+ls[64+c]+ls[128+c]+ls[192+c];
    q=lq[c]+lq[64+c]+lq[128+c]+lq[192+c];
    float mu=s/R;
    float var=q/R-mu*mu;
    st[c]=mu; st[64+c]=rsqrtf(var+1e-5f);
  }
}

__global__ void k_head(const float* __restrict__ skipacc, const float* __restrict__ W1,
  const float* __restrict__ b1, const float* __restrict__ W2, const float* __restrict__ b2,
  float* __restrict__ out){
  int gid=blockIdx.x; int tid=threadIdx.x;  // 512 threads
  int n=gid%N; int b=gid/N;
  __shared__ float s[SKC];
  __shared__ float hid[512];
  if(tid<SKC){
    float v=skipacc[(size_t)gid*SKC+tid];
    s[tid]=fmaxf(v,0.f);
  }
  __syncthreads();
  {
    float a=b1[tid];
    for(int i=0;i<SKC;i++) a+=s[i]*W1[(size_t)i*512+tid];
    hid[tid]=fmaxf(a,0.f);
  }
  __syncthreads();
  if(tid<T){
    float a=b2[tid];
    for(int j=0;j<512;j++) a+=hid[j]*W2[(size_t)j*T+tid];
    out[((size_t)b*T+tid)*N+n]=a;
  }
}

// ---------------- host-side layer driver ----------------
struct Ctx {
  const float *bq,*bk,*bv,*b1,*b2,*filt_b,*gate_b,*skip_w,*skip_b,*gcn_b,*bn_g,*bn_b;
  const unsigned short *qkvTh,*qkvTl,*w1Th,*w1Tl,*w2Th,*w2Tl,*cvTh,*cvTl,*wgh,*wgl;
  const unsigned short* matH[4];
  const unsigned short* matL[4];
  long long matStride[4];
  float *pH,*pAlt,*skipacc,*bnst,*bnpart;
  unsigned short *hThi,*hTlo,*Phi,*Plo,*Qhi,*Qlo;
  unsigned short *hTth,*hTtl,*PTh,*PTl;
  hipStream_t stream;
};

template<int TC, int D>
void run_layer(Ctx& c, int l, bool last){
  constexpr int TN=TC-D;
  // input BN params (producing layer l-1); layer 0 has no BN
  const float* ibnst=(l>0)?c.bnst:nullptr;
  const float* ibng =(l>0)?(c.bn_g+(size_t)(l-1)*C):nullptr;
  const float* ibnb =(l>0)?(c.bn_b+(size_t)(l-1)*C):nullptr;
  k_attconv<TC,D><<<B*N,256,0,c.stream>>>(c.pH,
    c.qkvTh+(size_t)l*12288, c.qkvTl+(size_t)l*12288,
    c.w1Th+(size_t)l*16384,  c.w1Tl+(size_t)l*16384,
    c.w2Th+(size_t)l*16384,  c.w2Tl+(size_t)l*16384,
    c.cvTh+(size_t)l*16384,  c.cvTl+(size_t)l*16384,
    c.bq+(size_t)l*C, c.bk+(size_t)l*C, c.bv+(size_t)l*C,
    c.b1+(size_t)l*4*C, c.b2+(size_t)l*C,
    c.filt_b+(size_t)l*C, c.gate_b+(size_t)l*C,
    c.skip_w+(size_t)l*C*SKC, c.skip_b+(size_t)l*SKC,
    ibnst, ibng, ibnb,
    c.hThi, c.hTlo, c.skipacc, l==0?1:0);
  if(!last){
    int M=C*TN, nMB=M/64;
    const unsigned short* Wh=c.wgh+(size_t)l*36864;
    const unsigned short* Wl=c.wgl+(size_t)l*36864;
    dim3 sg(DIVUP(N,64), nMB, B);
    k_trx<<<dim3(M/64,DIVUP(NP,64),B),256,0,c.stream>>>(c.hThi,c.hTlo, c.hTth,c.hTtl, M);
    for(int s=0;s<4;s++){
      k_spatmm<<<sg,256,0,c.stream>>>(c.matH[s],c.matL[s],c.matStride[s],
          nullptr,nullptr, c.hTth,c.hTtl, 1,
          c.Phi,c.Plo, c.PTh,c.PTl, M);
      if(c.PTh){
        k_spatmm<<<sg,256,0,c.stream>>>(c.matH[s],c.matL[s],c.matStride[s],
            nullptr,nullptr, c.PTh,c.PTl, 1,
            c.Qhi,c.Qlo, nullptr,nullptr, M);
      }else{
        k_spatmm<<<sg,256,0,c.stream>>>(c.matH[s],c.matL[s],c.matStride[s],
            c.Phi,c.Plo, nullptr,nullptr, 0,
            c.Qhi,c.Qlo, nullptr,nullptr, M);
      }
      if(s==0){
        k_gcnmm<TN,1><<<(B*N)/4,256,0,c.stream>>>(
            c.hThi,c.hTlo, c.Phi,c.Plo, c.Qhi,c.Qlo,
            Wh,Wl, 0, c.gcn_b+(size_t)l*C, c.pH,
            ibnst, ibng, ibnb, c.pAlt, TC);
      }else{
        k_gcnmm<TN,0><<<(B*N)/4,256,0,c.stream>>>(
            c.Phi,c.Plo, c.Qhi,c.Qlo, nullptr,nullptr,
            Wh,Wl, (1+2*s)*64, nullptr, nullptr,
            nullptr,nullptr,nullptr, c.pAlt, TC);
      }
    }
    int R=B*N*TN;
    k_bnstats1<<<256,256,0,c.stream>>>(c.pAlt, c.bnpart, R);
    k_bnstats2<<<1,256,0,c.stream>>>(c.bnpart, c.bnst, R);
    float* tmp=c.pH; c.pH=c.pAlt; c.pAlt=tmp;
  }
}

} // namespace

extern "C" void kernel_launch(void* const* d_in, const int* in_sizes, int n_in,
                              void* d_out, int out_size, void* d_ws, size_t ws_size,
                              hipStream_t stream){
  (void)in_sizes; (void)n_in;
  const float* x      =(const float*)d_in[0];
  const float* sup0   =(const float*)d_in[1];
  const float* sup1   =(const float*)d_in[2];
  const float* TiD    =(const float*)d_in[3];
  const float* DiW    =(const float*)d_in[4];
  const float* E1     =(const float*)d_in[5];
  const float* E2     =(const float*)d_in[6];
  const float* E3     =(const float*)d_in[7];
  const float* Wx     =(const float*)d_in[8];
  const float* Wd     =(const float*)d_in[9];
  const float* Wxabs  =(const float*)d_in[10];
  const float* start_w=(const float*)d_in[11];
  const float* start_b=(const float*)d_in[12];
  const float* Wq     =(const float*)d_in[13];
  const float* Wk     =(const float*)d_in[15];
  const float* Wv     =(const float*)d_in[17];
  const float* W1     =(const float*)d_in[19];
  const float* W2     =(const float*)d_in[21];
  const float* filt_w =(const float*)d_in[23];
  const float* gate_w =(const float*)d_in[25];
  const float* gcn_w  =(const float*)d_in[29];

  Ctx c;
  c.bq=(const float*)d_in[14];
  c.bk=(const float*)d_in[16];
  c.bv=(const float*)d_in[18];
  c.b1=(const float*)d_in[20];
  c.b2=(const float*)d_in[22];
  c.filt_b=(const float*)d_in[24];
  c.gate_b=(const float*)d_in[26];
  c.skip_w=(const float*)d_in[27]; c.skip_b=(const float*)d_in[28];
  c.gcn_b =(const float*)d_in[30];
  c.bn_g  =(const float*)d_in[31]; c.bn_b  =(const float*)d_in[32];
  const float* end1_w =(const float*)d_in[33];
  const float* end1_b =(const float*)d_in[34];
  const float* end2_w =(const float*)d_in[35];
  const float* end2_b =(const float*)d_in[36];
  c.stream=stream;

  // workspace carve (16B-aligned)
  size_t off=0;
  auto allocF=[&](size_t nf)->float*{
    nf=(nf+3)&~(size_t)3;
    float* p=(float*)((char*)d_ws+off);
    off += nf*sizeof(float);
    return p;
  };
  auto allocU=[&](size_t nu)->unsigned short*{
    nu=(nu+7)&~(size_t)7;
    unsigned short* p=(unsigned short*)((char*)d_ws+off);
    off += nu*sizeof(unsigned short);
    return p;
  };
  const size_t HMAX =(size_t)B*C*N*T13;
  const size_t XSZ  =(size_t)B*C*N*12;
  const size_t XTSZ =(size_t)768*NP*B;
  const size_t SUPP =(size_t)NP*NP;
  const size_t ADSZ =(size_t)B*NP*NP;

  float* xf     = allocF((size_t)B*F7*N);
  float* gx1    = allocF((size_t)B*N*E);
  float* gdew   = allocF((size_t)B*N*E);
  float* gst    = allocF(16);
  c.bnst        = allocF(2*C);
  c.bnpart      = allocF(256*128);
  float* adp    = allocF((size_t)B*N*N);   // dead after k_topk; hosts hT_T overlay
  c.pH          = allocF(HMAX);
  c.pAlt        = allocF(HMAX);
  c.skipacc     = allocF((size_t)B*N*SKC);
  unsigned short* matRegion=(unsigned short*)((char*)d_ws+off);
  unsigned short* s0h = allocU(SUPP);
  unsigned short* s0l = allocU(SUPP);
  unsigned short* s1h = allocU(SUPP);
  unsigned short* s1l = allocU(SUPP);
  unsigned short* aph = allocU(SUPP);
  unsigned short* apl = allocU(SUPP);
  unsigned short* adh = allocU(ADSZ);
  unsigned short* adl = allocU(ADSZ);
  long long matRegionN = (long long)(( (unsigned short*)((char*)d_ws+off) ) - matRegion);
  c.hThi = allocU(XSZ);  c.hTlo = allocU(XSZ);
  c.Phi  = allocU(XSZ);  c.Plo  = allocU(XSZ);
  c.Qhi  = allocU(XSZ);  c.Qlo  = allocU(XSZ);
  unsigned short* qkvTh = allocU((size_t)L*12288);
  unsigned short* qkvTl = allocU((size_t)L*12288);
  unsigned short* w1Th  = allocU((size_t)L*16384);
  unsigned short* w1Tl  = allocU((size_t)L*16384);
  unsigned short* w2Th  = allocU((size_t)L*16384);
  unsigned short* w2Tl  = allocU((size_t)L*16384);
  unsigned short* cvTh  = allocU((size_t)L*16384);
  unsigned short* cvTl  = allocU((size_t)L*16384);
  unsigned short* wgh   = allocU((size_t)L*36864);
  unsigned short* wgl   = allocU((size_t)L*36864);
  if(off > ws_size){
    k_zero<<<DIVUP(out_size,256),256,0,stream>>>((float*)d_out, out_size);
    return;
  }
  c.hTth = (unsigned short*)adp;
  c.hTtl = c.hTth + XTSZ;
  {
    size_t save=off;
    c.PTh = allocU(XTSZ);
    c.PTl = allocU(XTSZ);
    if(off > ws_size){ c.PTh=nullptr; c.PTl=nullptr; off=save; }
  }
  c.qkvTh=qkvTh; c.qkvTl=qkvTl; c.w1Th=w1Th; c.w1Tl=w1Tl;
  c.w2Th=w2Th; c.w2Tl=w2Tl; c.cvTh=cvTh; c.cvTl=cvTl;
  c.wgh=wgh; c.wgl=wgl;
  c.matH[0]=s0h; c.matL[0]=s0l; c.matStride[0]=0;
  c.matH[1]=s1h; c.matL[1]=s1l; c.matStride[1]=0;
  c.matH[2]=aph; c.matL[2]=apl; c.matStride[2]=0;
  c.matH[3]=adh; c.matL[3]=adl; c.matStride[3]=(long long)NP*NP;

  // ---- graph generation + conversions ----
  k_zeroUS<<<(int)DIVUP(matRegionN,256),256,0,stream>>>(matRegion, matRegionN);
  k_cvt_qkv <<<DIVUP(L*192*64,256),256,0,stream>>>(Wq,Wk,Wv,qkvTh,qkvTl);
  k_cvt_w1  <<<DIVUP(L*256*64,256),256,0,stream>>>(W1,w1Th,w1Tl);
  k_cvt_w2  <<<DIVUP(L*64*256,256),256,0,stream>>>(W2,w2Th,w2Tl);
  k_cvt_conv<<<DIVUP(L*128*128,256),256,0,stream>>>(filt_w,gate_w,cvTh,cvTl);
  k_cvt_gcn <<<DIVUP(L*64*576,256),256,0,stream>>>(gcn_w,wgh,wgl);
  k_dft <<<DIVUP(B*F7*N,256),256,0,stream>>>(x, xf);
  k_l2f <<<DIVUP(B*N,256),256,0,stream>>>(xf);
  k_l2n <<<B*F7,256,0,stream>>>(xf);
  k_x1  <<<DIVUP(B*N,256),256,0,stream>>>(x, xf, E3, TiD, DiW, Wx, Wd, gx1);
  k_lnstats<<<B,256,0,stream>>>(gx1, gst);
  k_dew <<<DIVUP(B*N,256),256,0,stream>>>(gx1, gst, Wxabs, gdew);
  k_adp <<<DIVUP(B*N*N,256),256,0,stream>>>(gdew, gx1, adp);
  k_topk<<<(B*N)/4,256,0,stream>>>(adp, adh, adl);
  k_adap<<<N,256,0,stream>>>(E1, E2, aph, apl);
  k_cvtT<<<DIVUP(N*N,256),256,0,stream>>>(sup0, s0h, s0l);
  k_cvtT<<<DIVUP(N*N,256),256,0,stream>>>(sup1, s1h, s1l);

  // ---- trunk ----
  k_start<<<DIVUP(B*N*T13*C,256),256,0,stream>>>(x, start_w, start_b, c.pH);

  run_layer<13,1>(c,0,false);
  run_layer<12,2>(c,1,false);
  run_layer<10,1>(c,2,false);
  run_layer< 9,2>(c,3,false);
  run_layer< 7,1>(c,4,false);
  run_layer< 6,2>(c,5,false);
  run_layer< 4,1>(c,6,false);
  run_layer< 3,2>(c,7,true);

  k_head<<<B*N,512,0,stream>>>(c.skipacc, end1_w, end1_b, end2_w, end2_b, (float*)d_out);
}

// Round 12
// 5644.332 us; speedup vs baseline: 1.1498x; 1.0021x over previous
//
#include <hip/hip_runtime.h>
#include <math.h>

#define DIVUP(a,b) (((a)+(b)-1)/(b))

namespace {

constexpr int B=8, T=12, N=883, CIN=3, C=64, E=10, H=8, HD=8, TOPK=48, L=8;
constexpr int SKC=256, F7=7, T13=13;
constexpr int NP=896;   // padded N for bf16 support matrices / transposed X

typedef __attribute__((ext_vector_type(8))) short bf16x8;
typedef __attribute__((ext_vector_type(4))) float f32x4;

__device__ __forceinline__ float geluf(float x){ return 0.5f*x*(1.0f+erff(x*0.7071067811865475f)); }
__device__ __forceinline__ float sigmf(float x){ return 1.0f/(1.0f+expf(-x)); }
__device__ __forceinline__ float us2f(unsigned short u){ return __uint_as_float(((unsigned)u)<<16); }
__device__ __forceinline__ unsigned short f2us(float f){
  unsigned x=__float_as_uint(f);
  return (unsigned short)((x + 0x7fffu + ((x>>16)&1u))>>16);
}

// 16x16 output tile: A from LDS (bf16 split, [row][k], row stride STRIDE),
// B from global W (bf16 split, [col][k], row stride KW). 3-term split product.
template<int KK, int STRIDE, int KW>
__device__ __forceinline__ f32x4 tile_mm(
    const unsigned short* sAh, const unsigned short* sAl,
    const unsigned short* __restrict__ Wh, const unsigned short* __restrict__ Wl,
    int colBase, int lane, f32x4 acc){
  int lr=lane&15, lg=lane>>4;
  #pragma unroll
  for(int k0=0;k0<KK;k0+=32){
    bf16x8 ah=*(const bf16x8*)&sAh[lr*STRIDE+k0+8*lg];
    bf16x8 al=*(const bf16x8*)&sAl[lr*STRIDE+k0+8*lg];
    bf16x8 bh=*(const bf16x8*)&Wh[(size_t)(colBase+lr)*KW+k0+8*lg];
    bf16x8 bl=*(const bf16x8*)&Wl[(size_t)(colBase+lr)*KW+k0+8*lg];
    acc=__builtin_amdgcn_mfma_f32_16x16x32_bf16(ah,bh,acc,0,0,0);
    acc=__builtin_amdgcn_mfma_f32_16x16x32_bf16(ah,bl,acc,0,0,0);
    acc=__builtin_amdgcn_mfma_f32_16x16x32_bf16(al,bh,acc,0,0,0);
  }
  return acc;
}

// ---------------- graph generation ----------------
__global__ void k_dft(const float* __restrict__ x, float* __restrict__ xf){
  int idx = blockIdx.x*256 + threadIdx.x;
  if(idx >= B*F7*N) return;
  int n = idx % N; int f = (idx/N) % F7; int b = idx/(N*F7);
  float re=0.f, im=0.f;
  for(int t=0;t<T;t++){
    float v = x[((size_t)(b*T+t)*N+n)*CIN];
    float ang = -6.283185307179586f * (float)(f*t) / 12.0f;
    re += v*cosf(ang); im += v*sinf(ang);
  }
  xf[idx] = sqrtf(re*re+im*im);
}

__global__ void k_l2f(float* __restrict__ xf){
  int idx = blockIdx.x*256 + threadIdx.x;
  if(idx >= B*N) return;
  int n = idx % N; int b = idx / N;
  float s=0.f;
  for(int f=0;f<F7;f++){ float v=xf[((size_t)b*F7+f)*N+n]; s+=v*v; }
  float inv = 1.0f/fmaxf(sqrtf(s), 1e-12f);
  for(int f=0;f<F7;f++) xf[((size_t)b*F7+f)*N+n] *= inv;
}

__global__ void k_l2n(float* __restrict__ xf){
  int bf = blockIdx.x; int tid = threadIdx.x;
  __shared__ float red[256];
  size_t base = (size_t)bf*N;
  float s=0.f;
  for(int i=tid;i<N;i+=256){ float v=xf[base+i]; s+=v*v; }
  red[tid]=s; __syncthreads();
  for(int k=128;k>0;k>>=1){ if(tid<k) red[tid]+=red[tid+k]; __syncthreads(); }
  float inv = 1.0f/fmaxf(sqrtf(red[0]), 1e-12f);
  __syncthreads();
  for(int i=tid;i<N;i+=256) xf[base+i]*=inv;
}

__global__ void k_x1(const float* __restrict__ x, const float* __restrict__ xf,
                     const float* __restrict__ E3, const float* __restrict__ TiD,
                     const float* __restrict__ DiW, const float* __restrict__ Wx,
                     const float* __restrict__ Wd, float* __restrict__ x1){
  int idx = blockIdx.x*256+threadIdx.x;
  if(idx>=B*N) return;
  int n=idx%N, b=idx/N;
  float xc[40];
  for(int d=0;d<E;d++){
    float a=0.f;
    for(int f=0;f<F7;f++) a += xf[((size_t)b*F7+f)*N+n]*Wx[f*E+d];
    xc[d]=a;
  }
  for(int d=0;d<E;d++) xc[10+d]=E3[n*E+d];
  int ti = (int)(x[((size_t)(b*T+(T-1))*N+n)*CIN+1]*288.0f);
  int dw = (int)(x[((size_t)(b*T+(T-1))*N+n)*CIN+2]);
  for(int d=0;d<E;d++) xc[20+d]=TiD[ti*E+d];
  for(int d=0;d<E;d++) xc[30+d]=DiW[dw*E+d];
  for(int e=0;e<E;e++){
    float a=0.f;
    for(int f=0;f<40;f++) a += xc[f]*Wd[((size_t)n*40+f)*E+e];
    x1[(size_t)idx*E+e]=fmaxf(a,0.f);
  }
}

__global__ void k_lnstats(const float* __restrict__ x1, float* __restrict__ st){
  int b=blockIdx.x, tid=threadIdx.x;
  __shared__ float rs[256], rq[256];
  const int M=N*E;
  float s=0.f,q=0.f;
  for(int i=tid;i<M;i+=256){ float v=x1[(size_t)b*M+i]; s+=v; q+=v*v; }
  rs[tid]=s; rq[tid]=q; __syncthreads();
  for(int k=128;k>0;k>>=1){ if(tid<k){ rs[tid]+=rs[tid+k]; rq[tid]+=rq[tid+k]; } __syncthreads(); }
  if(tid==0){ float mu=rs[0]/M; float var=rq[0]/M-mu*mu; st[b*2]=mu; st[b*2+1]=var; }
}

__global__ void k_dew(const float* __restrict__ x1, const float* __restrict__ st,
                      const float* __restrict__ Wxabs, float* __restrict__ dew){
  int idx=blockIdx.x*256+threadIdx.x;
  if(idx>=B*N) return;
  int b=idx/N;
  float mu=st[b*2], var=st[b*2+1];
  float rs=rsqrtf(var+1e-8f);
  float xk[E];
  for(int e=0;e<E;e++) xk[e]=(x1[(size_t)idx*E+e]-mu)*rs;
  for(int k=0;k<E;k++){
    float a=0.f;
    for(int e=0;e<E;e++) a+=xk[e]*Wxabs[e*E+k];
    dew[(size_t)idx*E+k]=a;
  }
}

__global__ void k_adp(const float* __restrict__ dew, const float* __restrict__ x1,
                      float* __restrict__ adp){
  size_t idx=(size_t)blockIdx.x*256+threadIdx.x;
  if(idx>=(size_t)B*N*N) return;
  int m=(int)(idx%N); int n=(int)((idx/N)%N); int b=(int)(idx/((size_t)N*N));
  const float* dr=dew+((size_t)b*N+n)*E;
  const float* xr=x1+((size_t)b*N+m)*E;
  float a=0.f;
  for(int k=0;k<E;k++) a+=dr[k]*xr[k];
  adp[idx]=fmaxf(a,0.f);
}

// wave-per-row top-48 + masked softmax -> bf16 hi/lo padded AD mats; zero barriers.
__global__ __launch_bounds__(256) void k_topk(const float* __restrict__ adp,
                       unsigned short* __restrict__ ADhi, unsigned short* __restrict__ ADlo){
  int row = blockIdx.x*4 + (threadIdx.x>>6);
  int lane = threadIdx.x & 63;
  const float* rp = adp + (size_t)row*N;
  float v[14];
  #pragma unroll
  for(int j=0;j<14;j++){
    int i = lane + j*64;
    v[j] = (i<N) ? rp[i] : -1.f;
  }
  unsigned sel = 0u;
  float m0 = 0.f;
  for(int k=0;k<TOPK;k++){
    float bv = -2.f; int bi = 1<<20;
    #pragma unroll
    for(int j=0;j<14;j++){
      if(!((sel>>j)&1u) && v[j] > bv){ bv = v[j]; bi = lane + j*64; }
    }
    #pragma unroll
    for(int off=1; off<64; off<<=1){
      float ov = __shfl_xor(bv, off);
      int   oi = __shfl_xor(bi, off);
      if(ov > bv || (ov==bv && oi<bi)){ bv=ov; bi=oi; }
    }
    if(k==0) m0 = bv;
    if((bi&63)==lane) sel |= 1u << (bi>>6);
  }
  float pv[14];
  float ls = 0.f;
  #pragma unroll
  for(int j=0;j<14;j++){
    int i = lane + j*64;
    float p = ((sel>>j)&1u) ? v[j] : 0.f;
    pv[j] = p;
    if(i<N) ls += expf(p - m0);
  }
  #pragma unroll
  for(int off=1; off<64; off<<=1) ls += __shfl_xor(ls, off);
  float invZ = 1.f/ls;
  size_t base = ((size_t)(row/N)*NP + (size_t)(row%N))*NP;
  #pragma unroll
  for(int j=0;j<14;j++){
    int i = lane + j*64;
    if(i<N){
      float f = expf(pv[j]-m0)*invZ;
      unsigned short h=f2us(f);
      ADhi[base+i]=h; ADlo[base+i]=f2us(f-us2f(h));
    }
  }
}

__global__ void k_adap(const float* __restrict__ E1, const float* __restrict__ E2,
                       unsigned short* __restrict__ Mh, unsigned short* __restrict__ Ml){
  int v=blockIdx.x, tid=threadIdx.x;
  __shared__ float rowv[N];
  __shared__ float rv[256];
  float e1[E];
  for(int e=0;e<E;e++) e1[e]=E1[v*E+e];
  for(int j=tid;j<N;j+=256){
    float s=0.f;
    for(int e=0;e<E;e++) s+=e1[e]*E2[j*E+e];
    rowv[j]=fmaxf(s,0.f);
  }
  __syncthreads();
  float lm=-1e30f;
  for(int j=tid;j<N;j+=256) lm=fmaxf(lm,rowv[j]);
  rv[tid]=lm; __syncthreads();
  for(int s=128;s>0;s>>=1){ if(tid<s) rv[tid]=fmaxf(rv[tid],rv[tid+s]); __syncthreads(); }
  float m=rv[0]; __syncthreads();
  float ls=0.f;
  for(int j=tid;j<N;j+=256) ls+=expf(rowv[j]-m);
  rv[tid]=ls; __syncthreads();
  for(int s=128;s>0;s>>=1){ if(tid<s) rv[tid]+=rv[tid+s]; __syncthreads(); }
  float invZ=1.0f/rv[0];
  for(int j=tid;j<N;j+=256){
    float f=expf(rowv[j]-m)*invZ;
    unsigned short h=f2us(f);
    Mh[(size_t)j*NP+v]=h; Ml[(size_t)j*NP+v]=f2us(f-us2f(h));
  }
}

__global__ void k_cvtT(const float* __restrict__ A, unsigned short* __restrict__ Mh,
                       unsigned short* __restrict__ Ml){
  int idx=blockIdx.x*256+threadIdx.x;
  if(idx>=N*N) return;
  int w=idx/N, v=idx%N;
  float f=A[(size_t)v*N+w];
  unsigned short h=f2us(f);
  Mh[(size_t)w*NP+v]=h;
  Ml[(size_t)w*NP+v]=f2us(f-us2f(h));
}

// ---- weight transpose+split conversions (run once) ----
__global__ void k_cvt_qkv(const float* __restrict__ Wq, const float* __restrict__ Wk,
                          const float* __restrict__ Wv,
                          unsigned short* __restrict__ dh, unsigned short* __restrict__ dl){
  int idx=blockIdx.x*256+threadIdx.x;
  if(idx>=L*192*64) return;
  int l=idx/12288, rem=idx%12288, col=rem/64, k=rem%64;
  int mat=col>>6, o=col&63;
  const float* W=(mat==0)?Wq:((mat==1)?Wk:Wv);
  float v=W[(size_t)l*4096 + k*64 + o];
  unsigned short h=f2us(v);
  dh[idx]=h; dl[idx]=f2us(v-us2f(h));
}
__global__ void k_cvt_w1(const float* __restrict__ W1,
                         unsigned short* __restrict__ dh, unsigned short* __restrict__ dl){
  int idx=blockIdx.x*256+threadIdx.x;
  if(idx>=L*256*64) return;
  int l=idx/16384, rem=idx%16384, col=rem/64, k=rem%64;
  float v=W1[(size_t)l*16384 + k*256 + col];
  unsigned short h=f2us(v);
  dh[idx]=h; dl[idx]=f2us(v-us2f(h));
}
__global__ void k_cvt_w2(const float* __restrict__ W2,
                         unsigned short* __restrict__ dh, unsigned short* __restrict__ dl){
  int idx=blockIdx.x*256+threadIdx.x;
  if(idx>=L*64*256) return;
  int l=idx/16384, rem=idx%16384, col=rem/256, k=rem%256;
  float v=W2[(size_t)l*16384 + k*64 + col];
  unsigned short h=f2us(v);
  dh[idx]=h; dl[idx]=f2us(v-us2f(h));
}
__global__ void k_cvt_conv(const float* __restrict__ fw, const float* __restrict__ gw,
                           unsigned short* __restrict__ dh, unsigned short* __restrict__ dl){
  int idx=blockIdx.x*256+threadIdx.x;
  if(idx>=L*128*128) return;
  int l=idx/16384, rem=idx%16384, col=rem/128, k=rem%128;
  int c=col&63, fg=col>>6, tap=k>>6, i=k&63;
  const float* W=fg?gw:fw;
  float v=W[(size_t)l*8192 + tap*4096 + i*64 + c];
  unsigned short h=f2us(v);
  dh[idx]=h; dl[idx]=f2us(v-us2f(h));
}
// gcn_w (L,576,64) -> [l][o][k=576] bf16 split
__global__ void k_cvt_gcn(const float* __restrict__ Wg,
                          unsigned short* __restrict__ dh, unsigned short* __restrict__ dl){
  int idx=blockIdx.x*256+threadIdx.x;
  if(idx>=L*64*576) return;
  int l=idx/36864, rem=idx%36864, o=rem/576, k=rem%576;
  float v=Wg[((size_t)l*576 + k)*64 + o];
  unsigned short h=f2us(v);
  dh[idx]=h; dl[idx]=f2us(v-us2f(h));
}

__global__ void k_zero(float* __restrict__ p, int n){
  int idx=blockIdx.x*256+threadIdx.x;
  if(idx<n) p[idx]=0.f;
}
__global__ void k_zeroUS(unsigned short* __restrict__ p, long long n){
  long long idx=(long long)blockIdx.x*256+threadIdx.x;
  if(idx<n) p[idx]=0;
}

// tiled transpose: S [b][n<N][m<M] (split bf16 pair) -> D [b][m][v<NP]
__global__ __launch_bounds__(256) void k_trx(
    const unsigned short* __restrict__ Sh, const unsigned short* __restrict__ Sl,
    unsigned short* __restrict__ Dh, unsigned short* __restrict__ Dl, int M){
  __shared__ unsigned short th[64][66], tl[64][66];
  int b=blockIdx.z;
  int m0=blockIdx.x*64, n0=blockIdx.y*64;
  int tid=threadIdx.x;
  const unsigned short* sbh=Sh + (size_t)b*N*M;
  const unsigned short* sbl=Sl + (size_t)b*N*M;
  for(int idx=tid; idx<64*64; idx+=256){
    int i=idx>>6, j=idx&63;
    int n=n0+i;
    unsigned short vh=0, vl=0;
    if(n<N){
      size_t o=(size_t)n*M + m0+j;
      vh=sbh[o]; vl=sbl[o];
    }
    th[j][i]=vh; tl[j][i]=vl;
  }
  __syncthreads();
  unsigned short* dbh=Dh + (size_t)b*M*NP;
  unsigned short* dbl=Dl + (size_t)b*M*NP;
  for(int idx=tid; idx<64*64; idx+=256){
    int r=idx>>6, cc=idx&63;
    size_t o=(size_t)(m0+r)*NP + n0+cc;
    dbh[o]=th[r][cc]; dbl[o]=tl[r][cc];
  }
}

// ---------------- trunk ----------------
// h layout: [b][n][t][c]
__global__ void k_start(const float* __restrict__ x, const float* __restrict__ sw,
                        const float* __restrict__ sb, float* __restrict__ h){
  int idx=blockIdx.x*256+threadIdx.x;
  if(idx>=B*N*T13*C) return;
  int c=idx&63; int t=(idx>>6)%T13; int n=(idx/(64*T13))%N; int b=idx/(64*T13*N);
  float a=sb[c];
  if(t>0){
    size_t xb=((size_t)(b*T+(t-1))*N+n)*CIN;
    for(int i=0;i<CIN;i++) a += sw[i*C+c]*x[xb+i];
  }
  h[idx]=a;
}

// Fused per-(b,n) MFMA transformer block; hin [b][n][t][c] (BN fused if bng!=0).
// LDS aliased into one 37.9KB arena -> 4 blocks/CU.
template<int TC, int D>
__global__ __launch_bounds__(256) void k_attconv(const float* __restrict__ hin,
  const unsigned short* __restrict__ Wqkvh, const unsigned short* __restrict__ Wqkvl,
  const unsigned short* __restrict__ W1h,   const unsigned short* __restrict__ W1l,
  const unsigned short* __restrict__ W2h,   const unsigned short* __restrict__ W2l,
  const unsigned short* __restrict__ Wch,   const unsigned short* __restrict__ Wcl,
  const float* __restrict__ bq, const float* __restrict__ bk, const float* __restrict__ bv,
  const float* __restrict__ b1, const float* __restrict__ b2,
  const float* __restrict__ fb, const float* __restrict__ gb,
  const float* __restrict__ skw, const float* __restrict__ skb,
  const float* __restrict__ bnst, const float* __restrict__ bng, const float* __restrict__ bnb,
  unsigned short* __restrict__ hThi, unsigned short* __restrict__ hTlo,
  float* __restrict__ skipacc, int first){
  constexpr int TN = TC - D;
  int bn=blockIdx.x; int tid=threadIdx.x;
  int lane=tid&63, wid=tid>>6;
  int lr=lane&15, lg=lane>>4;
  __shared__ __align__(16) char smem[37888];
  float* sxa=(float*)smem;                                   // [16][64] 4096B, dead after P5
  float* sq =(float*)(smem+4096);                            // [16][64] q / xc
  float* sk_=(float*)(smem+8192);                            // [16][64] k, dead after P3
  float* sv =(float*)(smem+12288);                           // [16][64] v, dead after P3
  unsigned short* sA1h=(unsigned short*)(smem+16384);        // [16][72]
  unsigned short* sA1l=(unsigned short*)(smem+18688);
  unsigned short* sA2h=(unsigned short*)(smem+20992);        // [16][264]
  unsigned short* sA2l=(unsigned short*)(smem+29440);        // ends 37888
  float* sfg=(float*)(smem+8192);                            // [16][128] aliases sk_,sv (P7+)
  unsigned short* cAh=(unsigned short*)(smem+20992);         // [16][136] aliases sA2 (P6+)
  unsigned short* cAl=(unsigned short*)(smem+25344);
  float* stg=(float*)smem;                                   // [64] skip staging aliases sxa (P8+)

  // phase 1: contiguous staging from [bn][t][c], BN fused
  const float* hp = hin + (size_t)bn*TC*64;
  for(int idx=tid; idx<TC*64; idx+=256){
    int t=idx>>6, c=idx&63;
    float v=hp[idx];
    if(bng) v=(v-bnst[c])*bnst[64+c]*bng[c]+bnb[c];
    sxa[idx]=v;
    unsigned short h=f2us(v);
    sA1h[t*72+c]=h; sA1l[t*72+c]=f2us(v-us2f(h));
  }
  for(int idx=tid; idx<(16-TC)*64; idx+=256){
    int t=TC+(idx>>6), c=idx&63;
    sxa[t*64+c]=0.f; sA1h[t*72+c]=0; sA1l[t*72+c]=0;
  }
  __syncthreads();

  // phase 2: QKV + bias + gelu
  #pragma unroll
  for(int it=0; it<3; ++it){
    int tile=it*4+wid;
    f32x4 acc={0.f,0.f,0.f,0.f};
    acc=tile_mm<64,72,64>(sA1h,sA1l,Wqkvh,Wqkvl,tile*16,lane,acc);
    int col=tile*16+lr; int mat=col>>6, o=col&63;
    const float* bm=(mat==0)?bq:((mat==1)?bk:bv);
    float* dst=(mat==0)?sq:((mat==1)?sk_:sv);
    float bias=bm[o];
    #pragma unroll
    for(int r=0;r<4;r++){
      int t=lg*4+r;
      if(t<TC) dst[t*64+o]=geluf(acc[r]+bias);
    }
  }
  __syncthreads();

  // phase 3: causal attention -> split bf16 into sA1
  if(tid<H*TC){
    int hh=tid/TC, t=tid%TC;
    const float* qr=&sq[t*64+hh*HD];
    float att[TC];
    float m=-1e30f;
    #pragma unroll
    for(int s=0;s<TC;s++){
      float a=0.f;
      #pragma unroll
      for(int d=0;d<HD;d++) a+=qr[d]*sk_[s*64+hh*HD+d];
      a*=0.3535533905932738f;
      a=(s<=t)?a:-1e30f;
      att[s]=a; m=fmaxf(m,a);
    }
    float Z=0.f;
    #pragma unroll
    for(int s=0;s<TC;s++){ float e=expf(att[s]-m); att[s]=e; Z+=e; }
    float invZ=1.0f/Z;
    #pragma unroll
    for(int d=0;d<HD;d++){
      float o=0.f;
      #pragma unroll
      for(int s=0;s<TC;s++) o+=att[s]*sv[s*64+hh*HD+d];
      float v=o*invZ;
      unsigned short h=f2us(v);
      sA1h[t*72+hh*8+d]=h; sA1l[t*72+hh*8+d]=f2us(v-us2f(h));
    }
  }
  __syncthreads();

  // phase 4: FFN1 + bias + gelu -> split bf16 sA2 (stride 264)
  #pragma unroll
  for(int it=0; it<4; ++it){
    int tile=it*4+wid;
    f32x4 acc={0.f,0.f,0.f,0.f};
    acc=tile_mm<64,72,64>(sA1h,sA1l,W1h,W1l,tile*16,lane,acc);
    int col=tile*16+lr;
    float bias=b1[col];
    #pragma unroll
    for(int r=0;r<4;r++){
      int t=lg*4+r;
      float v=(t<TC)?geluf(acc[r]+bias):0.f;
      unsigned short h=f2us(v);
      sA2h[t*264+col]=h; sA2l[t*264+col]=f2us(v-us2f(h));
    }
  }
  __syncthreads();

  // phase 5: FFN2 + bias + residual -> xc (into sq)
  {
    int tile=wid;
    f32x4 acc={0.f,0.f,0.f,0.f};
    acc=tile_mm<256,264,256>(sA2h,sA2l,W2h,W2l,tile*16,lane,acc);
    int col=tile*16+lr;
    float bias=b2[col];
    #pragma unroll
    for(int r=0;r<4;r++){
      int t=lg*4+r;
      if(t<TC) sq[t*64+col]=acc[r]+bias+sxa[t*64+col];
    }
  }
  __syncthreads();

  // phase 6: build conv A [16][128] split bf16 (stride 136, over dead sA2)
  for(int idx=tid; idx<16*128; idx+=256){
    int t=idx>>7, k=idx&127;
    int c=k&63;
    float v=0.f;
    if(t<TN) v=sq[((k<64)?t:(t+D))*64+c];
    unsigned short h=f2us(v);
    cAh[t*136+k]=h; cAl[t*136+k]=f2us(v-us2f(h));
  }
  __syncthreads();

  // phase 7: conv + bias + activation -> sfg [tt][128] (over dead sk_,sv)
  #pragma unroll
  for(int it=0; it<2; ++it){
    int tile=it*4+wid;
    f32x4 acc={0.f,0.f,0.f,0.f};
    acc=tile_mm<128,136,128>(cAh,cAl,Wch,Wcl,tile*16,lane,acc);
    int col=tile*16+lr;
    float bias=(col<64)?fb[col]:gb[col&63];
    #pragma unroll
    for(int r=0;r<4;r++){
      int t=lg*4+r;
      float v=acc[r]+bias;
      sfg[t*128+col]=(col<64)?tanhf(v):sigmf(v);
    }
  }
  __syncthreads();

  // phase 8: last-column conv output for skip (into stg over dead sxa)
  if(tid<C) stg[tid]=sfg[(TN-1)*128+tid]*sfg[(TN-1)*128+64+tid];
  __syncthreads();

  // phase 9: skip projection (contiguous [bn][256]) + hT write
  {
    float a=skb[tid];
    for(int i=0;i<C;i++) a+=stg[i]*skw[i*SKC+tid];
    size_t so_=(size_t)bn*SKC+tid;
    if(first) skipacc[so_]=a; else skipacc[so_]+=a;
  }
  size_t obase=(size_t)bn*64*TN;
  for(int idx=tid; idx<TN*64; idx+=256){
    int tt=idx>>6, c=idx&63;
    float v=sfg[tt*128+c]*sfg[tt*128+64+c];
    unsigned short h=f2us(v);
    hThi[obase+idx]=h;
    hTlo[obase+idx]=f2us(v-us2f(h));
  }
}

// ---- MFMA spatial GEMM: 128x64 tile, 4 waves each own 32 rows x 64 cols ----
__global__ __launch_bounds__(256) void k_spatmm(
    const unsigned short* __restrict__ Ah, const unsigned short* __restrict__ Al,
    long long aStride,
    const unsigned short* __restrict__ Xh, const unsigned short* __restrict__ Xl,
    const unsigned short* __restrict__ XTh, const unsigned short* __restrict__ XTl,
    int xT,
    unsigned short* __restrict__ Yh, unsigned short* __restrict__ Yl,
    unsigned short* __restrict__ YTh, unsigned short* __restrict__ YTl,
    int M){
  __shared__ unsigned short sAh[128*40];
  __shared__ unsigned short sAl[128*40];
  __shared__ unsigned short sXh[64*40];
  __shared__ unsigned short sXl[64*40];
  int b=blockIdx.z;
  const unsigned short* Abh=Ah+(size_t)b*aStride;
  const unsigned short* Abl=Al+(size_t)b*aStride;
  int tid=threadIdx.x;
  int w0=blockIdx.x*128, c0=blockIdx.y*64;
  int lane=tid&63, wid=tid>>6;
  int lr=lane&15, lg=lane>>4;
  f32x4 acc[2][4];
  #pragma unroll
  for(int j=0;j<2;j++){
    #pragma unroll
    for(int i=0;i<4;i++){ acc[j][i][0]=0.f; acc[j][i][1]=0.f; acc[j][i][2]=0.f; acc[j][i][3]=0.f; }
  }
  const int ar=tid>>1,  akb=(tid&1)*16;   // A: 128 rows, 2 thr/row, 16 elems each
  const int xr=tid>>2,  xkb=(tid&3)*8;    // XT: 64 cols, 4 thr/col
  const int xk=tid>>3,  xcb=(tid&7)*8;    // scatter path
  const int xkx=xk ^ (8*((xcb>>3)&3));
  for(int k0=0;k0<N;k0+=32){
    {
      uint4 qh0=*(const uint4*)&Abh[(size_t)(w0+ar)*NP + k0+akb];
      uint4 qh1=*(const uint4*)&Abh[(size_t)(w0+ar)*NP + k0+akb+8];
      uint4 ql0=*(const uint4*)&Abl[(size_t)(w0+ar)*NP + k0+akb];
      uint4 ql1=*(const uint4*)&Abl[(size_t)(w0+ar)*NP + k0+akb+8];
      *(uint4*)&sAh[ar*40+akb]=qh0;   *(uint4*)&sAh[ar*40+akb+8]=qh1;
      *(uint4*)&sAl[ar*40+akb]=ql0;   *(uint4*)&sAl[ar*40+akb+8]=ql1;
    }
    if(xT){
      const unsigned short* Xbth=XTh+(size_t)b*M*NP;
      const unsigned short* Xbtl=XTl+(size_t)b*M*NP;
      uint4 qh=*(const uint4*)&Xbth[(size_t)(c0+xr)*NP + k0+xkb];
      uint4 ql=*(const uint4*)&Xbtl[(size_t)(c0+xr)*NP + k0+xkb];
      *(uint4*)&sXh[xr*40+xkb]=qh;
      *(uint4*)&sXl[xr*40+xkb]=ql;
    }else{
      const unsigned short* Xbh=Xh+(size_t)b*N*M;
      const unsigned short* Xbl=Xl+(size_t)b*N*M;
      uint4 qh={0,0,0,0}, ql={0,0,0,0};
      if(k0+xk<N){
        qh=*(const uint4*)&Xbh[(size_t)(k0+xk)*M + c0+xcb];
        ql=*(const uint4*)&Xbl[(size_t)(k0+xk)*M + c0+xcb];
      }
      unsigned short uh[8], ul[8];
      uh[0]=(unsigned short)(qh.x&0xffff); uh[1]=(unsigned short)(qh.x>>16);
      uh[2]=(unsigned short)(qh.y&0xffff); uh[3]=(unsigned short)(qh.y>>16);
      uh[4]=(unsigned short)(qh.z&0xffff); uh[5]=(unsigned short)(qh.z>>16);
      uh[6]=(unsigned short)(qh.w&0xffff); uh[7]=(unsigned short)(qh.w>>16);
      ul[0]=(unsigned short)(ql.x&0xffff); ul[1]=(unsigned short)(ql.x>>16);
      ul[2]=(unsigned short)(ql.y&0xffff); ul[3]=(unsigned short)(ql.y>>16);
      ul[4]=(unsigned short)(ql.z&0xffff); ul[5]=(unsigned short)(ql.z>>16);
      ul[6]=(unsigned short)(ql.w&0xffff); ul[7]=(unsigned short)(ql.w>>16);
      #pragma unroll
      for(int j=0;j<8;j++){
        sXh[(xcb+j)*40+xkx]=uh[j];
        sXl[(xcb+j)*40+xkx]=ul[j];
      }
    }
    __syncthreads();
    bf16x8 a_h[2], a_l[2], x_h[4], x_l[4];
    #pragma unroll
    for(int j=0;j<2;j++){
      int r=32*wid+16*j+lr;
      a_h[j]=*(const bf16x8*)&sAh[r*40+8*lg];
      a_l[j]=*(const bf16x8*)&sAl[r*40+8*lg];
    }
    #pragma unroll
    for(int i=0;i<4;i++){
      int cc=16*i+lr;
      int g = xT ? lg : (lg ^ ((cc>>3)&3));
      x_h[i]=*(const bf16x8*)&sXh[cc*40+8*g];
      x_l[i]=*(const bf16x8*)&sXl[cc*40+8*g];
    }
    #pragma unroll
    for(int j=0;j<2;j++){
      #pragma unroll
      for(int i=0;i<4;i++){
        acc[j][i]=__builtin_amdgcn_mfma_f32_16x16x32_bf16(a_h[j],x_h[i],acc[j][i],0,0,0);
        acc[j][i]=__builtin_amdgcn_mfma_f32_16x16x32_bf16(a_h[j],x_l[i],acc[j][i],0,0,0);
        acc[j][i]=__builtin_amdgcn_mfma_f32_16x16x32_bf16(a_l[j],x_h[i],acc[j][i],0,0,0);
      }
    }
    __syncthreads();
  }
  #pragma unroll
  for(int j=0;j<2;j++){
    int rbase=w0+32*wid+16*j+lg*4;
    #pragma unroll
    for(int i=0;i<4;i++){
      int col=c0+16*i+lr;
      unsigned short hh[4], ll[4];
      #pragma unroll
      for(int r=0;r<4;r++){
        float v=acc[j][i][r];
        hh[r]=f2us(v);
        ll[r]=f2us(v-us2f(hh[r]));
      }
      #pragma unroll
      for(int r=0;r<4;r++){
        int row=rbase+r;
        if(row<N){
          size_t o=((size_t)b*N+row)*M+col;
          Yh[o]=hh[r]; Yl[o]=ll[r];
        }
      }
      if(YTh){
        size_t o=(size_t)b*M*NP + (size_t)col*NP + rbase;
        ushort4 ph; ph.x=hh[0]; ph.y=hh[1]; ph.z=hh[2]; ph.w=hh[3];
        ushort4 pl; pl.x=ll[0]; pl.y=ll[1]; pl.z=ll[2]; pl.w=ll[3];
        *(ushort4*)&YTh[o]=ph;
        *(ushort4*)&YTl[o]=pl;
      }
    }
  }
}

// ---- MFMA GCN projection (residual BN fused) ----
template<int TN, int FIRST>
__global__ __launch_bounds__(256) void k_gcnmm(
    const unsigned short* __restrict__ S0h, const unsigned short* __restrict__ S0l,
    const unsigned short* __restrict__ S1h, const unsigned short* __restrict__ S1l,
    const unsigned short* __restrict__ S2h, const unsigned short* __restrict__ S2l,
    const unsigned short* __restrict__ Wbh, const unsigned short* __restrict__ Wbl,
    int kOff,
    const float* __restrict__ gb, const float* __restrict__ res,
    const float* __restrict__ bnst, const float* __restrict__ bng, const float* __restrict__ bnb,
    float* __restrict__ acc, int Tc){
  constexpr int SL=64*TN;
  constexpr int NS=FIRST?3:2;
  constexpr int KK=NS*64;
  __shared__ unsigned short sAh[64*40], sAl[64*40];
  int bn0=blockIdx.x*4;
  int tid=threadIdx.x, lane=tid&63, wid=tid>>6;
  int lr=lane&15, lg=lane>>4;
  f32x4 a4[4];
  #pragma unroll
  for(int rt=0;rt<4;rt++){ a4[rt][0]=0.f; a4[rt][1]=0.f; a4[rt][2]=0.f; a4[rt][3]=0.f; }
  const int ar=tid>>2, akb=(tid&3)*8;
  const int ani=ar>>4, att_=ar&15;
  #pragma unroll
  for(int kc=0; kc<KK/32; ++kc){
    int k0=kc*32; int j=k0>>6; int i0=k0&63;
    const unsigned short* sh=(j==0)?S0h:((j==1)?S1h:S2h);
    const unsigned short* sl=(j==0)?S0l:((j==1)?S1l:S2l);
    uint4 qh={0,0,0,0}, ql={0,0,0,0};
    if(att_<TN){
      size_t o=(size_t)(bn0+ani)*SL + att_*64 + i0 + akb;
      qh=*(const uint4*)&sh[o]; ql=*(const uint4*)&sl[o];
    }
    *(uint4*)&sAh[ar*40+akb]=qh;
    *(uint4*)&sAl[ar*40+akb]=ql;
    __syncthreads();
    bf16x8 bh=*(const bf16x8*)&Wbh[(size_t)(wid*16+lr)*576 + kOff + k0 + 8*lg];
    bf16x8 bl=*(const bf16x8*)&Wbl[(size_t)(wid*16+lr)*576 + kOff + k0 + 8*lg];
    #pragma unroll
    for(int rt=0;rt<4;rt++){
      bf16x8 ah=*(const bf16x8*)&sAh[(rt*16+lr)*40+8*lg];
      bf16x8 al=*(const bf16x8*)&sAl[(rt*16+lr)*40+8*lg];
      a4[rt]=__builtin_amdgcn_mfma_f32_16x16x32_bf16(ah,bh,a4[rt],0,0,0);
      a4[rt]=__builtin_amdgcn_mfma_f32_16x16x32_bf16(ah,bl,a4[rt],0,0,0);
      a4[rt]=__builtin_amdgcn_mfma_f32_16x16x32_bf16(al,bh,a4[rt],0,0,0);
    }
    __syncthreads();
  }
  int o=wid*16+lr;
  #pragma unroll
  for(int rt=0;rt<4;rt++){
    int bn=bn0+rt;
    #pragma unroll
    for(int r=0;r<4;r++){
      int t2=lg*4+r;
      if(t2<TN){
        size_t oi=((size_t)bn*TN + t2)*64 + o;
        float v=a4[rt][r];
        if(FIRST){
          float rr=res[((size_t)bn*Tc + (Tc-TN) + t2)*64 + o];
          if(bng) rr=(rr-bnst[o])*bnst[64+o]*bng[o]+bnb[o];
          v += gb[o] + rr;
          acc[oi]=v;
        }else{
          acc[oi]+=v;
        }
      }
    }
  }
}

// BN stats (layout [b][n][tt][c]), two-stage
__global__ __launch_bounds__(256) void k_bnstats1(const float* __restrict__ h,
                                                  float* __restrict__ part, int R){
  int tid=threadIdx.x;
  int c=tid&63, rg=tid>>6;
  float s=0.f,q=0.f;
  for(int r=blockIdx.x*4+rg; r<R; r+=1024){
    float v=h[(size_t)r*64+c];
    s+=v; q+=v*v;
  }
  __shared__ float ls[256], lq[256];
  ls[tid]=s; lq[tid]=q; __syncthreads();
  if(rg==0){
    s=ls[c]+ls[64+c]+ls[128+c]+ls[192+c];
    q=lq[c]+lq[64+c]+lq[128+c]+lq[192+c];
    part[blockIdx.x*128+c]=s;
    part[blockIdx.x*128+64+c]=q;
  }
}
__global__ __launch_bounds__(256) void k_bnstats2(const float* __restrict__ part,
                                                  float* __restrict__ st, int R){
  int tid=threadIdx.x;
  int c=tid&63, g=tid>>6;
  float s=0.f,q=0.f;
  for(int p=g;p<256;p+=4){ s+=part[p*128+c]; q+=part[p*128+64+c]; }
  __shared__ float ls[256], lq[256];
  ls[tid]=s; lq[tid]=q; __syncthreads();
  if(g==0){
    s=ls[c]+ls[64+c]+ls[128+c]+ls[192+c];
    q=lq[c]+lq[64+c]+lq[128+c]+lq[192+c];
    float mu=s/R;
    float var=q/R-mu*mu;
    st[c]=mu; st[64+c]=rsqrtf(var+1e-5f);
  }
}

__global__ void k_head(const float* __restrict__ skipacc, const float* __restrict__ W1,
  const float* __restrict__ b1, const float* __restrict__ W2, const float* __restrict__ b2,
  float* __restrict__ out){
  int gid=blockIdx.x; int tid=threadIdx.x;  // 512 threads
  int n=gid%N; int b=gid/N;
  __shared__ float s[SKC];
  __shared__ float hid[512];
  if(tid<SKC){
    float v=skipacc[(size_t)gid*SKC+tid];
    s[tid]=fmaxf(v,0.f);
  }
  __syncthreads();
  {
    float a=b1[tid];
    for(int i=0;i<SKC;i++) a+=s[i]*W1[(size_t)i*512+tid];
    hid[tid]=fmaxf(a,0.f);
  }
  __syncthreads();
  if(tid<T){
    float a=b2[tid];
    for(int j=0;j<512;j++) a+=hid[j]*W2[(size_t)j*T+tid];
    out[((size_t)b*T+tid)*N+n]=a;
  }
}

// ---------------- host-side layer driver ----------------
struct Ctx {
  const float *bq,*bk,*bv,*b1,*b2,*filt_b,*gate_b,*skip_w,*skip_b,*gcn_b,*bn_g,*bn_b;
  const unsigned short *qkvTh,*qkvTl,*w1Th,*w1Tl,*w2Th,*w2Tl,*cvTh,*cvTl,*wgh,*wgl;
  const unsigned short* matH[4];
  const unsigned short* matL[4];
  long long matStride[4];
  float *pH,*pAlt,*skipacc,*bnst,*bnpart;
  unsigned short *hThi,*hTlo,*Phi,*Plo,*Qhi,*Qlo;
  unsigned short *hTth,*hTtl,*PTh,*PTl;
  hipStream_t stream;
};

template<int TC, int D>
void run_layer(Ctx& c, int l, bool last){
  constexpr int TN=TC-D;
  const float* ibnst=(l>0)?c.bnst:nullptr;
  const float* ibng =(l>0)?(c.bn_g+(size_t)(l-1)*C):nullptr;
  const float* ibnb =(l>0)?(c.bn_b+(size_t)(l-1)*C):nullptr;
  k_attconv<TC,D><<<B*N,256,0,c.stream>>>(c.pH,
    c.qkvTh+(size_t)l*12288, c.qkvTl+(size_t)l*12288,
    c.w1Th+(size_t)l*16384,  c.w1Tl+(size_t)l*16384,
    c.w2Th+(size_t)l*16384,  c.w2Tl+(size_t)l*16384,
    c.cvTh+(size_t)l*16384,  c.cvTl+(size_t)l*16384,
    c.bq+(size_t)l*C, c.bk+(size_t)l*C, c.bv+(size_t)l*C,
    c.b1+(size_t)l*4*C, c.b2+(size_t)l*C,
    c.filt_b+(size_t)l*C, c.gate_b+(size_t)l*C,
    c.skip_w+(size_t)l*C*SKC, c.skip_b+(size_t)l*SKC,
    ibnst, ibng, ibnb,
    c.hThi, c.hTlo, c.skipacc, l==0?1:0);
  if(!last){
    int M=C*TN, nMB=M/64;
    const unsigned short* Wh=c.wgh+(size_t)l*36864;
    const unsigned short* Wl=c.wgl+(size_t)l*36864;
    dim3 sg(DIVUP(N,128), nMB, B);
    k_trx<<<dim3(M/64,DIVUP(NP,64),B),256,0,c.stream>>>(c.hThi,c.hTlo, c.hTth,c.hTtl, M);
    for(int s=0;s<4;s++){
      k_spatmm<<<sg,256,0,c.stream>>>(c.matH[s],c.matL[s],c.matStride[s],
          nullptr,nullptr, c.hTth,c.hTtl, 1,
          c.Phi,c.Plo, c.PTh,c.PTl, M);
      if(c.PTh){
        k_spatmm<<<sg,256,0,c.stream>>>(c.matH[s],c.matL[s],c.matStride[s],
            nullptr,nullptr, c.PTh,c.PTl, 1,
            c.Qhi,c.Qlo, nullptr,nullptr, M);
      }else{
        k_spatmm<<<sg,256,0,c.stream>>>(c.matH[s],c.matL[s],c.matStride[s],
            c.Phi,c.Plo, nullptr,nullptr, 0,
            c.Qhi,c.Qlo, nullptr,nullptr, M);
      }
      if(s==0){
        k_gcnmm<TN,1><<<(B*N)/4,256,0,c.stream>>>(
            c.hThi,c.hTlo, c.Phi,c.Plo, c.Qhi,c.Qlo,
            Wh,Wl, 0, c.gcn_b+(size_t)l*C, c.pH,
            ibnst, ibng, ibnb, c.pAlt, TC);
      }else{
        k_gcnmm<TN,0><<<(B*N)/4,256,0,c.stream>>>(
            c.Phi,c.Plo, c.Qhi,c.Qlo, nullptr,nullptr,
            Wh,Wl, (1+2*s)*64, nullptr, nullptr,
            nullptr,nullptr,nullptr, c.pAlt, TC);
      }
    }
    int R=B*N*TN;
    k_bnstats1<<<256,256,0,c.stream>>>(c.pAlt, c.bnpart, R);
    k_bnstats2<<<1,256,0,c.stream>>>(c.bnpart, c.bnst, R);
    float* tmp=c.pH; c.pH=c.pAlt; c.pAlt=tmp;
  }
}

} // namespace

extern "C" void kernel_launch(void* const* d_in, const int* in_sizes, int n_in,
                              void* d_out, int out_size, void* d_ws, size_t ws_size,
                              hipStream_t stream){
  (void)in_sizes; (void)n_in;
  const float* x      =(const float*)d_in[0];
  const float* sup0   =(const float*)d_in[1];
  const float* sup1   =(const float*)d_in[2];
  const float* TiD    =(const float*)d_in[3];
  const float* DiW    =(const float*)d_in[4];
  const float* E1     =(const float*)d_in[5];
  const float* E2     =(const float*)d_in[6];
  const float* E3     =(const float*)d_in[7];
  const float* Wx     =(const float*)d_in[8];
  const float* Wd     =(const float*)d_in[9];
  const float* Wxabs  =(const float*)d_in[10];
  const float* start_w=(const float*)d_in[11];
  const float* start_b=(const float*)d_in[12];
  const float* Wq     =(const float*)d_in[13];
  const float* Wk     =(const float*)d_in[15];
  const float* Wv     =(const float*)d_in[17];
  const float* W1     =(const float*)d_in[19];
  const float* W2     =(const float*)d_in[21];
  const float* filt_w =(const float*)d_in[23];
  const float* gate_w =(const float*)d_in[25];
  const float* gcn_w  =(const float*)d_in[29];

  Ctx c;
  c.bq=(const float*)d_in[14];
  c.bk=(const float*)d_in[16];
  c.bv=(const float*)d_in[18];
  c.b1=(const float*)d_in[20];
  c.b2=(const float*)d_in[22];
  c.filt_b=(const float*)d_in[24];
  c.gate_b=(const float*)d_in[26];
  c.skip_w=(const float*)d_in[27]; c.skip_b=(const float*)d_in[28];
  c.gcn_b =(const float*)d_in[30];
  c.bn_g  =(const float*)d_in[31]; c.bn_b  =(const float*)d_in[32];
  const float* end1_w =(const float*)d_in[33];
  const float* end1_b =(const float*)d_in[34];
  const float* end2_w =(const float*)d_in[35];
  const float* end2_b =(const float*)d_in[36];
  c.stream=stream;

  // workspace carve (16B-aligned)
  size_t off=0;
  auto allocF=[&](size_t nf)->float*{
    nf=(nf+3)&~(size_t)3;
    float* p=(float*)((char*)d_ws+off);
    off += nf*sizeof(float);
    return p;
  };
  auto allocU=[&](size_t nu)->unsigned short*{
    nu=(nu+7)&~(size_t)7;
    unsigned short* p=(unsigned short*)((char*)d_ws+off);
    off += nu*sizeof(unsigned short);
    return p;
  };
  const size_t HMAX =(size_t)B*C*N*T13;
  const size_t XSZ  =(size_t)B*C*N*12;
  const size_t XTSZ =(size_t)768*NP*B;
  const size_t SUPP =(size_t)NP*NP;
  const size_t ADSZ =(size_t)B*NP*NP;

  float* xf     = allocF((size_t)B*F7*N);
  float* gx1    = allocF((size_t)B*N*E);
  float* gdew   = allocF((size_t)B*N*E);
  float* gst    = allocF(16);
  c.bnst        = allocF(2*C);
  c.bnpart      = allocF(256*128);
  float* adp    = allocF((size_t)B*N*N);   // dead after k_topk; hosts hT_T overlay
  c.pH          = allocF(HMAX);
  c.pAlt        = allocF(HMAX);
  c.skipacc     = allocF((size_t)B*N*SKC);
  unsigned short* matRegion=(unsigned short*)((char*)d_ws+off);
  unsigned short* s0h = allocU(SUPP);
  unsigned short* s0l = allocU(SUPP);
  unsigned short* s1h = allocU(SUPP);
  unsigned short* s1l = allocU(SUPP);
  unsigned short* aph = allocU(SUPP);
  unsigned short* apl = allocU(SUPP);
  unsigned short* adh = allocU(ADSZ);
  unsigned short* adl = allocU(ADSZ);
  long long matRegionN = (long long)(( (unsigned short*)((char*)d_ws+off) ) - matRegion);
  c.hThi = allocU(XSZ);  c.hTlo = allocU(XSZ);
  c.Phi  = allocU(XSZ);  c.Plo  = allocU(XSZ);
  c.Qhi  = allocU(XSZ);  c.Qlo  = allocU(XSZ);
  unsigned short* qkvTh = allocU((size_t)L*12288);
  unsigned short* qkvTl = allocU((size_t)L*12288);
  unsigned short* w1Th  = allocU((size_t)L*16384);
  unsigned short* w1Tl  = allocU((size_t)L*16384);
  unsigned short* w2Th  = allocU((size_t)L*16384);
  unsigned short* w2Tl  = allocU((size_t)L*16384);
  unsigned short* cvTh  = allocU((size_t)L*16384);
  unsigned short* cvTl  = allocU((size_t)L*16384);
  unsigned short* wgh   = allocU((size_t)L*36864);
  unsigned short* wgl   = allocU((size_t)L*36864);
  if(off > ws_size){
    k_zero<<<DIVUP(out_size,256),256,0,stream>>>((float*)d_out, out_size);
    return;
  }
  c.hTth = (unsigned short*)adp;
  c.hTtl = c.hTth + XTSZ;
  {
    size_t save=off;
    c.PTh = allocU(XTSZ);
    c.PTl = allocU(XTSZ);
    if(off > ws_size){ c.PTh=nullptr; c.PTl=nullptr; off=save; }
  }
  c.qkvTh=qkvTh; c.qkvTl=qkvTl; c.w1Th=w1Th; c.w1Tl=w1Tl;
  c.w2Th=w2Th; c.w2Tl=w2Tl; c.cvTh=cvTh; c.cvTl=cvTl;
  c.wgh=wgh; c.wgl=wgl;
  c.matH[0]=s0h; c.matL[0]=s0l; c.matStride[0]=0;
  c.matH[1]=s1h; c.matL[1]=s1l; c.matStride[1]=0;
  c.matH[2]=aph; c.matL[2]=apl; c.matStride[2]=0;
  c.matH[3]=adh; c.matL[3]=adl; c.matStride[3]=(long long)NP*NP;

  // ---- graph generation + conversions ----
  k_zeroUS<<<(int)DIVUP(matRegionN,256),256,0,stream>>>(matRegion, matRegionN);
  k_cvt_qkv <<<DIVUP(L*192*64,256),256,0,stream>>>(Wq,Wk,Wv,qkvTh,qkvTl);
  k_cvt_w1  <<<DIVUP(L*256*64,256),256,0,stream>>>(W1,w1Th,w1Tl);
  k_cvt_w2  <<<DIVUP(L*64*256,256),256,0,stream>>>(W2,w2Th,w2Tl);
  k_cvt_conv<<<DIVUP(L*128*128,256),256,0,stream>>>(filt_w,gate_w,cvTh,cvTl);
  k_cvt_gcn <<<DIVUP(L*64*576,256),256,0,stream>>>(gcn_w,wgh,wgl);
  k_dft <<<DIVUP(B*F7*N,256),256,0,stream>>>(x, xf);
  k_l2f <<<DIVUP(B*N,256),256,0,stream>>>(xf);
  k_l2n <<<B*F7,256,0,stream>>>(xf);
  k_x1  <<<DIVUP(B*N,256),256,0,stream>>>(x, xf, E3, TiD, DiW, Wx, Wd, gx1);
  k_lnstats<<<B,256,0,stream>>>(gx1, gst);
  k_dew <<<DIVUP(B*N,256),256,0,stream>>>(gx1, gst, Wxabs, gdew);
  k_adp <<<DIVUP(B*N*N,256),256,0,stream>>>(gdew, gx1, adp);
  k_topk<<<(B*N)/4,256,0,stream>>>(adp, adh, adl);
  k_adap<<<N,256,0,stream>>>(E1, E2, aph, apl);
  k_cvtT<<<DIVUP(N*N,256),256,0,stream>>>(sup0, s0h, s0l);
  k_cvtT<<<DIVUP(N*N,256),256,0,stream>>>(sup1, s1h, s1l);

  // ---- trunk ----
  k_start<<<DIVUP(B*N*T13*C,256),256,0,stream>>>(x, start_w, start_b, c.pH);

  run_layer<13,1>(c,0,false);
  run_layer<12,2>(c,1,false);
  run_layer<10,1>(c,2,false);
  run_layer< 9,2>(c,3,false);
  run_layer< 7,1>(c,4,false);
  run_layer< 6,2>(c,5,false);
  run_layer< 4,1>(c,6,false);
  run_layer< 3,2>(c,7,true);

  k_head<<<B*N,512,0,stream>>>(c.skipacc, end1_w, end1_b, end2_w, end2_b, (float*)d_out);
}

// Round 13
// 5108.603 us; speedup vs baseline: 1.2704x; 1.1049x over previous
//
#include <hip/hip_runtime.h>
#include <math.h>

#define DIVUP(a,b) (((a)+(b)-1)/(b))

namespace {

constexpr int B=8, T=12, N=883, CIN=3, C=64, E=10, H=8, HD=8, TOPK=48, L=8;
constexpr int SKC=256, F7=7, T13=13;
constexpr int NP=896;   // padded N for bf16 support matrices / transposed X

typedef __attribute__((ext_vector_type(8))) short bf16x8;
typedef __attribute__((ext_vector_type(4))) float f32x4;

__device__ __forceinline__ float geluf(float x){ return 0.5f*x*(1.0f+erff(x*0.7071067811865475f)); }
__device__ __forceinline__ float sigmf(float x){ return 1.0f/(1.0f+expf(-x)); }
__device__ __forceinline__ float us2f(unsigned short u){ return __uint_as_float(((unsigned)u)<<16); }
__device__ __forceinline__ unsigned short f2us(float f){
  unsigned x=__float_as_uint(f);
  return (unsigned short)((x + 0x7fffu + ((x>>16)&1u))>>16);
}

// 16x16 output tile (single row-group)
template<int KK, int STRIDE, int KW>
__device__ __forceinline__ f32x4 tile_mm(
    const unsigned short* sAh, const unsigned short* sAl,
    const unsigned short* __restrict__ Wh, const unsigned short* __restrict__ Wl,
    int colBase, int lane, f32x4 acc){
  int lr=lane&15, lg=lane>>4;
  #pragma unroll
  for(int k0=0;k0<KK;k0+=32){
    bf16x8 ah=*(const bf16x8*)&sAh[lr*STRIDE+k0+8*lg];
    bf16x8 al=*(const bf16x8*)&sAl[lr*STRIDE+k0+8*lg];
    bf16x8 bh=*(const bf16x8*)&Wh[(size_t)(colBase+lr)*KW+k0+8*lg];
    bf16x8 bl=*(const bf16x8*)&Wl[(size_t)(colBase+lr)*KW+k0+8*lg];
    acc=__builtin_amdgcn_mfma_f32_16x16x32_bf16(ah,bh,acc,0,0,0);
    acc=__builtin_amdgcn_mfma_f32_16x16x32_bf16(ah,bl,acc,0,0,0);
    acc=__builtin_amdgcn_mfma_f32_16x16x32_bf16(al,bh,acc,0,0,0);
  }
  return acc;
}

// two 16x16 output tiles (rows 0-15 and 16-31) sharing B-fragments
template<int KK, int STRIDE, int KW>
__device__ __forceinline__ void tile_mm2(
    const unsigned short* sAh, const unsigned short* sAl,
    const unsigned short* __restrict__ Wh, const unsigned short* __restrict__ Wl,
    int colBase, int lane, f32x4& acc0, f32x4& acc1){
  int lr=lane&15, lg=lane>>4;
  #pragma unroll
  for(int k0=0;k0<KK;k0+=32){
    bf16x8 bh=*(const bf16x8*)&Wh[(size_t)(colBase+lr)*KW+k0+8*lg];
    bf16x8 bl=*(const bf16x8*)&Wl[(size_t)(colBase+lr)*KW+k0+8*lg];
    bf16x8 ah0=*(const bf16x8*)&sAh[lr*STRIDE+k0+8*lg];
    bf16x8 al0=*(const bf16x8*)&sAl[lr*STRIDE+k0+8*lg];
    bf16x8 ah1=*(const bf16x8*)&sAh[(lr+16)*STRIDE+k0+8*lg];
    bf16x8 al1=*(const bf16x8*)&sAl[(lr+16)*STRIDE+k0+8*lg];
    acc0=__builtin_amdgcn_mfma_f32_16x16x32_bf16(ah0,bh,acc0,0,0,0);
    acc0=__builtin_amdgcn_mfma_f32_16x16x32_bf16(ah0,bl,acc0,0,0,0);
    acc0=__builtin_amdgcn_mfma_f32_16x16x32_bf16(al0,bh,acc0,0,0,0);
    acc1=__builtin_amdgcn_mfma_f32_16x16x32_bf16(ah1,bh,acc1,0,0,0);
    acc1=__builtin_amdgcn_mfma_f32_16x16x32_bf16(ah1,bl,acc1,0,0,0);
    acc1=__builtin_amdgcn_mfma_f32_16x16x32_bf16(al1,bh,acc1,0,0,0);
  }
}

// ---------------- graph generation ----------------
__global__ void k_dft(const float* __restrict__ x, float* __restrict__ xf){
  int idx = blockIdx.x*256 + threadIdx.x;
  if(idx >= B*F7*N) return;
  int n = idx % N; int f = (idx/N) % F7; int b = idx/(N*F7);
  float re=0.f, im=0.f;
  for(int t=0;t<T;t++){
    float v = x[((size_t)(b*T+t)*N+n)*CIN];
    float ang = -6.283185307179586f * (float)(f*t) / 12.0f;
    re += v*cosf(ang); im += v*sinf(ang);
  }
  xf[idx] = sqrtf(re*re+im*im);
}

__global__ void k_l2f(float* __restrict__ xf){
  int idx = blockIdx.x*256 + threadIdx.x;
  if(idx >= B*N) return;
  int n = idx % N; int b = idx / N;
  float s=0.f;
  for(int f=0;f<F7;f++){ float v=xf[((size_t)b*F7+f)*N+n]; s+=v*v; }
  float inv = 1.0f/fmaxf(sqrtf(s), 1e-12f);
  for(int f=0;f<F7;f++) xf[((size_t)b*F7+f)*N+n] *= inv;
}

__global__ void k_l2n(float* __restrict__ xf){
  int bf = blockIdx.x; int tid = threadIdx.x;
  __shared__ float red[256];
  size_t base = (size_t)bf*N;
  float s=0.f;
  for(int i=tid;i<N;i+=256){ float v=xf[base+i]; s+=v*v; }
  red[tid]=s; __syncthreads();
  for(int k=128;k>0;k>>=1){ if(tid<k) red[tid]+=red[tid+k]; __syncthreads(); }
  float inv = 1.0f/fmaxf(sqrtf(red[0]), 1e-12f);
  __syncthreads();
  for(int i=tid;i<N;i+=256) xf[base+i]*=inv;
}

__global__ void k_x1(const float* __restrict__ x, const float* __restrict__ xf,
                     const float* __restrict__ E3, const float* __restrict__ TiD,
                     const float* __restrict__ DiW, const float* __restrict__ Wx,
                     const float* __restrict__ Wd, float* __restrict__ x1){
  int idx = blockIdx.x*256+threadIdx.x;
  if(idx>=B*N) return;
  int n=idx%N, b=idx/N;
  float xc[40];
  for(int d=0;d<E;d++){
    float a=0.f;
    for(int f=0;f<F7;f++) a += xf[((size_t)b*F7+f)*N+n]*Wx[f*E+d];
    xc[d]=a;
  }
  for(int d=0;d<E;d++) xc[10+d]=E3[n*E+d];
  int ti = (int)(x[((size_t)(b*T+(T-1))*N+n)*CIN+1]*288.0f);
  int dw = (int)(x[((size_t)(b*T+(T-1))*N+n)*CIN+2]);
  for(int d=0;d<E;d++) xc[20+d]=TiD[ti*E+d];
  for(int d=0;d<E;d++) xc[30+d]=DiW[dw*E+d];
  for(int e=0;e<E;e++){
    float a=0.f;
    for(int f=0;f<40;f++) a += xc[f]*Wd[((size_t)n*40+f)*E+e];
    x1[(size_t)idx*E+e]=fmaxf(a,0.f);
  }
}

__global__ void k_lnstats(const float* __restrict__ x1, float* __restrict__ st){
  int b=blockIdx.x, tid=threadIdx.x;
  __shared__ float rs[256], rq[256];
  const int M=N*E;
  float s=0.f,q=0.f;
  for(int i=tid;i<M;i+=256){ float v=x1[(size_t)b*M+i]; s+=v; q+=v*v; }
  rs[tid]=s; rq[tid]=q; __syncthreads();
  for(int k=128;k>0;k>>=1){ if(tid<k){ rs[tid]+=rs[tid+k]; rq[tid]+=rq[tid+k]; } __syncthreads(); }
  if(tid==0){ float mu=rs[0]/M; float var=rq[0]/M-mu*mu; st[b*2]=mu; st[b*2+1]=var; }
}

__global__ void k_dew(const float* __restrict__ x1, const float* __restrict__ st,
                      const float* __restrict__ Wxabs, float* __restrict__ dew){
  int idx=blockIdx.x*256+threadIdx.x;
  if(idx>=B*N) return;
  int b=idx/N;
  float mu=st[b*2], var=st[b*2+1];
  float rs=rsqrtf(var+1e-8f);
  float xk[E];
  for(int e=0;e<E;e++) xk[e]=(x1[(size_t)idx*E+e]-mu)*rs;
  for(int k=0;k<E;k++){
    float a=0.f;
    for(int e=0;e<E;e++) a+=xk[e]*Wxabs[e*E+k];
    dew[(size_t)idx*E+k]=a;
  }
}

__global__ void k_adp(const float* __restrict__ dew, const float* __restrict__ x1,
                      float* __restrict__ adp){
  size_t idx=(size_t)blockIdx.x*256+threadIdx.x;
  if(idx>=(size_t)B*N*N) return;
  int m=(int)(idx%N); int n=(int)((idx/N)%N); int b=(int)(idx/((size_t)N*N));
  const float* dr=dew+((size_t)b*N+n)*E;
  const float* xr=x1+((size_t)b*N+m)*E;
  float a=0.f;
  for(int k=0;k<E;k++) a+=dr[k]*xr[k];
  adp[idx]=fmaxf(a,0.f);
}

// wave-per-row top-48 + masked softmax -> bf16 hi/lo padded AD mats; zero barriers.
__global__ __launch_bounds__(256) void k_topk(const float* __restrict__ adp,
                       unsigned short* __restrict__ ADhi, unsigned short* __restrict__ ADlo){
  int row = blockIdx.x*4 + (threadIdx.x>>6);
  int lane = threadIdx.x & 63;
  const float* rp = adp + (size_t)row*N;
  float v[14];
  #pragma unroll
  for(int j=0;j<14;j++){
    int i = lane + j*64;
    v[j] = (i<N) ? rp[i] : -1.f;
  }
  unsigned sel = 0u;
  float m0 = 0.f;
  for(int k=0;k<TOPK;k++){
    float bv = -2.f; int bi = 1<<20;
    #pragma unroll
    for(int j=0;j<14;j++){
      if(!((sel>>j)&1u) && v[j] > bv){ bv = v[j]; bi = lane + j*64; }
    }
    #pragma unroll
    for(int off=1; off<64; off<<=1){
      float ov = __shfl_xor(bv, off);
      int   oi = __shfl_xor(bi, off);
      if(ov > bv || (ov==bv && oi<bi)){ bv=ov; bi=oi; }
    }
    if(k==0) m0 = bv;
    if((bi&63)==lane) sel |= 1u << (bi>>6);
  }
  float pv[14];
  float ls = 0.f;
  #pragma unroll
  for(int j=0;j<14;j++){
    int i = lane + j*64;
    float p = ((sel>>j)&1u) ? v[j] : 0.f;
    pv[j] = p;
    if(i<N) ls += expf(p - m0);
  }
  #pragma unroll
  for(int off=1; off<64; off<<=1) ls += __shfl_xor(ls, off);
  float invZ = 1.f/ls;
  size_t base = ((size_t)(row/N)*NP + (size_t)(row%N))*NP;
  #pragma unroll
  for(int j=0;j<14;j++){
    int i = lane + j*64;
    if(i<N){
      float f = expf(pv[j]-m0)*invZ;
      unsigned short h=f2us(f);
      ADhi[base+i]=h; ADlo[base+i]=f2us(f-us2f(h));
    }
  }
}

__global__ void k_adap(const float* __restrict__ E1, const float* __restrict__ E2,
                       unsigned short* __restrict__ Mh, unsigned short* __restrict__ Ml){
  int v=blockIdx.x, tid=threadIdx.x;
  __shared__ float rowv[N];
  __shared__ float rv[256];
  float e1[E];
  for(int e=0;e<E;e++) e1[e]=E1[v*E+e];
  for(int j=tid;j<N;j+=256){
    float s=0.f;
    for(int e=0;e<E;e++) s+=e1[e]*E2[j*E+e];
    rowv[j]=fmaxf(s,0.f);
  }
  __syncthreads();
  float lm=-1e30f;
  for(int j=tid;j<N;j+=256) lm=fmaxf(lm,rowv[j]);
  rv[tid]=lm; __syncthreads();
  for(int s=128;s>0;s>>=1){ if(tid<s) rv[tid]=fmaxf(rv[tid],rv[tid+s]); __syncthreads(); }
  float m=rv[0]; __syncthreads();
  float ls=0.f;
  for(int j=tid;j<N;j+=256) ls+=expf(rowv[j]-m);
  rv[tid]=ls; __syncthreads();
  for(int s=128;s>0;s>>=1){ if(tid<s) rv[tid]+=rv[tid+s]; __syncthreads(); }
  float invZ=1.0f/rv[0];
  for(int j=tid;j<N;j+=256){
    float f=expf(rowv[j]-m)*invZ;
    unsigned short h=f2us(f);
    Mh[(size_t)j*NP+v]=h; Ml[(size_t)j*NP+v]=f2us(f-us2f(h));
  }
}

__global__ void k_cvtT(const float* __restrict__ A, unsigned short* __restrict__ Mh,
                       unsigned short* __restrict__ Ml){
  int idx=blockIdx.x*256+threadIdx.x;
  if(idx>=N*N) return;
  int w=idx/N, v=idx%N;
  float f=A[(size_t)v*N+w];
  unsigned short h=f2us(f);
  Mh[(size_t)w*NP+v]=h;
  Ml[(size_t)w*NP+v]=f2us(f-us2f(h));
}

// ---- weight transpose+split conversions (run once) ----
__global__ void k_cvt_qkv(const float* __restrict__ Wq, const float* __restrict__ Wk,
                          const float* __restrict__ Wv,
                          unsigned short* __restrict__ dh, unsigned short* __restrict__ dl){
  int idx=blockIdx.x*256+threadIdx.x;
  if(idx>=L*192*64) return;
  int l=idx/12288, rem=idx%12288, col=rem/64, k=rem%64;
  int mat=col>>6, o=col&63;
  const float* W=(mat==0)?Wq:((mat==1)?Wk:Wv);
  float v=W[(size_t)l*4096 + k*64 + o];
  unsigned short h=f2us(v);
  dh[idx]=h; dl[idx]=f2us(v-us2f(h));
}
__global__ void k_cvt_w1(const float* __restrict__ W1,
                         unsigned short* __restrict__ dh, unsigned short* __restrict__ dl){
  int idx=blockIdx.x*256+threadIdx.x;
  if(idx>=L*256*64) return;
  int l=idx/16384, rem=idx%16384, col=rem/64, k=rem%64;
  float v=W1[(size_t)l*16384 + k*256 + col];
  unsigned short h=f2us(v);
  dh[idx]=h; dl[idx]=f2us(v-us2f(h));
}
__global__ void k_cvt_w2(const float* __restrict__ W2,
                         unsigned short* __restrict__ dh, unsigned short* __restrict__ dl){
  int idx=blockIdx.x*256+threadIdx.x;
  if(idx>=L*64*256) return;
  int l=idx/16384, rem=idx%16384, col=rem/256, k=rem%256;
  float v=W2[(size_t)l*16384 + k*64 + col];
  unsigned short h=f2us(v);
  dh[idx]=h; dl[idx]=f2us(v-us2f(h));
}
__global__ void k_cvt_conv(const float* __restrict__ fw, const float* __restrict__ gw,
                           unsigned short* __restrict__ dh, unsigned short* __restrict__ dl){
  int idx=blockIdx.x*256+threadIdx.x;
  if(idx>=L*128*128) return;
  int l=idx/16384, rem=idx%16384, col=rem/128, k=rem%128;
  int c=col&63, fg=col>>6, tap=k>>6, i=k&63;
  const float* W=fg?gw:fw;
  float v=W[(size_t)l*8192 + tap*4096 + i*64 + c];
  unsigned short h=f2us(v);
  dh[idx]=h; dl[idx]=f2us(v-us2f(h));
}
// gcn_w (L,576,64) -> [l][o][k=576] bf16 split
__global__ void k_cvt_gcn(const float* __restrict__ Wg,
                          unsigned short* __restrict__ dh, unsigned short* __restrict__ dl){
  int idx=blockIdx.x*256+threadIdx.x;
  if(idx>=L*64*576) return;
  int l=idx/36864, rem=idx%36864, o=rem/576, k=rem%576;
  float v=Wg[((size_t)l*576 + k)*64 + o];
  unsigned short h=f2us(v);
  dh[idx]=h; dl[idx]=f2us(v-us2f(h));
}

__global__ void k_zero(float* __restrict__ p, int n){
  int idx=blockIdx.x*256+threadIdx.x;
  if(idx<n) p[idx]=0.f;
}
__global__ void k_zeroUS(unsigned short* __restrict__ p, long long n){
  long long idx=(long long)blockIdx.x*256+threadIdx.x;
  if(idx<n) p[idx]=0;
}

// tiled transpose: S [b][n<N][m<M] (split bf16 pair) -> D [b][m][v<NP]
__global__ __launch_bounds__(256) void k_trx(
    const unsigned short* __restrict__ Sh, const unsigned short* __restrict__ Sl,
    unsigned short* __restrict__ Dh, unsigned short* __restrict__ Dl, int M){
  __shared__ unsigned short th[64][66], tl[64][66];
  int b=blockIdx.z;
  int m0=blockIdx.x*64, n0=blockIdx.y*64;
  int tid=threadIdx.x;
  const unsigned short* sbh=Sh + (size_t)b*N*M;
  const unsigned short* sbl=Sl + (size_t)b*N*M;
  for(int idx=tid; idx<64*64; idx+=256){
    int i=idx>>6, j=idx&63;
    int n=n0+i;
    unsigned short vh=0, vl=0;
    if(n<N){
      size_t o=(size_t)n*M + m0+j;
      vh=sbh[o]; vl=sbl[o];
    }
    th[j][i]=vh; tl[j][i]=vl;
  }
  __syncthreads();
  unsigned short* dbh=Dh + (size_t)b*M*NP;
  unsigned short* dbl=Dl + (size_t)b*M*NP;
  for(int idx=tid; idx<64*64; idx+=256){
    int r=idx>>6, cc=idx&63;
    size_t o=(size_t)(m0+r)*NP + n0+cc;
    dbh[o]=th[r][cc]; dbl[o]=tl[r][cc];
  }
}

// ---------------- trunk ----------------
// h layout: [b][n][t][c]
__global__ void k_start(const float* __restrict__ x, const float* __restrict__ sw,
                        const float* __restrict__ sb, float* __restrict__ h){
  int idx=blockIdx.x*256+threadIdx.x;
  if(idx>=B*N*T13*C) return;
  int c=idx&63; int t=(idx>>6)%T13; int n=(idx/(64*T13))%N; int b=idx/(64*T13*N);
  float a=sb[c];
  if(t>0){
    size_t xb=((size_t)(b*T+(t-1))*N+n)*CIN;
    for(int i=0;i<CIN;i++) a += sw[i*C+c]*x[xb+i];
  }
  h[idx]=a;
}

// Fused 2-node MFMA transformer block; hin [b][n][t][c] (BN fused if bng!=0).
// 32-row A tiles; tile_mm2 shares B-fragments across the 2 nodes. 50KB LDS arena.
template<int TC, int D>
__global__ __launch_bounds__(256) void k_attconv(const float* __restrict__ hin,
  const unsigned short* __restrict__ Wqkvh, const unsigned short* __restrict__ Wqkvl,
  const unsigned short* __restrict__ W1h,   const unsigned short* __restrict__ W1l,
  const unsigned short* __restrict__ W2h,   const unsigned short* __restrict__ W2l,
  const unsigned short* __restrict__ Wch,   const unsigned short* __restrict__ Wcl,
  const float* __restrict__ bq, const float* __restrict__ bk, const float* __restrict__ bv,
  const float* __restrict__ b1, const float* __restrict__ b2,
  const float* __restrict__ fb, const float* __restrict__ gb,
  const float* __restrict__ skw, const float* __restrict__ skb,
  const float* __restrict__ bnst, const float* __restrict__ bng, const float* __restrict__ bnb,
  unsigned short* __restrict__ hThi, unsigned short* __restrict__ hTlo,
  float* __restrict__ skipacc, int first){
  constexpr int TN = TC - D;
  int bn0=blockIdx.x*2; int tid=threadIdx.x;
  int lane=tid&63, wid=tid>>6;
  int lr=lane&15, lg=lane>>4;
  __shared__ __align__(16) char smem[51200];
  float* sxa=(float*)smem;                                   // [32][64] 8KB (residual; xcf/stg later)
  unsigned short* sA1h=(unsigned short*)(smem+8192);         // [32][72]
  unsigned short* sA1l=(unsigned short*)(smem+12800);        // ends 17408
  float* sq =(float*)(smem+17408);                           // [32][64] (P2-3)
  float* sk_=(float*)(smem+25600);
  float* sv =(float*)(smem+33792);                           // ends 41984
  unsigned short* sA2h=(unsigned short*)(smem+17408);        // [32][264] (P4-5)
  unsigned short* sA2l=(unsigned short*)(smem+34304);        // ends 51200
  float* xcf=(float*)smem;                                   // [32][64] over sxa (P5 out)
  unsigned short* cAh=(unsigned short*)(smem+17408);         // [32][136] (P6+)
  unsigned short* cAl=(unsigned short*)(smem+26112);         // ends 34816
  float* sfg=(float*)(smem+34816);                           // [32][128] ends 51200 (P7+)
  float* stg=(float*)smem;                                   // [2][64] over sxa (P8+)

  // phase 1: contiguous staging of 2 nodes, BN fused
  const float* hp = hin + (size_t)bn0*TC*64;
  for(int idx=tid; idx<2*TC*64; idx+=256){
    int ni=idx/(TC*64); int rem=idx%(TC*64);
    int t=rem>>6, c=rem&63;
    float v=hp[idx];
    if(bng) v=(v-bnst[c])*bnst[64+c]*bng[c]+bnb[c];
    int row=ni*16+t;
    sxa[row*64+c]=v;
    unsigned short h=f2us(v);
    sA1h[row*72+c]=h; sA1l[row*72+c]=f2us(v-us2f(h));
  }
  for(int idx=tid; idx<2*(16-TC)*64; idx+=256){
    int pr=idx>>6, c=idx&63;
    int ni=pr/(16-TC), tp=TC+pr%(16-TC);
    int row=ni*16+tp;
    sxa[row*64+c]=0.f; sA1h[row*72+c]=0; sA1l[row*72+c]=0;
  }
  __syncthreads();

  // phase 2: QKV + bias + gelu (12 col-tiles, shared B)
  #pragma unroll
  for(int it=0; it<3; ++it){
    int tile=it*4+wid;
    f32x4 a0={0.f,0.f,0.f,0.f}, a1={0.f,0.f,0.f,0.f};
    tile_mm2<64,72,64>(sA1h,sA1l,Wqkvh,Wqkvl,tile*16,lane,a0,a1);
    int col=tile*16+lr; int mat=col>>6, o=col&63;
    const float* bm=(mat==0)?bq:((mat==1)?bk:bv);
    float* dst=(mat==0)?sq:((mat==1)?sk_:sv);
    float bias=bm[o];
    #pragma unroll
    for(int r=0;r<4;r++){
      int t=lg*4+r;
      if(t<TC){
        dst[t*64+o]      =geluf(a0[r]+bias);
        dst[(16+t)*64+o] =geluf(a1[r]+bias);
      }
    }
  }
  __syncthreads();

  // phase 3: causal attention (both nodes) -> split bf16 into sA1
  if(tid<2*H*TC){
    int ni=tid/(H*TC); int rr=tid%(H*TC);
    int hh=rr/TC, t=rr%TC;
    int rb=ni*16;
    const float* qr=&sq[(rb+t)*64+hh*HD];
    float att[TC];
    float m=-1e30f;
    #pragma unroll
    for(int s=0;s<TC;s++){
      float a=0.f;
      #pragma unroll
      for(int d=0;d<HD;d++) a+=qr[d]*sk_[(rb+s)*64+hh*HD+d];
      a*=0.3535533905932738f;
      a=(s<=t)?a:-1e30f;
      att[s]=a; m=fmaxf(m,a);
    }
    float Z=0.f;
    #pragma unroll
    for(int s=0;s<TC;s++){ float e=expf(att[s]-m); att[s]=e; Z+=e; }
    float invZ=1.0f/Z;
    #pragma unroll
    for(int d=0;d<HD;d++){
      float o=0.f;
      #pragma unroll
      for(int s=0;s<TC;s++) o+=att[s]*sv[(rb+s)*64+hh*HD+d];
      float v=o*invZ;
      unsigned short h=f2us(v);
      sA1h[(rb+t)*72+hh*8+d]=h; sA1l[(rb+t)*72+hh*8+d]=f2us(v-us2f(h));
    }
  }
  __syncthreads();

  // phase 4: FFN1 + bias + gelu -> split bf16 sA2 (stride 264)
  #pragma unroll
  for(int it=0; it<4; ++it){
    int tile=it*4+wid;
    f32x4 a0={0.f,0.f,0.f,0.f}, a1={0.f,0.f,0.f,0.f};
    tile_mm2<64,72,64>(sA1h,sA1l,W1h,W1l,tile*16,lane,a0,a1);
    int col=tile*16+lr;
    float bias=b1[col];
    #pragma unroll
    for(int r=0;r<4;r++){
      int t=lg*4+r;
      float v0=(t<TC)?geluf(a0[r]+bias):0.f;
      float v1=(t<TC)?geluf(a1[r]+bias):0.f;
      unsigned short h0=f2us(v0), h1=f2us(v1);
      sA2h[t*264+col]=h0;      sA2l[t*264+col]=f2us(v0-us2f(h0));
      sA2h[(16+t)*264+col]=h1; sA2l[(16+t)*264+col]=f2us(v1-us2f(h1));
    }
  }
  __syncthreads();

  // phase 5: FFN2 + bias + residual -> xcf (over dead sxa; same-thread RMW)
  {
    int tile=wid;
    f32x4 a0={0.f,0.f,0.f,0.f}, a1={0.f,0.f,0.f,0.f};
    tile_mm2<256,264,256>(sA2h,sA2l,W2h,W2l,tile*16,lane,a0,a1);
    int col=tile*16+lr;
    float bias=b2[col];
    #pragma unroll
    for(int r=0;r<4;r++){
      int t=lg*4+r;
      if(t<TC){
        xcf[t*64+col]     =a0[r]+bias+sxa[t*64+col];
        xcf[(16+t)*64+col]=a1[r]+bias+sxa[(16+t)*64+col];
      }
    }
  }
  __syncthreads();

  // phase 6: build conv A [32][136] split bf16 (over dead sA2 region)
  for(int idx=tid; idx<32*128; idx+=256){
    int row=idx>>7, k=idx&127;
    int ni=row>>4, t=row&15;
    int c=k&63;
    float v=0.f;
    if(t<TN) v=xcf[(ni*16+((k<64)?t:(t+D)))*64+c];
    unsigned short h=f2us(v);
    cAh[row*136+k]=h; cAl[row*136+k]=f2us(v-us2f(h));
  }
  __syncthreads();

  // phase 7: conv + bias + activation -> sfg [32][128]
  #pragma unroll
  for(int it=0; it<2; ++it){
    int tile=it*4+wid;
    f32x4 a0={0.f,0.f,0.f,0.f}, a1={0.f,0.f,0.f,0.f};
    tile_mm2<128,136,128>(cAh,cAl,Wch,Wcl,tile*16,lane,a0,a1);
    int col=tile*16+lr;
    float bias=(col<64)?fb[col]:gb[col&63];
    #pragma unroll
    for(int r=0;r<4;r++){
      int t=lg*4+r;
      float v0=a0[r]+bias, v1=a1[r]+bias;
      sfg[t*128+col]     =(col<64)?tanhf(v0):sigmf(v0);
      sfg[(16+t)*128+col]=(col<64)?tanhf(v1):sigmf(v1);
    }
  }
  __syncthreads();

  // phase 8: last-column conv output for skip (both nodes)
  if(tid<2*C){
    int ni=tid>>6, c=tid&63;
    stg[ni*64+c]=sfg[(ni*16+TN-1)*128+c]*sfg[(ni*16+TN-1)*128+64+c];
  }
  __syncthreads();

  // phase 9: skip projection (contiguous [bn][256], 2 nodes) + hT write
  for(int idx=tid; idx<2*SKC; idx+=256){
    int ni=idx>>8, o=idx&255;
    float a=skb[o];
    for(int i=0;i<C;i++) a+=stg[ni*64+i]*skw[i*SKC+o];
    size_t so_=(size_t)(bn0+ni)*SKC+o;
    if(first) skipacc[so_]=a; else skipacc[so_]+=a;
  }
  size_t obase=(size_t)bn0*64*TN;
  for(int idx=tid; idx<2*TN*64; idx+=256){
    int ni=idx/(TN*64); int rem=idx%(TN*64);
    int tt=rem>>6, c=rem&63;
    float v=sfg[(ni*16+tt)*128+c]*sfg[(ni*16+tt)*128+64+c];
    unsigned short h=f2us(v);
    hThi[obase+idx]=h;
    hTlo[obase+idx]=f2us(v-us2f(h));
  }
}

// ---- MFMA spatial GEMM: 128x64 tile, 4 waves each own 32 rows x 64 cols ----
__global__ __launch_bounds__(256) void k_spatmm(
    const unsigned short* __restrict__ Ah, const unsigned short* __restrict__ Al,
    long long aStride,
    const unsigned short* __restrict__ Xh, const unsigned short* __restrict__ Xl,
    const unsigned short* __restrict__ XTh, const unsigned short* __restrict__ XTl,
    int xT,
    unsigned short* __restrict__ Yh, unsigned short* __restrict__ Yl,
    unsigned short* __restrict__ YTh, unsigned short* __restrict__ YTl,
    int M){
  __shared__ unsigned short sAh[128*40];
  __shared__ unsigned short sAl[128*40];
  __shared__ unsigned short sXh[64*40];
  __shared__ unsigned short sXl[64*40];
  int b=blockIdx.z;
  const unsigned short* Abh=Ah+(size_t)b*aStride;
  const unsigned short* Abl=Al+(size_t)b*aStride;
  int tid=threadIdx.x;
  int w0=blockIdx.x*128, c0=blockIdx.y*64;
  int lane=tid&63, wid=tid>>6;
  int lr=lane&15, lg=lane>>4;
  f32x4 acc[2][4];
  #pragma unroll
  for(int j=0;j<2;j++){
    #pragma unroll
    for(int i=0;i<4;i++){ acc[j][i][0]=0.f; acc[j][i][1]=0.f; acc[j][i][2]=0.f; acc[j][i][3]=0.f; }
  }
  const int ar=tid>>1,  akb=(tid&1)*16;
  const int xr=tid>>2,  xkb=(tid&3)*8;
  const int xk=tid>>3,  xcb=(tid&7)*8;
  const int xkx=xk ^ (8*((xcb>>3)&3));
  for(int k0=0;k0<N;k0+=32){
    {
      uint4 qh0=*(const uint4*)&Abh[(size_t)(w0+ar)*NP + k0+akb];
      uint4 qh1=*(const uint4*)&Abh[(size_t)(w0+ar)*NP + k0+akb+8];
      uint4 ql0=*(const uint4*)&Abl[(size_t)(w0+ar)*NP + k0+akb];
      uint4 ql1=*(const uint4*)&Abl[(size_t)(w0+ar)*NP + k0+akb+8];
      *(uint4*)&sAh[ar*40+akb]=qh0;   *(uint4*)&sAh[ar*40+akb+8]=qh1;
      *(uint4*)&sAl[ar*40+akb]=ql0;   *(uint4*)&sAl[ar*40+akb+8]=ql1;
    }
    if(xT){
      const unsigned short* Xbth=XTh+(size_t)b*M*NP;
      const unsigned short* Xbtl=XTl+(size_t)b*M*NP;
      uint4 qh=*(const uint4*)&Xbth[(size_t)(c0+xr)*NP + k0+xkb];
      uint4 ql=*(const uint4*)&Xbtl[(size_t)(c0+xr)*NP + k0+xkb];
      *(uint4*)&sXh[xr*40+xkb]=qh;
      *(uint4*)&sXl[xr*40+xkb]=ql;
    }else{
      const unsigned short* Xbh=Xh+(size_t)b*N*M;
      const unsigned short* Xbl=Xl+(size_t)b*N*M;
      uint4 qh={0,0,0,0}, ql={0,0,0,0};
      if(k0+xk<N){
        qh=*(const uint4*)&Xbh[(size_t)(k0+xk)*M + c0+xcb];
        ql=*(const uint4*)&Xbl[(size_t)(k0+xk)*M + c0+xcb];
      }
      unsigned short uh[8], ul[8];
      uh[0]=(unsigned short)(qh.x&0xffff); uh[1]=(unsigned short)(qh.x>>16);
      uh[2]=(unsigned short)(qh.y&0xffff); uh[3]=(unsigned short)(qh.y>>16);
      uh[4]=(unsigned short)(qh.z&0xffff); uh[5]=(unsigned short)(qh.z>>16);
      uh[6]=(unsigned short)(qh.w&0xffff); uh[7]=(unsigned short)(qh.w>>16);
      ul[0]=(unsigned short)(ql.x&0xffff); ul[1]=(unsigned short)(ql.x>>16);
      ul[2]=(unsigned short)(ql.y&0xffff); ul[3]=(unsigned short)(ql.y>>16);
      ul[4]=(unsigned short)(ql.z&0xffff); ul[5]=(unsigned short)(ql.z>>16);
      ul[6]=(unsigned short)(ql.w&0xffff); ul[7]=(unsigned short)(ql.w>>16);
      #pragma unroll
      for(int j=0;j<8;j++){
        sXh[(xcb+j)*40+xkx]=uh[j];
        sXl[(xcb+j)*40+xkx]=ul[j];
      }
    }
    __syncthreads();
    bf16x8 a_h[2], a_l[2], x_h[4], x_l[4];
    #pragma unroll
    for(int j=0;j<2;j++){
      int r=32*wid+16*j+lr;
      a_h[j]=*(const bf16x8*)&sAh[r*40+8*lg];
      a_l[j]=*(const bf16x8*)&sAl[r*40+8*lg];
    }
    #pragma unroll
    for(int i=0;i<4;i++){
      int cc=16*i+lr;
      int g = xT ? lg : (lg ^ ((cc>>3)&3));
      x_h[i]=*(const bf16x8*)&sXh[cc*40+8*g];
      x_l[i]=*(const bf16x8*)&sXl[cc*40+8*g];
    }
    #pragma unroll
    for(int j=0;j<2;j++){
      #pragma unroll
      for(int i=0;i<4;i++){
        acc[j][i]=__builtin_amdgcn_mfma_f32_16x16x32_bf16(a_h[j],x_h[i],acc[j][i],0,0,0);
        acc[j][i]=__builtin_amdgcn_mfma_f32_16x16x32_bf16(a_h[j],x_l[i],acc[j][i],0,0,0);
        acc[j][i]=__builtin_amdgcn_mfma_f32_16x16x32_bf16(a_l[j],x_h[i],acc[j][i],0,0,0);
      }
    }
    __syncthreads();
  }
  #pragma unroll
  for(int j=0;j<2;j++){
    int rbase=w0+32*wid+16*j+lg*4;
    #pragma unroll
    for(int i=0;i<4;i++){
      int col=c0+16*i+lr;
      unsigned short hh[4], ll[4];
      #pragma unroll
      for(int r=0;r<4;r++){
        float v=acc[j][i][r];
        hh[r]=f2us(v);
        ll[r]=f2us(v-us2f(hh[r]));
      }
      #pragma unroll
      for(int r=0;r<4;r++){
        int row=rbase+r;
        if(row<N){
          size_t o=((size_t)b*N+row)*M+col;
          Yh[o]=hh[r]; Yl[o]=ll[r];
        }
      }
      if(YTh){
        size_t o=(size_t)b*M*NP + (size_t)col*NP + rbase;
        ushort4 ph; ph.x=hh[0]; ph.y=hh[1]; ph.z=hh[2]; ph.w=hh[3];
        ushort4 pl; pl.x=ll[0]; pl.y=ll[1]; pl.z=ll[2]; pl.w=ll[3];
        *(ushort4*)&YTh[o]=ph;
        *(ushort4*)&YTl[o]=pl;
      }
    }
  }
}

// ---- MFMA GCN projection (residual BN fused) ----
template<int TN, int FIRST>
__global__ __launch_bounds__(256) void k_gcnmm(
    const unsigned short* __restrict__ S0h, const unsigned short* __restrict__ S0l,
    const unsigned short* __restrict__ S1h, const unsigned short* __restrict__ S1l,
    const unsigned short* __restrict__ S2h, const unsigned short* __restrict__ S2l,
    const unsigned short* __restrict__ Wbh, const unsigned short* __restrict__ Wbl,
    int kOff,
    const float* __restrict__ gb, const float* __restrict__ res,
    const float* __restrict__ bnst, const float* __restrict__ bng, const float* __restrict__ bnb,
    float* __restrict__ acc, int Tc){
  constexpr int SL=64*TN;
  constexpr int NS=FIRST?3:2;
  constexpr int KK=NS*64;
  __shared__ unsigned short sAh[64*40], sAl[64*40];
  int bn0=blockIdx.x*4;
  int tid=threadIdx.x, lane=tid&63, wid=tid>>6;
  int lr=lane&15, lg=lane>>4;
  f32x4 a4[4];
  #pragma unroll
  for(int rt=0;rt<4;rt++){ a4[rt][0]=0.f; a4[rt][1]=0.f; a4[rt][2]=0.f; a4[rt][3]=0.f; }
  const int ar=tid>>2, akb=(tid&3)*8;
  const int ani=ar>>4, att_=ar&15;
  #pragma unroll
  for(int kc=0; kc<KK/32; ++kc){
    int k0=kc*32; int j=k0>>6; int i0=k0&63;
    const unsigned short* sh=(j==0)?S0h:((j==1)?S1h:S2h);
    const unsigned short* sl=(j==0)?S0l:((j==1)?S1l:S2l);
    uint4 qh={0,0,0,0}, ql={0,0,0,0};
    if(att_<TN){
      size_t o=(size_t)(bn0+ani)*SL + att_*64 + i0 + akb;
      qh=*(const uint4*)&sh[o]; ql=*(const uint4*)&sl[o];
    }
    *(uint4*)&sAh[ar*40+akb]=qh;
    *(uint4*)&sAl[ar*40+akb]=ql;
    __syncthreads();
    bf16x8 bh=*(const bf16x8*)&Wbh[(size_t)(wid*16+lr)*576 + kOff + k0 + 8*lg];
    bf16x8 bl=*(const bf16x8*)&Wbl[(size_t)(wid*16+lr)*576 + kOff + k0 + 8*lg];
    #pragma unroll
    for(int rt=0;rt<4;rt++){
      bf16x8 ah=*(const bf16x8*)&sAh[(rt*16+lr)*40+8*lg];
      bf16x8 al=*(const bf16x8*)&sAl[(rt*16+lr)*40+8*lg];
      a4[rt]=__builtin_amdgcn_mfma_f32_16x16x32_bf16(ah,bh,a4[rt],0,0,0);
      a4[rt]=__builtin_amdgcn_mfma_f32_16x16x32_bf16(ah,bl,a4[rt],0,0,0);
      a4[rt]=__builtin_amdgcn_mfma_f32_16x16x32_bf16(al,bh,a4[rt],0,0,0);
    }
    __syncthreads();
  }
  int o=wid*16+lr;
  #pragma unroll
  for(int rt=0;rt<4;rt++){
    int bn=bn0+rt;
    #pragma unroll
    for(int r=0;r<4;r++){
      int t2=lg*4+r;
      if(t2<TN){
        size_t oi=((size_t)bn*TN + t2)*64 + o;
        float v=a4[rt][r];
        if(FIRST){
          float rr=res[((size_t)bn*Tc + (Tc-TN) + t2)*64 + o];
          if(bng) rr=(rr-bnst[o])*bnst[64+o]*bng[o]+bnb[o];
          v += gb[o] + rr;
          acc[oi]=v;
        }else{
          acc[oi]+=v;
        }
      }
    }
  }
}

// BN stats (layout [b][n][tt][c]), two-stage
__global__ __launch_bounds__(256) void k_bnstats1(const float* __restrict__ h,
                                                  float* __restrict__ part, int R){
  int tid=threadIdx.x;
  int c=tid&63, rg=tid>>6;
  float s=0.f,q=0.f;
  for(int r=blockIdx.x*4+rg; r<R; r+=1024){
    float v=h[(size_t)r*64+c];
    s+=v; q+=v*v;
  }
  __shared__ float ls[256], lq[256];
  ls[tid]=s; lq[tid]=q; __syncthreads();
  if(rg==0){
    s=ls[c]+ls[64+c]+ls[128+c]+ls[192+c];
    q=lq[c]+lq[64+c]+lq[128+c]+lq[192+c];
    part[blockIdx.x*128+c]=s;
    part[blockIdx.x*128+64+c]=q;
  }
}
__global__ __launch_bounds__(256) void k_bnstats2(const float* __restrict__ part,
                                                  float* __restrict__ st, int R){
  int tid=threadIdx.x;
  int c=tid&63, g=tid>>6;
  float s=0.f,q=0.f;
  for(int p=g;p<256;p+=4){ s+=part[p*128+c]; q+=part[p*128+64+c]; }
  __shared__ float ls[256], lq[256];
  ls[tid]=s; lq[tid]=q; __syncthreads();
  if(g==0){
    s=ls[c]+ls[64+c]+ls[128+c]+ls[192+c];
    q=lq[c]+lq[64+c]+lq[128+c]+lq[192+c];
    float mu=s/R;
    float var=q/R-mu*mu;
    st[c]=mu; st[64+c]=rsqrtf(var+1e-5f);
  }
}

__global__ void k_head(const float* __restrict__ skipacc, const float* __restrict__ W1,
  const float* __restrict__ b1, const float* __restrict__ W2, const float* __restrict__ b2,
  float* __restrict__ out){
  int gid=blockIdx.x; int tid=threadIdx.x;  // 512 threads
  int n=gid%N; int b=gid/N;
  __shared__ float s[SKC];
  __shared__ float hid[512];
  if(tid<SKC){
    float v=skipacc[(size_t)gid*SKC+tid];
    s[tid]=fmaxf(v,0.f);
  }
  __syncthreads();
  {
    float a=b1[tid];
    for(int i=0;i<SKC;i++) a+=s[i]*W1[(size_t)i*512+tid];
    hid[tid]=fmaxf(a,0.f);
  }
  __syncthreads();
  if(tid<T){
    float a=b2[tid];
    for(int j=0;j<512;j++) a+=hid[j]*W2[(size_t)j*T+tid];
    out[((size_t)b*T+tid)*N+n]=a;
  }
}

// ---------------- host-side layer driver ----------------
struct Ctx {
  const float *bq,*bk,*bv,*b1,*b2,*filt_b,*gate_b,*skip_w,*skip_b,*gcn_b,*bn_g,*bn_b;
  const unsigned short *qkvTh,*qkvTl,*w1Th,*w1Tl,*w2Th,*w2Tl,*cvTh,*cvTl,*wgh,*wgl;
  const unsigned short* matH[4];
  const unsigned short* matL[4];
  long long matStride[4];
  float *pH,*pAlt,*skipacc,*bnst,*bnpart;
  unsigned short *hThi,*hTlo,*Phi,*Plo,*Qhi,*Qlo;
  unsigned short *hTth,*hTtl,*PTh,*PTl;
  hipStream_t stream;
};

template<int TC, int D>
void run_layer(Ctx& c, int l, bool last){
  constexpr int TN=TC-D;
  const float* ibnst=(l>0)?c.bnst:nullptr;
  const float* ibng =(l>0)?(c.bn_g+(size_t)(l-1)*C):nullptr;
  const float* ibnb =(l>0)?(c.bn_b+(size_t)(l-1)*C):nullptr;
  k_attconv<TC,D><<<(B*N)/2,256,0,c.stream>>>(c.pH,
    c.qkvTh+(size_t)l*12288, c.qkvTl+(size_t)l*12288,
    c.w1Th+(size_t)l*16384,  c.w1Tl+(size_t)l*16384,
    c.w2Th+(size_t)l*16384,  c.w2Tl+(size_t)l*16384,
    c.cvTh+(size_t)l*16384,  c.cvTl+(size_t)l*16384,
    c.bq+(size_t)l*C, c.bk+(size_t)l*C, c.bv+(size_t)l*C,
    c.b1+(size_t)l*4*C, c.b2+(size_t)l*C,
    c.filt_b+(size_t)l*C, c.gate_b+(size_t)l*C,
    c.skip_w+(size_t)l*C*SKC, c.skip_b+(size_t)l*SKC,
    ibnst, ibng, ibnb,
    c.hThi, c.hTlo, c.skipacc, l==0?1:0);
  if(!last){
    int M=C*TN, nMB=M/64;
    const unsigned short* Wh=c.wgh+(size_t)l*36864;
    const unsigned short* Wl=c.wgl+(size_t)l*36864;
    dim3 sg(DIVUP(N,128), nMB, B);
    k_trx<<<dim3(M/64,DIVUP(NP,64),B),256,0,c.stream>>>(c.hThi,c.hTlo, c.hTth,c.hTtl, M);
    for(int s=0;s<4;s++){
      k_spatmm<<<sg,256,0,c.stream>>>(c.matH[s],c.matL[s],c.matStride[s],
          nullptr,nullptr, c.hTth,c.hTtl, 1,
          c.Phi,c.Plo, c.PTh,c.PTl, M);
      if(c.PTh){
        k_spatmm<<<sg,256,0,c.stream>>>(c.matH[s],c.matL[s],c.matStride[s],
            nullptr,nullptr, c.PTh,c.PTl, 1,
            c.Qhi,c.Qlo, nullptr,nullptr, M);
      }else{
        k_spatmm<<<sg,256,0,c.stream>>>(c.matH[s],c.matL[s],c.matStride[s],
            c.Phi,c.Plo, nullptr,nullptr, 0,
            c.Qhi,c.Qlo, nullptr,nullptr, M);
      }
      if(s==0){
        k_gcnmm<TN,1><<<(B*N)/4,256,0,c.stream>>>(
            c.hThi,c.hTlo, c.Phi,c.Plo, c.Qhi,c.Qlo,
            Wh,Wl, 0, c.gcn_b+(size_t)l*C, c.pH,
            ibnst, ibng, ibnb, c.pAlt, TC);
      }else{
        k_gcnmm<TN,0><<<(B*N)/4,256,0,c.stream>>>(
            c.Phi,c.Plo, c.Qhi,c.Qlo, nullptr,nullptr,
            Wh,Wl, (1+2*s)*64, nullptr, nullptr,
            nullptr,nullptr,nullptr, c.pAlt, TC);
      }
    }
    int R=B*N*TN;
    k_bnstats1<<<256,256,0,c.stream>>>(c.pAlt, c.bnpart, R);
    k_bnstats2<<<1,256,0,c.stream>>>(c.bnpart, c.bnst, R);
    float* tmp=c.pH; c.pH=c.pAlt; c.pAlt=tmp;
  }
}

} // namespace

extern "C" void kernel_launch(void* const* d_in, const int* in_sizes, int n_in,
                              void* d_out, int out_size, void* d_ws, size_t ws_size,
                              hipStream_t stream){
  (void)in_sizes; (void)n_in;
  const float* x      =(const float*)d_in[0];
  const float* sup0   =(const float*)d_in[1];
  const float* sup1   =(const float*)d_in[2];
  const float* TiD    =(const float*)d_in[3];
  const float* DiW    =(const float*)d_in[4];
  const float* E1     =(const float*)d_in[5];
  const float* E2     =(const float*)d_in[6];
  const float* E3     =(const float*)d_in[7];
  const float* Wx     =(const float*)d_in[8];
  const float* Wd     =(const float*)d_in[9];
  const float* Wxabs  =(const float*)d_in[10];
  const float* start_w=(const float*)d_in[11];
  const float* start_b=(const float*)d_in[12];
  const float* Wq     =(const float*)d_in[13];
  const float* Wk     =(const float*)d_in[15];
  const float* Wv     =(const float*)d_in[17];
  const float* W1     =(const float*)d_in[19];
  const float* W2     =(const float*)d_in[21];
  const float* filt_w =(const float*)d_in[23];
  const float* gate_w =(const float*)d_in[25];
  const float* gcn_w  =(const float*)d_in[29];

  Ctx c;
  c.bq=(const float*)d_in[14];
  c.bk=(const float*)d_in[16];
  c.bv=(const float*)d_in[18];
  c.b1=(const float*)d_in[20];
  c.b2=(const float*)d_in[22];
  c.filt_b=(const float*)d_in[24];
  c.gate_b=(const float*)d_in[26];
  c.skip_w=(const float*)d_in[27]; c.skip_b=(const float*)d_in[28];
  c.gcn_b =(const float*)d_in[30];
  c.bn_g  =(const float*)d_in[31]; c.bn_b  =(const float*)d_in[32];
  const float* end1_w =(const float*)d_in[33];
  const float* end1_b =(const float*)d_in[34];
  const float* end2_w =(const float*)d_in[35];
  const float* end2_b =(const float*)d_in[36];
  c.stream=stream;

  // workspace carve (16B-aligned)
  size_t off=0;
  auto allocF=[&](size_t nf)->float*{
    nf=(nf+3)&~(size_t)3;
    float* p=(float*)((char*)d_ws+off);
    off += nf*sizeof(float);
    return p;
  };
  auto allocU=[&](size_t nu)->unsigned short*{
    nu=(nu+7)&~(size_t)7;
    unsigned short* p=(unsigned short*)((char*)d_ws+off);
    off += nu*sizeof(unsigned short);
    return p;
  };
  const size_t HMAX =(size_t)B*C*N*T13;
  const size_t XSZ  =(size_t)B*C*N*12;
  const size_t XTSZ =(size_t)768*NP*B;
  const size_t SUPP =(size_t)NP*NP;
  const size_t ADSZ =(size_t)B*NP*NP;

  float* xf     = allocF((size_t)B*F7*N);
  float* gx1    = allocF((size_t)B*N*E);
  float* gdew   = allocF((size_t)B*N*E);
  float* gst    = allocF(16);
  c.bnst        = allocF(2*C);
  c.bnpart      = allocF(256*128);
  float* adp    = allocF((size_t)B*N*N);   // dead after k_topk; hosts hT_T overlay
  c.pH          = allocF(HMAX);
  c.pAlt        = allocF(HMAX);
  c.skipacc     = allocF((size_t)B*N*SKC);
  unsigned short* matRegion=(unsigned short*)((char*)d_ws+off);
  unsigned short* s0h = allocU(SUPP);
  unsigned short* s0l = allocU(SUPP);
  unsigned short* s1h = allocU(SUPP);
  unsigned short* s1l = allocU(SUPP);
  unsigned short* aph = allocU(SUPP);
  unsigned short* apl = allocU(SUPP);
  unsigned short* adh = allocU(ADSZ);
  unsigned short* adl = allocU(ADSZ);
  long long matRegionN = (long long)(( (unsigned short*)((char*)d_ws+off) ) - matRegion);
  c.hThi = allocU(XSZ);  c.hTlo = allocU(XSZ);
  c.Phi  = allocU(XSZ);  c.Plo  = allocU(XSZ);
  c.Qhi  = allocU(XSZ);  c.Qlo  = allocU(XSZ);
  unsigned short* qkvTh = allocU((size_t)L*12288);
  unsigned short* qkvTl = allocU((size_t)L*12288);
  unsigned short* w1Th  = allocU((size_t)L*16384);
  unsigned short* w1Tl  = allocU((size_t)L*16384);
  unsigned short* w2Th  = allocU((size_t)L*16384);
  unsigned short* w2Tl  = allocU((size_t)L*16384);
  unsigned short* cvTh  = allocU((size_t)L*16384);
  unsigned short* cvTl  = allocU((size_t)L*16384);
  unsigned short* wgh   = allocU((size_t)L*36864);
  unsigned short* wgl   = allocU((size_t)L*36864);
  if(off > ws_size){
    k_zero<<<DIVUP(out_size,256),256,0,stream>>>((float*)d_out, out_size);
    return;
  }
  c.hTth = (unsigned short*)adp;
  c.hTtl = c.hTth + XTSZ;
  {
    size_t save=off;
    c.PTh = allocU(XTSZ);
    c.PTl = allocU(XTSZ);
    if(off > ws_size){ c.PTh=nullptr; c.PTl=nullptr; off=save; }
  }
  c.qkvTh=qkvTh; c.qkvTl=qkvTl; c.w1Th=w1Th; c.w1Tl=w1Tl;
  c.w2Th=w2Th; c.w2Tl=w2Tl; c.cvTh=cvTh; c.cvTl=cvTl;
  c.wgh=wgh; c.wgl=wgl;
  c.matH[0]=s0h; c.matL[0]=s0l; c.matStride[0]=0;
  c.matH[1]=s1h; c.matL[1]=s1l; c.matStride[1]=0;
  c.matH[2]=aph; c.matL[2]=apl; c.matStride[2]=0;
  c.matH[3]=adh; c.matL[3]=adl; c.matStride[3]=(long long)NP*NP;

  // ---- graph generation + conversions ----
  k_zeroUS<<<(int)DIVUP(matRegionN,256),256,0,stream>>>(matRegion, matRegionN);
  k_cvt_qkv <<<DIVUP(L*192*64,256),256,0,stream>>>(Wq,Wk,Wv,qkvTh,qkvTl);
  k_cvt_w1  <<<DIVUP(L*256*64,256),256,0,stream>>>(W1,w1Th,w1Tl);
  k_cvt_w2  <<<DIVUP(L*64*256,256),256,0,stream>>>(W2,w2Th,w2Tl);
  k_cvt_conv<<<DIVUP(L*128*128,256),256,0,stream>>>(filt_w,gate_w,cvTh,cvTl);
  k_cvt_gcn <<<DIVUP(L*64*576,256),256,0,stream>>>(gcn_w,wgh,wgl);
  k_dft <<<DIVUP(B*F7*N,256),256,0,stream>>>(x, xf);
  k_l2f <<<DIVUP(B*N,256),256,0,stream>>>(xf);
  k_l2n <<<B*F7,256,0,stream>>>(xf);
  k_x1  <<<DIVUP(B*N,256),256,0,stream>>>(x, xf, E3, TiD, DiW, Wx, Wd, gx1);
  k_lnstats<<<B,256,0,stream>>>(gx1, gst);
  k_dew <<<DIVUP(B*N,256),256,0,stream>>>(gx1, gst, Wxabs, gdew);
  k_adp <<<DIVUP(B*N*N,256),256,0,stream>>>(gdew, gx1, adp);
  k_topk<<<(B*N)/4,256,0,stream>>>(adp, adh, adl);
  k_adap<<<N,256,0,stream>>>(E1, E2, aph, apl);
  k_cvtT<<<DIVUP(N*N,256),256,0,stream>>>(sup0, s0h, s0l);
  k_cvtT<<<DIVUP(N*N,256),256,0,stream>>>(sup1, s1h, s1l);

  // ---- trunk ----
  k_start<<<DIVUP(B*N*T13*C,256),256,0,stream>>>(x, start_w, start_b, c.pH);

  run_layer<13,1>(c,0,false);
  run_layer<12,2>(c,1,false);
  run_layer<10,1>(c,2,false);
  run_layer< 9,2>(c,3,false);
  run_layer< 7,1>(c,4,false);
  run_layer< 6,2>(c,5,false);
  run_layer< 4,1>(c,6,false);
  run_layer< 3,2>(c,7,true);

  k_head<<<B*N,512,0,stream>>>(c.skipacc, end1_w, end1_b, end2_w, end2_b, (float*)d_out);
}

// Round 14
// 4979.995 us; speedup vs baseline: 1.3032x; 1.0258x over previous
//
#include <hip/hip_runtime.h>
#include <math.h>

#define DIVUP(a,b) (((a)+(b)-1)/(b))

namespace {

constexpr int B=8, T=12, N=883, CIN=3, C=64, E=10, H=8, HD=8, TOPK=48, L=8;
constexpr int SKC=256, F7=7, T13=13;
constexpr int NP=896;   // padded N for bf16 support matrices / transposed X

typedef __attribute__((ext_vector_type(8))) short bf16x8;
typedef __attribute__((ext_vector_type(4))) float f32x4;

__device__ __forceinline__ float geluf(float x){ return 0.5f*x*(1.0f+erff(x*0.7071067811865475f)); }
__device__ __forceinline__ float sigmf(float x){ return 1.0f/(1.0f+expf(-x)); }
__device__ __forceinline__ float us2f(unsigned short u){ return __uint_as_float(((unsigned)u)<<16); }
__device__ __forceinline__ unsigned short f2us(float f){
  unsigned x=__float_as_uint(f);
  return (unsigned short)((x + 0x7fffu + ((x>>16)&1u))>>16);
}

// 16x16 output tile (single row-group)
template<int KK, int STRIDE, int KW>
__device__ __forceinline__ f32x4 tile_mm(
    const unsigned short* sAh, const unsigned short* sAl,
    const unsigned short* __restrict__ Wh, const unsigned short* __restrict__ Wl,
    int colBase, int lane, f32x4 acc){
  int lr=lane&15, lg=lane>>4;
  #pragma unroll
  for(int k0=0;k0<KK;k0+=32){
    bf16x8 ah=*(const bf16x8*)&sAh[lr*STRIDE+k0+8*lg];
    bf16x8 al=*(const bf16x8*)&sAl[lr*STRIDE+k0+8*lg];
    bf16x8 bh=*(const bf16x8*)&Wh[(size_t)(colBase+lr)*KW+k0+8*lg];
    bf16x8 bl=*(const bf16x8*)&Wl[(size_t)(colBase+lr)*KW+k0+8*lg];
    acc=__builtin_amdgcn_mfma_f32_16x16x32_bf16(ah,bh,acc,0,0,0);
    acc=__builtin_amdgcn_mfma_f32_16x16x32_bf16(ah,bl,acc,0,0,0);
    acc=__builtin_amdgcn_mfma_f32_16x16x32_bf16(al,bh,acc,0,0,0);
  }
  return acc;
}

// two 16x16 output tiles (rows 0-15 and 16-31) sharing B-fragments
template<int KK, int STRIDE, int KW>
__device__ __forceinline__ void tile_mm2(
    const unsigned short* sAh, const unsigned short* sAl,
    const unsigned short* __restrict__ Wh, const unsigned short* __restrict__ Wl,
    int colBase, int lane, f32x4& acc0, f32x4& acc1){
  int lr=lane&15, lg=lane>>4;
  #pragma unroll
  for(int k0=0;k0<KK;k0+=32){
    bf16x8 bh=*(const bf16x8*)&Wh[(size_t)(colBase+lr)*KW+k0+8*lg];
    bf16x8 bl=*(const bf16x8*)&Wl[(size_t)(colBase+lr)*KW+k0+8*lg];
    bf16x8 ah0=*(const bf16x8*)&sAh[lr*STRIDE+k0+8*lg];
    bf16x8 al0=*(const bf16x8*)&sAl[lr*STRIDE+k0+8*lg];
    bf16x8 ah1=*(const bf16x8*)&sAh[(lr+16)*STRIDE+k0+8*lg];
    bf16x8 al1=*(const bf16x8*)&sAl[(lr+16)*STRIDE+k0+8*lg];
    acc0=__builtin_amdgcn_mfma_f32_16x16x32_bf16(ah0,bh,acc0,0,0,0);
    acc0=__builtin_amdgcn_mfma_f32_16x16x32_bf16(ah0,bl,acc0,0,0,0);
    acc0=__builtin_amdgcn_mfma_f32_16x16x32_bf16(al0,bh,acc0,0,0,0);
    acc1=__builtin_amdgcn_mfma_f32_16x16x32_bf16(ah1,bh,acc1,0,0,0);
    acc1=__builtin_amdgcn_mfma_f32_16x16x32_bf16(ah1,bl,acc1,0,0,0);
    acc1=__builtin_amdgcn_mfma_f32_16x16x32_bf16(al1,bh,acc1,0,0,0);
  }
}

// ---------------- graph generation ----------------
__global__ void k_dft(const float* __restrict__ x, float* __restrict__ xf){
  int idx = blockIdx.x*256 + threadIdx.x;
  if(idx >= B*F7*N) return;
  int n = idx % N; int f = (idx/N) % F7; int b = idx/(N*F7);
  float re=0.f, im=0.f;
  for(int t=0;t<T;t++){
    float v = x[((size_t)(b*T+t)*N+n)*CIN];
    float ang = -6.283185307179586f * (float)(f*t) / 12.0f;
    re += v*cosf(ang); im += v*sinf(ang);
  }
  xf[idx] = sqrtf(re*re+im*im);
}

__global__ void k_l2f(float* __restrict__ xf){
  int idx = blockIdx.x*256 + threadIdx.x;
  if(idx >= B*N) return;
  int n = idx % N; int b = idx / N;
  float s=0.f;
  for(int f=0;f<F7;f++){ float v=xf[((size_t)b*F7+f)*N+n]; s+=v*v; }
  float inv = 1.0f/fmaxf(sqrtf(s), 1e-12f);
  for(int f=0;f<F7;f++) xf[((size_t)b*F7+f)*N+n] *= inv;
}

__global__ void k_l2n(float* __restrict__ xf){
  int bf = blockIdx.x; int tid = threadIdx.x;
  __shared__ float red[256];
  size_t base = (size_t)bf*N;
  float s=0.f;
  for(int i=tid;i<N;i+=256){ float v=xf[base+i]; s+=v*v; }
  red[tid]=s; __syncthreads();
  for(int k=128;k>0;k>>=1){ if(tid<k) red[tid]+=red[tid+k]; __syncthreads(); }
  float inv = 1.0f/fmaxf(sqrtf(red[0]), 1e-12f);
  __syncthreads();
  for(int i=tid;i<N;i+=256) xf[base+i]*=inv;
}

__global__ void k_x1(const float* __restrict__ x, const float* __restrict__ xf,
                     const float* __restrict__ E3, const float* __restrict__ TiD,
                     const float* __restrict__ DiW, const float* __restrict__ Wx,
                     const float* __restrict__ Wd, float* __restrict__ x1){
  int idx = blockIdx.x*256+threadIdx.x;
  if(idx>=B*N) return;
  int n=idx%N, b=idx/N;
  float xc[40];
  for(int d=0;d<E;d++){
    float a=0.f;
    for(int f=0;f<F7;f++) a += xf[((size_t)b*F7+f)*N+n]*Wx[f*E+d];
    xc[d]=a;
  }
  for(int d=0;d<E;d++) xc[10+d]=E3[n*E+d];
  int ti = (int)(x[((size_t)(b*T+(T-1))*N+n)*CIN+1]*288.0f);
  int dw = (int)(x[((size_t)(b*T+(T-1))*N+n)*CIN+2]);
  for(int d=0;d<E;d++) xc[20+d]=TiD[ti*E+d];
  for(int d=0;d<E;d++) xc[30+d]=DiW[dw*E+d];
  for(int e=0;e<E;e++){
    float a=0.f;
    for(int f=0;f<40;f++) a += xc[f]*Wd[((size_t)n*40+f)*E+e];
    x1[(size_t)idx*E+e]=fmaxf(a,0.f);
  }
}

__global__ void k_lnstats(const float* __restrict__ x1, float* __restrict__ st){
  int b=blockIdx.x, tid=threadIdx.x;
  __shared__ float rs[256], rq[256];
  const int M=N*E;
  float s=0.f,q=0.f;
  for(int i=tid;i<M;i+=256){ float v=x1[(size_t)b*M+i]; s+=v; q+=v*v; }
  rs[tid]=s; rq[tid]=q; __syncthreads();
  for(int k=128;k>0;k>>=1){ if(tid<k){ rs[tid]+=rs[tid+k]; rq[tid]+=rq[tid+k]; } __syncthreads(); }
  if(tid==0){ float mu=rs[0]/M; float var=rq[0]/M-mu*mu; st[b*2]=mu; st[b*2+1]=var; }
}

__global__ void k_dew(const float* __restrict__ x1, const float* __restrict__ st,
                      const float* __restrict__ Wxabs, float* __restrict__ dew){
  int idx=blockIdx.x*256+threadIdx.x;
  if(idx>=B*N) return;
  int b=idx/N;
  float mu=st[b*2], var=st[b*2+1];
  float rs=rsqrtf(var+1e-8f);
  float xk[E];
  for(int e=0;e<E;e++) xk[e]=(x1[(size_t)idx*E+e]-mu)*rs;
  for(int k=0;k<E;k++){
    float a=0.f;
    for(int e=0;e<E;e++) a+=xk[e]*Wxabs[e*E+k];
    dew[(size_t)idx*E+k]=a;
  }
}

__global__ void k_adp(const float* __restrict__ dew, const float* __restrict__ x1,
                      float* __restrict__ adp){
  size_t idx=(size_t)blockIdx.x*256+threadIdx.x;
  if(idx>=(size_t)B*N*N) return;
  int m=(int)(idx%N); int n=(int)((idx/N)%N); int b=(int)(idx/((size_t)N*N));
  const float* dr=dew+((size_t)b*N+n)*E;
  const float* xr=x1+((size_t)b*N+m)*E;
  float a=0.f;
  for(int k=0;k<E;k++) a+=dr[k]*xr[k];
  adp[idx]=fmaxf(a,0.f);
}

// wave-per-row top-48 + masked softmax -> bf16 hi/lo padded AD mats; zero barriers.
__global__ __launch_bounds__(256) void k_topk(const float* __restrict__ adp,
                       unsigned short* __restrict__ ADhi, unsigned short* __restrict__ ADlo){
  int row = blockIdx.x*4 + (threadIdx.x>>6);
  int lane = threadIdx.x & 63;
  const float* rp = adp + (size_t)row*N;
  float v[14];
  #pragma unroll
  for(int j=0;j<14;j++){
    int i = lane + j*64;
    v[j] = (i<N) ? rp[i] : -1.f;
  }
  unsigned sel = 0u;
  float m0 = 0.f;
  for(int k=0;k<TOPK;k++){
    float bv = -2.f; int bi = 1<<20;
    #pragma unroll
    for(int j=0;j<14;j++){
      if(!((sel>>j)&1u) && v[j] > bv){ bv = v[j]; bi = lane + j*64; }
    }
    #pragma unroll
    for(int off=1; off<64; off<<=1){
      float ov = __shfl_xor(bv, off);
      int   oi = __shfl_xor(bi, off);
      if(ov > bv || (ov==bv && oi<bi)){ bv=ov; bi=oi; }
    }
    if(k==0) m0 = bv;
    if((bi&63)==lane) sel |= 1u << (bi>>6);
  }
  float pv[14];
  float ls = 0.f;
  #pragma unroll
  for(int j=0;j<14;j++){
    int i = lane + j*64;
    float p = ((sel>>j)&1u) ? v[j] : 0.f;
    pv[j] = p;
    if(i<N) ls += expf(p - m0);
  }
  #pragma unroll
  for(int off=1; off<64; off<<=1) ls += __shfl_xor(ls, off);
  float invZ = 1.f/ls;
  size_t base = ((size_t)(row/N)*NP + (size_t)(row%N))*NP;
  #pragma unroll
  for(int j=0;j<14;j++){
    int i = lane + j*64;
    if(i<N){
      float f = expf(pv[j]-m0)*invZ;
      unsigned short h=f2us(f);
      ADhi[base+i]=h; ADlo[base+i]=f2us(f-us2f(h));
    }
  }
}

__global__ void k_adap(const float* __restrict__ E1, const float* __restrict__ E2,
                       unsigned short* __restrict__ Mh, unsigned short* __restrict__ Ml){
  int v=blockIdx.x, tid=threadIdx.x;
  __shared__ float rowv[N];
  __shared__ float rv[256];
  float e1[E];
  for(int e=0;e<E;e++) e1[e]=E1[v*E+e];
  for(int j=tid;j<N;j+=256){
    float s=0.f;
    for(int e=0;e<E;e++) s+=e1[e]*E2[j*E+e];
    rowv[j]=fmaxf(s,0.f);
  }
  __syncthreads();
  float lm=-1e30f;
  for(int j=tid;j<N;j+=256) lm=fmaxf(lm,rowv[j]);
  rv[tid]=lm; __syncthreads();
  for(int s=128;s>0;s>>=1){ if(tid<s) rv[tid]=fmaxf(rv[tid],rv[tid+s]); __syncthreads(); }
  float m=rv[0]; __syncthreads();
  float ls=0.f;
  for(int j=tid;j<N;j+=256) ls+=expf(rowv[j]-m);
  rv[tid]=ls; __syncthreads();
  for(int s=128;s>0;s>>=1){ if(tid<s) rv[tid]+=rv[tid+s]; __syncthreads(); }
  float invZ=1.0f/rv[0];
  for(int j=tid;j<N;j+=256){
    float f=expf(rowv[j]-m)*invZ;
    unsigned short h=f2us(f);
    Mh[(size_t)j*NP+v]=h; Ml[(size_t)j*NP+v]=f2us(f-us2f(h));
  }
}

__global__ void k_cvtT(const float* __restrict__ A, unsigned short* __restrict__ Mh,
                       unsigned short* __restrict__ Ml){
  int idx=blockIdx.x*256+threadIdx.x;
  if(idx>=N*N) return;
  int w=idx/N, v=idx%N;
  float f=A[(size_t)v*N+w];
  unsigned short h=f2us(f);
  Mh[(size_t)w*NP+v]=h;
  Ml[(size_t)w*NP+v]=f2us(f-us2f(h));
}

// ---- weight transpose+split conversions (run once) ----
__global__ void k_cvt_qkv(const float* __restrict__ Wq, const float* __restrict__ Wk,
                          const float* __restrict__ Wv,
                          unsigned short* __restrict__ dh, unsigned short* __restrict__ dl){
  int idx=blockIdx.x*256+threadIdx.x;
  if(idx>=L*192*64) return;
  int l=idx/12288, rem=idx%12288, col=rem/64, k=rem%64;
  int mat=col>>6, o=col&63;
  const float* W=(mat==0)?Wq:((mat==1)?Wk:Wv);
  float v=W[(size_t)l*4096 + k*64 + o];
  unsigned short h=f2us(v);
  dh[idx]=h; dl[idx]=f2us(v-us2f(h));
}
__global__ void k_cvt_w1(const float* __restrict__ W1,
                         unsigned short* __restrict__ dh, unsigned short* __restrict__ dl){
  int idx=blockIdx.x*256+threadIdx.x;
  if(idx>=L*256*64) return;
  int l=idx/16384, rem=idx%16384, col=rem/64, k=rem%64;
  float v=W1[(size_t)l*16384 + k*256 + col];
  unsigned short h=f2us(v);
  dh[idx]=h; dl[idx]=f2us(v-us2f(h));
}
__global__ void k_cvt_w2(const float* __restrict__ W2,
                         unsigned short* __restrict__ dh, unsigned short* __restrict__ dl){
  int idx=blockIdx.x*256+threadIdx.x;
  if(idx>=L*64*256) return;
  int l=idx/16384, rem=idx%16384, col=rem/256, k=rem%256;
  float v=W2[(size_t)l*16384 + k*64 + col];
  unsigned short h=f2us(v);
  dh[idx]=h; dl[idx]=f2us(v-us2f(h));
}
__global__ void k_cvt_conv(const float* __restrict__ fw, const float* __restrict__ gw,
                           unsigned short* __restrict__ dh, unsigned short* __restrict__ dl){
  int idx=blockIdx.x*256+threadIdx.x;
  if(idx>=L*128*128) return;
  int l=idx/16384, rem=idx%16384, col=rem/128, k=rem%128;
  int c=col&63, fg=col>>6, tap=k>>6, i=k&63;
  const float* W=fg?gw:fw;
  float v=W[(size_t)l*8192 + tap*4096 + i*64 + c];
  unsigned short h=f2us(v);
  dh[idx]=h; dl[idx]=f2us(v-us2f(h));
}
// gcn_w (L,576,64) -> [l][o][k=576] bf16 split
__global__ void k_cvt_gcn(const float* __restrict__ Wg,
                          unsigned short* __restrict__ dh, unsigned short* __restrict__ dl){
  int idx=blockIdx.x*256+threadIdx.x;
  if(idx>=L*64*576) return;
  int l=idx/36864, rem=idx%36864, o=rem/576, k=rem%576;
  float v=Wg[((size_t)l*576 + k)*64 + o];
  unsigned short h=f2us(v);
  dh[idx]=h; dl[idx]=f2us(v-us2f(h));
}

__global__ void k_zero(float* __restrict__ p, int n){
  int idx=blockIdx.x*256+threadIdx.x;
  if(idx<n) p[idx]=0.f;
}
__global__ void k_zeroUS(unsigned short* __restrict__ p, long long n){
  long long idx=(long long)blockIdx.x*256+threadIdx.x;
  if(idx<n) p[idx]=0;
}

// tiled transpose: S [b][n<N][m<M] (split bf16 pair) -> D [b][m][v<NP]
__global__ __launch_bounds__(256) void k_trx(
    const unsigned short* __restrict__ Sh, const unsigned short* __restrict__ Sl,
    unsigned short* __restrict__ Dh, unsigned short* __restrict__ Dl, int M){
  __shared__ unsigned short th[64][66], tl[64][66];
  int b=blockIdx.z;
  int m0=blockIdx.x*64, n0=blockIdx.y*64;
  int tid=threadIdx.x;
  const unsigned short* sbh=Sh + (size_t)b*N*M;
  const unsigned short* sbl=Sl + (size_t)b*N*M;
  for(int idx=tid; idx<64*64; idx+=256){
    int i=idx>>6, j=idx&63;
    int n=n0+i;
    unsigned short vh=0, vl=0;
    if(n<N){
      size_t o=(size_t)n*M + m0+j;
      vh=sbh[o]; vl=sbl[o];
    }
    th[j][i]=vh; tl[j][i]=vl;
  }
  __syncthreads();
  unsigned short* dbh=Dh + (size_t)b*M*NP;
  unsigned short* dbl=Dl + (size_t)b*M*NP;
  for(int idx=tid; idx<64*64; idx+=256){
    int r=idx>>6, cc=idx&63;
    size_t o=(size_t)(m0+r)*NP + n0+cc;
    dbh[o]=th[r][cc]; dbl[o]=tl[r][cc];
  }
}

// ---------------- trunk ----------------
// h layout: [b][n][t][c]
__global__ void k_start(const float* __restrict__ x, const float* __restrict__ sw,
                        const float* __restrict__ sb, float* __restrict__ h){
  int idx=blockIdx.x*256+threadIdx.x;
  if(idx>=B*N*T13*C) return;
  int c=idx&63; int t=(idx>>6)%T13; int n=(idx/(64*T13))%N; int b=idx/(64*T13*N);
  float a=sb[c];
  if(t>0){
    size_t xb=((size_t)(b*T+(t-1))*N+n)*CIN;
    for(int i=0;i<CIN;i++) a += sw[i*C+c]*x[xb+i];
  }
  h[idx]=a;
}

// Fused 2-node MFMA transformer block; hin [b][n][t][c] (BN fused if bng!=0).
// 32-row A tiles; tile_mm2 shares B-fragments across the 2 nodes. 50KB LDS arena.
template<int TC, int D>
__global__ __launch_bounds__(256) void k_attconv(const float* __restrict__ hin,
  const unsigned short* __restrict__ Wqkvh, const unsigned short* __restrict__ Wqkvl,
  const unsigned short* __restrict__ W1h,   const unsigned short* __restrict__ W1l,
  const unsigned short* __restrict__ W2h,   const unsigned short* __restrict__ W2l,
  const unsigned short* __restrict__ Wch,   const unsigned short* __restrict__ Wcl,
  const float* __restrict__ bq, const float* __restrict__ bk, const float* __restrict__ bv,
  const float* __restrict__ b1, const float* __restrict__ b2,
  const float* __restrict__ fb, const float* __restrict__ gb,
  const float* __restrict__ skw, const float* __restrict__ skb,
  const float* __restrict__ bnst, const float* __restrict__ bng, const float* __restrict__ bnb,
  unsigned short* __restrict__ hThi, unsigned short* __restrict__ hTlo,
  float* __restrict__ skipacc, int first){
  constexpr int TN = TC - D;
  int bn0=blockIdx.x*2; int tid=threadIdx.x;
  int lane=tid&63, wid=tid>>6;
  int lr=lane&15, lg=lane>>4;
  __shared__ __align__(16) char smem[51200];
  float* sxa=(float*)smem;                                   // [32][64] 8KB
  unsigned short* sA1h=(unsigned short*)(smem+8192);         // [32][72]
  unsigned short* sA1l=(unsigned short*)(smem+12800);        // ends 17408
  float* sq =(float*)(smem+17408);                           // [32][64] (P2-3)
  float* sk_=(float*)(smem+25600);
  float* sv =(float*)(smem+33792);                           // ends 41984
  unsigned short* sA2h=(unsigned short*)(smem+17408);        // [32][264] (P4-5)
  unsigned short* sA2l=(unsigned short*)(smem+34304);        // ends 51200
  float* xcf=(float*)smem;                                   // [32][64] over sxa (P5 out)
  unsigned short* cAh=(unsigned short*)(smem+17408);         // [32][136] (P6+)
  unsigned short* cAl=(unsigned short*)(smem+26112);         // ends 34816
  float* sfg=(float*)(smem+34816);                           // [32][128] ends 51200 (P7+)
  float* stg=(float*)smem;                                   // [2][64] over sxa (P8+)

  // phase 1: contiguous staging of 2 nodes, BN fused
  const float* hp = hin + (size_t)bn0*TC*64;
  for(int idx=tid; idx<2*TC*64; idx+=256){
    int ni=idx/(TC*64); int rem=idx%(TC*64);
    int t=rem>>6, c=rem&63;
    float v=hp[idx];
    if(bng) v=(v-bnst[c])*bnst[64+c]*bng[c]+bnb[c];
    int row=ni*16+t;
    sxa[row*64+c]=v;
    unsigned short h=f2us(v);
    sA1h[row*72+c]=h; sA1l[row*72+c]=f2us(v-us2f(h));
  }
  for(int idx=tid; idx<2*(16-TC)*64; idx+=256){
    int pr=idx>>6, c=idx&63;
    int ni=pr/(16-TC), tp=TC+pr%(16-TC);
    int row=ni*16+tp;
    sxa[row*64+c]=0.f; sA1h[row*72+c]=0; sA1l[row*72+c]=0;
  }
  __syncthreads();

  // phase 2: QKV + bias + gelu (12 col-tiles, shared B)
  #pragma unroll
  for(int it=0; it<3; ++it){
    int tile=it*4+wid;
    f32x4 a0={0.f,0.f,0.f,0.f}, a1={0.f,0.f,0.f,0.f};
    tile_mm2<64,72,64>(sA1h,sA1l,Wqkvh,Wqkvl,tile*16,lane,a0,a1);
    int col=tile*16+lr; int mat=col>>6, o=col&63;
    const float* bm=(mat==0)?bq:((mat==1)?bk:bv);
    float* dst=(mat==0)?sq:((mat==1)?sk_:sv);
    float bias=bm[o];
    #pragma unroll
    for(int r=0;r<4;r++){
      int t=lg*4+r;
      if(t<TC){
        dst[t*64+o]      =geluf(a0[r]+bias);
        dst[(16+t)*64+o] =geluf(a1[r]+bias);
      }
    }
  }
  __syncthreads();

  // phase 3: causal attention (both nodes) -> split bf16 into sA1
  if(tid<2*H*TC){
    int ni=tid/(H*TC); int rr=tid%(H*TC);
    int hh=rr/TC, t=rr%TC;
    int rb=ni*16;
    const float* qr=&sq[(rb+t)*64+hh*HD];
    float att[TC];
    float m=-1e30f;
    #pragma unroll
    for(int s=0;s<TC;s++){
      float a=0.f;
      #pragma unroll
      for(int d=0;d<HD;d++) a+=qr[d]*sk_[(rb+s)*64+hh*HD+d];
      a*=0.3535533905932738f;
      a=(s<=t)?a:-1e30f;
      att[s]=a; m=fmaxf(m,a);
    }
    float Z=0.f;
    #pragma unroll
    for(int s=0;s<TC;s++){ float e=expf(att[s]-m); att[s]=e; Z+=e; }
    float invZ=1.0f/Z;
    #pragma unroll
    for(int d=0;d<HD;d++){
      float o=0.f;
      #pragma unroll
      for(int s=0;s<TC;s++) o+=att[s]*sv[(rb+s)*64+hh*HD+d];
      float v=o*invZ;
      unsigned short h=f2us(v);
      sA1h[(rb+t)*72+hh*8+d]=h; sA1l[(rb+t)*72+hh*8+d]=f2us(v-us2f(h));
    }
  }
  __syncthreads();

  // phase 4: FFN1 + bias + gelu -> split bf16 sA2 (stride 264)
  #pragma unroll
  for(int it=0; it<4; ++it){
    int tile=it*4+wid;
    f32x4 a0={0.f,0.f,0.f,0.f}, a1={0.f,0.f,0.f,0.f};
    tile_mm2<64,72,64>(sA1h,sA1l,W1h,W1l,tile*16,lane,a0,a1);
    int col=tile*16+lr;
    float bias=b1[col];
    #pragma unroll
    for(int r=0;r<4;r++){
      int t=lg*4+r;
      float v0=(t<TC)?geluf(a0[r]+bias):0.f;
      float v1=(t<TC)?geluf(a1[r]+bias):0.f;
      unsigned short h0=f2us(v0), h1=f2us(v1);
      sA2h[t*264+col]=h0;      sA2l[t*264+col]=f2us(v0-us2f(h0));
      sA2h[(16+t)*264+col]=h1; sA2l[(16+t)*264+col]=f2us(v1-us2f(h1));
    }
  }
  __syncthreads();

  // phase 5: FFN2 + bias + residual -> xcf (over dead sxa; same-thread RMW)
  {
    int tile=wid;
    f32x4 a0={0.f,0.f,0.f,0.f}, a1={0.f,0.f,0.f,0.f};
    tile_mm2<256,264,256>(sA2h,sA2l,W2h,W2l,tile*16,lane,a0,a1);
    int col=tile*16+lr;
    float bias=b2[col];
    #pragma unroll
    for(int r=0;r<4;r++){
      int t=lg*4+r;
      if(t<TC){
        xcf[t*64+col]     =a0[r]+bias+sxa[t*64+col];
        xcf[(16+t)*64+col]=a1[r]+bias+sxa[(16+t)*64+col];
      }
    }
  }
  __syncthreads();

  // phase 6: build conv A [32][136] split bf16 (over dead sA2 region)
  for(int idx=tid; idx<32*128; idx+=256){
    int row=idx>>7, k=idx&127;
    int ni=row>>4, t=row&15;
    int c=k&63;
    float v=0.f;
    if(t<TN) v=xcf[(ni*16+((k<64)?t:(t+D)))*64+c];
    unsigned short h=f2us(v);
    cAh[row*136+k]=h; cAl[row*136+k]=f2us(v-us2f(h));
  }
  __syncthreads();

  // phase 7: conv + bias + activation -> sfg [32][128]
  #pragma unroll
  for(int it=0; it<2; ++it){
    int tile=it*4+wid;
    f32x4 a0={0.f,0.f,0.f,0.f}, a1={0.f,0.f,0.f,0.f};
    tile_mm2<128,136,128>(cAh,cAl,Wch,Wcl,tile*16,lane,a0,a1);
    int col=tile*16+lr;
    float bias=(col<64)?fb[col]:gb[col&63];
    #pragma unroll
    for(int r=0;r<4;r++){
      int t=lg*4+r;
      float v0=a0[r]+bias, v1=a1[r]+bias;
      sfg[t*128+col]     =(col<64)?tanhf(v0):sigmf(v0);
      sfg[(16+t)*128+col]=(col<64)?tanhf(v1):sigmf(v1);
    }
  }
  __syncthreads();

  // phase 8: last-column conv output for skip (both nodes)
  if(tid<2*C){
    int ni=tid>>6, c=tid&63;
    stg[ni*64+c]=sfg[(ni*16+TN-1)*128+c]*sfg[(ni*16+TN-1)*128+64+c];
  }
  __syncthreads();

  // phase 9: skip projection (contiguous [bn][256], 2 nodes) + hT write
  for(int idx=tid; idx<2*SKC; idx+=256){
    int ni=idx>>8, o=idx&255;
    float a=skb[o];
    for(int i=0;i<C;i++) a+=stg[ni*64+i]*skw[i*SKC+o];
    size_t so_=(size_t)(bn0+ni)*SKC+o;
    if(first) skipacc[so_]=a; else skipacc[so_]+=a;
  }
  size_t obase=(size_t)bn0*64*TN;
  for(int idx=tid; idx<2*TN*64; idx+=256){
    int ni=idx/(TN*64); int rem=idx%(TN*64);
    int tt=rem>>6, c=rem&63;
    float v=sfg[(ni*16+tt)*128+c]*sfg[(ni*16+tt)*128+64+c];
    unsigned short h=f2us(v);
    hThi[obase+idx]=h;
    hTlo[obase+idx]=f2us(v-us2f(h));
  }
}

// ---- MFMA spatial GEMM: TRx64 tile (TR in {128,64}); waves own 16*(TR/64) rows x 64 cols ----
template<int TR>
__global__ __launch_bounds__(256) void k_spatmm(
    const unsigned short* __restrict__ Ah, const unsigned short* __restrict__ Al,
    long long aStride,
    const unsigned short* __restrict__ Xh, const unsigned short* __restrict__ Xl,
    const unsigned short* __restrict__ XTh, const unsigned short* __restrict__ XTl,
    int xT,
    unsigned short* __restrict__ Yh, unsigned short* __restrict__ Yl,
    unsigned short* __restrict__ YTh, unsigned short* __restrict__ YTl,
    int M){
  constexpr int NJ = TR/64;   // j-tiles per wave
  __shared__ unsigned short sAh[TR*40];
  __shared__ unsigned short sAl[TR*40];
  __shared__ unsigned short sXh[64*40];
  __shared__ unsigned short sXl[64*40];
  int b=blockIdx.z;
  const unsigned short* Abh=Ah+(size_t)b*aStride;
  const unsigned short* Abl=Al+(size_t)b*aStride;
  int tid=threadIdx.x;
  int w0=blockIdx.x*TR, c0=blockIdx.y*64;
  int lane=tid&63, wid=tid>>6;
  int lr=lane&15, lg=lane>>4;
  f32x4 acc[NJ][4];
  #pragma unroll
  for(int j=0;j<NJ;j++){
    #pragma unroll
    for(int i=0;i<4;i++){ acc[j][i][0]=0.f; acc[j][i][1]=0.f; acc[j][i][2]=0.f; acc[j][i][3]=0.f; }
  }
  const int xr=tid>>2,  xkb=(tid&3)*8;    // XT path: 64 cols, 4 thr/col
  const int xk=tid>>3,  xcb=(tid&7)*8;    // scatter path
  const int xkx=xk ^ (8*((xcb>>3)&3));
  for(int k0=0;k0<N;k0+=32){
    if(TR==128){
      int ar=tid>>1, akb=(tid&1)*16;
      uint4 qh0=*(const uint4*)&Abh[(size_t)(w0+ar)*NP + k0+akb];
      uint4 qh1=*(const uint4*)&Abh[(size_t)(w0+ar)*NP + k0+akb+8];
      uint4 ql0=*(const uint4*)&Abl[(size_t)(w0+ar)*NP + k0+akb];
      uint4 ql1=*(const uint4*)&Abl[(size_t)(w0+ar)*NP + k0+akb+8];
      *(uint4*)&sAh[ar*40+akb]=qh0;   *(uint4*)&sAh[ar*40+akb+8]=qh1;
      *(uint4*)&sAl[ar*40+akb]=ql0;   *(uint4*)&sAl[ar*40+akb+8]=ql1;
    }else{
      int ar=tid>>2, akb=(tid&3)*8;
      uint4 qh=*(const uint4*)&Abh[(size_t)(w0+ar)*NP + k0+akb];
      uint4 ql=*(const uint4*)&Abl[(size_t)(w0+ar)*NP + k0+akb];
      *(uint4*)&sAh[ar*40+akb]=qh;
      *(uint4*)&sAl[ar*40+akb]=ql;
    }
    if(xT){
      const unsigned short* Xbth=XTh+(size_t)b*M*NP;
      const unsigned short* Xbtl=XTl+(size_t)b*M*NP;
      uint4 qh=*(const uint4*)&Xbth[(size_t)(c0+xr)*NP + k0+xkb];
      uint4 ql=*(const uint4*)&Xbtl[(size_t)(c0+xr)*NP + k0+xkb];
      *(uint4*)&sXh[xr*40+xkb]=qh;
      *(uint4*)&sXl[xr*40+xkb]=ql;
    }else{
      const unsigned short* Xbh=Xh+(size_t)b*N*M;
      const unsigned short* Xbl=Xl+(size_t)b*N*M;
      uint4 qh={0,0,0,0}, ql={0,0,0,0};
      if(k0+xk<N){
        qh=*(const uint4*)&Xbh[(size_t)(k0+xk)*M + c0+xcb];
        ql=*(const uint4*)&Xbl[(size_t)(k0+xk)*M + c0+xcb];
      }
      unsigned short uh[8], ul[8];
      uh[0]=(unsigned short)(qh.x&0xffff); uh[1]=(unsigned short)(qh.x>>16);
      uh[2]=(unsigned short)(qh.y&0xffff); uh[3]=(unsigned short)(qh.y>>16);
      uh[4]=(unsigned short)(qh.z&0xffff); uh[5]=(unsigned short)(qh.z>>16);
      uh[6]=(unsigned short)(qh.w&0xffff); uh[7]=(unsigned short)(qh.w>>16);
      ul[0]=(unsigned short)(ql.x&0xffff); ul[1]=(unsigned short)(ql.x>>16);
      ul[2]=(unsigned short)(ql.y&0xffff); ul[3]=(unsigned short)(ql.y>>16);
      ul[4]=(unsigned short)(ql.z&0xffff); ul[5]=(unsigned short)(ql.z>>16);
      ul[6]=(unsigned short)(ql.w&0xffff); ul[7]=(unsigned short)(ql.w>>16);
      #pragma unroll
      for(int j=0;j<8;j++){
        sXh[(xcb+j)*40+xkx]=uh[j];
        sXl[(xcb+j)*40+xkx]=ul[j];
      }
    }
    __syncthreads();
    bf16x8 a_h[NJ], a_l[NJ], x_h[4], x_l[4];
    #pragma unroll
    for(int j=0;j<NJ;j++){
      int r=16*NJ*wid+16*j+lr;
      a_h[j]=*(const bf16x8*)&sAh[r*40+8*lg];
      a_l[j]=*(const bf16x8*)&sAl[r*40+8*lg];
    }
    #pragma unroll
    for(int i=0;i<4;i++){
      int cc=16*i+lr;
      int g = xT ? lg : (lg ^ ((cc>>3)&3));
      x_h[i]=*(const bf16x8*)&sXh[cc*40+8*g];
      x_l[i]=*(const bf16x8*)&sXl[cc*40+8*g];
    }
    #pragma unroll
    for(int j=0;j<NJ;j++){
      #pragma unroll
      for(int i=0;i<4;i++){
        acc[j][i]=__builtin_amdgcn_mfma_f32_16x16x32_bf16(a_h[j],x_h[i],acc[j][i],0,0,0);
        acc[j][i]=__builtin_amdgcn_mfma_f32_16x16x32_bf16(a_h[j],x_l[i],acc[j][i],0,0,0);
        acc[j][i]=__builtin_amdgcn_mfma_f32_16x16x32_bf16(a_l[j],x_h[i],acc[j][i],0,0,0);
      }
    }
    __syncthreads();
  }
  #pragma unroll
  for(int j=0;j<NJ;j++){
    int rbase=w0+16*NJ*wid+16*j+lg*4;
    #pragma unroll
    for(int i=0;i<4;i++){
      int col=c0+16*i+lr;
      unsigned short hh[4], ll[4];
      #pragma unroll
      for(int r=0;r<4;r++){
        float v=acc[j][i][r];
        hh[r]=f2us(v);
        ll[r]=f2us(v-us2f(hh[r]));
      }
      #pragma unroll
      for(int r=0;r<4;r++){
        int row=rbase+r;
        if(row<N){
          size_t o=((size_t)b*N+row)*M+col;
          Yh[o]=hh[r]; Yl[o]=ll[r];
        }
      }
      if(YTh){
        size_t o=(size_t)b*M*NP + (size_t)col*NP + rbase;
        ushort4 ph; ph.x=hh[0]; ph.y=hh[1]; ph.z=hh[2]; ph.w=hh[3];
        ushort4 pl; pl.x=ll[0]; pl.y=ll[1]; pl.z=ll[2]; pl.w=ll[3];
        *(ushort4*)&YTh[o]=ph;
        *(ushort4*)&YTl[o]=pl;
      }
    }
  }
}

// ---- MFMA GCN projection (residual BN fused) ----
template<int TN, int FIRST>
__global__ __launch_bounds__(256) void k_gcnmm(
    const unsigned short* __restrict__ S0h, const unsigned short* __restrict__ S0l,
    const unsigned short* __restrict__ S1h, const unsigned short* __restrict__ S1l,
    const unsigned short* __restrict__ S2h, const unsigned short* __restrict__ S2l,
    const unsigned short* __restrict__ Wbh, const unsigned short* __restrict__ Wbl,
    int kOff,
    const float* __restrict__ gb, const float* __restrict__ res,
    const float* __restrict__ bnst, const float* __restrict__ bng, const float* __restrict__ bnb,
    float* __restrict__ acc, int Tc){
  constexpr int SL=64*TN;
  constexpr int NS=FIRST?3:2;
  constexpr int KK=NS*64;
  __shared__ unsigned short sAh[64*40], sAl[64*40];
  int bn0=blockIdx.x*4;
  int tid=threadIdx.x, lane=tid&63, wid=tid>>6;
  int lr=lane&15, lg=lane>>4;
  f32x4 a4[4];
  #pragma unroll
  for(int rt=0;rt<4;rt++){ a4[rt][0]=0.f; a4[rt][1]=0.f; a4[rt][2]=0.f; a4[rt][3]=0.f; }
  const int ar=tid>>2, akb=(tid&3)*8;
  const int ani=ar>>4, att_=ar&15;
  #pragma unroll
  for(int kc=0; kc<KK/32; ++kc){
    int k0=kc*32; int j=k0>>6; int i0=k0&63;
    const unsigned short* sh=(j==0)?S0h:((j==1)?S1h:S2h);
    const unsigned short* sl=(j==0)?S0l:((j==1)?S1l:S2l);
    uint4 qh={0,0,0,0}, ql={0,0,0,0};
    if(att_<TN){
      size_t o=(size_t)(bn0+ani)*SL + att_*64 + i0 + akb;
      qh=*(const uint4*)&sh[o]; ql=*(const uint4*)&sl[o];
    }
    *(uint4*)&sAh[ar*40+akb]=qh;
    *(uint4*)&sAl[ar*40+akb]=ql;
    __syncthreads();
    bf16x8 bh=*(const bf16x8*)&Wbh[(size_t)(wid*16+lr)*576 + kOff + k0 + 8*lg];
    bf16x8 bl=*(const bf16x8*)&Wbl[(size_t)(wid*16+lr)*576 + kOff + k0 + 8*lg];
    #pragma unroll
    for(int rt=0;rt<4;rt++){
      bf16x8 ah=*(const bf16x8*)&sAh[(rt*16+lr)*40+8*lg];
      bf16x8 al=*(const bf16x8*)&sAl[(rt*16+lr)*40+8*lg];
      a4[rt]=__builtin_amdgcn_mfma_f32_16x16x32_bf16(ah,bh,a4[rt],0,0,0);
      a4[rt]=__builtin_amdgcn_mfma_f32_16x16x32_bf16(ah,bl,a4[rt],0,0,0);
      a4[rt]=__builtin_amdgcn_mfma_f32_16x16x32_bf16(al,bh,a4[rt],0,0,0);
    }
    __syncthreads();
  }
  int o=wid*16+lr;
  #pragma unroll
  for(int rt=0;rt<4;rt++){
    int bn=bn0+rt;
    #pragma unroll
    for(int r=0;r<4;r++){
      int t2=lg*4+r;
      if(t2<TN){
        size_t oi=((size_t)bn*TN + t2)*64 + o;
        float v=a4[rt][r];
        if(FIRST){
          float rr=res[((size_t)bn*Tc + (Tc-TN) + t2)*64 + o];
          if(bng) rr=(rr-bnst[o])*bnst[64+o]*bng[o]+bnb[o];
          v += gb[o] + rr;
          acc[oi]=v;
        }else{
          acc[oi]+=v;
        }
      }
    }
  }
}

// BN stats (layout [b][n][tt][c]), two-stage
__global__ __launch_bounds__(256) void k_bnstats1(const float* __restrict__ h,
                                                  float* __restrict__ part, int R){
  int tid=threadIdx.x;
  int c=tid&63, rg=tid>>6;
  float s=0.f,q=0.f;
  for(int r=blockIdx.x*4+rg; r<R; r+=1024){
    float v=h[(size_t)r*64+c];
    s+=v; q+=v*v;
  }
  __shared__ float ls[256], lq[256];
  ls[tid]=s; lq[tid]=q; __syncthreads();
  if(rg==0){
    s=ls[c]+ls[64+c]+ls[128+c]+ls[192+c];
    q=lq[c]+lq[64+c]+lq[128+c]+lq[192+c];
    part[blockIdx.x*128+c]=s;
    part[blockIdx.x*128+64+c]=q;
  }
}
__global__ __launch_bounds__(256) void k_bnstats2(const float* __restrict__ part,
                                                  float* __restrict__ st, int R){
  int tid=threadIdx.x;
  int c=tid&63, g=tid>>6;
  float s=0.f,q=0.f;
  for(int p=g;p<256;p+=4){ s+=part[p*128+c]; q+=part[p*128+64+c]; }
  __shared__ float ls[256], lq[256];
  ls[tid]=s; lq[tid]=q; __syncthreads();
  if(g==0){
    s=ls[c]+ls[64+c]+ls[128+c]+ls[192+c];
    q=lq[c]+lq[64+c]+lq[128+c]+lq[192+c];
    float mu=s/R;
    float var=q/R-mu*mu;
    st[c]=mu; st[64+c]=rsqrtf(var+1e-5f);
  }
}

__global__ void k_head(const float* __restrict__ skipacc, const float* __restrict__ W1,
  const float* __restrict__ b1, const float* __restrict__ W2, const float* __restrict__ b2,
  float* __restrict__ out){
  int gid=blockIdx.x; int tid=threadIdx.x;  // 512 threads
  int n=gid%N; int b=gid/N;
  __shared__ float s[SKC];
  __shared__ float hid[512];
  if(tid<SKC){
    float v=skipacc[(size_t)gid*SKC+tid];
    s[tid]=fmaxf(v,0.f);
  }
  __syncthreads();
  {
    float a=b1[tid];
    for(int i=0;i<SKC;i++) a+=s[i]*W1[(size_t)i*512+tid];
    hid[tid]=fmaxf(a,0.f);
  }
  __syncthreads();
  if(tid<T){
    float a=b2[tid];
    for(int j=0;j<512;j++) a+=hid[j]*W2[(size_t)j*T+tid];
    out[((size_t)b*T+tid)*N+n]=a;
  }
}

// ---------------- host-side layer driver ----------------
struct Ctx {
  const float *bq,*bk,*bv,*b1,*b2,*filt_b,*gate_b,*skip_w,*skip_b,*gcn_b,*bn_g,*bn_b;
  const unsigned short *qkvTh,*qkvTl,*w1Th,*w1Tl,*w2Th,*w2Tl,*cvTh,*cvTl,*wgh,*wgl;
  const unsigned short* matH[4];
  const unsigned short* matL[4];
  long long matStride[4];
  float *pH,*pAlt,*skipacc,*bnst,*bnpart;
  unsigned short *hThi,*hTlo,*Phi,*Plo,*Qhi,*Qlo;
  unsigned short *hTth,*hTtl,*PTh,*PTl;
  hipStream_t stream;
};

template<int TC, int D>
void run_layer(Ctx& c, int l, bool last){
  constexpr int TN=TC-D;
  const float* ibnst=(l>0)?c.bnst:nullptr;
  const float* ibng =(l>0)?(c.bn_g+(size_t)(l-1)*C):nullptr;
  const float* ibnb =(l>0)?(c.bn_b+(size_t)(l-1)*C):nullptr;
  k_attconv<TC,D><<<(B*N)/2,256,0,c.stream>>>(c.pH,
    c.qkvTh+(size_t)l*12288, c.qkvTl+(size_t)l*12288,
    c.w1Th+(size_t)l*16384,  c.w1Tl+(size_t)l*16384,
    c.w2Th+(size_t)l*16384,  c.w2Tl+(size_t)l*16384,
    c.cvTh+(size_t)l*16384,  c.cvTl+(size_t)l*16384,
    c.bq+(size_t)l*C, c.bk+(size_t)l*C, c.bv+(size_t)l*C,
    c.b1+(size_t)l*4*C, c.b2+(size_t)l*C,
    c.filt_b+(size_t)l*C, c.gate_b+(size_t)l*C,
    c.skip_w+(size_t)l*C*SKC, c.skip_b+(size_t)l*SKC,
    ibnst, ibng, ibnb,
    c.hThi, c.hTlo, c.skipacc, l==0?1:0);
  if(!last){
    constexpr int TR = (TN>=7) ? 128 : 64;   // smaller tiles for tail layers (parallelism)
    int M=C*TN, nMB=M/64;
    const unsigned short* Wh=c.wgh+(size_t)l*36864;
    const unsigned short* Wl=c.wgl+(size_t)l*36864;
    dim3 sg(DIVUP(N,TR), nMB, B);
    k_trx<<<dim3(M/64,DIVUP(NP,64),B),256,0,c.stream>>>(c.hThi,c.hTlo, c.hTth,c.hTtl, M);
    for(int s=0;s<4;s++){
      k_spatmm<TR><<<sg,256,0,c.stream>>>(c.matH[s],c.matL[s],c.matStride[s],
          nullptr,nullptr, c.hTth,c.hTtl, 1,
          c.Phi,c.Plo, c.PTh,c.PTl, M);
      if(c.PTh){
        k_spatmm<TR><<<sg,256,0,c.stream>>>(c.matH[s],c.matL[s],c.matStride[s],
            nullptr,nullptr, c.PTh,c.PTl, 1,
            c.Qhi,c.Qlo, nullptr,nullptr, M);
      }else{
        k_spatmm<TR><<<sg,256,0,c.stream>>>(c.matH[s],c.matL[s],c.matStride[s],
            c.Phi,c.Plo, nullptr,nullptr, 0,
            c.Qhi,c.Qlo, nullptr,nullptr, M);
      }
      if(s==0){
        k_gcnmm<TN,1><<<(B*N)/4,256,0,c.stream>>>(
            c.hThi,c.hTlo, c.Phi,c.Plo, c.Qhi,c.Qlo,
            Wh,Wl, 0, c.gcn_b+(size_t)l*C, c.pH,
            ibnst, ibng, ibnb, c.pAlt, TC);
      }else{
        k_gcnmm<TN,0><<<(B*N)/4,256,0,c.stream>>>(
            c.Phi,c.Plo, c.Qhi,c.Qlo, nullptr,nullptr,
            Wh,Wl, (1+2*s)*64, nullptr, nullptr,
            nullptr,nullptr,nullptr, c.pAlt, TC);
      }
    }
    int R=B*N*TN;
    k_bnstats1<<<256,256,0,c.stream>>>(c.pAlt, c.bnpart, R);
    k_bnstats2<<<1,256,0,c.stream>>>(c.bnpart, c.bnst, R);
    float* tmp=c.pH; c.pH=c.pAlt; c.pAlt=tmp;
  }
}

} // namespace

extern "C" void kernel_launch(void* const* d_in, const int* in_sizes, int n_in,
                              void* d_out, int out_size, void* d_ws, size_t ws_size,
                              hipStream_t stream){
  (void)in_sizes; (void)n_in;
  const float* x      =(const float*)d_in[0];
  const float* sup0   =(const float*)d_in[1];
  const float* sup1   =(const float*)d_in[2];
  const float* TiD    =(const float*)d_in[3];
  const float* DiW    =(const float*)d_in[4];
  const float* E1     =(const float*)d_in[5];
  const float* E2     =(const float*)d_in[6];
  const float* E3     =(const float*)d_in[7];
  const float* Wx     =(const float*)d_in[8];
  const float* Wd     =(const float*)d_in[9];
  const float* Wxabs  =(const float*)d_in[10];
  const float* start_w=(const float*)d_in[11];
  const float* start_b=(const float*)d_in[12];
  const float* Wq     =(const float*)d_in[13];
  const float* Wk     =(const float*)d_in[15];
  const float* Wv     =(const float*)d_in[17];
  const float* W1     =(const float*)d_in[19];
  const float* W2     =(const float*)d_in[21];
  const float* filt_w =(const float*)d_in[23];
  const float* gate_w =(const float*)d_in[25];
  const float* gcn_w  =(const float*)d_in[29];

  Ctx c;
  c.bq=(const float*)d_in[14];
  c.bk=(const float*)d_in[16];
  c.bv=(const float*)d_in[18];
  c.b1=(const float*)d_in[20];
  c.b2=(const float*)d_in[22];
  c.filt_b=(const float*)d_in[24];
  c.gate_b=(const float*)d_in[26];
  c.skip_w=(const float*)d_in[27]; c.skip_b=(const float*)d_in[28];
  c.gcn_b =(const float*)d_in[30];
  c.bn_g  =(const float*)d_in[31]; c.bn_b  =(const float*)d_in[32];
  const float* end1_w =(const float*)d_in[33];
  const float* end1_b =(const float*)d_in[34];
  const float* end2_w =(const float*)d_in[35];
  const float* end2_b =(const float*)d_in[36];
  c.stream=stream;

  // workspace carve (16B-aligned)
  size_t off=0;
  auto allocF=[&](size_t nf)->float*{
    nf=(nf+3)&~(size_t)3;
    float* p=(float*)((char*)d_ws+off);
    off += nf*sizeof(float);
    return p;
  };
  auto allocU=[&](size_t nu)->unsigned short*{
    nu=(nu+7)&~(size_t)7;
    unsigned short* p=(unsigned short*)((char*)d_ws+off);
    off += nu*sizeof(unsigned short);
    return p;
  };
  const size_t HMAX =(size_t)B*C*N*T13;
  const size_t XSZ  =(size_t)B*C*N*12;
  const size_t XTSZ =(size_t)768*NP*B;
  const size_t SUPP =(size_t)NP*NP;
  const size_t ADSZ =(size_t)B*NP*NP;

  float* xf     = allocF((size_t)B*F7*N);
  float* gx1    = allocF((size_t)B*N*E);
  float* gdew   = allocF((size_t)B*N*E);
  float* gst    = allocF(16);
  c.bnst        = allocF(2*C);
  c.bnpart      = allocF(256*128);
  float* adp    = allocF((size_t)B*N*N);   // dead after k_topk; hosts hT_T overlay
  c.pH          = allocF(HMAX);
  c.pAlt        = allocF(HMAX);
  c.skipacc     = allocF((size_t)B*N*SKC);
  unsigned short* matRegion=(unsigned short*)((char*)d_ws+off);
  unsigned short* s0h = allocU(SUPP);
  unsigned short* s0l = allocU(SUPP);
  unsigned short* s1h = allocU(SUPP);
  unsigned short* s1l = allocU(SUPP);
  unsigned short* aph = allocU(SUPP);
  unsigned short* apl = allocU(SUPP);
  unsigned short* adh = allocU(ADSZ);
  unsigned short* adl = allocU(ADSZ);
  long long matRegionN = (long long)(( (unsigned short*)((char*)d_ws+off) ) - matRegion);
  c.hThi = allocU(XSZ);  c.hTlo = allocU(XSZ);
  c.Phi  = allocU(XSZ);  c.Plo  = allocU(XSZ);
  c.Qhi  = allocU(XSZ);  c.Qlo  = allocU(XSZ);
  unsigned short* qkvTh = allocU((size_t)L*12288);
  unsigned short* qkvTl = allocU((size_t)L*12288);
  unsigned short* w1Th  = allocU((size_t)L*16384);
  unsigned short* w1Tl  = allocU((size_t)L*16384);
  unsigned short* w2Th  = allocU((size_t)L*16384);
  unsigned short* w2Tl  = allocU((size_t)L*16384);
  unsigned short* cvTh  = allocU((size_t)L*16384);
  unsigned short* cvTl  = allocU((size_t)L*16384);
  unsigned short* wgh   = allocU((size_t)L*36864);
  unsigned short* wgl   = allocU((size_t)L*36864);
  if(off > ws_size){
    k_zero<<<DIVUP(out_size,256),256,0,stream>>>((float*)d_out, out_size);
    return;
  }
  c.hTth = (unsigned short*)adp;
  c.hTtl = c.hTth + XTSZ;
  {
    size_t save=off;
    c.PTh = allocU(XTSZ);
    c.PTl = allocU(XTSZ);
    if(off > ws_size){ c.PTh=nullptr; c.PTl=nullptr; off=save; }
  }
  c.qkvTh=qkvTh; c.qkvTl=qkvTl; c.w1Th=w1Th; c.w1Tl=w1Tl;
  c.w2Th=w2Th; c.w2Tl=w2Tl; c.cvTh=cvTh; c.cvTl=cvTl;
  c.wgh=wgh; c.wgl=wgl;
  c.matH[0]=s0h; c.matL[0]=s0l; c.matStride[0]=0;
  c.matH[1]=s1h; c.matL[1]=s1l; c.matStride[1]=0;
  c.matH[2]=aph; c.matL[2]=apl; c.matStride[2]=0;
  c.matH[3]=adh; c.matL[3]=adl; c.matStride[3]=(long long)NP*NP;

  // ---- graph generation + conversions ----
  k_zeroUS<<<(int)DIVUP(matRegionN,256),256,0,stream>>>(matRegion, matRegionN);
  k_cvt_qkv <<<DIVUP(L*192*64,256),256,0,stream>>>(Wq,Wk,Wv,qkvTh,qkvTl);
  k_cvt_w1  <<<DIVUP(L*256*64,256),256,0,stream>>>(W1,w1Th,w1Tl);
  k_cvt_w2  <<<DIVUP(L*64*256,256),256,0,stream>>>(W2,w2Th,w2Tl);
  k_cvt_conv<<<DIVUP(L*128*128,256),256,0,stream>>>(filt_w,gate_w,cvTh,cvTl);
  k_cvt_gcn <<<DIVUP(L*64*576,256),256,0,stream>>>(gcn_w,wgh,wgl);
  k_dft <<<DIVUP(B*F7*N,256),256,0,stream>>>(x, xf);
  k_l2f <<<DIVUP(B*N,256),256,0,stream>>>(xf);
  k_l2n <<<B*F7,256,0,stream>>>(xf);
  k_x1  <<<DIVUP(B*N,256),256,0,stream>>>(x, xf, E3, TiD, DiW, Wx, Wd, gx1);
  k_lnstats<<<B,256,0,stream>>>(gx1, gst);
  k_dew <<<DIVUP(B*N,256),256,0,stream>>>(gx1, gst, Wxabs, gdew);
  k_adp <<<DIVUP(B*N*N,256),256,0,stream>>>(gdew, gx1, adp);
  k_topk<<<(B*N)/4,256,0,stream>>>(adp, adh, adl);
  k_adap<<<N,256,0,stream>>>(E1, E2, aph, apl);
  k_cvtT<<<DIVUP(N*N,256),256,0,stream>>>(sup0, s0h, s0l);
  k_cvtT<<<DIVUP(N*N,256),256,0,stream>>>(sup1, s1h, s1l);

  // ---- trunk ----
  k_start<<<DIVUP(B*N*T13*C,256),256,0,stream>>>(x, start_w, start_b, c.pH);

  run_layer<13,1>(c,0,false);
  run_layer<12,2>(c,1,false);
  run_layer<10,1>(c,2,false);
  run_layer< 9,2>(c,3,false);
  run_layer< 7,1>(c,4,false);
  run_layer< 6,2>(c,5,false);
  run_layer< 4,1>(c,6,false);
  run_layer< 3,2>(c,7,true);

  k_head<<<B*N,512,0,stream>>>(c.skipacc, end1_w, end1_b, end2_w, end2_b, (float*)d_out);
}

// Round 15
// 4956.589 us; speedup vs baseline: 1.3093x; 1.0047x over previous
//
#include <hip/hip_runtime.h>
#include <math.h>

#define DIVUP(a,b) (((a)+(b)-1)/(b))

namespace {

constexpr int B=8, T=12, N=883, CIN=3, C=64, E=10, H=8, HD=8, TOPK=48, L=8;
constexpr int SKC=256, F7=7, T13=13;
constexpr int NP=896;   // padded N for bf16 support matrices / transposed X

typedef __attribute__((ext_vector_type(8))) short bf16x8;
typedef __attribute__((ext_vector_type(4))) float f32x4;

__device__ __forceinline__ float geluf(float x){ return 0.5f*x*(1.0f+erff(x*0.7071067811865475f)); }
__device__ __forceinline__ float sigmf(float x){ return 1.0f/(1.0f+expf(-x)); }
__device__ __forceinline__ float us2f(unsigned short u){ return __uint_as_float(((unsigned)u)<<16); }
// truncation split: v ~= hi + lo with |err| <= 2^-17 |v| (self-correcting; hi needn't be RNE)
__device__ __forceinline__ void splitbf(float v, unsigned short& h, unsigned short& l){
  unsigned u=__float_as_uint(v);
  h=(unsigned short)(u>>16);
  float r=v-__uint_as_float(u&0xffff0000u);
  l=(unsigned short)(__float_as_uint(r)>>16);
}

// 16x16 output tile (single row-group)
template<int KK, int STRIDE, int KW>
__device__ __forceinline__ f32x4 tile_mm(
    const unsigned short* sAh, const unsigned short* sAl,
    const unsigned short* __restrict__ Wh, const unsigned short* __restrict__ Wl,
    int colBase, int lane, f32x4 acc){
  int lr=lane&15, lg=lane>>4;
  #pragma unroll
  for(int k0=0;k0<KK;k0+=32){
    bf16x8 ah=*(const bf16x8*)&sAh[lr*STRIDE+k0+8*lg];
    bf16x8 al=*(const bf16x8*)&sAl[lr*STRIDE+k0+8*lg];
    bf16x8 bh=*(const bf16x8*)&Wh[(size_t)(colBase+lr)*KW+k0+8*lg];
    bf16x8 bl=*(const bf16x8*)&Wl[(size_t)(colBase+lr)*KW+k0+8*lg];
    acc=__builtin_amdgcn_mfma_f32_16x16x32_bf16(ah,bh,acc,0,0,0);
    acc=__builtin_amdgcn_mfma_f32_16x16x32_bf16(ah,bl,acc,0,0,0);
    acc=__builtin_amdgcn_mfma_f32_16x16x32_bf16(al,bh,acc,0,0,0);
  }
  return acc;
}

// two 16x16 output tiles (rows 0-15 and 16-31) sharing B-fragments
template<int KK, int STRIDE, int KW>
__device__ __forceinline__ void tile_mm2(
    const unsigned short* sAh, const unsigned short* sAl,
    const unsigned short* __restrict__ Wh, const unsigned short* __restrict__ Wl,
    int colBase, int lane, f32x4& acc0, f32x4& acc1){
  int lr=lane&15, lg=lane>>4;
  #pragma unroll
  for(int k0=0;k0<KK;k0+=32){
    bf16x8 bh=*(const bf16x8*)&Wh[(size_t)(colBase+lr)*KW+k0+8*lg];
    bf16x8 bl=*(const bf16x8*)&Wl[(size_t)(colBase+lr)*KW+k0+8*lg];
    bf16x8 ah0=*(const bf16x8*)&sAh[lr*STRIDE+k0+8*lg];
    bf16x8 al0=*(const bf16x8*)&sAl[lr*STRIDE+k0+8*lg];
    bf16x8 ah1=*(const bf16x8*)&sAh[(lr+16)*STRIDE+k0+8*lg];
    bf16x8 al1=*(const bf16x8*)&sAl[(lr+16)*STRIDE+k0+8*lg];
    acc0=__builtin_amdgcn_mfma_f32_16x16x32_bf16(ah0,bh,acc0,0,0,0);
    acc0=__builtin_amdgcn_mfma_f32_16x16x32_bf16(ah0,bl,acc0,0,0,0);
    acc0=__builtin_amdgcn_mfma_f32_16x16x32_bf16(al0,bh,acc0,0,0,0);
    acc1=__builtin_amdgcn_mfma_f32_16x16x32_bf16(ah1,bh,acc1,0,0,0);
    acc1=__builtin_amdgcn_mfma_f32_16x16x32_bf16(ah1,bl,acc1,0,0,0);
    acc1=__builtin_amdgcn_mfma_f32_16x16x32_bf16(al1,bh,acc1,0,0,0);
  }
}

// ---------------- graph generation ----------------
__global__ void k_dft(const float* __restrict__ x, float* __restrict__ xf){
  int idx = blockIdx.x*256 + threadIdx.x;
  if(idx >= B*F7*N) return;
  int n = idx % N; int f = (idx/N) % F7; int b = idx/(N*F7);
  float re=0.f, im=0.f;
  for(int t=0;t<T;t++){
    float v = x[((size_t)(b*T+t)*N+n)*CIN];
    float ang = -6.283185307179586f * (float)(f*t) / 12.0f;
    re += v*cosf(ang); im += v*sinf(ang);
  }
  xf[idx] = sqrtf(re*re+im*im);
}

__global__ void k_l2f(float* __restrict__ xf){
  int idx = blockIdx.x*256 + threadIdx.x;
  if(idx >= B*N) return;
  int n = idx % N; int b = idx / N;
  float s=0.f;
  for(int f=0;f<F7;f++){ float v=xf[((size_t)b*F7+f)*N+n]; s+=v*v; }
  float inv = 1.0f/fmaxf(sqrtf(s), 1e-12f);
  for(int f=0;f<F7;f++) xf[((size_t)b*F7+f)*N+n] *= inv;
}

__global__ void k_l2n(float* __restrict__ xf){
  int bf = blockIdx.x; int tid = threadIdx.x;
  __shared__ float red[256];
  size_t base = (size_t)bf*N;
  float s=0.f;
  for(int i=tid;i<N;i+=256){ float v=xf[base+i]; s+=v*v; }
  red[tid]=s; __syncthreads();
  for(int k=128;k>0;k>>=1){ if(tid<k) red[tid]+=red[tid+k]; __syncthreads(); }
  float inv = 1.0f/fmaxf(sqrtf(red[0]), 1e-12f);
  __syncthreads();
  for(int i=tid;i<N;i+=256) xf[base+i]*=inv;
}

__global__ void k_x1(const float* __restrict__ x, const float* __restrict__ xf,
                     const float* __restrict__ E3, const float* __restrict__ TiD,
                     const float* __restrict__ DiW, const float* __restrict__ Wx,
                     const float* __restrict__ Wd, float* __restrict__ x1){
  int idx = blockIdx.x*256+threadIdx.x;
  if(idx>=B*N) return;
  int n=idx%N, b=idx/N;
  float xc[40];
  for(int d=0;d<E;d++){
    float a=0.f;
    for(int f=0;f<F7;f++) a += xf[((size_t)b*F7+f)*N+n]*Wx[f*E+d];
    xc[d]=a;
  }
  for(int d=0;d<E;d++) xc[10+d]=E3[n*E+d];
  int ti = (int)(x[((size_t)(b*T+(T-1))*N+n)*CIN+1]*288.0f);
  int dw = (int)(x[((size_t)(b*T+(T-1))*N+n)*CIN+2]);
  for(int d=0;d<E;d++) xc[20+d]=TiD[ti*E+d];
  for(int d=0;d<E;d++) xc[30+d]=DiW[dw*E+d];
  for(int e=0;e<E;e++){
    float a=0.f;
    for(int f=0;f<40;f++) a += xc[f]*Wd[((size_t)n*40+f)*E+e];
    x1[(size_t)idx*E+e]=fmaxf(a,0.f);
  }
}

__global__ void k_lnstats(const float* __restrict__ x1, float* __restrict__ st){
  int b=blockIdx.x, tid=threadIdx.x;
  __shared__ float rs[256], rq[256];
  const int M=N*E;
  float s=0.f,q=0.f;
  for(int i=tid;i<M;i+=256){ float v=x1[(size_t)b*M+i]; s+=v; q+=v*v; }
  rs[tid]=s; rq[tid]=q; __syncthreads();
  for(int k=128;k>0;k>>=1){ if(tid<k){ rs[tid]+=rs[tid+k]; rq[tid]+=rq[tid+k]; } __syncthreads(); }
  if(tid==0){ float mu=rs[0]/M; float var=rq[0]/M-mu*mu; st[b*2]=mu; st[b*2+1]=var; }
}

__global__ void k_dew(const float* __restrict__ x1, const float* __restrict__ st,
                      const float* __restrict__ Wxabs, float* __restrict__ dew){
  int idx=blockIdx.x*256+threadIdx.x;
  if(idx>=B*N) return;
  int b=idx/N;
  float mu=st[b*2], var=st[b*2+1];
  float rs=rsqrtf(var+1e-8f);
  float xk[E];
  for(int e=0;e<E;e++) xk[e]=(x1[(size_t)idx*E+e]-mu)*rs;
  for(int k=0;k<E;k++){
    float a=0.f;
    for(int e=0;e<E;e++) a+=xk[e]*Wxabs[e*E+k];
    dew[(size_t)idx*E+k]=a;
  }
}

__global__ void k_adp(const float* __restrict__ dew, const float* __restrict__ x1,
                      float* __restrict__ adp){
  size_t idx=(size_t)blockIdx.x*256+threadIdx.x;
  if(idx>=(size_t)B*N*N) return;
  int m=(int)(idx%N); int n=(int)((idx/N)%N); int b=(int)(idx/((size_t)N*N));
  const float* dr=dew+((size_t)b*N+n)*E;
  const float* xr=x1+((size_t)b*N+m)*E;
  float a=0.f;
  for(int k=0;k<E;k++) a+=dr[k]*xr[k];
  adp[idx]=fmaxf(a,0.f);
}

// wave-per-row top-48 + masked softmax -> bf16 hi/lo padded AD mats; zero barriers.
__global__ __launch_bounds__(256) void k_topk(const float* __restrict__ adp,
                       unsigned short* __restrict__ ADhi, unsigned short* __restrict__ ADlo){
  int row = blockIdx.x*4 + (threadIdx.x>>6);
  int lane = threadIdx.x & 63;
  const float* rp = adp + (size_t)row*N;
  float v[14];
  #pragma unroll
  for(int j=0;j<14;j++){
    int i = lane + j*64;
    v[j] = (i<N) ? rp[i] : -1.f;
  }
  unsigned sel = 0u;
  float m0 = 0.f;
  for(int k=0;k<TOPK;k++){
    float bv = -2.f; int bi = 1<<20;
    #pragma unroll
    for(int j=0;j<14;j++){
      if(!((sel>>j)&1u) && v[j] > bv){ bv = v[j]; bi = lane + j*64; }
    }
    #pragma unroll
    for(int off=1; off<64; off<<=1){
      float ov = __shfl_xor(bv, off);
      int   oi = __shfl_xor(bi, off);
      if(ov > bv || (ov==bv && oi<bi)){ bv=ov; bi=oi; }
    }
    if(k==0) m0 = bv;
    if((bi&63)==lane) sel |= 1u << (bi>>6);
  }
  float pv[14];
  float ls = 0.f;
  #pragma unroll
  for(int j=0;j<14;j++){
    int i = lane + j*64;
    float p = ((sel>>j)&1u) ? v[j] : 0.f;
    pv[j] = p;
    if(i<N) ls += expf(p - m0);
  }
  #pragma unroll
  for(int off=1; off<64; off<<=1) ls += __shfl_xor(ls, off);
  float invZ = 1.f/ls;
  size_t base = ((size_t)(row/N)*NP + (size_t)(row%N))*NP;
  #pragma unroll
  for(int j=0;j<14;j++){
    int i = lane + j*64;
    if(i<N){
      float f = expf(pv[j]-m0)*invZ;
      unsigned short h,l; splitbf(f,h,l);
      ADhi[base+i]=h; ADlo[base+i]=l;
    }
  }
}

__global__ void k_adap(const float* __restrict__ E1, const float* __restrict__ E2,
                       unsigned short* __restrict__ Mh, unsigned short* __restrict__ Ml){
  int v=blockIdx.x, tid=threadIdx.x;
  __shared__ float rowv[N];
  __shared__ float rv[256];
  float e1[E];
  for(int e=0;e<E;e++) e1[e]=E1[v*E+e];
  for(int j=tid;j<N;j+=256){
    float s=0.f;
    for(int e=0;e<E;e++) s+=e1[e]*E2[j*E+e];
    rowv[j]=fmaxf(s,0.f);
  }
  __syncthreads();
  float lm=-1e30f;
  for(int j=tid;j<N;j+=256) lm=fmaxf(lm,rowv[j]);
  rv[tid]=lm; __syncthreads();
  for(int s=128;s>0;s>>=1){ if(tid<s) rv[tid]=fmaxf(rv[tid],rv[tid+s]); __syncthreads(); }
  float m=rv[0]; __syncthreads();
  float ls=0.f;
  for(int j=tid;j<N;j+=256) ls+=expf(rowv[j]-m);
  rv[tid]=ls; __syncthreads();
  for(int s=128;s>0;s>>=1){ if(tid<s) rv[tid]+=rv[tid+s]; __syncthreads(); }
  float invZ=1.0f/rv[0];
  for(int j=tid;j<N;j+=256){
    float f=expf(rowv[j]-m)*invZ;
    unsigned short h,l; splitbf(f,h,l);
    Mh[(size_t)j*NP+v]=h; Ml[(size_t)j*NP+v]=l;
  }
}

__global__ void k_cvtT(const float* __restrict__ A, unsigned short* __restrict__ Mh,
                       unsigned short* __restrict__ Ml){
  int idx=blockIdx.x*256+threadIdx.x;
  if(idx>=N*N) return;
  int w=idx/N, v=idx%N;
  float f=A[(size_t)v*N+w];
  unsigned short h,l; splitbf(f,h,l);
  Mh[(size_t)w*NP+v]=h;
  Ml[(size_t)w*NP+v]=l;
}

// ---- weight transpose+split conversions (run once) ----
__global__ void k_cvt_qkv(const float* __restrict__ Wq, const float* __restrict__ Wk,
                          const float* __restrict__ Wv,
                          unsigned short* __restrict__ dh, unsigned short* __restrict__ dl){
  int idx=blockIdx.x*256+threadIdx.x;
  if(idx>=L*192*64) return;
  int l=idx/12288, rem=idx%12288, col=rem/64, k=rem%64;
  int mat=col>>6, o=col&63;
  const float* W=(mat==0)?Wq:((mat==1)?Wk:Wv);
  float v=W[(size_t)l*4096 + k*64 + o];
  unsigned short h,lo; splitbf(v,h,lo);
  dh[idx]=h; dl[idx]=lo;
}
__global__ void k_cvt_w1(const float* __restrict__ W1,
                         unsigned short* __restrict__ dh, unsigned short* __restrict__ dl){
  int idx=blockIdx.x*256+threadIdx.x;
  if(idx>=L*256*64) return;
  int l=idx/16384, rem=idx%16384, col=rem/64, k=rem%64;
  float v=W1[(size_t)l*16384 + k*256 + col];
  unsigned short h,lo; splitbf(v,h,lo);
  dh[idx]=h; dl[idx]=lo;
}
__global__ void k_cvt_w2(const float* __restrict__ W2,
                         unsigned short* __restrict__ dh, unsigned short* __restrict__ dl){
  int idx=blockIdx.x*256+threadIdx.x;
  if(idx>=L*64*256) return;
  int l=idx/16384, rem=idx%16384, col=rem/256, k=rem%256;
  float v=W2[(size_t)l*16384 + k*64 + col];
  unsigned short h,lo; splitbf(v,h,lo);
  dh[idx]=h; dl[idx]=lo;
}
__global__ void k_cvt_conv(const float* __restrict__ fw, const float* __restrict__ gw,
                           unsigned short* __restrict__ dh, unsigned short* __restrict__ dl){
  int idx=blockIdx.x*256+threadIdx.x;
  if(idx>=L*128*128) return;
  int l=idx/16384, rem=idx%16384, col=rem/128, k=rem%128;
  int c=col&63, fg=col>>6, tap=k>>6, i=k&63;
  const float* W=fg?gw:fw;
  float v=W[(size_t)l*8192 + tap*4096 + i*64 + c];
  unsigned short h,lo; splitbf(v,h,lo);
  dh[idx]=h; dl[idx]=lo;
}
// gcn_w (L,576,64) -> [l][o][k=576] bf16 split
__global__ void k_cvt_gcn(const float* __restrict__ Wg,
                          unsigned short* __restrict__ dh, unsigned short* __restrict__ dl){
  int idx=blockIdx.x*256+threadIdx.x;
  if(idx>=L*64*576) return;
  int l=idx/36864, rem=idx%36864, o=rem/576, k=rem%576;
  float v=Wg[((size_t)l*576 + k)*64 + o];
  unsigned short h,lo; splitbf(v,h,lo);
  dh[idx]=h; dl[idx]=lo;
}

__global__ void k_zero(float* __restrict__ p, int n){
  int idx=blockIdx.x*256+threadIdx.x;
  if(idx<n) p[idx]=0.f;
}
__global__ void k_zeroUS(unsigned short* __restrict__ p, long long n){
  long long idx=(long long)blockIdx.x*256+threadIdx.x;
  if(idx<n) p[idx]=0;
}

// tiled transpose: S [b][n<N][m<M] (split bf16 pair) -> D [b][m][v<NP]
__global__ __launch_bounds__(256) void k_trx(
    const unsigned short* __restrict__ Sh, const unsigned short* __restrict__ Sl,
    unsigned short* __restrict__ Dh, unsigned short* __restrict__ Dl, int M){
  __shared__ unsigned short th[64][66], tl[64][66];
  int b=blockIdx.z;
  int m0=blockIdx.x*64, n0=blockIdx.y*64;
  int tid=threadIdx.x;
  const unsigned short* sbh=Sh + (size_t)b*N*M;
  const unsigned short* sbl=Sl + (size_t)b*N*M;
  for(int idx=tid; idx<64*64; idx+=256){
    int i=idx>>6, j=idx&63;
    int n=n0+i;
    unsigned short vh=0, vl=0;
    if(n<N){
      size_t o=(size_t)n*M + m0+j;
      vh=sbh[o]; vl=sbl[o];
    }
    th[j][i]=vh; tl[j][i]=vl;
  }
  __syncthreads();
  unsigned short* dbh=Dh + (size_t)b*M*NP;
  unsigned short* dbl=Dl + (size_t)b*M*NP;
  for(int idx=tid; idx<64*64; idx+=256){
    int r=idx>>6, cc=idx&63;
    size_t o=(size_t)(m0+r)*NP + n0+cc;
    dbh[o]=th[r][cc]; dbl[o]=tl[r][cc];
  }
}

// ---------------- trunk ----------------
// h layout: [b][n][t][c]
__global__ void k_start(const float* __restrict__ x, const float* __restrict__ sw,
                        const float* __restrict__ sb, float* __restrict__ h){
  int idx=blockIdx.x*256+threadIdx.x;
  if(idx>=B*N*T13*C) return;
  int c=idx&63; int t=(idx>>6)%T13; int n=(idx/(64*T13))%N; int b=idx/(64*T13*N);
  float a=sb[c];
  if(t>0){
    size_t xb=((size_t)(b*T+(t-1))*N+n)*CIN;
    for(int i=0;i<CIN;i++) a += sw[i*C+c]*x[xb+i];
  }
  h[idx]=a;
}

// Fused 2-node MFMA transformer block; hin [b][n][t][c] (BN fused if bng!=0).
// 32-row A tiles; tile_mm2 shares B-fragments across the 2 nodes. 50KB LDS arena.
template<int TC, int D>
__global__ __launch_bounds__(256) void k_attconv(const float* __restrict__ hin,
  const unsigned short* __restrict__ Wqkvh, const unsigned short* __restrict__ Wqkvl,
  const unsigned short* __restrict__ W1h,   const unsigned short* __restrict__ W1l,
  const unsigned short* __restrict__ W2h,   const unsigned short* __restrict__ W2l,
  const unsigned short* __restrict__ Wch,   const unsigned short* __restrict__ Wcl,
  const float* __restrict__ bq, const float* __restrict__ bk, const float* __restrict__ bv,
  const float* __restrict__ b1, const float* __restrict__ b2,
  const float* __restrict__ fb, const float* __restrict__ gb,
  const float* __restrict__ skw, const float* __restrict__ skb,
  const float* __restrict__ bnst, const float* __restrict__ bng, const float* __restrict__ bnb,
  unsigned short* __restrict__ hThi, unsigned short* __restrict__ hTlo,
  float* __restrict__ skipacc, int first){
  constexpr int TN = TC - D;
  int bn0=blockIdx.x*2; int tid=threadIdx.x;
  int lane=tid&63, wid=tid>>6;
  int lr=lane&15, lg=lane>>4;
  __shared__ __align__(16) char smem[51200];
  float* sxa=(float*)smem;                                   // [32][64] 8KB
  unsigned short* sA1h=(unsigned short*)(smem+8192);         // [32][72]
  unsigned short* sA1l=(unsigned short*)(smem+12800);        // ends 17408
  float* sq =(float*)(smem+17408);                           // [32][64] (P2-3)
  float* sk_=(float*)(smem+25600);
  float* sv =(float*)(smem+33792);                           // ends 41984
  unsigned short* sA2h=(unsigned short*)(smem+17408);        // [32][264] (P4-5)
  unsigned short* sA2l=(unsigned short*)(smem+34304);        // ends 51200
  float* xcf=(float*)smem;                                   // [32][64] over sxa (P5 out)
  unsigned short* cAh=(unsigned short*)(smem+17408);         // [32][136] (P6+)
  unsigned short* cAl=(unsigned short*)(smem+26112);         // ends 34816
  float* sfg=(float*)(smem+34816);                           // [32][128] ends 51200 (P7+)
  float* stg=(float*)smem;                                   // [2][64] over sxa (P8+)

  // phase 1: contiguous staging of 2 nodes, BN fused
  const float* hp = hin + (size_t)bn0*TC*64;
  for(int idx=tid; idx<2*TC*64; idx+=256){
    int ni=idx/(TC*64); int rem=idx%(TC*64);
    int t=rem>>6, c=rem&63;
    float v=hp[idx];
    if(bng) v=(v-bnst[c])*bnst[64+c]*bng[c]+bnb[c];
    int row=ni*16+t;
    sxa[row*64+c]=v;
    unsigned short h,l; splitbf(v,h,l);
    sA1h[row*72+c]=h; sA1l[row*72+c]=l;
  }
  for(int idx=tid; idx<2*(16-TC)*64; idx+=256){
    int pr=idx>>6, c=idx&63;
    int ni=pr/(16-TC), tp=TC+pr%(16-TC);
    int row=ni*16+tp;
    sxa[row*64+c]=0.f; sA1h[row*72+c]=0; sA1l[row*72+c]=0;
  }
  __syncthreads();

  // phase 2: QKV + bias + gelu (12 col-tiles, shared B)
  #pragma unroll
  for(int it=0; it<3; ++it){
    int tile=it*4+wid;
    f32x4 a0={0.f,0.f,0.f,0.f}, a1={0.f,0.f,0.f,0.f};
    tile_mm2<64,72,64>(sA1h,sA1l,Wqkvh,Wqkvl,tile*16,lane,a0,a1);
    int col=tile*16+lr; int mat=col>>6, o=col&63;
    const float* bm=(mat==0)?bq:((mat==1)?bk:bv);
    float* dst=(mat==0)?sq:((mat==1)?sk_:sv);
    float bias=bm[o];
    #pragma unroll
    for(int r=0;r<4;r++){
      int t=lg*4+r;
      if(t<TC){
        dst[t*64+o]      =geluf(a0[r]+bias);
        dst[(16+t)*64+o] =geluf(a1[r]+bias);
      }
    }
  }
  __syncthreads();

  // phase 3: causal attention (both nodes) -> split bf16 into sA1
  if(tid<2*H*TC){
    int ni=tid/(H*TC); int rr=tid%(H*TC);
    int hh=rr/TC, t=rr%TC;
    int rb=ni*16;
    const float* qr=&sq[(rb+t)*64+hh*HD];
    float att[TC];
    float m=-1e30f;
    #pragma unroll
    for(int s=0;s<TC;s++){
      float a=0.f;
      #pragma unroll
      for(int d=0;d<HD;d++) a+=qr[d]*sk_[(rb+s)*64+hh*HD+d];
      a*=0.3535533905932738f;
      a=(s<=t)?a:-1e30f;
      att[s]=a; m=fmaxf(m,a);
    }
    float Z=0.f;
    #pragma unroll
    for(int s=0;s<TC;s++){ float e=expf(att[s]-m); att[s]=e; Z+=e; }
    float invZ=1.0f/Z;
    #pragma unroll
    for(int d=0;d<HD;d++){
      float o=0.f;
      #pragma unroll
      for(int s=0;s<TC;s++) o+=att[s]*sv[(rb+s)*64+hh*HD+d];
      float v=o*invZ;
      unsigned short h,l; splitbf(v,h,l);
      sA1h[(rb+t)*72+hh*8+d]=h; sA1l[(rb+t)*72+hh*8+d]=l;
    }
  }
  __syncthreads();

  // phase 4: FFN1 + bias + gelu -> split bf16 sA2 (stride 264)
  #pragma unroll
  for(int it=0; it<4; ++it){
    int tile=it*4+wid;
    f32x4 a0={0.f,0.f,0.f,0.f}, a1={0.f,0.f,0.f,0.f};
    tile_mm2<64,72,64>(sA1h,sA1l,W1h,W1l,tile*16,lane,a0,a1);
    int col=tile*16+lr;
    float bias=b1[col];
    #pragma unroll
    for(int r=0;r<4;r++){
      int t=lg*4+r;
      float v0=(t<TC)?geluf(a0[r]+bias):0.f;
      float v1=(t<TC)?geluf(a1[r]+bias):0.f;
      unsigned short h0,l0,h1,l1; splitbf(v0,h0,l0); splitbf(v1,h1,l1);
      sA2h[t*264+col]=h0;      sA2l[t*264+col]=l0;
      sA2h[(16+t)*264+col]=h1; sA2l[(16+t)*264+col]=l1;
    }
  }
  __syncthreads();

  // phase 5: FFN2 + bias + residual -> xcf (over dead sxa; same-thread RMW)
  {
    int tile=wid;
    f32x4 a0={0.f,0.f,0.f,0.f}, a1={0.f,0.f,0.f,0.f};
    tile_mm2<256,264,256>(sA2h,sA2l,W2h,W2l,tile*16,lane,a0,a1);
    int col=tile*16+lr;
    float bias=b2[col];
    #pragma unroll
    for(int r=0;r<4;r++){
      int t=lg*4+r;
      if(t<TC){
        xcf[t*64+col]     =a0[r]+bias+sxa[t*64+col];
        xcf[(16+t)*64+col]=a1[r]+bias+sxa[(16+t)*64+col];
      }
    }
  }
  __syncthreads();

  // phase 6: build conv A [32][136] split bf16 (over dead sA2 region)
  for(int idx=tid; idx<32*128; idx+=256){
    int row=idx>>7, k=idx&127;
    int ni=row>>4, t=row&15;
    int c=k&63;
    float v=0.f;
    if(t<TN) v=xcf[(ni*16+((k<64)?t:(t+D)))*64+c];
    unsigned short h,l; splitbf(v,h,l);
    cAh[row*136+k]=h; cAl[row*136+k]=l;
  }
  __syncthreads();

  // phase 7: conv + bias + activation -> sfg [32][128]
  #pragma unroll
  for(int it=0; it<2; ++it){
    int tile=it*4+wid;
    f32x4 a0={0.f,0.f,0.f,0.f}, a1={0.f,0.f,0.f,0.f};
    tile_mm2<128,136,128>(cAh,cAl,Wch,Wcl,tile*16,lane,a0,a1);
    int col=tile*16+lr;
    float bias=(col<64)?fb[col]:gb[col&63];
    #pragma unroll
    for(int r=0;r<4;r++){
      int t=lg*4+r;
      float v0=a0[r]+bias, v1=a1[r]+bias;
      sfg[t*128+col]     =(col<64)?tanhf(v0):sigmf(v0);
      sfg[(16+t)*128+col]=(col<64)?tanhf(v1):sigmf(v1);
    }
  }
  __syncthreads();

  // phase 8: last-column conv output for skip (both nodes)
  if(tid<2*C){
    int ni=tid>>6, c=tid&63;
    stg[ni*64+c]=sfg[(ni*16+TN-1)*128+c]*sfg[(ni*16+TN-1)*128+64+c];
  }
  __syncthreads();

  // phase 9: skip projection (contiguous [bn][256], 2 nodes) + hT write
  for(int idx=tid; idx<2*SKC; idx+=256){
    int ni=idx>>8, o=idx&255;
    float a=skb[o];
    for(int i=0;i<C;i++) a+=stg[ni*64+i]*skw[i*SKC+o];
    size_t so_=(size_t)(bn0+ni)*SKC+o;
    if(first) skipacc[so_]=a; else skipacc[so_]+=a;
  }
  size_t obase=(size_t)bn0*64*TN;
  for(int idx=tid; idx<2*TN*64; idx+=256){
    int ni=idx/(TN*64); int rem=idx%(TN*64);
    int tt=rem>>6, c=rem&63;
    float v=sfg[(ni*16+tt)*128+c]*sfg[(ni*16+tt)*128+64+c];
    unsigned short h,l; splitbf(v,h,l);
    hThi[obase+idx]=h;
    hTlo[obase+idx]=l;
  }
}

// ---- MFMA spatial GEMM: TRx64 tile (TR in {128,64}); waves own 16*(TR/64) rows x 64 cols ----
template<int TR>
__global__ __launch_bounds__(256) void k_spatmm(
    const unsigned short* __restrict__ Ah, const unsigned short* __restrict__ Al,
    long long aStride,
    const unsigned short* __restrict__ Xh, const unsigned short* __restrict__ Xl,
    const unsigned short* __restrict__ XTh, const unsigned short* __restrict__ XTl,
    int xT,
    unsigned short* __restrict__ Yh, unsigned short* __restrict__ Yl,
    unsigned short* __restrict__ YTh, unsigned short* __restrict__ YTl,
    int M){
  constexpr int NJ = TR/64;   // j-tiles per wave
  __shared__ unsigned short sAh[TR*40];
  __shared__ unsigned short sAl[TR*40];
  __shared__ unsigned short sXh[64*40];
  __shared__ unsigned short sXl[64*40];
  int b=blockIdx.z;
  const unsigned short* Abh=Ah+(size_t)b*aStride;
  const unsigned short* Abl=Al+(size_t)b*aStride;
  int tid=threadIdx.x;
  int w0=blockIdx.x*TR, c0=blockIdx.y*64;
  int lane=tid&63, wid=tid>>6;
  int lr=lane&15, lg=lane>>4;
  f32x4 acc[NJ][4];
  #pragma unroll
  for(int j=0;j<NJ;j++){
    #pragma unroll
    for(int i=0;i<4;i++){ acc[j][i][0]=0.f; acc[j][i][1]=0.f; acc[j][i][2]=0.f; acc[j][i][3]=0.f; }
  }
  const int xr=tid>>2,  xkb=(tid&3)*8;    // XT path: 64 cols, 4 thr/col
  const int xk=tid>>3,  xcb=(tid&7)*8;    // scatter path
  const int xkx=xk ^ (8*((xcb>>3)&3));
  for(int k0=0;k0<N;k0+=32){
    if(TR==128){
      int ar=tid>>1, akb=(tid&1)*16;
      uint4 qh0=*(const uint4*)&Abh[(size_t)(w0+ar)*NP + k0+akb];
      uint4 qh1=*(const uint4*)&Abh[(size_t)(w0+ar)*NP + k0+akb+8];
      uint4 ql0=*(const uint4*)&Abl[(size_t)(w0+ar)*NP + k0+akb];
      uint4 ql1=*(const uint4*)&Abl[(size_t)(w0+ar)*NP + k0+akb+8];
      *(uint4*)&sAh[ar*40+akb]=qh0;   *(uint4*)&sAh[ar*40+akb+8]=qh1;
      *(uint4*)&sAl[ar*40+akb]=ql0;   *(uint4*)&sAl[ar*40+akb+8]=ql1;
    }else{
      int ar=tid>>2, akb=(tid&3)*8;
      uint4 qh=*(const uint4*)&Abh[(size_t)(w0+ar)*NP + k0+akb];
      uint4 ql=*(const uint4*)&Abl[(size_t)(w0+ar)*NP + k0+akb];
      *(uint4*)&sAh[ar*40+akb]=qh;
      *(uint4*)&sAl[ar*40+akb]=ql;
    }
    if(xT){
      const unsigned short* Xbth=XTh+(size_t)b*M*NP;
      const unsigned short* Xbtl=XTl+(size_t)b*M*NP;
      uint4 qh=*(const uint4*)&Xbth[(size_t)(c0+xr)*NP + k0+xkb];
      uint4 ql=*(const uint4*)&Xbtl[(size_t)(c0+xr)*NP + k0+xkb];
      *(uint4*)&sXh[xr*40+xkb]=qh;
      *(uint4*)&sXl[xr*40+xkb]=ql;
    }else{
      const unsigned short* Xbh=Xh+(size_t)b*N*M;
      const unsigned short* Xbl=Xl+(size_t)b*N*M;
      uint4 qh={0,0,0,0}, ql={0,0,0,0};
      if(k0+xk<N){
        qh=*(const uint4*)&Xbh[(size_t)(k0+xk)*M + c0+xcb];
        ql=*(const uint4*)&Xbl[(size_t)(k0+xk)*M + c0+xcb];
      }
      unsigned short uh[8], ul[8];
      uh[0]=(unsigned short)(qh.x&0xffff); uh[1]=(unsigned short)(qh.x>>16);
      uh[2]=(unsigned short)(qh.y&0xffff); uh[3]=(unsigned short)(qh.y>>16);
      uh[4]=(unsigned short)(qh.z&0xffff); uh[5]=(unsigned short)(qh.z>>16);
      uh[6]=(unsigned short)(qh.w&0xffff); uh[7]=(unsigned short)(qh.w>>16);
      ul[0]=(unsigned short)(ql.x&0xffff); ul[1]=(unsigned short)(ql.x>>16);
      ul[2]=(unsigned short)(ql.y&0xffff); ul[3]=(unsigned short)(ql.y>>16);
      ul[4]=(unsigned short)(ql.z&0xffff); ul[5]=(unsigned short)(ql.z>>16);
      ul[6]=(unsigned short)(ql.w&0xffff); ul[7]=(unsigned short)(ql.w>>16);
      #pragma unroll
      for(int j=0;j<8;j++){
        sXh[(xcb+j)*40+xkx]=uh[j];
        sXl[(xcb+j)*40+xkx]=ul[j];
      }
    }
    __syncthreads();
    bf16x8 a_h[NJ], a_l[NJ], x_h[4], x_l[4];
    #pragma unroll
    for(int j=0;j<NJ;j++){
      int r=16*NJ*wid+16*j+lr;
      a_h[j]=*(const bf16x8*)&sAh[r*40+8*lg];
      a_l[j]=*(const bf16x8*)&sAl[r*40+8*lg];
    }
    #pragma unroll
    for(int i=0;i<4;i++){
      int cc=16*i+lr;
      int g = xT ? lg : (lg ^ ((cc>>3)&3));
      x_h[i]=*(const bf16x8*)&sXh[cc*40+8*g];
      x_l[i]=*(const bf16x8*)&sXl[cc*40+8*g];
    }
    #pragma unroll
    for(int j=0;j<NJ;j++){
      #pragma unroll
      for(int i=0;i<4;i++){
        acc[j][i]=__builtin_amdgcn_mfma_f32_16x16x32_bf16(a_h[j],x_h[i],acc[j][i],0,0,0);
        acc[j][i]=__builtin_amdgcn_mfma_f32_16x16x32_bf16(a_h[j],x_l[i],acc[j][i],0,0,0);
        acc[j][i]=__builtin_amdgcn_mfma_f32_16x16x32_bf16(a_l[j],x_h[i],acc[j][i],0,0,0);
      }
    }
    __syncthreads();
  }
  #pragma unroll
  for(int j=0;j<NJ;j++){
    int rbase=w0+16*NJ*wid+16*j+lg*4;
    #pragma unroll
    for(int i=0;i<4;i++){
      int col=c0+16*i+lr;
      unsigned short hh[4], ll[4];
      #pragma unroll
      for(int r=0;r<4;r++){
        splitbf(acc[j][i][r], hh[r], ll[r]);
      }
      #pragma unroll
      for(int r=0;r<4;r++){
        int row=rbase+r;
        if(row<N){
          size_t o=((size_t)b*N+row)*M+col;
          Yh[o]=hh[r]; Yl[o]=ll[r];
        }
      }
      if(YTh){
        size_t o=(size_t)b*M*NP + (size_t)col*NP + rbase;
        ushort4 ph; ph.x=hh[0]; ph.y=hh[1]; ph.z=hh[2]; ph.w=hh[3];
        ushort4 pl; pl.x=ll[0]; pl.y=ll[1]; pl.z=ll[2]; pl.w=ll[3];
        *(ushort4*)&YTh[o]=ph;
        *(ushort4*)&YTl[o]=pl;
      }
    }
  }
}

// ---- MFMA GCN projection (residual BN fused) ----
template<int TN, int FIRST>
__global__ __launch_bounds__(256) void k_gcnmm(
    const unsigned short* __restrict__ S0h, const unsigned short* __restrict__ S0l,
    const unsigned short* __restrict__ S1h, const unsigned short* __restrict__ S1l,
    const unsigned short* __restrict__ S2h, const unsigned short* __restrict__ S2l,
    const unsigned short* __restrict__ Wbh, const unsigned short* __restrict__ Wbl,
    int kOff,
    const float* __restrict__ gb, const float* __restrict__ res,
    const float* __restrict__ bnst, const float* __restrict__ bng, const float* __restrict__ bnb,
    float* __restrict__ acc, int Tc){
  constexpr int SL=64*TN;
  constexpr int NS=FIRST?3:2;
  constexpr int KK=NS*64;
  __shared__ unsigned short sAh[64*40], sAl[64*40];
  int bn0=blockIdx.x*4;
  int tid=threadIdx.x, lane=tid&63, wid=tid>>6;
  int lr=lane&15, lg=lane>>4;
  f32x4 a4[4];
  #pragma unroll
  for(int rt=0;rt<4;rt++){ a4[rt][0]=0.f; a4[rt][1]=0.f; a4[rt][2]=0.f; a4[rt][3]=0.f; }
  const int ar=tid>>2, akb=(tid&3)*8;
  const int ani=ar>>4, att_=ar&15;
  #pragma unroll
  for(int kc=0; kc<KK/32; ++kc){
    int k0=kc*32; int j=k0>>6; int i0=k0&63;
    const unsigned short* sh=(j==0)?S0h:((j==1)?S1h:S2h);
    const unsigned short* sl=(j==0)?S0l:((j==1)?S1l:S2l);
    uint4 qh={0,0,0,0}, ql={0,0,0,0};
    if(att_<TN){
      size_t o=(size_t)(bn0+ani)*SL + att_*64 + i0 + akb;
      qh=*(const uint4*)&sh[o]; ql=*(const uint4*)&sl[o];
    }
    *(uint4*)&sAh[ar*40+akb]=qh;
    *(uint4*)&sAl[ar*40+akb]=ql;
    __syncthreads();
    bf16x8 bh=*(const bf16x8*)&Wbh[(size_t)(wid*16+lr)*576 + kOff + k0 + 8*lg];
    bf16x8 bl=*(const bf16x8*)&Wbl[(size_t)(wid*16+lr)*576 + kOff + k0 + 8*lg];
    #pragma unroll
    for(int rt=0;rt<4;rt++){
      bf16x8 ah=*(const bf16x8*)&sAh[(rt*16+lr)*40+8*lg];
      bf16x8 al=*(const bf16x8*)&sAl[(rt*16+lr)*40+8*lg];
      a4[rt]=__builtin_amdgcn_mfma_f32_16x16x32_bf16(ah,bh,a4[rt],0,0,0);
      a4[rt]=__builtin_amdgcn_mfma_f32_16x16x32_bf16(ah,bl,a4[rt],0,0,0);
      a4[rt]=__builtin_amdgcn_mfma_f32_16x16x32_bf16(al,bh,a4[rt],0,0,0);
    }
    __syncthreads();
  }
  int o=wid*16+lr;
  #pragma unroll
  for(int rt=0;rt<4;rt++){
    int bn=bn0+rt;
    #pragma unroll
    for(int r=0;r<4;r++){
      int t2=lg*4+r;
      if(t2<TN){
        size_t oi=((size_t)bn*TN + t2)*64 + o;
        float v=a4[rt][r];
        if(FIRST){
          float rr=res[((size_t)bn*Tc + (Tc-TN) + t2)*64 + o];
          if(bng) rr=(rr-bnst[o])*bnst[64+o]*bng[o]+bnb[o];
          v += gb[o] + rr;
          acc[oi]=v;
        }else{
          acc[oi]+=v;
        }
      }
    }
  }
}

// BN stats (layout [b][n][tt][c]), two-stage
__global__ __launch_bounds__(256) void k_bnstats1(const float* __restrict__ h,
                                                  float* __restrict__ part, int R){
  int tid=threadIdx.x;
  int c=tid&63, rg=tid>>6;
  float s=0.f,q=0.f;
  for(int r=blockIdx.x*4+rg; r<R; r+=1024){
    float v=h[(size_t)r*64+c];
    s+=v; q+=v*v;
  }
  __shared__ float ls[256], lq[256];
  ls[tid]=s; lq[tid]=q; __syncthreads();
  if(rg==0){
    s=ls[c]+ls[64+c]+ls[128+c]+ls[192+c];
    q=lq[c]+lq[64+c]+lq[128+c]+lq[192+c];
    part[blockIdx.x*128+c]=s;
    part[blockIdx.x*128+64+c]=q;
  }
}
__global__ __launch_bounds__(256) void k_bnstats2(const float* __restrict__ part,
                                                  float* __restrict__ st, int R){
  int tid=threadIdx.x;
  int c=tid&63, g=tid>>6;
  float s=0.f,q=0.f;
  for(int p=g;p<256;p+=4){ s+=part[p*128+c]; q+=part[p*128+64+c]; }
  __shared__ float ls[256], lq[256];
  ls[tid]=s; lq[tid]=q; __syncthreads();
  if(g==0){
    s=ls[c]+ls[64+c]+ls[128+c]+ls[192+c];
    q=lq[c]+lq[64+c]+lq[128+c]+lq[192+c];
    float mu=s/R;
    float var=q/R-mu*mu;
    st[c]=mu; st[64+c]=rsqrtf(var+1e-5f);
  }
}

__global__ void k_head(const float* __restrict__ skipacc, const float* __restrict__ W1,
  const float* __restrict__ b1, const float* __restrict__ W2, const float* __restrict__ b2,
  float* __restrict__ out){
  int gid=blockIdx.x; int tid=threadIdx.x;  // 512 threads
  int n=gid%N; int b=gid/N;
  __shared__ float s[SKC];
  __shared__ float hid[512];
  if(tid<SKC){
    float v=skipacc[(size_t)gid*SKC+tid];
    s[tid]=fmaxf(v,0.f);
  }
  __syncthreads();
  {
    float a=b1[tid];
    for(int i=0;i<SKC;i++) a+=s[i]*W1[(size_t)i*512+tid];
    hid[tid]=fmaxf(a,0.f);
  }
  __syncthreads();
  if(tid<T){
    float a=b2[tid];
    for(int j=0;j<512;j++) a+=hid[j]*W2[(size_t)j*T+tid];
    out[((size_t)b*T+tid)*N+n]=a;
  }
}

// ---------------- host-side layer driver ----------------
struct Ctx {
  const float *bq,*bk,*bv,*b1,*b2,*filt_b,*gate_b,*skip_w,*skip_b,*gcn_b,*bn_g,*bn_b;
  const unsigned short *qkvTh,*qkvTl,*w1Th,*w1Tl,*w2Th,*w2Tl,*cvTh,*cvTl,*wgh,*wgl;
  const unsigned short* matH[4];
  const unsigned short* matL[4];
  long long matStride[4];
  float *pH,*pAlt,*skipacc,*bnst,*bnpart;
  unsigned short *hThi,*hTlo,*Phi,*Plo,*Qhi,*Qlo;
  unsigned short *hTth,*hTtl,*PTh,*PTl;
  hipStream_t stream;
};

template<int TC, int D>
void run_layer(Ctx& c, int l, bool last){
  constexpr int TN=TC-D;
  const float* ibnst=(l>0)?c.bnst:nullptr;
  const float* ibng =(l>0)?(c.bn_g+(size_t)(l-1)*C):nullptr;
  const float* ibnb =(l>0)?(c.bn_b+(size_t)(l-1)*C):nullptr;
  k_attconv<TC,D><<<(B*N)/2,256,0,c.stream>>>(c.pH,
    c.qkvTh+(size_t)l*12288, c.qkvTl+(size_t)l*12288,
    c.w1Th+(size_t)l*16384,  c.w1Tl+(size_t)l*16384,
    c.w2Th+(size_t)l*16384,  c.w2Tl+(size_t)l*16384,
    c.cvTh+(size_t)l*16384,  c.cvTl+(size_t)l*16384,
    c.bq+(size_t)l*C, c.bk+(size_t)l*C, c.bv+(size_t)l*C,
    c.b1+(size_t)l*4*C, c.b2+(size_t)l*C,
    c.filt_b+(size_t)l*C, c.gate_b+(size_t)l*C,
    c.skip_w+(size_t)l*C*SKC, c.skip_b+(size_t)l*SKC,
    ibnst, ibng, ibnb,
    c.hThi, c.hTlo, c.skipacc, l==0?1:0);
  if(!last){
    constexpr int TR = (TN>=7) ? 128 : 64;   // smaller tiles for tail layers (parallelism)
    int M=C*TN, nMB=M/64;
    const unsigned short* Wh=c.wgh+(size_t)l*36864;
    const unsigned short* Wl=c.wgl+(size_t)l*36864;
    dim3 sg(DIVUP(N,TR), nMB, B);
    k_trx<<<dim3(M/64,DIVUP(NP,64),B),256,0,c.stream>>>(c.hThi,c.hTlo, c.hTth,c.hTtl, M);
    for(int s=0;s<4;s++){
      k_spatmm<TR><<<sg,256,0,c.stream>>>(c.matH[s],c.matL[s],c.matStride[s],
          nullptr,nullptr, c.hTth,c.hTtl, 1,
          c.Phi,c.Plo, c.PTh,c.PTl, M);
      if(c.PTh){
        k_spatmm<TR><<<sg,256,0,c.stream>>>(c.matH[s],c.matL[s],c.matStride[s],
            nullptr,nullptr, c.PTh,c.PTl, 1,
            c.Qhi,c.Qlo, nullptr,nullptr, M);
      }else{
        k_spatmm<TR><<<sg,256,0,c.stream>>>(c.matH[s],c.matL[s],c.matStride[s],
            c.Phi,c.Plo, nullptr,nullptr, 0,
            c.Qhi,c.Qlo, nullptr,nullptr, M);
      }
      if(s==0){
        k_gcnmm<TN,1><<<(B*N)/4,256,0,c.stream>>>(
            c.hThi,c.hTlo, c.Phi,c.Plo, c.Qhi,c.Qlo,
            Wh,Wl, 0, c.gcn_b+(size_t)l*C, c.pH,
            ibnst, ibng, ibnb, c.pAlt, TC);
      }else{
        k_gcnmm<TN,0><<<(B*N)/4,256,0,c.stream>>>(
            c.Phi,c.Plo, c.Qhi,c.Qlo, nullptr,nullptr,
            Wh,Wl, (1+2*s)*64, nullptr, nullptr,
            nullptr,nullptr,nullptr, c.pAlt, TC);
      }
    }
    int R=B*N*TN;
    k_bnstats1<<<256,256,0,c.stream>>>(c.pAlt, c.bnpart, R);
    k_bnstats2<<<1,256,0,c.stream>>>(c.bnpart, c.bnst, R);
    float* tmp=c.pH; c.pH=c.pAlt; c.pAlt=tmp;
  }
}

} // namespace

extern "C" void kernel_launch(void* const* d_in, const int* in_sizes, int n_in,
                              void* d_out, int out_size, void* d_ws, size_t ws_size,
                              hipStream_t stream){
  (void)in_sizes; (void)n_in;
  const float* x      =(const float*)d_in[0];
  const float* sup0   =(const float*)d_in[1];
  const float* sup1   =(const float*)d_in[2];
  const float* TiD    =(const float*)d_in[3];
  const float* DiW    =(const float*)d_in[4];
  const float* E1     =(const float*)d_in[5];
  const float* E2     =(const float*)d_in[6];
  const float* E3     =(const float*)d_in[7];
  const float* Wx     =(const float*)d_in[8];
  const float* Wd     =(const float*)d_in[9];
  const float* Wxabs  =(const float*)d_in[10];
  const float* start_w=(const float*)d_in[11];
  const float* start_b=(const float*)d_in[12];
  const float* Wq     =(const float*)d_in[13];
  const float* Wk     =(const float*)d_in[15];
  const float* Wv     =(const float*)d_in[17];
  const float* W1     =(const float*)d_in[19];
  const float* W2     =(const float*)d_in[21];
  const float* filt_w =(const float*)d_in[23];
  const float* gate_w =(const float*)d_in[25];
  const float* gcn_w  =(const float*)d_in[29];

  Ctx c;
  c.bq=(const float*)d_in[14];
  c.bk=(const float*)d_in[16];
  c.bv=(const float*)d_in[18];
  c.b1=(const float*)d_in[20];
  c.b2=(const float*)d_in[22];
  c.filt_b=(const float*)d_in[24];
  c.gate_b=(const float*)d_in[26];
  c.skip_w=(const float*)d_in[27]; c.skip_b=(const float*)d_in[28];
  c.gcn_b =(const float*)d_in[30];
  c.bn_g  =(const float*)d_in[31]; c.bn_b  =(const float*)d_in[32];
  const float* end1_w =(const float*)d_in[33];
  const float* end1_b =(const float*)d_in[34];
  const float* end2_w =(const float*)d_in[35];
  const float* end2_b =(const float*)d_in[36];
  c.stream=stream;

  // workspace carve (16B-aligned)
  size_t off=0;
  auto allocF=[&](size_t nf)->float*{
    nf=(nf+3)&~(size_t)3;
    float* p=(float*)((char*)d_ws+off);
    off += nf*sizeof(float);
    return p;
  };
  auto allocU=[&](size_t nu)->unsigned short*{
    nu=(nu+7)&~(size_t)7;
    unsigned short* p=(unsigned short*)((char*)d_ws+off);
    off += nu*sizeof(unsigned short);
    return p;
  };
  const size_t HMAX =(size_t)B*C*N*T13;
  const size_t XSZ  =(size_t)B*C*N*12;
  const size_t XTSZ =(size_t)768*NP*B;
  const size_t SUPP =(size_t)NP*NP;
  const size_t ADSZ =(size_t)B*NP*NP;

  float* xf     = allocF((size_t)B*F7*N);
  float* gx1    = allocF((size_t)B*N*E);
  float* gdew   = allocF((size_t)B*N*E);
  float* gst    = allocF(16);
  c.bnst        = allocF(2*C);
  c.bnpart      = allocF(256*128);
  float* adp    = allocF((size_t)B*N*N);   // dead after k_topk; hosts hT_T overlay
  c.pH          = allocF(HMAX);
  c.pAlt        = allocF(HMAX);
  c.skipacc     = allocF((size_t)B*N*SKC);
  unsigned short* matRegion=(unsigned short*)((char*)d_ws+off);
  unsigned short* s0h = allocU(SUPP);
  unsigned short* s0l = allocU(SUPP);
  unsigned short* s1h = allocU(SUPP);
  unsigned short* s1l = allocU(SUPP);
  unsigned short* aph = allocU(SUPP);
  unsigned short* apl = allocU(SUPP);
  unsigned short* adh = allocU(ADSZ);
  unsigned short* adl = allocU(ADSZ);
  long long matRegionN = (long long)(( (unsigned short*)((char*)d_ws+off) ) - matRegion);
  c.hThi = allocU(XSZ);  c.hTlo = allocU(XSZ);
  c.Phi  = allocU(XSZ);  c.Plo  = allocU(XSZ);
  c.Qhi  = allocU(XSZ);  c.Qlo  = allocU(XSZ);
  unsigned short* qkvTh = allocU((size_t)L*12288);
  unsigned short* qkvTl = allocU((size_t)L*12288);
  unsigned short* w1Th  = allocU((size_t)L*16384);
  unsigned short* w1Tl  = allocU((size_t)L*16384);
  unsigned short* w2Th  = allocU((size_t)L*16384);
  unsigned short* w2Tl  = allocU((size_t)L*16384);
  unsigned short* cvTh  = allocU((size_t)L*16384);
  unsigned short* cvTl  = allocU((size_t)L*16384);
  unsigned short* wgh   = allocU((size_t)L*36864);
  unsigned short* wgl   = allocU((size_t)L*36864);
  if(off > ws_size){
    k_zero<<<DIVUP(out_size,256),256,0,stream>>>((float*)d_out, out_size);
    return;
  }
  c.hTth = (unsigned short*)adp;
  c.hTtl = c.hTth + XTSZ;
  {
    size_t save=off;
    c.PTh = allocU(XTSZ);
    c.PTl = allocU(XTSZ);
    if(off > ws_size){ c.PTh=nullptr; c.PTl=nullptr; off=save; }
  }
  c.qkvTh=qkvTh; c.qkvTl=qkvTl; c.w1Th=w1Th; c.w1Tl=w1Tl;
  c.w2Th=w2Th; c.w2Tl=w2Tl; c.cvTh=cvTh; c.cvTl=cvTl;
  c.wgh=wgh; c.wgl=wgl;
  c.matH[0]=s0h; c.matL[0]=s0l; c.matStride[0]=0;
  c.matH[1]=s1h; c.matL[1]=s1l; c.matStride[1]=0;
  c.matH[2]=aph; c.matL[2]=apl; c.matStride[2]=0;
  c.matH[3]=adh; c.matL[3]=adl; c.matStride[3]=(long long)NP*NP;

  // ---- graph generation + conversions ----
  k_zeroUS<<<(int)DIVUP(matRegionN,256),256,0,stream>>>(matRegion, matRegionN);
  k_cvt_qkv <<<DIVUP(L*192*64,256),256,0,stream>>>(Wq,Wk,Wv,qkvTh,qkvTl);
  k_cvt_w1  <<<DIVUP(L*256*64,256),256,0,stream>>>(W1,w1Th,w1Tl);
  k_cvt_w2  <<<DIVUP(L*64*256,256),256,0,stream>>>(W2,w2Th,w2Tl);
  k_cvt_conv<<<DIVUP(L*128*128,256),256,0,stream>>>(filt_w,gate_w,cvTh,cvTl);
  k_cvt_gcn <<<DIVUP(L*64*576,256),256,0,stream>>>(gcn_w,wgh,wgl);
  k_dft <<<DIVUP(B*F7*N,256),256,0,stream>>>(x, xf);
  k_l2f <<<DIVUP(B*N,256),256,0,stream>>>(xf);
  k_l2n <<<B*F7,256,0,stream>>>(xf);
  k_x1  <<<DIVUP(B*N,256),256,0,stream>>>(x, xf, E3, TiD, DiW, Wx, Wd, gx1);
  k_lnstats<<<B,256,0,stream>>>(gx1, gst);
  k_dew <<<DIVUP(B*N,256),256,0,stream>>>(gx1, gst, Wxabs, gdew);
  k_adp <<<DIVUP(B*N*N,256),256,0,stream>>>(gdew, gx1, adp);
  k_topk<<<(B*N)/4,256,0,stream>>>(adp, adh, adl);
  k_adap<<<N,256,0,stream>>>(E1, E2, aph, apl);
  k_cvtT<<<DIVUP(N*N,256),256,0,stream>>>(sup0, s0h, s0l);
  k_cvtT<<<DIVUP(N*N,256),256,0,stream>>>(sup1, s1h, s1l);

  // ---- trunk ----
  k_start<<<DIVUP(B*N*T13*C,256),256,0,stream>>>(x, start_w, start_b, c.pH);

  run_layer<13,1>(c,0,false);
  run_layer<12,2>(c,1,false);
  run_layer<10,1>(c,2,false);
  run_layer< 9,2>(c,3,false);
  run_layer< 7,1>(c,4,false);
  run_layer< 6,2>(c,5,false);
  run_layer< 4,1>(c,6,false);
  run_layer< 3,2>(c,7,true);

  k_head<<<B*N,512,0,stream>>>(c.skipacc, end1_w, end1_b, end2_w, end2_b, (float*)d_out);
}